// Round 1
// baseline (3479.973 us; speedup 1.0000x reference)
//
#include <hip/hip_runtime.h>
#include <math.h>

#define N4    4096
#define FDIM  6
#define CC    1000
#define KNN   40
#define CHUNK 1024
#define NRB   20
#define SSC   205

// ---------------- graph build ----------------

__global__ __launch_bounds__(256) void sqx_kernel(const float* __restrict__ x,
                                                  float* __restrict__ sq1,
                                                  float* __restrict__ xhat) {
    int n = blockIdx.x * blockDim.x + threadIdx.x;
    if (n >= N4) return;
    float s = 0.f;
#pragma unroll
    for (int f = 0; f < FDIM; ++f) {
        float v = x[n * FDIM + f];
        s += v * v;
        xhat[n * 18 + f] = v;
    }
    sq1[n] = s;
}

__global__ __launch_bounds__(256) void gram1_kernel(const float* __restrict__ x,
                                                    const float* __restrict__ sq1,
                                                    float* __restrict__ S, int base) {
    __shared__ float xn[FDIM];
    __shared__ float sn;
    int r = blockIdx.y;
    int n = base + r;
    int m = blockIdx.x * 256 + threadIdx.x;
    if (threadIdx.x < FDIM) xn[threadIdx.x] = x[n * FDIM + threadIdx.x];
    if (threadIdx.x == FDIM) sn = sq1[n];
    __syncthreads();
    float d = 0.f;
#pragma unroll
    for (int f = 0; f < FDIM; ++f) d += xn[f] * x[m * FDIM + f];
    float e = sn + sq1[m] - 2.f * d;
    S[(size_t)r * N4 + m] = __expf(-e);
}

// iterative-extract top-40 per row; ties -> lower index (matches lax.top_k)
__global__ __launch_bounds__(256) void topk_kernel(const float* __restrict__ S, int base,
                                                   int* __restrict__ idx, float* __restrict__ val,
                                                   float* __restrict__ rowsum) {
    __shared__ float sv[N4];
    __shared__ float rv[4];
    __shared__ int ri[4];
    int r = blockIdx.x;
    int n = base + r;
    const float* row = S + (size_t)r * N4;
    for (int i = threadIdx.x; i < N4; i += 256) sv[i] = row[i];
    __syncthreads();
    int tid = threadIdx.x, lane = tid & 63, w = tid >> 6;
    float ssum = 0.f;
    for (int it = 0; it < KNN; ++it) {
        float bv = -1.f; int bi = N4;
        for (int i = tid; i < N4; i += 256) {
            float v = sv[i];
            if (v > bv || (v == bv && i < bi)) { bv = v; bi = i; }
        }
#pragma unroll
        for (int o = 32; o; o >>= 1) {
            float ov = __shfl_down(bv, o);
            int   oi = __shfl_down(bi, o);
            if (ov > bv || (ov == bv && oi < bi)) { bv = ov; bi = oi; }
        }
        if (lane == 0) { rv[w] = bv; ri[w] = bi; }
        __syncthreads();
        if (tid == 0) {
            float fv = rv[0]; int fi = ri[0];
#pragma unroll
            for (int q = 1; q < 4; ++q)
                if (rv[q] > fv || (rv[q] == fv && ri[q] < fi)) { fv = rv[q]; fi = ri[q]; }
            idx[(size_t)n * KNN + it] = fi;
            val[(size_t)n * KNN + it] = fv;
            ssum += fv;
            sv[fi] = -1.f;
            if (it == KNN - 1) rowsum[n] = ssum;
        }
        __syncthreads();
    }
}

__global__ __launch_bounds__(256) void dinv_kernel(float* __restrict__ rs) {
    int n = blockIdx.x * 256 + threadIdx.x;
    if (n < N4) rs[n] = rsqrtf(rs[n]);
}

__global__ __launch_bounds__(256) void wnorm_kernel(float* __restrict__ wv,
                                                    const int* __restrict__ idx,
                                                    const float* __restrict__ dinv) {
    int i = blockIdx.x * 256 + threadIdx.x;
    if (i >= N4 * KNN) return;
    int n = i / KNN;
    wv[i] = wv[i] * dinv[n] * dinv[idx[i]];
}

// Tn[n,:] = a*(Tc[n,:] - sum_j wv[n,j]*Tc[idx[n,j],:]) - b*Tp[n,:]
__global__ __launch_bounds__(256) void spmv_cheb(const float* __restrict__ Tc,
                                                 const float* __restrict__ Tp,
                                                 float* __restrict__ Tn,
                                                 const int* __restrict__ idx,
                                                 const float* __restrict__ wv,
                                                 int F, int sC, int sP, int sN,
                                                 float a, float b) {
    __shared__ int   si[KNN];
    __shared__ float sw[KNN];
    int n = blockIdx.x;
    if (threadIdx.x < KNN) {
        si[threadIdx.x] = idx[(size_t)n * KNN + threadIdx.x];
        sw[threadIdx.x] = wv[(size_t)n * KNN + threadIdx.x];
    }
    __syncthreads();
    for (int c = threadIdx.x; c < F; c += blockDim.x) {
        float s = 0.f;
#pragma unroll 8
        for (int j = 0; j < KNN; ++j) s += sw[j] * Tc[(size_t)si[j] * sC + c];
        float v = a * (Tc[(size_t)n * sC + c] - s);
        if (b != 0.f) v -= b * Tp[(size_t)n * sP + c];
        Tn[(size_t)n * sN + c] = v;
    }
}

// ---------------- cheb conv 1 ----------------

__global__ __launch_bounds__(256) void cheb1_out_kernel(const float* __restrict__ xhat,
                                                        const float* __restrict__ W1,
                                                        const float* __restrict__ b1,
                                                        float* __restrict__ outF) {
    __shared__ float xh[16][18];
    int n0 = blockIdx.x * 16;
    int tid = threadIdx.x;
    for (int i = tid; i < 16 * 18; i += 256) xh[i / 18][i % 18] = xhat[(size_t)n0 * 18 + i];
    __syncthreads();
    for (int c0 = 0; c0 < CC; c0 += 256) {
        int c = c0 + tid;
        if (c < CC) {
            float acc[16];
#pragma unroll
            for (int r = 0; r < 16; ++r) acc[r] = 0.f;
            for (int f = 0; f < 18; ++f) {
                float wv = W1[(size_t)f * CC + c];
#pragma unroll
                for (int r = 0; r < 16; ++r) acc[r] += xh[r][f] * wv;
            }
            float bb = b1[c];
#pragma unroll
            for (int r = 0; r < 16; ++r)
                outF[(size_t)(n0 + r) * CC + c] = fmaxf(acc[r] + bb, 0.f);
        }
    }
}

// ---------------- regs (frobenius of O^T @ T) ----------------

__global__ __launch_bounds__(256) void matT_partial(const float* __restrict__ O,
                                                    const float* __restrict__ T, int ts,
                                                    float* __restrict__ M) {
    int c = blockIdx.x * 256 + threadIdx.x;
    int f = blockIdx.y;
    int n0 = blockIdx.z * 512;
    if (c >= CC) return;
    float s = 0.f;
    for (int n = n0; n < n0 + 512; ++n) s += O[(size_t)n * CC + c] * T[(size_t)n * ts + f];
    atomicAdd(&M[(size_t)f * CC + c], s);
}

__global__ __launch_bounds__(256) void fro_kernel(const float* __restrict__ M, float* __restrict__ dst) {
    __shared__ float red[256];
    int t = threadIdx.x;
    int i = blockIdx.x * 256 + t;
    float v = (i < 6 * CC) ? M[i] : 0.f;
    red[t] = v * v;
    __syncthreads();
    for (int o = 128; o; o >>= 1) { if (t < o) red[t] += red[t + o]; __syncthreads(); }
    if (t == 0) atomicAdd(dst, red[0]);
}

// ---------------- pooling ----------------

__global__ __launch_bounds__(256) void vfr_kernel(const float* __restrict__ outF,
                                                  const int* __restrict__ sccs,
                                                  float* __restrict__ vfr) {
    int r = blockIdx.y;
    int c = blockIdx.x * 256 + threadIdx.x;
    if (c >= CC) return;
    float m = 0.f;
    for (int s = 0; s < SSC; ++s) {
        int n = sccs[r * SSC + s];
        m = fmaxf(m, outF[(size_t)n * CC + c]);
    }
    vfr[(size_t)r * CC + c] = m;
}

__global__ __launch_bounds__(256) void sq2_kernel(const float* __restrict__ outF,
                                                  float* __restrict__ sq2) {
    int lane = threadIdx.x & 63, w = threadIdx.x >> 6;
    int n = blockIdx.x * 4 + w;
    const float* row = outF + (size_t)n * CC;
    float s = 0.f;
    for (int i = lane; i < CC; i += 64) { float v = row[i]; s += v * v; }
#pragma unroll
    for (int o = 32; o; o >>= 1) s += __shfl_down(s, o);
    if (lane == 0) sq2[n] = s;
}

__global__ __launch_bounds__(256) void colmax_kernel(const float* __restrict__ O,
                                                     float* __restrict__ dst) {
    int c = blockIdx.x * 256 + threadIdx.x;
    if (c >= CC) return;
    int n0 = blockIdx.y * 256;
    float m = 0.f;
    for (int n = n0; n < n0 + 256; ++n) m = fmaxf(m, O[(size_t)n * CC + c]);
    atomicMax((int*)&dst[c], __float_as_int(m));  // values >= 0: int order == float order
}

// ---------------- big GEMMs (fp32 baseline, 128x128 tiles) ----------------

__global__ __launch_bounds__(256) void gram2_kernel(const float* __restrict__ outF,
                                                    const float* __restrict__ sq2,
                                                    float* __restrict__ S, int base) {
    __shared__ float As[8][128];
    __shared__ float Bs[8][128];
    int tid = threadIdx.x;
    int m0 = blockIdx.x * 128;
    int r0 = blockIdx.y * 128;
    const float* A = outF + (size_t)(base + r0) * CC;
    const float* B = outF + (size_t)m0 * CC;
    int srow = tid >> 1, skk = (tid & 1) * 4;
    int ty = tid >> 4, tx = tid & 15;
    float acc[8][8];
#pragma unroll
    for (int i = 0; i < 8; ++i)
#pragma unroll
        for (int j = 0; j < 8; ++j) acc[i][j] = 0.f;
    for (int k0 = 0; k0 < CC; k0 += 8) {
        float4 av = *(const float4*)(A + (size_t)srow * CC + k0 + skk);
        float4 bv = *(const float4*)(B + (size_t)srow * CC + k0 + skk);
        __syncthreads();
        As[skk + 0][srow] = av.x; As[skk + 1][srow] = av.y;
        As[skk + 2][srow] = av.z; As[skk + 3][srow] = av.w;
        Bs[skk + 0][srow] = bv.x; Bs[skk + 1][srow] = bv.y;
        Bs[skk + 2][srow] = bv.z; Bs[skk + 3][srow] = bv.w;
        __syncthreads();
#pragma unroll
        for (int k = 0; k < 8; ++k) {
            float ra[8], rb[8];
#pragma unroll
            for (int i = 0; i < 8; ++i) ra[i] = As[k][ty * 8 + i];
#pragma unroll
            for (int j = 0; j < 4; ++j) { rb[j] = Bs[k][tx * 4 + j]; rb[4 + j] = Bs[k][64 + tx * 4 + j]; }
#pragma unroll
            for (int i = 0; i < 8; ++i)
#pragma unroll
                for (int j = 0; j < 8; ++j) acc[i][j] += ra[i] * rb[j];
        }
    }
#pragma unroll
    for (int i = 0; i < 8; ++i) {
        int r = r0 + ty * 8 + i;
        float sn = sq2[base + r];
#pragma unroll
        for (int j = 0; j < 8; ++j) {
            int m = m0 + ((j < 4) ? (tx * 4 + j) : (64 + tx * 4 + (j - 4)));
            float d = sn + sq2[m] - 2.f * acc[i][j];
            S[(size_t)r * N4 + m] = __expf(-d);
        }
    }
}

__global__ __launch_bounds__(256) void gemm_acc_kernel(const float* __restrict__ A,
                                                       const float* __restrict__ B,
                                                       float* __restrict__ C) {
    __shared__ float As[8][128];
    __shared__ float Bs[8][128];
    int tid = threadIdx.x;
    int n0 = blockIdx.x * 128;
    int m0 = blockIdx.y * 128;
    int srow = tid >> 1, skk = (tid & 1) * 4;
    int bkk = tid >> 5, bnn = (tid & 31) * 4;
    int ty = tid >> 4, tx = tid & 15;
    float acc[8][8];
#pragma unroll
    for (int i = 0; i < 8; ++i)
#pragma unroll
        for (int j = 0; j < 8; ++j) acc[i][j] = 0.f;
    const float* Aptr = A + (size_t)(m0 + srow) * CC + skk;
    int bn = n0 + bnn;
    const bool bok = (bn < CC);
    for (int k0 = 0; k0 < CC; k0 += 8) {
        float4 av = *(const float4*)(Aptr + k0);
        float4 bv = make_float4(0.f, 0.f, 0.f, 0.f);
        if (bok) bv = *(const float4*)(B + (size_t)(k0 + bkk) * CC + bn);
        __syncthreads();
        As[skk + 0][srow] = av.x; As[skk + 1][srow] = av.y;
        As[skk + 2][srow] = av.z; As[skk + 3][srow] = av.w;
        *(float4*)&Bs[bkk][bnn] = bv;
        __syncthreads();
#pragma unroll
        for (int k = 0; k < 8; ++k) {
            float ra[8], rb[8];
#pragma unroll
            for (int i = 0; i < 8; ++i) ra[i] = As[k][ty * 8 + i];
#pragma unroll
            for (int j = 0; j < 4; ++j) { rb[j] = Bs[k][tx * 4 + j]; rb[4 + j] = Bs[k][64 + tx * 4 + j]; }
#pragma unroll
            for (int i = 0; i < 8; ++i)
#pragma unroll
                for (int j = 0; j < 8; ++j) acc[i][j] += ra[i] * rb[j];
        }
    }
#pragma unroll
    for (int i = 0; i < 8; ++i) {
        int m = m0 + ty * 8 + i;
#pragma unroll
        for (int j = 0; j < 8; ++j) {
            int n = n0 + ((j < 4) ? (tx * 4 + j) : (64 + tx * 4 + (j - 4)));
            if (n < CC) C[(size_t)m * CC + n] += acc[i][j];
        }
    }
}

__global__ __launch_bounds__(256) void bias_relu_kernel(float* __restrict__ acc,
                                                        const float* __restrict__ b2) {
    size_t i = (size_t)blockIdx.x * 256 + threadIdx.x;
    if (i >= (size_t)N4 * CC) return;
    int c = (int)(i % CC);
    acc[i] = fmaxf(acc[i] + b2[c], 0.f);
}

// ---------------- reeb branch ----------------

__global__ __launch_bounds__(256) void reeb_mm_kernel(const float* __restrict__ Lr,
                                                      const float* __restrict__ Vin,
                                                      const float* __restrict__ Vsub,
                                                      float* __restrict__ Vout, float a2) {
    int c = blockIdx.x * 256 + threadIdx.x;
    if (c >= CC) return;
    int r = blockIdx.y;
    float s = 0.f;
#pragma unroll
    for (int j = 0; j < NRB; ++j) s += Lr[r * NRB + j] * Vin[(size_t)j * CC + c];
    float v = a2 * s;
    if (Vsub) v -= Vsub[(size_t)r * CC + c];
    Vout[(size_t)r * CC + c] = v;
}

__global__ __launch_bounds__(256) void reeb_conv_kernel(const float* __restrict__ vfr,
                                                        const float* __restrict__ tr1,
                                                        const float* __restrict__ tr2,
                                                        const float* __restrict__ Wr,
                                                        const float* __restrict__ br,
                                                        float* __restrict__ pre) {
    int c = blockIdx.x * 256 + threadIdx.x;
    if (c >= CC) return;
    int r = blockIdx.y;
    float s = br[c];
    for (int i = 0; i < CC; ++i) s += vfr[(size_t)r * CC + i] * Wr[(size_t)i * CC + c];
    for (int i = 0; i < CC; ++i) s += tr1[(size_t)r * CC + i] * Wr[(size_t)(CC + i) * CC + c];
    for (int i = 0; i < CC; ++i) s += tr2[(size_t)r * CC + i] * Wr[(size_t)(2 * CC + i) * CC + c];
    pre[(size_t)r * CC + c] = s;
}

__global__ __launch_bounds__(256) void reeb_max_kernel(const float* __restrict__ pre,
                                                       float* __restrict__ rbm) {
    int c = blockIdx.x * 256 + threadIdx.x;
    if (c >= CC) return;
    float m = 0.f;
    for (int r = 0; r < NRB; ++r) m = fmaxf(m, fmaxf(pre[(size_t)r * CC + c], 0.f));
    rbm[c] = m;
}

// ---------------- FC head ----------------

__global__ __launch_bounds__(256) void fc1_kernel(const float* __restrict__ rbm,
                                                  const float* __restrict__ otm,
                                                  const float* __restrict__ w,
                                                  float* __restrict__ h1pre) {
    int j = blockIdx.x * 256 + threadIdx.x;
    if (j >= 512) return;
    int i0 = blockIdx.y * 250;
    float s = 0.f;
    for (int i = i0; i < i0 + 250; ++i) {
        float v = (i < CC) ? rbm[i] : otm[i - CC];
        s += v * w[(size_t)i * 512 + j];
    }
    atomicAdd(&h1pre[j], s);
}

__global__ __launch_bounds__(512) void fc23_kernel(const float* __restrict__ h1pre,
                                                   const float* __restrict__ b1f,
                                                   const float* __restrict__ w2,
                                                   const float* __restrict__ b2f,
                                                   const float* __restrict__ w3,
                                                   const float* __restrict__ b3f,
                                                   float* __restrict__ dout) {
    __shared__ float h1[512];
    __shared__ float h2[128];
    int t = threadIdx.x;
    h1[t] = fmaxf(h1pre[t] + b1f[t], 0.f);
    __syncthreads();
    if (t < 128) {
        float s = b2f[t];
        for (int i = 0; i < 512; ++i) s += h1[i] * w2[(size_t)i * 128 + t];
        h2[t] = fmaxf(s, 0.f);
    }
    __syncthreads();
    if (t < 40) {
        float s = b3f[t];
        for (int i = 0; i < 128; ++i) s += h2[i] * w3[(size_t)i * 40 + t];
        dout[t] = s;
    }
}

__global__ __launch_bounds__(256) void finalize_kernel(const float* __restrict__ racc,
                                                       const float* __restrict__ f1w,
                                                       const float* __restrict__ f1b,
                                                       const float* __restrict__ f2w,
                                                       const float* __restrict__ f2b,
                                                       const float* __restrict__ f3w,
                                                       const float* __restrict__ f3b,
                                                       float* __restrict__ dout) {
    __shared__ float red[256];
    __shared__ float res[3];
    int t = threadIdx.x;
    float s1 = 0.f, s2 = 0.f, s3 = 0.f;
    for (int i = t; i < 2000; i += 256) { float v = f1w[(size_t)i * 512]; s1 += v * v; }
    for (int i = t; i < 512; i += 256) { float v = f2w[(size_t)i * 128]; s2 += v * v; }
    if (t < 128) { float v = f3w[(size_t)t * 40]; s3 = v * v; }

    red[t] = s1; __syncthreads();
    for (int o = 128; o; o >>= 1) { if (t < o) red[t] += red[t + o]; __syncthreads(); }
    if (t == 0) res[0] = red[0];
    __syncthreads();
    red[t] = s2; __syncthreads();
    for (int o = 128; o; o >>= 1) { if (t < o) red[t] += red[t + o]; __syncthreads(); }
    if (t == 0) res[1] = red[0];
    __syncthreads();
    red[t] = s3; __syncthreads();
    for (int o = 128; o; o >>= 1) { if (t < o) red[t] += red[t + o]; __syncthreads(); }
    if (t == 0) res[2] = red[0];
    __syncthreads();

    if (t == 0) {
        dout[40] = sqrtf(racc[0]);
        dout[41] = sqrtf(racc[1]);
        dout[42] = res[0];
        dout[43] = f1b[0] * f1b[0];
        dout[44] = res[1];
        dout[45] = f2b[0] * f2b[0];
        dout[46] = res[2];
        dout[47] = f3b[0] * f3b[0];
    }
}

// ---------------- host ----------------

extern "C" void kernel_launch(void* const* d_in, const int* in_sizes, int n_in,
                              void* d_out, int out_size, void* d_ws, size_t ws_size,
                              hipStream_t stream) {
    const float* x    = (const float*)d_in[0];
    const float* Lr   = (const float*)d_in[5];
    const int*   sccs = (const int*)d_in[6];
    const float* W1   = (const float*)d_in[7];
    const float* b1   = (const float*)d_in[8];
    const float* W2   = (const float*)d_in[9];
    const float* b2   = (const float*)d_in[10];
    const float* Wr   = (const float*)d_in[11];
    const float* br   = (const float*)d_in[12];
    const float* f1w  = (const float*)d_in[13];
    const float* f1b  = (const float*)d_in[14];
    const float* f2w  = (const float*)d_in[15];
    const float* f2b  = (const float*)d_in[16];
    const float* f3w  = (const float*)d_in[17];
    const float* f3b  = (const float*)d_in[18];
    float* dout = (float*)d_out;

    char* ws = (char*)d_ws;
    size_t off = 0;
    auto alloc = [&](size_t bytes) -> char* {
        char* p = ws + off;
        off = (off + bytes + 255) & ~(size_t)255;
        return p;
    };
    float* outF = (float*)alloc((size_t)N4 * CC * 4);   // Tx0 / ping
    float* T1   = (float*)alloc((size_t)N4 * CC * 4);   // pong
    float* accC = (float*)alloc((size_t)N4 * CC * 4);   // cheb2 accumulator -> out2
    float* Sb   = (float*)alloc((size_t)CHUNK * N4 * 4);
    float* xhat = (float*)alloc((size_t)N4 * 18 * 4);
    float* sq1  = (float*)alloc(N4 * 4);
    float* sq2  = (float*)alloc(N4 * 4);
    float* di1  = (float*)alloc(N4 * 4);
    float* di2  = (float*)alloc(N4 * 4);
    float* wv1  = (float*)alloc((size_t)N4 * KNN * 4);
    float* wv2  = (float*)alloc((size_t)N4 * KNN * 4);
    int*   ix1  = (int*)alloc((size_t)N4 * KNN * 4);
    int*   ix2  = (int*)alloc((size_t)N4 * KNN * 4);
    float* t2x  = (float*)alloc((size_t)N4 * FDIM * 4);
    float* vfr  = (float*)alloc((size_t)NRB * CC * 4);
    float* tr1  = (float*)alloc((size_t)NRB * CC * 4);
    float* tr2  = (float*)alloc((size_t)NRB * CC * 4);
    float* rpre = (float*)alloc((size_t)NRB * CC * 4);
    float* Mb   = (float*)alloc(6 * CC * 4);
    float* rbm  = (float*)alloc(CC * 4);
    float* otm  = (float*)alloc(CC * 4);
    float* h1p  = (float*)alloc(512 * 4);
    float* racc = (float*)alloc(64 * 4);
    if (off > ws_size) return;  // workspace too small -> fail loudly (wrong output)

    // zero accumulators (ws is poisoned 0xAA before every timed call)
    hipMemsetAsync(accC, 0, (size_t)N4 * CC * 4, stream);
    hipMemsetAsync(Mb,   0, 6 * CC * 4, stream);
    hipMemsetAsync(rbm,  0, CC * 4, stream);
    hipMemsetAsync(otm,  0, CC * 4, stream);
    hipMemsetAsync(h1p,  0, 512 * 4, stream);
    hipMemsetAsync(racc, 0, 64 * 4, stream);

    // ---- graph 1 (on x) ----
    sqx_kernel<<<(N4 + 255) / 256, 256, 0, stream>>>(x, sq1, xhat);
    for (int cb = 0; cb < N4; cb += CHUNK) {
        gram1_kernel<<<dim3(N4 / 256, CHUNK), 256, 0, stream>>>(x, sq1, Sb, cb);
        topk_kernel<<<CHUNK, 256, 0, stream>>>(Sb, cb, ix1, wv1, di1);
    }
    dinv_kernel<<<N4 / 256, 256, 0, stream>>>(di1);
    wnorm_kernel<<<(N4 * KNN + 255) / 256, 256, 0, stream>>>(wv1, ix1, di1);

    // ---- cheb conv 1: xhat cols [0:6)=x, [6:12)=Lx, [12:18)=2L(Lx)-x ----
    spmv_cheb<<<N4, 64, 0, stream>>>(xhat, xhat, xhat + 6, ix1, wv1, FDIM, 18, 18, 18, 1.f, 0.f);
    spmv_cheb<<<N4, 64, 0, stream>>>(xhat + 6, xhat, xhat + 12, ix1, wv1, FDIM, 18, 18, 18, 2.f, 1.f);
    cheb1_out_kernel<<<N4 / 16, 256, 0, stream>>>(xhat, W1, b1, outF);

    // reg1 = ||outF^T @ (L1 x)||_F   (L1 x == xhat cols 6..11)
    matT_partial<<<dim3(4, 6, 8), 256, 0, stream>>>(outF, xhat + 6, 18, Mb);
    fro_kernel<<<24, 256, 0, stream>>>(Mb, racc + 0);

    // reeb pooling input
    vfr_kernel<<<dim3(4, NRB), 256, 0, stream>>>(outF, sccs, vfr);

    // ---- graph 2 (on outF) ----
    sq2_kernel<<<N4 / 4, 256, 0, stream>>>(outF, sq2);
    for (int cb = 0; cb < N4; cb += CHUNK) {
        gram2_kernel<<<dim3(N4 / 128, CHUNK / 128), 256, 0, stream>>>(outF, sq2, Sb, cb);
        topk_kernel<<<CHUNK, 256, 0, stream>>>(Sb, cb, ix2, wv2, di2);
    }
    dinv_kernel<<<N4 / 256, 256, 0, stream>>>(di2);
    wnorm_kernel<<<(N4 * KNN + 255) / 256, 256, 0, stream>>>(wv2, ix2, di2);

    // L2 @ x for reg2
    spmv_cheb<<<N4, 64, 0, stream>>>(x, x, t2x, ix2, wv2, FDIM, FDIM, FDIM, FDIM, 1.f, 0.f);

    // ---- cheb conv 2 (K=6), ping-pong Tx in {outF, T1}, accumulate into accC ----
    gemm_acc_kernel<<<dim3(8, 32), 256, 0, stream>>>(outF, W2 + (size_t)0 * CC * CC, accC);
    spmv_cheb<<<N4, 256, 0, stream>>>(outF, outF, T1, ix2, wv2, CC, CC, CC, CC, 1.f, 0.f);
    gemm_acc_kernel<<<dim3(8, 32), 256, 0, stream>>>(T1, W2 + (size_t)1 * CC * CC, accC);
    spmv_cheb<<<N4, 256, 0, stream>>>(T1, outF, outF, ix2, wv2, CC, CC, CC, CC, 2.f, 1.f);
    gemm_acc_kernel<<<dim3(8, 32), 256, 0, stream>>>(outF, W2 + (size_t)2 * CC * CC, accC);
    spmv_cheb<<<N4, 256, 0, stream>>>(outF, T1, T1, ix2, wv2, CC, CC, CC, CC, 2.f, 1.f);
    gemm_acc_kernel<<<dim3(8, 32), 256, 0, stream>>>(T1, W2 + (size_t)3 * CC * CC, accC);
    spmv_cheb<<<N4, 256, 0, stream>>>(T1, outF, outF, ix2, wv2, CC, CC, CC, CC, 2.f, 1.f);
    gemm_acc_kernel<<<dim3(8, 32), 256, 0, stream>>>(outF, W2 + (size_t)4 * CC * CC, accC);
    spmv_cheb<<<N4, 256, 0, stream>>>(outF, T1, T1, ix2, wv2, CC, CC, CC, CC, 2.f, 1.f);
    gemm_acc_kernel<<<dim3(8, 32), 256, 0, stream>>>(T1, W2 + (size_t)5 * CC * CC, accC);
    bias_relu_kernel<<<(int)(((size_t)N4 * CC + 255) / 256), 256, 0, stream>>>(accC, b2);  // accC = out2

    // reg2 = ||out2^T @ (L2 x)||_F
    hipMemsetAsync(Mb, 0, 6 * CC * 4, stream);
    matT_partial<<<dim3(4, 6, 8), 256, 0, stream>>>(accC, t2x, FDIM, Mb);
    fro_kernel<<<24, 256, 0, stream>>>(Mb, racc + 1);

    // global max pool of out2
    colmax_kernel<<<dim3(4, 16), 256, 0, stream>>>(accC, otm);

    // ---- reeb cheb conv (K=3) ----
    reeb_mm_kernel<<<dim3(4, NRB), 256, 0, stream>>>(Lr, vfr, nullptr, tr1, 1.f);
    reeb_mm_kernel<<<dim3(4, NRB), 256, 0, stream>>>(Lr, tr1, vfr, tr2, 2.f);
    reeb_conv_kernel<<<dim3(4, NRB), 256, 0, stream>>>(vfr, tr1, tr2, Wr, br, rpre);
    reeb_max_kernel<<<4, 256, 0, stream>>>(rpre, rbm);

    // ---- FC head ----
    fc1_kernel<<<dim3(2, 8), 256, 0, stream>>>(rbm, otm, f1w, h1p);
    fc23_kernel<<<1, 512, 0, stream>>>(h1p, f1b, f2w, f2b, f3w, f3b, dout);
    finalize_kernel<<<1, 256, 0, stream>>>(racc, f1w, f1b, f2w, f2b, f3w, f3b, dout);
}

// Round 2
// 2071.300 us; speedup vs baseline: 1.6801x; 1.6801x over previous
//
#include <hip/hip_runtime.h>
#include <math.h>

#define N4    4096
#define FDIM  6
#define CC    1000
#define KP    1024   // padded K for bf16 GEMMs
#define KNN   40
#define CHUNK 1024
#define NRB   20
#define SSC   205

typedef __attribute__((ext_vector_type(8))) short bf16x8;
typedef __attribute__((ext_vector_type(4))) float f32x4;

__device__ __forceinline__ unsigned short f2bf(float f) {
    unsigned u = __float_as_uint(f);
    u = (u + 0x7fffu + ((u >> 16) & 1u)) >> 16;
    return (unsigned short)u;
}

// ---------------- graph build ----------------

__global__ __launch_bounds__(256) void sqx_kernel(const float* __restrict__ x,
                                                  float* __restrict__ sq1,
                                                  float* __restrict__ xhat) {
    int n = blockIdx.x * blockDim.x + threadIdx.x;
    if (n >= N4) return;
    float s = 0.f;
#pragma unroll
    for (int f = 0; f < FDIM; ++f) {
        float v = x[n * FDIM + f];
        s += v * v;
        xhat[n * 18 + f] = v;
    }
    sq1[n] = s;
}

__global__ __launch_bounds__(256) void gram1_kernel(const float* __restrict__ x,
                                                    const float* __restrict__ sq1,
                                                    float* __restrict__ S, int base) {
    __shared__ float xn[FDIM];
    __shared__ float sn;
    int r = blockIdx.y;
    int n = base + r;
    int m = blockIdx.x * 256 + threadIdx.x;
    if (threadIdx.x < FDIM) xn[threadIdx.x] = x[n * FDIM + threadIdx.x];
    if (threadIdx.x == FDIM) sn = sq1[n];
    __syncthreads();
    float d = 0.f;
#pragma unroll
    for (int f = 0; f < FDIM; ++f) d += xn[f] * x[m * FDIM + f];
    float e = sn + sq1[m] - 2.f * d;
    S[(size_t)r * N4 + m] = __expf(-e);
}

// iterative-extract top-40 per row; ties -> lower index (matches lax.top_k)
__global__ __launch_bounds__(256) void topk_kernel(const float* __restrict__ S, int base,
                                                   int* __restrict__ idx, float* __restrict__ val,
                                                   float* __restrict__ rowsum) {
    __shared__ float sv[N4];
    __shared__ float rv[4];
    __shared__ int ri[4];
    int r = blockIdx.x;
    int n = base + r;
    const float* row = S + (size_t)r * N4;
    for (int i = threadIdx.x; i < N4; i += 256) sv[i] = row[i];
    __syncthreads();
    int tid = threadIdx.x, lane = tid & 63, w = tid >> 6;
    float ssum = 0.f;
    for (int it = 0; it < KNN; ++it) {
        float bv = -1.f; int bi = N4;
        for (int i = tid; i < N4; i += 256) {
            float v = sv[i];
            if (v > bv || (v == bv && i < bi)) { bv = v; bi = i; }
        }
#pragma unroll
        for (int o = 32; o; o >>= 1) {
            float ov = __shfl_down(bv, o);
            int   oi = __shfl_down(bi, o);
            if (ov > bv || (ov == bv && oi < bi)) { bv = ov; bi = oi; }
        }
        if (lane == 0) { rv[w] = bv; ri[w] = bi; }
        __syncthreads();
        if (tid == 0) {
            float fv = rv[0]; int fi = ri[0];
#pragma unroll
            for (int q = 1; q < 4; ++q)
                if (rv[q] > fv || (rv[q] == fv && ri[q] < fi)) { fv = rv[q]; fi = ri[q]; }
            idx[(size_t)n * KNN + it] = fi;
            val[(size_t)n * KNN + it] = fv;
            ssum += fv;
            sv[fi] = -1.f;
            if (it == KNN - 1) rowsum[n] = ssum;
        }
        __syncthreads();
    }
}

__global__ __launch_bounds__(256) void dinv_kernel(float* __restrict__ rs) {
    int n = blockIdx.x * 256 + threadIdx.x;
    if (n < N4) rs[n] = rsqrtf(rs[n]);
}

__global__ __launch_bounds__(256) void wnorm_kernel(float* __restrict__ wv,
                                                    const int* __restrict__ idx,
                                                    const float* __restrict__ dinv) {
    int i = blockIdx.x * 256 + threadIdx.x;
    if (i >= N4 * KNN) return;
    int n = i / KNN;
    wv[i] = wv[i] * dinv[n] * dinv[idx[i]];
}

// Tn[n,:] = a*(Tc[n,:] - sum_j wv[n,j]*Tc[idx[n,j],:]) - b*Tp[n,:]
__global__ __launch_bounds__(256) void spmv_cheb(const float* __restrict__ Tc,
                                                 const float* __restrict__ Tp,
                                                 float* __restrict__ Tn,
                                                 const int* __restrict__ idx,
                                                 const float* __restrict__ wv,
                                                 int F, int sC, int sP, int sN,
                                                 float a, float b) {
    __shared__ int   si[KNN];
    __shared__ float sw[KNN];
    int n = blockIdx.x;
    if (threadIdx.x < KNN) {
        si[threadIdx.x] = idx[(size_t)n * KNN + threadIdx.x];
        sw[threadIdx.x] = wv[(size_t)n * KNN + threadIdx.x];
    }
    __syncthreads();
    for (int c = threadIdx.x; c < F; c += blockDim.x) {
        float s = 0.f;
#pragma unroll 8
        for (int j = 0; j < KNN; ++j) s += sw[j] * Tc[(size_t)si[j] * sC + c];
        float v = a * (Tc[(size_t)n * sC + c] - s);
        if (b != 0.f) v -= b * Tp[(size_t)n * sP + c];
        Tn[(size_t)n * sN + c] = v;
    }
}

// ---------------- bf16 conversion / transpose ----------------

// [N4 x CC] fp32 -> [N4 x KP] bf16 (zero-padded)
__global__ __launch_bounds__(256) void cvt_bf16_kernel(const float* __restrict__ in,
                                                       unsigned short* __restrict__ out) {
    int i = blockIdx.x * 256 + threadIdx.x;     // N4*128 total
    int r = i >> 7, g = i & 127;
    bf16x8 v;
    if (g < 125) {
        float4 a = *(const float4*)(in + (size_t)r * CC + g * 8);
        float4 b = *(const float4*)(in + (size_t)r * CC + g * 8 + 4);
        v[0] = (short)f2bf(a.x); v[1] = (short)f2bf(a.y);
        v[2] = (short)f2bf(a.z); v[3] = (short)f2bf(a.w);
        v[4] = (short)f2bf(b.x); v[5] = (short)f2bf(b.y);
        v[6] = (short)f2bf(b.z); v[7] = (short)f2bf(b.w);
    } else {
#pragma unroll
        for (int q = 0; q < 8; ++q) v[q] = 0;
    }
    *(bf16x8*)(out + (size_t)r * KP + g * 8) = v;
}

// W2 [6*CC x CC] fp32 -> W2T [6][KP(n) x KP(k)] bf16, W2T[s][n][k] = W2[s*CC+k][n]
__global__ __launch_bounds__(256) void w2t_kernel(const float* __restrict__ W2,
                                                  unsigned short* __restrict__ out) {
    __shared__ unsigned short tile[64][65];
    int t = threadIdx.x;
    int k0 = blockIdx.x * 64, n0 = blockIdx.y * 64, s = blockIdx.z;
#pragma unroll
    for (int p = 0; p < 16; ++p) {
        int i = p * 256 + t;
        int kk = i >> 6, nn = i & 63;
        int k = k0 + kk, n = n0 + nn;
        float v = (k < CC && n < CC) ? W2[((size_t)s * CC + k) * CC + n] : 0.f;
        tile[kk][nn] = f2bf(v);
    }
    __syncthreads();
#pragma unroll
    for (int p = 0; p < 16; ++p) {
        int i = p * 256 + t;
        int nn = i >> 6, kk = i & 63;
        out[((size_t)s * KP + n0 + nn) * KP + k0 + kk] = tile[kk][nn];
    }
}

// ---------------- MFMA GEMMs (128x128 tile, BK=32, bf16 in / fp32 acc) ----------------
// LDS rows padded to 40 shorts (80 B) -> 2-way bank aliasing only (free).

#define LDP 40

__global__ __launch_bounds__(256) void gemm_mfma_acc(const unsigned short* __restrict__ A,
                                                     const unsigned short* __restrict__ B,
                                                     float* __restrict__ C) {
    __shared__ short As[128 * LDP];
    __shared__ short Bs[128 * LDP];
    int t = threadIdx.x;
    int n0 = blockIdx.x * 128, m0 = blockIdx.y * 128;
    int l = t & 63, w = t >> 6;
    int wm = (w >> 1) * 64, wn = (w & 1) * 64;
    f32x4 acc[4][4] = {};
    int ar0 = t >> 2, ak0 = (t & 3) * 8;
    int ar1 = (t + 256) >> 2, ak1 = ((t + 256) & 3) * 8;
    const unsigned short* Ag = A + (size_t)m0 * KP;
    const unsigned short* Bg = B + (size_t)n0 * KP;
    int lr = l & 15, lq8 = (l >> 4) * 8;
    for (int k0 = 0; k0 < KP; k0 += 32) {
        bf16x8 a0 = *(const bf16x8*)(Ag + (size_t)ar0 * KP + k0 + ak0);
        bf16x8 a1 = *(const bf16x8*)(Ag + (size_t)ar1 * KP + k0 + ak1);
        bf16x8 b0 = *(const bf16x8*)(Bg + (size_t)ar0 * KP + k0 + ak0);
        bf16x8 b1 = *(const bf16x8*)(Bg + (size_t)ar1 * KP + k0 + ak1);
        __syncthreads();
        *(bf16x8*)&As[ar0 * LDP + ak0] = a0;
        *(bf16x8*)&As[ar1 * LDP + ak1] = a1;
        *(bf16x8*)&Bs[ar0 * LDP + ak0] = b0;
        *(bf16x8*)&Bs[ar1 * LDP + ak1] = b1;
        __syncthreads();
        bf16x8 af[4], bfr[4];
#pragma unroll
        for (int mi = 0; mi < 4; ++mi)
            af[mi] = *(const bf16x8*)&As[(wm + mi * 16 + lr) * LDP + lq8];
#pragma unroll
        for (int ni = 0; ni < 4; ++ni)
            bfr[ni] = *(const bf16x8*)&Bs[(wn + ni * 16 + lr) * LDP + lq8];
#pragma unroll
        for (int mi = 0; mi < 4; ++mi)
#pragma unroll
            for (int ni = 0; ni < 4; ++ni)
                acc[mi][ni] = __builtin_amdgcn_mfma_f32_16x16x32_bf16(af[mi], bfr[ni], acc[mi][ni], 0, 0, 0);
    }
    int lq4 = (l >> 4) * 4;
#pragma unroll
    for (int ni = 0; ni < 4; ++ni) {
        int n = n0 + wn + ni * 16 + lr;
        if (n >= CC) continue;
#pragma unroll
        for (int mi = 0; mi < 4; ++mi) {
            int m = m0 + wm + mi * 16 + lq4;
            f32x4 v = acc[mi][ni];
#pragma unroll
            for (int r = 0; r < 4; ++r) C[(size_t)(m + r) * CC + n] += v[r];
        }
    }
}

__global__ __launch_bounds__(256) void gram2_mfma(const unsigned short* __restrict__ Abf,
                                                  const float* __restrict__ sq2,
                                                  float* __restrict__ S, int base) {
    __shared__ short As[128 * LDP];
    __shared__ short Bs[128 * LDP];
    int t = threadIdx.x;
    int n0 = blockIdx.x * 128, m0 = blockIdx.y * 128;
    int l = t & 63, w = t >> 6;
    int wm = (w >> 1) * 64, wn = (w & 1) * 64;
    f32x4 acc[4][4] = {};
    int ar0 = t >> 2, ak0 = (t & 3) * 8;
    int ar1 = (t + 256) >> 2, ak1 = ((t + 256) & 3) * 8;
    const unsigned short* Ag = Abf + (size_t)(base + m0) * KP;
    const unsigned short* Bg = Abf + (size_t)n0 * KP;
    int lr = l & 15, lq8 = (l >> 4) * 8;
    for (int k0 = 0; k0 < KP; k0 += 32) {
        bf16x8 a0 = *(const bf16x8*)(Ag + (size_t)ar0 * KP + k0 + ak0);
        bf16x8 a1 = *(const bf16x8*)(Ag + (size_t)ar1 * KP + k0 + ak1);
        bf16x8 b0 = *(const bf16x8*)(Bg + (size_t)ar0 * KP + k0 + ak0);
        bf16x8 b1 = *(const bf16x8*)(Bg + (size_t)ar1 * KP + k0 + ak1);
        __syncthreads();
        *(bf16x8*)&As[ar0 * LDP + ak0] = a0;
        *(bf16x8*)&As[ar1 * LDP + ak1] = a1;
        *(bf16x8*)&Bs[ar0 * LDP + ak0] = b0;
        *(bf16x8*)&Bs[ar1 * LDP + ak1] = b1;
        __syncthreads();
        bf16x8 af[4], bfr[4];
#pragma unroll
        for (int mi = 0; mi < 4; ++mi)
            af[mi] = *(const bf16x8*)&As[(wm + mi * 16 + lr) * LDP + lq8];
#pragma unroll
        for (int ni = 0; ni < 4; ++ni)
            bfr[ni] = *(const bf16x8*)&Bs[(wn + ni * 16 + lr) * LDP + lq8];
#pragma unroll
        for (int mi = 0; mi < 4; ++mi)
#pragma unroll
            for (int ni = 0; ni < 4; ++ni)
                acc[mi][ni] = __builtin_amdgcn_mfma_f32_16x16x32_bf16(af[mi], bfr[ni], acc[mi][ni], 0, 0, 0);
    }
    int lq4 = (l >> 4) * 4;
#pragma unroll
    for (int ni = 0; ni < 4; ++ni) {
        int n = n0 + wn + ni * 16 + lr;
        float sn = sq2[n];
#pragma unroll
        for (int mi = 0; mi < 4; ++mi) {
            int mrow = m0 + wm + mi * 16 + lq4;
            f32x4 v = acc[mi][ni];
#pragma unroll
            for (int r = 0; r < 4; ++r) {
                float d = sq2[base + mrow + r] + sn - 2.f * v[r];
                S[(size_t)(mrow + r) * N4 + n] = __expf(-d);
            }
        }
    }
}

// ---------------- cheb conv 1 ----------------

__global__ __launch_bounds__(256) void cheb1_out_kernel(const float* __restrict__ xhat,
                                                        const float* __restrict__ W1,
                                                        const float* __restrict__ b1,
                                                        float* __restrict__ outF) {
    __shared__ float xh[16][18];
    int n0 = blockIdx.x * 16;
    int tid = threadIdx.x;
    for (int i = tid; i < 16 * 18; i += 256) xh[i / 18][i % 18] = xhat[(size_t)n0 * 18 + i];
    __syncthreads();
    for (int c0 = 0; c0 < CC; c0 += 256) {
        int c = c0 + tid;
        if (c < CC) {
            float acc[16];
#pragma unroll
            for (int r = 0; r < 16; ++r) acc[r] = 0.f;
            for (int f = 0; f < 18; ++f) {
                float wv = W1[(size_t)f * CC + c];
#pragma unroll
                for (int r = 0; r < 16; ++r) acc[r] += xh[r][f] * wv;
            }
            float bb = b1[c];
#pragma unroll
            for (int r = 0; r < 16; ++r)
                outF[(size_t)(n0 + r) * CC + c] = fmaxf(acc[r] + bb, 0.f);
        }
    }
}

// ---------------- regs (frobenius of O^T @ T) ----------------

__global__ __launch_bounds__(256) void matT_partial(const float* __restrict__ O,
                                                    const float* __restrict__ T, int ts,
                                                    float* __restrict__ M) {
    int c = blockIdx.x * 256 + threadIdx.x;
    int f = blockIdx.y;
    int n0 = blockIdx.z * 512;
    if (c >= CC) return;
    float s = 0.f;
    for (int n = n0; n < n0 + 512; ++n) s += O[(size_t)n * CC + c] * T[(size_t)n * ts + f];
    atomicAdd(&M[(size_t)f * CC + c], s);
}

__global__ __launch_bounds__(256) void fro_kernel(const float* __restrict__ M, float* __restrict__ dst) {
    __shared__ float red[256];
    int t = threadIdx.x;
    int i = blockIdx.x * 256 + t;
    float v = (i < 6 * CC) ? M[i] : 0.f;
    red[t] = v * v;
    __syncthreads();
    for (int o = 128; o; o >>= 1) { if (t < o) red[t] += red[t + o]; __syncthreads(); }
    if (t == 0) atomicAdd(dst, red[0]);
}

// ---------------- pooling ----------------

__global__ __launch_bounds__(256) void vfr_kernel(const float* __restrict__ outF,
                                                  const int* __restrict__ sccs,
                                                  float* __restrict__ vfr) {
    int r = blockIdx.y;
    int c = blockIdx.x * 256 + threadIdx.x;
    if (c >= CC) return;
    float m = 0.f;
    for (int s = 0; s < SSC; ++s) {
        int n = sccs[r * SSC + s];
        m = fmaxf(m, outF[(size_t)n * CC + c]);
    }
    vfr[(size_t)r * CC + c] = m;
}

__global__ __launch_bounds__(256) void sq2_kernel(const float* __restrict__ outF,
                                                  float* __restrict__ sq2) {
    int lane = threadIdx.x & 63, w = threadIdx.x >> 6;
    int n = blockIdx.x * 4 + w;
    const float* row = outF + (size_t)n * CC;
    float s = 0.f;
    for (int i = lane; i < CC; i += 64) { float v = row[i]; s += v * v; }
#pragma unroll
    for (int o = 32; o; o >>= 1) s += __shfl_down(s, o);
    if (lane == 0) sq2[n] = s;
}

__global__ __launch_bounds__(256) void colmax_kernel(const float* __restrict__ O,
                                                     float* __restrict__ dst) {
    int c = blockIdx.x * 256 + threadIdx.x;
    if (c >= CC) return;
    int n0 = blockIdx.y * 256;
    float m = 0.f;
    for (int n = n0; n < n0 + 256; ++n) m = fmaxf(m, O[(size_t)n * CC + c]);
    atomicMax((int*)&dst[c], __float_as_int(m));  // values >= 0: int order == float order
}

__global__ __launch_bounds__(256) void bias_relu_kernel(float* __restrict__ acc,
                                                        const float* __restrict__ b2) {
    size_t i = (size_t)blockIdx.x * 256 + threadIdx.x;
    if (i >= (size_t)N4 * CC) return;
    int c = (int)(i % CC);
    acc[i] = fmaxf(acc[i] + b2[c], 0.f);
}

// ---------------- reeb branch ----------------

__global__ __launch_bounds__(256) void reeb_mm_kernel(const float* __restrict__ Lr,
                                                      const float* __restrict__ Vin,
                                                      const float* __restrict__ Vsub,
                                                      float* __restrict__ Vout, float a2) {
    int c = blockIdx.x * 256 + threadIdx.x;
    if (c >= CC) return;
    int r = blockIdx.y;
    float s = 0.f;
#pragma unroll
    for (int j = 0; j < NRB; ++j) s += Lr[r * NRB + j] * Vin[(size_t)j * CC + c];
    float v = a2 * s;
    if (Vsub) v -= Vsub[(size_t)r * CC + c];
    Vout[(size_t)r * CC + c] = v;
}

// split-K: rpre[r][c] += sum_{k in chunk} A[r][k] * Wr[k][c], A = [vfr; tr1; tr2]
#define RKC 125
__global__ __launch_bounds__(256) void reeb_conv_splitk(const float* __restrict__ vfr,
                                                        const float* __restrict__ tr1,
                                                        const float* __restrict__ tr2,
                                                        const float* __restrict__ Wr,
                                                        float* __restrict__ rpre) {
    __shared__ float sA[NRB][RKC];
    int t = threadIdx.x;
    int kbase = blockIdx.y * RKC;
    for (int i = t; i < NRB * RKC; i += 256) {
        int r = i / RKC, kk = i % RKC;
        int kg = kbase + kk;
        float v;
        if (kg < CC)           v = vfr[(size_t)r * CC + kg];
        else if (kg < 2 * CC)  v = tr1[(size_t)r * CC + kg - CC];
        else                   v = tr2[(size_t)r * CC + kg - 2 * CC];
        sA[r][kk] = v;
    }
    __syncthreads();
    int c = blockIdx.x * 256 + t;
    if (c >= CC) return;
    float acc[NRB];
#pragma unroll
    for (int r = 0; r < NRB; ++r) acc[r] = 0.f;
    for (int kk = 0; kk < RKC; ++kk) {
        float wv = Wr[(size_t)(kbase + kk) * CC + c];
#pragma unroll
        for (int r = 0; r < NRB; ++r) acc[r] += sA[r][kk] * wv;
    }
#pragma unroll
    for (int r = 0; r < NRB; ++r) atomicAdd(&rpre[(size_t)r * CC + c], acc[r]);
}

__global__ __launch_bounds__(256) void reeb_max_kernel(const float* __restrict__ pre,
                                                       const float* __restrict__ br,
                                                       float* __restrict__ rbm) {
    int c = blockIdx.x * 256 + threadIdx.x;
    if (c >= CC) return;
    float bb = br[c];
    float m = 0.f;
    for (int r = 0; r < NRB; ++r) m = fmaxf(m, fmaxf(pre[(size_t)r * CC + c] + bb, 0.f));
    rbm[c] = m;
}

// ---------------- FC head ----------------

__global__ __launch_bounds__(256) void fc1_kernel(const float* __restrict__ rbm,
                                                  const float* __restrict__ otm,
                                                  const float* __restrict__ w,
                                                  float* __restrict__ h1pre) {
    int j = blockIdx.x * 256 + threadIdx.x;
    if (j >= 512) return;
    int i0 = blockIdx.y * 250;
    float s = 0.f;
    for (int i = i0; i < i0 + 250; ++i) {
        float v = (i < CC) ? rbm[i] : otm[i - CC];
        s += v * w[(size_t)i * 512 + j];
    }
    atomicAdd(&h1pre[j], s);
}

__global__ __launch_bounds__(512) void fc23_kernel(const float* __restrict__ h1pre,
                                                   const float* __restrict__ b1f,
                                                   const float* __restrict__ w2,
                                                   const float* __restrict__ b2f,
                                                   const float* __restrict__ w3,
                                                   const float* __restrict__ b3f,
                                                   float* __restrict__ dout) {
    __shared__ float h1[512];
    __shared__ float h2[128];
    int t = threadIdx.x;
    h1[t] = fmaxf(h1pre[t] + b1f[t], 0.f);
    __syncthreads();
    if (t < 128) {
        float s = b2f[t];
        for (int i = 0; i < 512; ++i) s += h1[i] * w2[(size_t)i * 128 + t];
        h2[t] = fmaxf(s, 0.f);
    }
    __syncthreads();
    if (t < 40) {
        float s = b3f[t];
        for (int i = 0; i < 128; ++i) s += h2[i] * w3[(size_t)i * 40 + t];
        dout[t] = s;
    }
}

__global__ __launch_bounds__(256) void finalize_kernel(const float* __restrict__ racc,
                                                       const float* __restrict__ f1w,
                                                       const float* __restrict__ f1b,
                                                       const float* __restrict__ f2w,
                                                       const float* __restrict__ f2b,
                                                       const float* __restrict__ f3w,
                                                       const float* __restrict__ f3b,
                                                       float* __restrict__ dout) {
    __shared__ float red[256];
    __shared__ float res[3];
    int t = threadIdx.x;
    float s1 = 0.f, s2 = 0.f, s3 = 0.f;
    for (int i = t; i < 2000; i += 256) { float v = f1w[(size_t)i * 512]; s1 += v * v; }
    for (int i = t; i < 512; i += 256) { float v = f2w[(size_t)i * 128]; s2 += v * v; }
    if (t < 128) { float v = f3w[(size_t)t * 40]; s3 = v * v; }

    red[t] = s1; __syncthreads();
    for (int o = 128; o; o >>= 1) { if (t < o) red[t] += red[t + o]; __syncthreads(); }
    if (t == 0) res[0] = red[0];
    __syncthreads();
    red[t] = s2; __syncthreads();
    for (int o = 128; o; o >>= 1) { if (t < o) red[t] += red[t + o]; __syncthreads(); }
    if (t == 0) res[1] = red[0];
    __syncthreads();
    red[t] = s3; __syncthreads();
    for (int o = 128; o; o >>= 1) { if (t < o) red[t] += red[t + o]; __syncthreads(); }
    if (t == 0) res[2] = red[0];
    __syncthreads();

    if (t == 0) {
        dout[40] = sqrtf(racc[0]);
        dout[41] = sqrtf(racc[1]);
        dout[42] = res[0];
        dout[43] = f1b[0] * f1b[0];
        dout[44] = res[1];
        dout[45] = f2b[0] * f2b[0];
        dout[46] = res[2];
        dout[47] = f3b[0] * f3b[0];
    }
}

// ---------------- host ----------------

extern "C" void kernel_launch(void* const* d_in, const int* in_sizes, int n_in,
                              void* d_out, int out_size, void* d_ws, size_t ws_size,
                              hipStream_t stream) {
    const float* x    = (const float*)d_in[0];
    const float* Lr   = (const float*)d_in[5];
    const int*   sccs = (const int*)d_in[6];
    const float* W1   = (const float*)d_in[7];
    const float* b1   = (const float*)d_in[8];
    const float* W2   = (const float*)d_in[9];
    const float* b2   = (const float*)d_in[10];
    const float* Wr   = (const float*)d_in[11];
    const float* br   = (const float*)d_in[12];
    const float* f1w  = (const float*)d_in[13];
    const float* f1b  = (const float*)d_in[14];
    const float* f2w  = (const float*)d_in[15];
    const float* f2b  = (const float*)d_in[16];
    const float* f3w  = (const float*)d_in[17];
    const float* f3b  = (const float*)d_in[18];
    float* dout = (float*)d_out;

    char* ws = (char*)d_ws;
    size_t off = 0;
    auto alloc = [&](size_t bytes) -> char* {
        char* p = ws + off;
        off = (off + bytes + 255) & ~(size_t)255;
        return p;
    };
    float* outF = (float*)alloc((size_t)N4 * CC * 4);   // Tx0 / ping
    float* T1   = (float*)alloc((size_t)N4 * CC * 4);   // pong
    float* accC = (float*)alloc((size_t)N4 * CC * 4);   // cheb2 accumulator -> out2
    float* Sb   = (float*)alloc((size_t)CHUNK * N4 * 4);
    unsigned short* Abf = (unsigned short*)alloc((size_t)N4 * KP * 2);
    unsigned short* Bbf = (unsigned short*)alloc((size_t)N4 * KP * 2);
    unsigned short* W2T = (unsigned short*)Sb;  // alias: Sb dead after last topk, W2T built after
    float* xhat = (float*)alloc((size_t)N4 * 18 * 4);
    float* sq1  = (float*)alloc(N4 * 4);
    float* sq2  = (float*)alloc(N4 * 4);
    float* di1  = (float*)alloc(N4 * 4);
    float* di2  = (float*)alloc(N4 * 4);
    float* wv1  = (float*)alloc((size_t)N4 * KNN * 4);
    float* wv2  = (float*)alloc((size_t)N4 * KNN * 4);
    int*   ix1  = (int*)alloc((size_t)N4 * KNN * 4);
    int*   ix2  = (int*)alloc((size_t)N4 * KNN * 4);
    float* t2x  = (float*)alloc((size_t)N4 * FDIM * 4);
    float* vfr  = (float*)alloc((size_t)NRB * CC * 4);
    float* tr1  = (float*)alloc((size_t)NRB * CC * 4);
    float* tr2  = (float*)alloc((size_t)NRB * CC * 4);
    float* rpre = (float*)alloc((size_t)NRB * CC * 4);
    float* Mb   = (float*)alloc(6 * CC * 4);
    float* rbm  = (float*)alloc(CC * 4);
    float* otm  = (float*)alloc(CC * 4);
    float* h1p  = (float*)alloc(512 * 4);
    float* racc = (float*)alloc(64 * 4);
    if (off > ws_size) return;  // workspace too small -> fail loudly (wrong output)

    hipMemsetAsync(accC, 0, (size_t)N4 * CC * 4, stream);
    hipMemsetAsync(Mb,   0, 6 * CC * 4, stream);
    hipMemsetAsync(rbm,  0, CC * 4, stream);
    hipMemsetAsync(otm,  0, CC * 4, stream);
    hipMemsetAsync(h1p,  0, 512 * 4, stream);
    hipMemsetAsync(racc, 0, 64 * 4, stream);
    hipMemsetAsync(rpre, 0, (size_t)NRB * CC * 4, stream);

    // ---- graph 1 (on x) ----
    sqx_kernel<<<(N4 + 255) / 256, 256, 0, stream>>>(x, sq1, xhat);
    for (int cb = 0; cb < N4; cb += CHUNK) {
        gram1_kernel<<<dim3(N4 / 256, CHUNK), 256, 0, stream>>>(x, sq1, Sb, cb);
        topk_kernel<<<CHUNK, 256, 0, stream>>>(Sb, cb, ix1, wv1, di1);
    }
    dinv_kernel<<<N4 / 256, 256, 0, stream>>>(di1);
    wnorm_kernel<<<(N4 * KNN + 255) / 256, 256, 0, stream>>>(wv1, ix1, di1);

    // ---- cheb conv 1: xhat cols [0:6)=x, [6:12)=Lx, [12:18)=2L(Lx)-x ----
    spmv_cheb<<<N4, 64, 0, stream>>>(xhat, xhat, xhat + 6, ix1, wv1, FDIM, 18, 18, 18, 1.f, 0.f);
    spmv_cheb<<<N4, 64, 0, stream>>>(xhat + 6, xhat, xhat + 12, ix1, wv1, FDIM, 18, 18, 18, 2.f, 1.f);
    cheb1_out_kernel<<<N4 / 16, 256, 0, stream>>>(xhat, W1, b1, outF);

    // reg1 = ||outF^T @ (L1 x)||_F
    matT_partial<<<dim3(4, 6, 8), 256, 0, stream>>>(outF, xhat + 6, 18, Mb);
    fro_kernel<<<24, 256, 0, stream>>>(Mb, racc + 0);

    vfr_kernel<<<dim3(4, NRB), 256, 0, stream>>>(outF, sccs, vfr);

    // ---- graph 2 (on outF), bf16 MFMA gram ----
    sq2_kernel<<<N4 / 4, 256, 0, stream>>>(outF, sq2);
    cvt_bf16_kernel<<<N4 * 128 / 256, 256, 0, stream>>>(outF, Abf);
    for (int cb = 0; cb < N4; cb += CHUNK) {
        gram2_mfma<<<dim3(N4 / 128, CHUNK / 128), 256, 0, stream>>>(Abf, sq2, Sb, cb);
        topk_kernel<<<CHUNK, 256, 0, stream>>>(Sb, cb, ix2, wv2, di2);
    }
    dinv_kernel<<<N4 / 256, 256, 0, stream>>>(di2);
    wnorm_kernel<<<(N4 * KNN + 255) / 256, 256, 0, stream>>>(wv2, ix2, di2);

    // Sb is dead now -> build W2T in its space
    w2t_kernel<<<dim3(16, 16, 6), 256, 0, stream>>>(W2, W2T);

    // L2 @ x for reg2
    spmv_cheb<<<N4, 64, 0, stream>>>(x, x, t2x, ix2, wv2, FDIM, FDIM, FDIM, FDIM, 1.f, 0.f);

    // ---- cheb conv 2 (K=6), ping-pong Tx in {outF, T1}, bf16 copies in {Abf, Bbf} ----
    gemm_mfma_acc<<<dim3(8, 32), 256, 0, stream>>>(Abf, W2T + (size_t)0 * KP * KP, accC);
    spmv_cheb<<<N4, 256, 0, stream>>>(outF, outF, T1, ix2, wv2, CC, CC, CC, CC, 1.f, 0.f);
    cvt_bf16_kernel<<<N4 * 128 / 256, 256, 0, stream>>>(T1, Bbf);
    gemm_mfma_acc<<<dim3(8, 32), 256, 0, stream>>>(Bbf, W2T + (size_t)1 * KP * KP, accC);
    spmv_cheb<<<N4, 256, 0, stream>>>(T1, outF, outF, ix2, wv2, CC, CC, CC, CC, 2.f, 1.f);
    cvt_bf16_kernel<<<N4 * 128 / 256, 256, 0, stream>>>(outF, Abf);
    gemm_mfma_acc<<<dim3(8, 32), 256, 0, stream>>>(Abf, W2T + (size_t)2 * KP * KP, accC);
    spmv_cheb<<<N4, 256, 0, stream>>>(outF, T1, T1, ix2, wv2, CC, CC, CC, CC, 2.f, 1.f);
    cvt_bf16_kernel<<<N4 * 128 / 256, 256, 0, stream>>>(T1, Bbf);
    gemm_mfma_acc<<<dim3(8, 32), 256, 0, stream>>>(Bbf, W2T + (size_t)3 * KP * KP, accC);
    spmv_cheb<<<N4, 256, 0, stream>>>(T1, outF, outF, ix2, wv2, CC, CC, CC, CC, 2.f, 1.f);
    cvt_bf16_kernel<<<N4 * 128 / 256, 256, 0, stream>>>(outF, Abf);
    gemm_mfma_acc<<<dim3(8, 32), 256, 0, stream>>>(Abf, W2T + (size_t)4 * KP * KP, accC);
    spmv_cheb<<<N4, 256, 0, stream>>>(outF, T1, T1, ix2, wv2, CC, CC, CC, CC, 2.f, 1.f);
    cvt_bf16_kernel<<<N4 * 128 / 256, 256, 0, stream>>>(T1, Bbf);
    gemm_mfma_acc<<<dim3(8, 32), 256, 0, stream>>>(Bbf, W2T + (size_t)5 * KP * KP, accC);
    bias_relu_kernel<<<(int)(((size_t)N4 * CC + 255) / 256), 256, 0, stream>>>(accC, b2);

    // reg2 = ||out2^T @ (L2 x)||_F
    hipMemsetAsync(Mb, 0, 6 * CC * 4, stream);
    matT_partial<<<dim3(4, 6, 8), 256, 0, stream>>>(accC, t2x, FDIM, Mb);
    fro_kernel<<<24, 256, 0, stream>>>(Mb, racc + 1);

    colmax_kernel<<<dim3(4, 16), 256, 0, stream>>>(accC, otm);

    // ---- reeb cheb conv (K=3) ----
    reeb_mm_kernel<<<dim3(4, NRB), 256, 0, stream>>>(Lr, vfr, nullptr, tr1, 1.f);
    reeb_mm_kernel<<<dim3(4, NRB), 256, 0, stream>>>(Lr, tr1, vfr, tr2, 2.f);
    reeb_conv_splitk<<<dim3(4, 24), 256, 0, stream>>>(vfr, tr1, tr2, Wr, rpre);
    reeb_max_kernel<<<4, 256, 0, stream>>>(rpre, br, rbm);

    // ---- FC head ----
    fc1_kernel<<<dim3(2, 8), 256, 0, stream>>>(rbm, otm, f1w, h1p);
    fc23_kernel<<<1, 512, 0, stream>>>(h1p, f1b, f2w, f2b, f3w, f3b, dout);
    finalize_kernel<<<1, 256, 0, stream>>>(racc, f1w, f1b, f2w, f2b, f3w, f3b, dout);
}

// Round 3
// 1667.862 us; speedup vs baseline: 2.0865x; 1.2419x over previous
//
#include <hip/hip_runtime.h>
#include <math.h>

#define N4    4096
#define FDIM  6
#define CC    1000
#define KP    1024   // padded K for bf16 GEMMs
#define KNN   40
#define CHUNK 1024
#define NRB   20
#define SSC   205

typedef __attribute__((ext_vector_type(8))) short bf16x8;
typedef __attribute__((ext_vector_type(4))) float f32x4;

__device__ __forceinline__ unsigned short f2bf(float f) {
    unsigned u = __float_as_uint(f);
    u = (u + 0x7fffu + ((u >> 16) & 1u)) >> 16;
    return (unsigned short)u;
}

// ---------------- graph build ----------------

__global__ __launch_bounds__(256) void sqx_kernel(const float* __restrict__ x,
                                                  float* __restrict__ sq1,
                                                  float* __restrict__ xhat) {
    int n = blockIdx.x * blockDim.x + threadIdx.x;
    if (n >= N4) return;
    float s = 0.f;
#pragma unroll
    for (int f = 0; f < FDIM; ++f) {
        float v = x[n * FDIM + f];
        s += v * v;
        xhat[n * 18 + f] = v;
    }
    sq1[n] = s;
}

__global__ __launch_bounds__(256) void gram1_kernel(const float* __restrict__ x,
                                                    const float* __restrict__ sq1,
                                                    float* __restrict__ S, int base) {
    __shared__ float xn[FDIM];
    __shared__ float sn;
    int r = blockIdx.y;
    int n = base + r;
    int m = blockIdx.x * 256 + threadIdx.x;
    if (threadIdx.x < FDIM) xn[threadIdx.x] = x[n * FDIM + threadIdx.x];
    if (threadIdx.x == FDIM) sn = sq1[n];
    __syncthreads();
    float d = 0.f;
#pragma unroll
    for (int f = 0; f < FDIM; ++f) d += xn[f] * x[m * FDIM + f];
    float e = sn + sq1[m] - 2.f * d;
    S[(size_t)r * N4 + m] = __expf(-e);
}

// radix-select top-40 per row. Exact: finds 40th-largest value T via byte-wise
// histogram refinement (float>=0 -> uint order == float order), scatters >T
// unordered (W-build is a scatter; order irrelevant), takes ==T ties in
// ascending index order (matches lax.top_k lower-index tie-break).
__global__ __launch_bounds__(256) void topk_radix(const float* __restrict__ S, int base,
                                                  int* __restrict__ idx, float* __restrict__ val,
                                                  float* __restrict__ rowsum) {
    __shared__ unsigned sv[N4];
    __shared__ int h0[256], h1[256];
    __shared__ unsigned s_pfx;
    __shared__ int s_need;
    __shared__ int s_cnt;
    __shared__ float red[256];
    int t = threadIdx.x;
    int r = blockIdx.x;
    int n = base + r;
    const float* row = S + (size_t)r * N4;
    for (int i = t; i < N4; i += 256) sv[i] = __float_as_uint(row[i]);
    if (t == 0) { s_pfx = 0u; s_need = KNN; s_cnt = 0; }
    __syncthreads();

    int* myh = ((t >> 6) & 1) ? h1 : h0;
#pragma unroll
    for (int level = 24; level >= 0; level -= 8) {
        if (t < 256) { h0[t] = 0; h1[t] = 0; }
        __syncthreads();
        unsigned pfx = s_pfx;
        for (int i = t; i < N4; i += 256) {
            unsigned u = sv[i];
            bool match = (level == 24) || ((u >> (level + 8)) == (pfx >> (level + 8)));
            if (match) atomicAdd(&myh[(u >> level) & 255], 1);
        }
        __syncthreads();
        if (t == 0) {
            int need = s_need, cum = 0, b = 0;
            for (int j = 255; j >= 0; --j) {
                int c = h0[j] + h1[j];
                if (cum + c >= need) { b = j; break; }
                cum += c;
            }
            s_need = need - cum;        // remaining to take within bucket b
            s_pfx = pfx | ((unsigned)b << level);
        }
        __syncthreads();
    }
    unsigned Tbits = s_pfx;
    float Tf = __uint_as_float(Tbits);
    int needEq = s_need;

    // collect strictly-greater (count = KNN - needEq), accumulate their sum
    float psum = 0.f;
    for (int i = t; i < N4; i += 256) {
        unsigned u = sv[i];
        if (u > Tbits) {
            int p = atomicAdd(&s_cnt, 1);
            idx[(size_t)n * KNN + p] = i;
            float v = __uint_as_float(u);
            val[(size_t)n * KNN + p] = v;
            psum += v;
        }
    }
    red[t] = psum;
    __syncthreads();
    for (int o = 128; o; o >>= 1) { if (t < o) red[t] += red[t + o]; __syncthreads(); }
    if (t == 0) rowsum[n] = red[0] + (float)needEq * Tf;

    // equals: earliest indices first (wave 0 ballot scan)
    if (t < 64) {
        int filled = KNN - needEq;
        for (int ib = 0; ib < N4 && filled < KNN; ib += 64) {
            bool eq = (sv[ib + t] == Tbits);
            unsigned long long m = __ballot(eq);
            int pre = __popcll(m & ((1ull << t) - 1ull));
            if (eq && (filled + pre) < KNN) {
                idx[(size_t)n * KNN + filled + pre] = ib + t;
                val[(size_t)n * KNN + filled + pre] = Tf;
            }
            filled += __popcll(m);
        }
    }
}

__global__ __launch_bounds__(256) void dinv_kernel(float* __restrict__ rs) {
    int n = blockIdx.x * 256 + threadIdx.x;
    if (n < N4) rs[n] = rsqrtf(rs[n]);
}

__global__ __launch_bounds__(256) void wnorm_kernel(float* __restrict__ wv,
                                                    const int* __restrict__ idx,
                                                    const float* __restrict__ dinv) {
    int i = blockIdx.x * 256 + threadIdx.x;
    if (i >= N4 * KNN) return;
    int n = i / KNN;
    wv[i] = wv[i] * dinv[n] * dinv[idx[i]];
}

// Tn[n,:] = a*(Tc[n,:] - sum_j wv[n,j]*Tc[idx[n,j],:]) - b*Tp[n,:]
__global__ __launch_bounds__(256) void spmv_cheb(const float* __restrict__ Tc,
                                                 const float* __restrict__ Tp,
                                                 float* __restrict__ Tn,
                                                 const int* __restrict__ idx,
                                                 const float* __restrict__ wv,
                                                 int F, int sC, int sP, int sN,
                                                 float a, float b) {
    __shared__ int   si[KNN];
    __shared__ float sw[KNN];
    int n = blockIdx.x;
    if (threadIdx.x < KNN) {
        si[threadIdx.x] = idx[(size_t)n * KNN + threadIdx.x];
        sw[threadIdx.x] = wv[(size_t)n * KNN + threadIdx.x];
    }
    __syncthreads();
    for (int c = threadIdx.x; c < F; c += blockDim.x) {
        float s = 0.f;
#pragma unroll 8
        for (int j = 0; j < KNN; ++j) s += sw[j] * Tc[(size_t)si[j] * sC + c];
        float v = a * (Tc[(size_t)n * sC + c] - s);
        if (b != 0.f) v -= b * Tp[(size_t)n * sP + c];
        Tn[(size_t)n * sN + c] = v;
    }
}

// ---------------- bf16 conversion / transpose ----------------

__global__ __launch_bounds__(256) void cvt_bf16_kernel(const float* __restrict__ in,
                                                       unsigned short* __restrict__ out) {
    int i = blockIdx.x * 256 + threadIdx.x;     // N4*128 total
    int r = i >> 7, g = i & 127;
    bf16x8 v;
    if (g < 125) {
        float4 a = *(const float4*)(in + (size_t)r * CC + g * 8);
        float4 b = *(const float4*)(in + (size_t)r * CC + g * 8 + 4);
        v[0] = (short)f2bf(a.x); v[1] = (short)f2bf(a.y);
        v[2] = (short)f2bf(a.z); v[3] = (short)f2bf(a.w);
        v[4] = (short)f2bf(b.x); v[5] = (short)f2bf(b.y);
        v[6] = (short)f2bf(b.z); v[7] = (short)f2bf(b.w);
    } else {
#pragma unroll
        for (int q = 0; q < 8; ++q) v[q] = 0;
    }
    *(bf16x8*)(out + (size_t)r * KP + g * 8) = v;
}

// W2 [6*CC x CC] fp32 -> W2T [6][KP(n) x KP(k)] bf16, W2T[s][n][k] = W2[s*CC+k][n]
__global__ __launch_bounds__(256) void w2t_kernel(const float* __restrict__ W2,
                                                  unsigned short* __restrict__ out) {
    __shared__ unsigned short tile[64][65];
    int t = threadIdx.x;
    int k0 = blockIdx.x * 64, n0 = blockIdx.y * 64, s = blockIdx.z;
#pragma unroll
    for (int p = 0; p < 16; ++p) {
        int i = p * 256 + t;
        int kk = i >> 6, nn = i & 63;
        int k = k0 + kk, n = n0 + nn;
        float v = (k < CC && n < CC) ? W2[((size_t)s * CC + k) * CC + n] : 0.f;
        tile[kk][nn] = f2bf(v);
    }
    __syncthreads();
#pragma unroll
    for (int p = 0; p < 16; ++p) {
        int i = p * 256 + t;
        int nn = i >> 6, kk = i & 63;
        out[((size_t)s * KP + n0 + nn) * KP + k0 + kk] = tile[kk][nn];
    }
}

// ---------------- MFMA GEMMs (128x128 tile, BK=32, bf16 in / fp32 acc) ----------------

#define LDP 40

__global__ __launch_bounds__(256) void gemm_mfma_acc(const unsigned short* __restrict__ A,
                                                     const unsigned short* __restrict__ B,
                                                     float* __restrict__ C) {
    __shared__ short As[128 * LDP];
    __shared__ short Bs[128 * LDP];
    int t = threadIdx.x;
    int n0 = blockIdx.x * 128, m0 = blockIdx.y * 128;
    int l = t & 63, w = t >> 6;
    int wm = (w >> 1) * 64, wn = (w & 1) * 64;
    f32x4 acc[4][4] = {};
    int ar0 = t >> 2, ak0 = (t & 3) * 8;
    int ar1 = (t + 256) >> 2, ak1 = ((t + 256) & 3) * 8;
    const unsigned short* Ag = A + (size_t)m0 * KP;
    const unsigned short* Bg = B + (size_t)n0 * KP;
    int lr = l & 15, lq8 = (l >> 4) * 8;
    for (int k0 = 0; k0 < KP; k0 += 32) {
        bf16x8 a0 = *(const bf16x8*)(Ag + (size_t)ar0 * KP + k0 + ak0);
        bf16x8 a1 = *(const bf16x8*)(Ag + (size_t)ar1 * KP + k0 + ak1);
        bf16x8 b0 = *(const bf16x8*)(Bg + (size_t)ar0 * KP + k0 + ak0);
        bf16x8 b1 = *(const bf16x8*)(Bg + (size_t)ar1 * KP + k0 + ak1);
        __syncthreads();
        *(bf16x8*)&As[ar0 * LDP + ak0] = a0;
        *(bf16x8*)&As[ar1 * LDP + ak1] = a1;
        *(bf16x8*)&Bs[ar0 * LDP + ak0] = b0;
        *(bf16x8*)&Bs[ar1 * LDP + ak1] = b1;
        __syncthreads();
        bf16x8 af[4], bfr[4];
#pragma unroll
        for (int mi = 0; mi < 4; ++mi)
            af[mi] = *(const bf16x8*)&As[(wm + mi * 16 + lr) * LDP + lq8];
#pragma unroll
        for (int ni = 0; ni < 4; ++ni)
            bfr[ni] = *(const bf16x8*)&Bs[(wn + ni * 16 + lr) * LDP + lq8];
#pragma unroll
        for (int mi = 0; mi < 4; ++mi)
#pragma unroll
            for (int ni = 0; ni < 4; ++ni)
                acc[mi][ni] = __builtin_amdgcn_mfma_f32_16x16x32_bf16(af[mi], bfr[ni], acc[mi][ni], 0, 0, 0);
    }
    int lq4 = (l >> 4) * 4;
#pragma unroll
    for (int ni = 0; ni < 4; ++ni) {
        int n = n0 + wn + ni * 16 + lr;
        if (n >= CC) continue;
#pragma unroll
        for (int mi = 0; mi < 4; ++mi) {
            int m = m0 + wm + mi * 16 + lq4;
            f32x4 v = acc[mi][ni];
#pragma unroll
            for (int r = 0; r < 4; ++r) C[(size_t)(m + r) * CC + n] += v[r];
        }
    }
}

__global__ __launch_bounds__(256) void gram2_mfma(const unsigned short* __restrict__ Abf,
                                                  const float* __restrict__ sq2,
                                                  float* __restrict__ S, int base) {
    __shared__ short As[128 * LDP];
    __shared__ short Bs[128 * LDP];
    int t = threadIdx.x;
    int n0 = blockIdx.x * 128, m0 = blockIdx.y * 128;
    int l = t & 63, w = t >> 6;
    int wm = (w >> 1) * 64, wn = (w & 1) * 64;
    f32x4 acc[4][4] = {};
    int ar0 = t >> 2, ak0 = (t & 3) * 8;
    int ar1 = (t + 256) >> 2, ak1 = ((t + 256) & 3) * 8;
    const unsigned short* Ag = Abf + (size_t)(base + m0) * KP;
    const unsigned short* Bg = Abf + (size_t)n0 * KP;
    int lr = l & 15, lq8 = (l >> 4) * 8;
    for (int k0 = 0; k0 < KP; k0 += 32) {
        bf16x8 a0 = *(const bf16x8*)(Ag + (size_t)ar0 * KP + k0 + ak0);
        bf16x8 a1 = *(const bf16x8*)(Ag + (size_t)ar1 * KP + k0 + ak1);
        bf16x8 b0 = *(const bf16x8*)(Bg + (size_t)ar0 * KP + k0 + ak0);
        bf16x8 b1 = *(const bf16x8*)(Bg + (size_t)ar1 * KP + k0 + ak1);
        __syncthreads();
        *(bf16x8*)&As[ar0 * LDP + ak0] = a0;
        *(bf16x8*)&As[ar1 * LDP + ak1] = a1;
        *(bf16x8*)&Bs[ar0 * LDP + ak0] = b0;
        *(bf16x8*)&Bs[ar1 * LDP + ak1] = b1;
        __syncthreads();
        bf16x8 af[4], bfr[4];
#pragma unroll
        for (int mi = 0; mi < 4; ++mi)
            af[mi] = *(const bf16x8*)&As[(wm + mi * 16 + lr) * LDP + lq8];
#pragma unroll
        for (int ni = 0; ni < 4; ++ni)
            bfr[ni] = *(const bf16x8*)&Bs[(wn + ni * 16 + lr) * LDP + lq8];
#pragma unroll
        for (int mi = 0; mi < 4; ++mi)
#pragma unroll
            for (int ni = 0; ni < 4; ++ni)
                acc[mi][ni] = __builtin_amdgcn_mfma_f32_16x16x32_bf16(af[mi], bfr[ni], acc[mi][ni], 0, 0, 0);
    }
    int lq4 = (l >> 4) * 4;
#pragma unroll
    for (int ni = 0; ni < 4; ++ni) {
        int n = n0 + wn + ni * 16 + lr;
        float sn = sq2[n];
#pragma unroll
        for (int mi = 0; mi < 4; ++mi) {
            int mrow = m0 + wm + mi * 16 + lq4;
            f32x4 v = acc[mi][ni];
#pragma unroll
            for (int r = 0; r < 4; ++r) {
                float d = sq2[base + mrow + r] + sn - 2.f * v[r];
                S[(size_t)(mrow + r) * N4 + n] = __expf(-d);
            }
        }
    }
}

// ---------------- cheb conv 1 ----------------

__global__ __launch_bounds__(256) void cheb1_out_kernel(const float* __restrict__ xhat,
                                                        const float* __restrict__ W1,
                                                        const float* __restrict__ b1,
                                                        float* __restrict__ outF) {
    __shared__ float xh[16][18];
    int n0 = blockIdx.x * 16;
    int tid = threadIdx.x;
    for (int i = tid; i < 16 * 18; i += 256) xh[i / 18][i % 18] = xhat[(size_t)n0 * 18 + i];
    __syncthreads();
    for (int c0 = 0; c0 < CC; c0 += 256) {
        int c = c0 + tid;
        if (c < CC) {
            float acc[16];
#pragma unroll
            for (int r = 0; r < 16; ++r) acc[r] = 0.f;
            for (int f = 0; f < 18; ++f) {
                float wv = W1[(size_t)f * CC + c];
#pragma unroll
                for (int r = 0; r < 16; ++r) acc[r] += xh[r][f] * wv;
            }
            float bb = b1[c];
#pragma unroll
            for (int r = 0; r < 16; ++r)
                outF[(size_t)(n0 + r) * CC + c] = fmaxf(acc[r] + bb, 0.f);
        }
    }
}

// ---------------- regs (frobenius of O^T @ T) ----------------

__global__ __launch_bounds__(256) void matT_partial(const float* __restrict__ O,
                                                    const float* __restrict__ T, int ts,
                                                    float* __restrict__ M) {
    int c = blockIdx.x * 256 + threadIdx.x;
    int f = blockIdx.y;
    int n0 = blockIdx.z * 512;
    if (c >= CC) return;
    float s = 0.f;
    for (int n = n0; n < n0 + 512; ++n) s += O[(size_t)n * CC + c] * T[(size_t)n * ts + f];
    atomicAdd(&M[(size_t)f * CC + c], s);
}

__global__ __launch_bounds__(256) void fro_kernel(const float* __restrict__ M, float* __restrict__ dst) {
    __shared__ float red[256];
    int t = threadIdx.x;
    int i = blockIdx.x * 256 + t;
    float v = (i < 6 * CC) ? M[i] : 0.f;
    red[t] = v * v;
    __syncthreads();
    for (int o = 128; o; o >>= 1) { if (t < o) red[t] += red[t + o]; __syncthreads(); }
    if (t == 0) atomicAdd(dst, red[0]);
}

// ---------------- pooling ----------------

__global__ __launch_bounds__(256) void vfr_kernel(const float* __restrict__ outF,
                                                  const int* __restrict__ sccs,
                                                  float* __restrict__ vfr) {
    int r = blockIdx.y;
    int c = blockIdx.x * 256 + threadIdx.x;
    if (c >= CC) return;
    float m = 0.f;
    for (int s = 0; s < SSC; ++s) {
        int n = sccs[r * SSC + s];
        m = fmaxf(m, outF[(size_t)n * CC + c]);
    }
    vfr[(size_t)r * CC + c] = m;
}

__global__ __launch_bounds__(256) void sq2_kernel(const float* __restrict__ outF,
                                                  float* __restrict__ sq2) {
    int lane = threadIdx.x & 63, w = threadIdx.x >> 6;
    int n = blockIdx.x * 4 + w;
    const float* row = outF + (size_t)n * CC;
    float s = 0.f;
    for (int i = lane; i < CC; i += 64) { float v = row[i]; s += v * v; }
#pragma unroll
    for (int o = 32; o; o >>= 1) s += __shfl_down(s, o);
    if (lane == 0) sq2[n] = s;
}

__global__ __launch_bounds__(256) void colmax_kernel(const float* __restrict__ O,
                                                     float* __restrict__ dst) {
    int c = blockIdx.x * 256 + threadIdx.x;
    if (c >= CC) return;
    int n0 = blockIdx.y * 256;
    float m = 0.f;
    for (int n = n0; n < n0 + 256; ++n) m = fmaxf(m, O[(size_t)n * CC + c]);
    atomicMax((int*)&dst[c], __float_as_int(m));
}

__global__ __launch_bounds__(256) void bias_relu_kernel(float* __restrict__ acc,
                                                        const float* __restrict__ b2) {
    size_t i = (size_t)blockIdx.x * 256 + threadIdx.x;
    if (i >= (size_t)N4 * CC) return;
    int c = (int)(i % CC);
    acc[i] = fmaxf(acc[i] + b2[c], 0.f);
}

// ---------------- reeb branch ----------------

__global__ __launch_bounds__(256) void reeb_mm_kernel(const float* __restrict__ Lr,
                                                      const float* __restrict__ Vin,
                                                      const float* __restrict__ Vsub,
                                                      float* __restrict__ Vout, float a2) {
    int c = blockIdx.x * 256 + threadIdx.x;
    if (c >= CC) return;
    int r = blockIdx.y;
    float s = 0.f;
#pragma unroll
    for (int j = 0; j < NRB; ++j) s += Lr[r * NRB + j] * Vin[(size_t)j * CC + c];
    float v = a2 * s;
    if (Vsub) v -= Vsub[(size_t)r * CC + c];
    Vout[(size_t)r * CC + c] = v;
}

#define RKC 125
__global__ __launch_bounds__(256) void reeb_conv_splitk(const float* __restrict__ vfr,
                                                        const float* __restrict__ tr1,
                                                        const float* __restrict__ tr2,
                                                        const float* __restrict__ Wr,
                                                        float* __restrict__ rpre) {
    __shared__ float sA[NRB][RKC];
    int t = threadIdx.x;
    int kbase = blockIdx.y * RKC;
    for (int i = t; i < NRB * RKC; i += 256) {
        int r = i / RKC, kk = i % RKC;
        int kg = kbase + kk;
        float v;
        if (kg < CC)           v = vfr[(size_t)r * CC + kg];
        else if (kg < 2 * CC)  v = tr1[(size_t)r * CC + kg - CC];
        else                   v = tr2[(size_t)r * CC + kg - 2 * CC];
        sA[r][kk] = v;
    }
    __syncthreads();
    int c = blockIdx.x * 256 + t;
    if (c >= CC) return;
    float acc[NRB];
#pragma unroll
    for (int r = 0; r < NRB; ++r) acc[r] = 0.f;
    for (int kk = 0; kk < RKC; ++kk) {
        float wv = Wr[(size_t)(kbase + kk) * CC + c];
#pragma unroll
        for (int r = 0; r < NRB; ++r) acc[r] += sA[r][kk] * wv;
    }
#pragma unroll
    for (int r = 0; r < NRB; ++r) atomicAdd(&rpre[(size_t)r * CC + c], acc[r]);
}

__global__ __launch_bounds__(256) void reeb_max_kernel(const float* __restrict__ pre,
                                                       const float* __restrict__ br,
                                                       float* __restrict__ rbm) {
    int c = blockIdx.x * 256 + threadIdx.x;
    if (c >= CC) return;
    float bb = br[c];
    float m = 0.f;
    for (int r = 0; r < NRB; ++r) m = fmaxf(m, fmaxf(pre[(size_t)r * CC + c] + bb, 0.f));
    rbm[c] = m;
}

// ---------------- FC head ----------------

__global__ __launch_bounds__(256) void fc1_kernel(const float* __restrict__ rbm,
                                                  const float* __restrict__ otm,
                                                  const float* __restrict__ w,
                                                  float* __restrict__ h1pre) {
    int j = blockIdx.x * 256 + threadIdx.x;
    if (j >= 512) return;
    int i0 = blockIdx.y * 250;
    float s = 0.f;
    for (int i = i0; i < i0 + 250; ++i) {
        float v = (i < CC) ? rbm[i] : otm[i - CC];
        s += v * w[(size_t)i * 512 + j];
    }
    atomicAdd(&h1pre[j], s);
}

__global__ __launch_bounds__(512) void fc23_kernel(const float* __restrict__ h1pre,
                                                   const float* __restrict__ b1f,
                                                   const float* __restrict__ w2,
                                                   const float* __restrict__ b2f,
                                                   const float* __restrict__ w3,
                                                   const float* __restrict__ b3f,
                                                   float* __restrict__ dout) {
    __shared__ float h1[512];
    __shared__ float h2[128];
    int t = threadIdx.x;
    h1[t] = fmaxf(h1pre[t] + b1f[t], 0.f);
    __syncthreads();
    if (t < 128) {
        float s = b2f[t];
        for (int i = 0; i < 512; ++i) s += h1[i] * w2[(size_t)i * 128 + t];
        h2[t] = fmaxf(s, 0.f);
    }
    __syncthreads();
    if (t < 40) {
        float s = b3f[t];
        for (int i = 0; i < 128; ++i) s += h2[i] * w3[(size_t)i * 40 + t];
        dout[t] = s;
    }
}

__global__ __launch_bounds__(256) void finalize_kernel(const float* __restrict__ racc,
                                                       const float* __restrict__ f1w,
                                                       const float* __restrict__ f1b,
                                                       const float* __restrict__ f2w,
                                                       const float* __restrict__ f2b,
                                                       const float* __restrict__ f3w,
                                                       const float* __restrict__ f3b,
                                                       float* __restrict__ dout) {
    __shared__ float red[256];
    __shared__ float res[3];
    int t = threadIdx.x;
    float s1 = 0.f, s2 = 0.f, s3 = 0.f;
    for (int i = t; i < 2000; i += 256) { float v = f1w[(size_t)i * 512]; s1 += v * v; }
    for (int i = t; i < 512; i += 256) { float v = f2w[(size_t)i * 128]; s2 += v * v; }
    if (t < 128) { float v = f3w[(size_t)t * 40]; s3 = v * v; }

    red[t] = s1; __syncthreads();
    for (int o = 128; o; o >>= 1) { if (t < o) red[t] += red[t + o]; __syncthreads(); }
    if (t == 0) res[0] = red[0];
    __syncthreads();
    red[t] = s2; __syncthreads();
    for (int o = 128; o; o >>= 1) { if (t < o) red[t] += red[t + o]; __syncthreads(); }
    if (t == 0) res[1] = red[0];
    __syncthreads();
    red[t] = s3; __syncthreads();
    for (int o = 128; o; o >>= 1) { if (t < o) red[t] += red[t + o]; __syncthreads(); }
    if (t == 0) res[2] = red[0];
    __syncthreads();

    if (t == 0) {
        dout[40] = sqrtf(racc[0]);
        dout[41] = sqrtf(racc[1]);
        dout[42] = res[0];
        dout[43] = f1b[0] * f1b[0];
        dout[44] = res[1];
        dout[45] = f2b[0] * f2b[0];
        dout[46] = res[2];
        dout[47] = f3b[0] * f3b[0];
    }
}

// ---------------- host ----------------

extern "C" void kernel_launch(void* const* d_in, const int* in_sizes, int n_in,
                              void* d_out, int out_size, void* d_ws, size_t ws_size,
                              hipStream_t stream) {
    const float* x    = (const float*)d_in[0];
    const float* Lr   = (const float*)d_in[5];
    const int*   sccs = (const int*)d_in[6];
    const float* W1   = (const float*)d_in[7];
    const float* b1   = (const float*)d_in[8];
    const float* W2   = (const float*)d_in[9];
    const float* b2   = (const float*)d_in[10];
    const float* Wr   = (const float*)d_in[11];
    const float* br   = (const float*)d_in[12];
    const float* f1w  = (const float*)d_in[13];
    const float* f1b  = (const float*)d_in[14];
    const float* f2w  = (const float*)d_in[15];
    const float* f2b  = (const float*)d_in[16];
    const float* f3w  = (const float*)d_in[17];
    const float* f3b  = (const float*)d_in[18];
    float* dout = (float*)d_out;

    char* ws = (char*)d_ws;
    size_t off = 0;
    auto alloc = [&](size_t bytes) -> char* {
        char* p = ws + off;
        off = (off + bytes + 255) & ~(size_t)255;
        return p;
    };
    float* outF = (float*)alloc((size_t)N4 * CC * 4);
    float* T1   = (float*)alloc((size_t)N4 * CC * 4);
    float* accC = (float*)alloc((size_t)N4 * CC * 4);
    float* Sb   = (float*)alloc((size_t)CHUNK * N4 * 4);
    unsigned short* Abf = (unsigned short*)alloc((size_t)N4 * KP * 2);
    unsigned short* Bbf = (unsigned short*)alloc((size_t)N4 * KP * 2);
    unsigned short* W2T = (unsigned short*)Sb;  // alias: Sb dead after last topk
    float* xhat = (float*)alloc((size_t)N4 * 18 * 4);
    float* sq1  = (float*)alloc(N4 * 4);
    float* sq2  = (float*)alloc(N4 * 4);
    float* di1  = (float*)alloc(N4 * 4);
    float* di2  = (float*)alloc(N4 * 4);
    float* wv1  = (float*)alloc((size_t)N4 * KNN * 4);
    float* wv2  = (float*)alloc((size_t)N4 * KNN * 4);
    int*   ix1  = (int*)alloc((size_t)N4 * KNN * 4);
    int*   ix2  = (int*)alloc((size_t)N4 * KNN * 4);
    float* t2x  = (float*)alloc((size_t)N4 * FDIM * 4);
    float* vfr  = (float*)alloc((size_t)NRB * CC * 4);
    float* tr1  = (float*)alloc((size_t)NRB * CC * 4);
    float* tr2  = (float*)alloc((size_t)NRB * CC * 4);
    float* rpre = (float*)alloc((size_t)NRB * CC * 4);
    float* Mb   = (float*)alloc(6 * CC * 4);
    float* rbm  = (float*)alloc(CC * 4);
    float* otm  = (float*)alloc(CC * 4);
    float* h1p  = (float*)alloc(512 * 4);
    float* racc = (float*)alloc(64 * 4);
    if (off > ws_size) return;

    hipMemsetAsync(accC, 0, (size_t)N4 * CC * 4, stream);
    hipMemsetAsync(Mb,   0, 6 * CC * 4, stream);
    hipMemsetAsync(rbm,  0, CC * 4, stream);
    hipMemsetAsync(otm,  0, CC * 4, stream);
    hipMemsetAsync(h1p,  0, 512 * 4, stream);
    hipMemsetAsync(racc, 0, 64 * 4, stream);
    hipMemsetAsync(rpre, 0, (size_t)NRB * CC * 4, stream);

    // ---- graph 1 (on x) ----
    sqx_kernel<<<(N4 + 255) / 256, 256, 0, stream>>>(x, sq1, xhat);
    for (int cb = 0; cb < N4; cb += CHUNK) {
        gram1_kernel<<<dim3(N4 / 256, CHUNK), 256, 0, stream>>>(x, sq1, Sb, cb);
        topk_radix<<<CHUNK, 256, 0, stream>>>(Sb, cb, ix1, wv1, di1);
    }
    dinv_kernel<<<N4 / 256, 256, 0, stream>>>(di1);
    wnorm_kernel<<<(N4 * KNN + 255) / 256, 256, 0, stream>>>(wv1, ix1, di1);

    // ---- cheb conv 1 ----
    spmv_cheb<<<N4, 64, 0, stream>>>(xhat, xhat, xhat + 6, ix1, wv1, FDIM, 18, 18, 18, 1.f, 0.f);
    spmv_cheb<<<N4, 64, 0, stream>>>(xhat + 6, xhat, xhat + 12, ix1, wv1, FDIM, 18, 18, 18, 2.f, 1.f);
    cheb1_out_kernel<<<N4 / 16, 256, 0, stream>>>(xhat, W1, b1, outF);

    matT_partial<<<dim3(4, 6, 8), 256, 0, stream>>>(outF, xhat + 6, 18, Mb);
    fro_kernel<<<24, 256, 0, stream>>>(Mb, racc + 0);

    vfr_kernel<<<dim3(4, NRB), 256, 0, stream>>>(outF, sccs, vfr);

    // ---- graph 2 (on outF), bf16 MFMA gram ----
    sq2_kernel<<<N4 / 4, 256, 0, stream>>>(outF, sq2);
    cvt_bf16_kernel<<<N4 * 128 / 256, 256, 0, stream>>>(outF, Abf);
    for (int cb = 0; cb < N4; cb += CHUNK) {
        gram2_mfma<<<dim3(N4 / 128, CHUNK / 128), 256, 0, stream>>>(Abf, sq2, Sb, cb);
        topk_radix<<<CHUNK, 256, 0, stream>>>(Sb, cb, ix2, wv2, di2);
    }
    dinv_kernel<<<N4 / 256, 256, 0, stream>>>(di2);
    wnorm_kernel<<<(N4 * KNN + 255) / 256, 256, 0, stream>>>(wv2, ix2, di2);

    // Sb dead -> build W2T in its space
    w2t_kernel<<<dim3(16, 16, 6), 256, 0, stream>>>(W2, W2T);

    spmv_cheb<<<N4, 64, 0, stream>>>(x, x, t2x, ix2, wv2, FDIM, FDIM, FDIM, FDIM, 1.f, 0.f);

    // ---- cheb conv 2 (K=6) ----
    gemm_mfma_acc<<<dim3(8, 32), 256, 0, stream>>>(Abf, W2T + (size_t)0 * KP * KP, accC);
    spmv_cheb<<<N4, 256, 0, stream>>>(outF, outF, T1, ix2, wv2, CC, CC, CC, CC, 1.f, 0.f);
    cvt_bf16_kernel<<<N4 * 128 / 256, 256, 0, stream>>>(T1, Bbf);
    gemm_mfma_acc<<<dim3(8, 32), 256, 0, stream>>>(Bbf, W2T + (size_t)1 * KP * KP, accC);
    spmv_cheb<<<N4, 256, 0, stream>>>(T1, outF, outF, ix2, wv2, CC, CC, CC, CC, 2.f, 1.f);
    cvt_bf16_kernel<<<N4 * 128 / 256, 256, 0, stream>>>(outF, Abf);
    gemm_mfma_acc<<<dim3(8, 32), 256, 0, stream>>>(Abf, W2T + (size_t)2 * KP * KP, accC);
    spmv_cheb<<<N4, 256, 0, stream>>>(outF, T1, T1, ix2, wv2, CC, CC, CC, CC, 2.f, 1.f);
    cvt_bf16_kernel<<<N4 * 128 / 256, 256, 0, stream>>>(T1, Bbf);
    gemm_mfma_acc<<<dim3(8, 32), 256, 0, stream>>>(Bbf, W2T + (size_t)3 * KP * KP, accC);
    spmv_cheb<<<N4, 256, 0, stream>>>(T1, outF, outF, ix2, wv2, CC, CC, CC, CC, 2.f, 1.f);
    cvt_bf16_kernel<<<N4 * 128 / 256, 256, 0, stream>>>(outF, Abf);
    gemm_mfma_acc<<<dim3(8, 32), 256, 0, stream>>>(Abf, W2T + (size_t)4 * KP * KP, accC);
    spmv_cheb<<<N4, 256, 0, stream>>>(outF, T1, T1, ix2, wv2, CC, CC, CC, CC, 2.f, 1.f);
    cvt_bf16_kernel<<<N4 * 128 / 256, 256, 0, stream>>>(T1, Bbf);
    gemm_mfma_acc<<<dim3(8, 32), 256, 0, stream>>>(Bbf, W2T + (size_t)5 * KP * KP, accC);
    bias_relu_kernel<<<(int)(((size_t)N4 * CC + 255) / 256), 256, 0, stream>>>(accC, b2);

    hipMemsetAsync(Mb, 0, 6 * CC * 4, stream);
    matT_partial<<<dim3(4, 6, 8), 256, 0, stream>>>(accC, t2x, FDIM, Mb);
    fro_kernel<<<24, 256, 0, stream>>>(Mb, racc + 1);

    colmax_kernel<<<dim3(4, 16), 256, 0, stream>>>(accC, otm);

    // ---- reeb cheb conv (K=3) ----
    reeb_mm_kernel<<<dim3(4, NRB), 256, 0, stream>>>(Lr, vfr, nullptr, tr1, 1.f);
    reeb_mm_kernel<<<dim3(4, NRB), 256, 0, stream>>>(Lr, tr1, vfr, tr2, 2.f);
    reeb_conv_splitk<<<dim3(4, 24), 256, 0, stream>>>(vfr, tr1, tr2, Wr, rpre);
    reeb_max_kernel<<<4, 256, 0, stream>>>(rpre, br, rbm);

    // ---- FC head ----
    fc1_kernel<<<dim3(2, 8), 256, 0, stream>>>(rbm, otm, f1w, h1p);
    fc23_kernel<<<1, 512, 0, stream>>>(h1p, f1b, f2w, f2b, f3w, f3b, dout);
    finalize_kernel<<<1, 256, 0, stream>>>(racc, f1w, f1b, f2w, f2b, f3w, f3b, dout);
}

// Round 4
// 1393.331 us; speedup vs baseline: 2.4976x; 1.1970x over previous
//
#include <hip/hip_runtime.h>
#include <math.h>

#define N4    4096
#define FDIM  6
#define CC    1000
#define KP    1024   // padded K for bf16 GEMMs
#define KNN   40
#define CHUNK 1024
#define NRB   20
#define SSC   205

typedef __attribute__((ext_vector_type(8))) short bf16x8;
typedef __attribute__((ext_vector_type(4))) float f32x4;

__device__ __forceinline__ unsigned short f2bf(float f) {
    unsigned u = __float_as_uint(f);
    u = (u + 0x7fffu + ((u >> 16) & 1u)) >> 16;
    return (unsigned short)u;
}

// ---------------- graph build ----------------

__global__ __launch_bounds__(256) void sqx_kernel(const float* __restrict__ x,
                                                  float* __restrict__ sq1,
                                                  float* __restrict__ xhat) {
    int n = blockIdx.x * blockDim.x + threadIdx.x;
    if (n >= N4) return;
    float s = 0.f;
#pragma unroll
    for (int f = 0; f < FDIM; ++f) {
        float v = x[n * FDIM + f];
        s += v * v;
        xhat[n * 18 + f] = v;
    }
    sq1[n] = s;
}

__global__ __launch_bounds__(256) void gram1_kernel(const float* __restrict__ x,
                                                    const float* __restrict__ sq1,
                                                    float* __restrict__ S, int base) {
    __shared__ float xn[FDIM];
    __shared__ float sn;
    int r = blockIdx.y;
    int n = base + r;
    int m = blockIdx.x * 256 + threadIdx.x;
    if (threadIdx.x < FDIM) xn[threadIdx.x] = x[n * FDIM + threadIdx.x];
    if (threadIdx.x == FDIM) sn = sq1[n];
    __syncthreads();
    float d = 0.f;
#pragma unroll
    for (int f = 0; f < FDIM; ++f) d += xn[f] * x[m * FDIM + f];
    float e = sn + sq1[m] - 2.f * d;
    S[(size_t)r * N4 + m] = __expf(-e);
}

// radix-select top-40 per row. Exact: byte-wise histogram refinement
// (float>=0 -> uint order == float order). Bucket selection is a parallel
// suffix scan (no serial thread-0 loop). >T scattered unordered; ==T ties
// taken in ascending index order (matches lax.top_k tie-break).
__global__ __launch_bounds__(256) void topk_radix(const float* __restrict__ S, int base,
                                                  int* __restrict__ idx, float* __restrict__ val,
                                                  float* __restrict__ rowsum) {
    __shared__ unsigned sv[N4];
    __shared__ int hist[4 * 256];
    __shared__ int sc[256];
    __shared__ float red[256];
    __shared__ unsigned s_pfx;
    __shared__ int s_need;
    __shared__ int s_cnt;
    int t = threadIdx.x;
    int r = blockIdx.x;
    int n = base + r;
    const float* row = S + (size_t)r * N4;
    for (int i = t; i < N4; i += 256) sv[i] = __float_as_uint(row[i]);
    if (t == 0) { s_pfx = 0u; s_need = KNN; s_cnt = 0; }
    __syncthreads();

    int* hw = &hist[(t >> 6) * 256];   // per-wave histogram copy
#pragma unroll
    for (int level = 24; level >= 0; level -= 8) {
        hist[t] = 0; hist[256 + t] = 0; hist[512 + t] = 0; hist[768 + t] = 0;
        __syncthreads();
        unsigned pfx = s_pfx;
        int need = s_need;
        for (int i = t; i < N4; i += 256) {
            unsigned u = sv[i];
            bool m = (level == 24) || ((u >> (level + 8)) == (pfx >> (level + 8)));
            if (m) atomicAdd(&hw[(u >> level) & 255], 1);
        }
        __syncthreads();
        int cnt = hist[t] + hist[256 + t] + hist[512 + t] + hist[768 + t];
        sc[t] = cnt;
        __syncthreads();
        // inclusive suffix sum over 256 buckets (Hillis-Steele, 8 steps)
#pragma unroll
        for (int off = 1; off < 256; off <<= 1) {
            int v = sc[t] + ((t + off < 256) ? sc[t + off] : 0);
            __syncthreads();
            sc[t] = v;
            __syncthreads();
        }
        int incl = sc[t];
        int excl = incl - cnt;
        if (incl >= need && excl < need) {     // unique winner bucket
            s_need = need - excl;
            s_pfx = pfx | ((unsigned)t << level);
        }
        __syncthreads();
    }
    unsigned Tbits = s_pfx;
    float Tf = __uint_as_float(Tbits);
    int needEq = s_need;

    // collect strictly-greater (count = KNN - needEq), accumulate their sum
    float psum = 0.f;
    for (int i = t; i < N4; i += 256) {
        unsigned u = sv[i];
        if (u > Tbits) {
            int p = atomicAdd(&s_cnt, 1);
            idx[(size_t)n * KNN + p] = i;
            float v = __uint_as_float(u);
            val[(size_t)n * KNN + p] = v;
            psum += v;
        }
    }
    red[t] = psum;
    __syncthreads();
    for (int o = 128; o; o >>= 1) { if (t < o) red[t] += red[t + o]; __syncthreads(); }
    if (t == 0) rowsum[n] = red[0] + (float)needEq * Tf;

    // equals: earliest indices first (wave 0 ballot scan)
    if (t < 64) {
        int filled = KNN - needEq;
        for (int ib = 0; ib < N4 && filled < KNN; ib += 64) {
            bool eq = (sv[ib + t] == Tbits);
            unsigned long long m = __ballot(eq);
            int pre = __popcll(m & ((1ull << t) - 1ull));
            if (eq && (filled + pre) < KNN) {
                idx[(size_t)n * KNN + filled + pre] = ib + t;
                val[(size_t)n * KNN + filled + pre] = Tf;
            }
            filled += __popcll(m);
        }
    }
}

__global__ __launch_bounds__(256) void dinv_kernel(float* __restrict__ rs) {
    int n = blockIdx.x * 256 + threadIdx.x;
    if (n < N4) rs[n] = rsqrtf(rs[n]);
}

__global__ __launch_bounds__(256) void wnorm_kernel(float* __restrict__ wv,
                                                    const int* __restrict__ idx,
                                                    const float* __restrict__ dinv) {
    int i = blockIdx.x * 256 + threadIdx.x;
    if (i >= N4 * KNN) return;
    int n = i / KNN;
    wv[i] = wv[i] * dinv[n] * dinv[idx[i]];
}

// Tn[n,:] = a*(Tc[n,:] - sum_j wv[n,j]*Tc[idx[n,j],:]) - b*Tp[n,:]   (F small)
__global__ __launch_bounds__(64) void spmv_cheb(const float* __restrict__ Tc,
                                                const float* __restrict__ Tp,
                                                float* __restrict__ Tn,
                                                const int* __restrict__ idx,
                                                const float* __restrict__ wv,
                                                int F, int sC, int sP, int sN,
                                                float a, float b) {
    __shared__ int   si[KNN];
    __shared__ float sw[KNN];
    int n = blockIdx.x;
    if (threadIdx.x < KNN) {
        si[threadIdx.x] = idx[(size_t)n * KNN + threadIdx.x];
        sw[threadIdx.x] = wv[(size_t)n * KNN + threadIdx.x];
    }
    __syncthreads();
    for (int c = threadIdx.x; c < F; c += blockDim.x) {
        float s = 0.f;
#pragma unroll 8
        for (int j = 0; j < KNN; ++j) s += sw[j] * Tc[(size_t)si[j] * sC + c];
        float v = a * (Tc[(size_t)n * sC + c] - s);
        if (b != 0.f) v -= b * Tp[(size_t)n * sP + c];
        Tn[(size_t)n * sN + c] = v;
    }
}

// F=1000 vectorized variant: 250 lanes x float4 (rows are 16B-aligned: 4000B)
__global__ __launch_bounds__(256) void spmv_cheb_f4(const float* __restrict__ Tc,
                                                    const float* __restrict__ Tp,
                                                    float* __restrict__ Tn,
                                                    const int* __restrict__ idx,
                                                    const float* __restrict__ wv,
                                                    float a, float b) {
    __shared__ int   si[KNN];
    __shared__ float sw[KNN];
    int n = blockIdx.x;
    int t = threadIdx.x;
    if (t < KNN) {
        si[t] = idx[(size_t)n * KNN + t];
        sw[t] = wv[(size_t)n * KNN + t];
    }
    __syncthreads();
    if (t >= 250) return;
    int c = t * 4;
    float sx = 0.f, sy = 0.f, sz = 0.f, sw4 = 0.f;
#pragma unroll 8
    for (int j = 0; j < KNN; ++j) {
        float wj = sw[j];
        float4 v = *(const float4*)(Tc + (size_t)si[j] * CC + c);
        sx += wj * v.x; sy += wj * v.y; sz += wj * v.z; sw4 += wj * v.w;
    }
    float4 tc = *(const float4*)(Tc + (size_t)n * CC + c);
    float4 o;
    o.x = a * (tc.x - sx); o.y = a * (tc.y - sy);
    o.z = a * (tc.z - sz); o.w = a * (tc.w - sw4);
    if (b != 0.f) {
        float4 tp = *(const float4*)(Tp + (size_t)n * CC + c);
        o.x -= b * tp.x; o.y -= b * tp.y; o.z -= b * tp.z; o.w -= b * tp.w;
    }
    *(float4*)(Tn + (size_t)n * CC + c) = o;
}

// ---------------- bf16 conversion / transpose ----------------

__global__ __launch_bounds__(256) void cvt_bf16_kernel(const float* __restrict__ in,
                                                       unsigned short* __restrict__ out) {
    int i = blockIdx.x * 256 + threadIdx.x;     // N4*128 total
    int r = i >> 7, g = i & 127;
    bf16x8 v;
    if (g < 125) {
        float4 a = *(const float4*)(in + (size_t)r * CC + g * 8);
        float4 b = *(const float4*)(in + (size_t)r * CC + g * 8 + 4);
        v[0] = (short)f2bf(a.x); v[1] = (short)f2bf(a.y);
        v[2] = (short)f2bf(a.z); v[3] = (short)f2bf(a.w);
        v[4] = (short)f2bf(b.x); v[5] = (short)f2bf(b.y);
        v[6] = (short)f2bf(b.z); v[7] = (short)f2bf(b.w);
    } else {
#pragma unroll
        for (int q = 0; q < 8; ++q) v[q] = 0;
    }
    *(bf16x8*)(out + (size_t)r * KP + g * 8) = v;
}

// W2 [6*CC x CC] fp32 -> W2T [6][KP(n) x KP(k)] bf16, W2T[s][n][k] = W2[s*CC+k][n]
__global__ __launch_bounds__(256) void w2t_kernel(const float* __restrict__ W2,
                                                  unsigned short* __restrict__ out) {
    __shared__ unsigned short tile[64][65];
    int t = threadIdx.x;
    int k0 = blockIdx.x * 64, n0 = blockIdx.y * 64, s = blockIdx.z;
#pragma unroll
    for (int p = 0; p < 16; ++p) {
        int i = p * 256 + t;
        int kk = i >> 6, nn = i & 63;
        int k = k0 + kk, n = n0 + nn;
        float v = (k < CC && n < CC) ? W2[((size_t)s * CC + k) * CC + n] : 0.f;
        tile[kk][nn] = f2bf(v);
    }
    __syncthreads();
#pragma unroll
    for (int p = 0; p < 16; ++p) {
        int i = p * 256 + t;
        int nn = i >> 6, kk = i & 63;
        out[((size_t)s * KP + n0 + nn) * KP + k0 + kk] = tile[kk][nn];
    }
}

// ---------------- MFMA GEMMs (128x128 tile, BK=32, bf16 in / fp32 acc) ----------------

#define LDP 40

__global__ __launch_bounds__(256) void gemm_mfma_acc(const unsigned short* __restrict__ A,
                                                     const unsigned short* __restrict__ B,
                                                     float* __restrict__ C) {
    __shared__ short As[128 * LDP];
    __shared__ short Bs[128 * LDP];
    int t = threadIdx.x;
    int n0 = blockIdx.x * 128, m0 = blockIdx.y * 128;
    int l = t & 63, w = t >> 6;
    int wm = (w >> 1) * 64, wn = (w & 1) * 64;
    f32x4 acc[4][4] = {};
    int ar0 = t >> 2, ak0 = (t & 3) * 8;
    int ar1 = (t + 256) >> 2, ak1 = ((t + 256) & 3) * 8;
    const unsigned short* Ag = A + (size_t)m0 * KP;
    const unsigned short* Bg = B + (size_t)n0 * KP;
    int lr = l & 15, lq8 = (l >> 4) * 8;
    for (int k0 = 0; k0 < KP; k0 += 32) {
        bf16x8 a0 = *(const bf16x8*)(Ag + (size_t)ar0 * KP + k0 + ak0);
        bf16x8 a1 = *(const bf16x8*)(Ag + (size_t)ar1 * KP + k0 + ak1);
        bf16x8 b0 = *(const bf16x8*)(Bg + (size_t)ar0 * KP + k0 + ak0);
        bf16x8 b1 = *(const bf16x8*)(Bg + (size_t)ar1 * KP + k0 + ak1);
        __syncthreads();
        *(bf16x8*)&As[ar0 * LDP + ak0] = a0;
        *(bf16x8*)&As[ar1 * LDP + ak1] = a1;
        *(bf16x8*)&Bs[ar0 * LDP + ak0] = b0;
        *(bf16x8*)&Bs[ar1 * LDP + ak1] = b1;
        __syncthreads();
        bf16x8 af[4], bfr[4];
#pragma unroll
        for (int mi = 0; mi < 4; ++mi)
            af[mi] = *(const bf16x8*)&As[(wm + mi * 16 + lr) * LDP + lq8];
#pragma unroll
        for (int ni = 0; ni < 4; ++ni)
            bfr[ni] = *(const bf16x8*)&Bs[(wn + ni * 16 + lr) * LDP + lq8];
#pragma unroll
        for (int mi = 0; mi < 4; ++mi)
#pragma unroll
            for (int ni = 0; ni < 4; ++ni)
                acc[mi][ni] = __builtin_amdgcn_mfma_f32_16x16x32_bf16(af[mi], bfr[ni], acc[mi][ni], 0, 0, 0);
    }
    int lq4 = (l >> 4) * 4;
#pragma unroll
    for (int ni = 0; ni < 4; ++ni) {
        int n = n0 + wn + ni * 16 + lr;
        if (n >= CC) continue;
#pragma unroll
        for (int mi = 0; mi < 4; ++mi) {
            int m = m0 + wm + mi * 16 + lq4;
            f32x4 v = acc[mi][ni];
#pragma unroll
            for (int r = 0; r < 4; ++r) C[(size_t)(m + r) * CC + n] += v[r];
        }
    }
}

__global__ __launch_bounds__(256) void gram2_mfma(const unsigned short* __restrict__ Abf,
                                                  const float* __restrict__ sq2,
                                                  float* __restrict__ S, int base) {
    __shared__ short As[128 * LDP];
    __shared__ short Bs[128 * LDP];
    int t = threadIdx.x;
    int n0 = blockIdx.x * 128, m0 = blockIdx.y * 128;
    int l = t & 63, w = t >> 6;
    int wm = (w >> 1) * 64, wn = (w & 1) * 64;
    f32x4 acc[4][4] = {};
    int ar0 = t >> 2, ak0 = (t & 3) * 8;
    int ar1 = (t + 256) >> 2, ak1 = ((t + 256) & 3) * 8;
    const unsigned short* Ag = Abf + (size_t)(base + m0) * KP;
    const unsigned short* Bg = Abf + (size_t)n0 * KP;
    int lr = l & 15, lq8 = (l >> 4) * 8;
    for (int k0 = 0; k0 < KP; k0 += 32) {
        bf16x8 a0 = *(const bf16x8*)(Ag + (size_t)ar0 * KP + k0 + ak0);
        bf16x8 a1 = *(const bf16x8*)(Ag + (size_t)ar1 * KP + k0 + ak1);
        bf16x8 b0 = *(const bf16x8*)(Bg + (size_t)ar0 * KP + k0 + ak0);
        bf16x8 b1 = *(const bf16x8*)(Bg + (size_t)ar1 * KP + k0 + ak1);
        __syncthreads();
        *(bf16x8*)&As[ar0 * LDP + ak0] = a0;
        *(bf16x8*)&As[ar1 * LDP + ak1] = a1;
        *(bf16x8*)&Bs[ar0 * LDP + ak0] = b0;
        *(bf16x8*)&Bs[ar1 * LDP + ak1] = b1;
        __syncthreads();
        bf16x8 af[4], bfr[4];
#pragma unroll
        for (int mi = 0; mi < 4; ++mi)
            af[mi] = *(const bf16x8*)&As[(wm + mi * 16 + lr) * LDP + lq8];
#pragma unroll
        for (int ni = 0; ni < 4; ++ni)
            bfr[ni] = *(const bf16x8*)&Bs[(wn + ni * 16 + lr) * LDP + lq8];
#pragma unroll
        for (int mi = 0; mi < 4; ++mi)
#pragma unroll
            for (int ni = 0; ni < 4; ++ni)
                acc[mi][ni] = __builtin_amdgcn_mfma_f32_16x16x32_bf16(af[mi], bfr[ni], acc[mi][ni], 0, 0, 0);
    }
    int lq4 = (l >> 4) * 4;
#pragma unroll
    for (int ni = 0; ni < 4; ++ni) {
        int n = n0 + wn + ni * 16 + lr;
        float sn = sq2[n];
#pragma unroll
        for (int mi = 0; mi < 4; ++mi) {
            int mrow = m0 + wm + mi * 16 + lq4;
            f32x4 v = acc[mi][ni];
#pragma unroll
            for (int r = 0; r < 4; ++r) {
                float d = sq2[base + mrow + r] + sn - 2.f * v[r];
                S[(size_t)(mrow + r) * N4 + n] = __expf(-d);
            }
        }
    }
}

// ---------------- cheb conv 1 ----------------

__global__ __launch_bounds__(256) void cheb1_out_kernel(const float* __restrict__ xhat,
                                                        const float* __restrict__ W1,
                                                        const float* __restrict__ b1,
                                                        float* __restrict__ outF) {
    __shared__ float xh[16][18];
    int n0 = blockIdx.x * 16;
    int tid = threadIdx.x;
    for (int i = tid; i < 16 * 18; i += 256) xh[i / 18][i % 18] = xhat[(size_t)n0 * 18 + i];
    __syncthreads();
    for (int c0 = 0; c0 < CC; c0 += 256) {
        int c = c0 + tid;
        if (c < CC) {
            float acc[16];
#pragma unroll
            for (int r = 0; r < 16; ++r) acc[r] = 0.f;
            for (int f = 0; f < 18; ++f) {
                float wv = W1[(size_t)f * CC + c];
#pragma unroll
                for (int r = 0; r < 16; ++r) acc[r] += xh[r][f] * wv;
            }
            float bb = b1[c];
#pragma unroll
            for (int r = 0; r < 16; ++r)
                outF[(size_t)(n0 + r) * CC + c] = fmaxf(acc[r] + bb, 0.f);
        }
    }
}

// ---------------- regs (frobenius of O^T @ T) ----------------

// all 6 f columns in one pass over O; T chunk staged in LDS
__global__ __launch_bounds__(256) void matT6_partial(const float* __restrict__ O,
                                                     const float* __restrict__ T, int ts,
                                                     float* __restrict__ M) {
    __shared__ float sT[512][6];
    int t = threadIdx.x;
    int c = blockIdx.x * 256 + t;
    int n0 = blockIdx.y * 512;
    for (int i = t; i < 512 * 6; i += 256) {
        int nn = i / 6, f = i % 6;
        sT[nn][f] = T[(size_t)(n0 + nn) * ts + f];
    }
    __syncthreads();
    if (c >= CC) return;
    float a0 = 0, a1 = 0, a2 = 0, a3 = 0, a4 = 0, a5 = 0;
    for (int nn = 0; nn < 512; ++nn) {
        float o = O[(size_t)(n0 + nn) * CC + c];
        a0 += o * sT[nn][0]; a1 += o * sT[nn][1]; a2 += o * sT[nn][2];
        a3 += o * sT[nn][3]; a4 += o * sT[nn][4]; a5 += o * sT[nn][5];
    }
    atomicAdd(&M[0 * CC + c], a0);
    atomicAdd(&M[1 * CC + c], a1);
    atomicAdd(&M[2 * CC + c], a2);
    atomicAdd(&M[3 * CC + c], a3);
    atomicAdd(&M[4 * CC + c], a4);
    atomicAdd(&M[5 * CC + c], a5);
}

__global__ __launch_bounds__(256) void fro_kernel(const float* __restrict__ M, float* __restrict__ dst) {
    __shared__ float red[256];
    int t = threadIdx.x;
    int i = blockIdx.x * 256 + t;
    float v = (i < 6 * CC) ? M[i] : 0.f;
    red[t] = v * v;
    __syncthreads();
    for (int o = 128; o; o >>= 1) { if (t < o) red[t] += red[t + o]; __syncthreads(); }
    if (t == 0) atomicAdd(dst, red[0]);
}

// ---------------- pooling ----------------

__global__ __launch_bounds__(256) void vfr_kernel(const float* __restrict__ outF,
                                                  const int* __restrict__ sccs,
                                                  float* __restrict__ vfr) {
    int r = blockIdx.y;
    int c = blockIdx.x * 256 + threadIdx.x;
    if (c >= CC) return;
    float m = 0.f;
    for (int s = 0; s < SSC; ++s) {
        int n = sccs[r * SSC + s];
        m = fmaxf(m, outF[(size_t)n * CC + c]);
    }
    vfr[(size_t)r * CC + c] = m;
}

__global__ __launch_bounds__(256) void sq2_kernel(const float* __restrict__ outF,
                                                  float* __restrict__ sq2) {
    int lane = threadIdx.x & 63, w = threadIdx.x >> 6;
    int n = blockIdx.x * 4 + w;
    const float* row = outF + (size_t)n * CC;
    float s = 0.f;
    for (int i = lane; i < CC; i += 64) { float v = row[i]; s += v * v; }
#pragma unroll
    for (int o = 32; o; o >>= 1) s += __shfl_down(s, o);
    if (lane == 0) sq2[n] = s;
}

__global__ __launch_bounds__(256) void colmax_kernel(const float* __restrict__ O,
                                                     float* __restrict__ dst) {
    int c = blockIdx.x * 256 + threadIdx.x;
    if (c >= CC) return;
    int n0 = blockIdx.y * 256;
    float m = 0.f;
    for (int n = n0; n < n0 + 256; ++n) m = fmaxf(m, O[(size_t)n * CC + c]);
    atomicMax((int*)&dst[c], __float_as_int(m));
}

__global__ __launch_bounds__(256) void bias_relu_kernel(float* __restrict__ acc,
                                                        const float* __restrict__ b2) {
    size_t i = (size_t)blockIdx.x * 256 + threadIdx.x;
    if (i >= (size_t)N4 * CC) return;
    int c = (int)(i % CC);
    acc[i] = fmaxf(acc[i] + b2[c], 0.f);
}

// ---------------- reeb branch ----------------

__global__ __launch_bounds__(256) void reeb_mm_kernel(const float* __restrict__ Lr,
                                                      const float* __restrict__ Vin,
                                                      const float* __restrict__ Vsub,
                                                      float* __restrict__ Vout, float a2) {
    int c = blockIdx.x * 256 + threadIdx.x;
    if (c >= CC) return;
    int r = blockIdx.y;
    float s = 0.f;
#pragma unroll
    for (int j = 0; j < NRB; ++j) s += Lr[r * NRB + j] * Vin[(size_t)j * CC + c];
    float v = a2 * s;
    if (Vsub) v -= Vsub[(size_t)r * CC + c];
    Vout[(size_t)r * CC + c] = v;
}

#define RKC 125
__global__ __launch_bounds__(256) void reeb_conv_splitk(const float* __restrict__ vfr,
                                                        const float* __restrict__ tr1,
                                                        const float* __restrict__ tr2,
                                                        const float* __restrict__ Wr,
                                                        float* __restrict__ rpre) {
    __shared__ float sA[NRB][RKC];
    int t = threadIdx.x;
    int kbase = blockIdx.y * RKC;
    for (int i = t; i < NRB * RKC; i += 256) {
        int r = i / RKC, kk = i % RKC;
        int kg = kbase + kk;
        float v;
        if (kg < CC)           v = vfr[(size_t)r * CC + kg];
        else if (kg < 2 * CC)  v = tr1[(size_t)r * CC + kg - CC];
        else                   v = tr2[(size_t)r * CC + kg - 2 * CC];
        sA[r][kk] = v;
    }
    __syncthreads();
    int c = blockIdx.x * 256 + t;
    if (c >= CC) return;
    float acc[NRB];
#pragma unroll
    for (int r = 0; r < NRB; ++r) acc[r] = 0.f;
    for (int kk = 0; kk < RKC; ++kk) {
        float wv = Wr[(size_t)(kbase + kk) * CC + c];
#pragma unroll
        for (int r = 0; r < NRB; ++r) acc[r] += sA[r][kk] * wv;
    }
#pragma unroll
    for (int r = 0; r < NRB; ++r) atomicAdd(&rpre[(size_t)r * CC + c], acc[r]);
}

__global__ __launch_bounds__(256) void reeb_max_kernel(const float* __restrict__ pre,
                                                       const float* __restrict__ br,
                                                       float* __restrict__ rbm) {
    int c = blockIdx.x * 256 + threadIdx.x;
    if (c >= CC) return;
    float bb = br[c];
    float m = 0.f;
    for (int r = 0; r < NRB; ++r) m = fmaxf(m, fmaxf(pre[(size_t)r * CC + c] + bb, 0.f));
    rbm[c] = m;
}

// ---------------- FC head ----------------

__global__ __launch_bounds__(256) void fc1_kernel(const float* __restrict__ rbm,
                                                  const float* __restrict__ otm,
                                                  const float* __restrict__ w,
                                                  float* __restrict__ h1pre) {
    int j = blockIdx.x * 256 + threadIdx.x;
    if (j >= 512) return;
    int i0 = blockIdx.y * 250;
    float s = 0.f;
    for (int i = i0; i < i0 + 250; ++i) {
        float v = (i < CC) ? rbm[i] : otm[i - CC];
        s += v * w[(size_t)i * 512 + j];
    }
    atomicAdd(&h1pre[j], s);
}

__global__ __launch_bounds__(512) void fc23_kernel(const float* __restrict__ h1pre,
                                                   const float* __restrict__ b1f,
                                                   const float* __restrict__ w2,
                                                   const float* __restrict__ b2f,
                                                   const float* __restrict__ w3,
                                                   const float* __restrict__ b3f,
                                                   float* __restrict__ dout) {
    __shared__ float h1[512];
    __shared__ float h2[128];
    int t = threadIdx.x;
    h1[t] = fmaxf(h1pre[t] + b1f[t], 0.f);
    __syncthreads();
    if (t < 128) {
        float s = b2f[t];
        for (int i = 0; i < 512; ++i) s += h1[i] * w2[(size_t)i * 128 + t];
        h2[t] = fmaxf(s, 0.f);
    }
    __syncthreads();
    if (t < 40) {
        float s = b3f[t];
        for (int i = 0; i < 128; ++i) s += h2[i] * w3[(size_t)i * 40 + t];
        dout[t] = s;
    }
}

__global__ __launch_bounds__(256) void finalize_kernel(const float* __restrict__ racc,
                                                       const float* __restrict__ f1w,
                                                       const float* __restrict__ f1b,
                                                       const float* __restrict__ f2w,
                                                       const float* __restrict__ f2b,
                                                       const float* __restrict__ f3w,
                                                       const float* __restrict__ f3b,
                                                       float* __restrict__ dout) {
    __shared__ float red[256];
    __shared__ float res[3];
    int t = threadIdx.x;
    float s1 = 0.f, s2 = 0.f, s3 = 0.f;
    for (int i = t; i < 2000; i += 256) { float v = f1w[(size_t)i * 512]; s1 += v * v; }
    for (int i = t; i < 512; i += 256) { float v = f2w[(size_t)i * 128]; s2 += v * v; }
    if (t < 128) { float v = f3w[(size_t)t * 40]; s3 = v * v; }

    red[t] = s1; __syncthreads();
    for (int o = 128; o; o >>= 1) { if (t < o) red[t] += red[t + o]; __syncthreads(); }
    if (t == 0) res[0] = red[0];
    __syncthreads();
    red[t] = s2; __syncthreads();
    for (int o = 128; o; o >>= 1) { if (t < o) red[t] += red[t + o]; __syncthreads(); }
    if (t == 0) res[1] = red[0];
    __syncthreads();
    red[t] = s3; __syncthreads();
    for (int o = 128; o; o >>= 1) { if (t < o) red[t] += red[t + o]; __syncthreads(); }
    if (t == 0) res[2] = red[0];
    __syncthreads();

    if (t == 0) {
        dout[40] = sqrtf(racc[0]);
        dout[41] = sqrtf(racc[1]);
        dout[42] = res[0];
        dout[43] = f1b[0] * f1b[0];
        dout[44] = res[1];
        dout[45] = f2b[0] * f2b[0];
        dout[46] = res[2];
        dout[47] = f3b[0] * f3b[0];
    }
}

// ---------------- host ----------------

extern "C" void kernel_launch(void* const* d_in, const int* in_sizes, int n_in,
                              void* d_out, int out_size, void* d_ws, size_t ws_size,
                              hipStream_t stream) {
    const float* x    = (const float*)d_in[0];
    const float* Lr   = (const float*)d_in[5];
    const int*   sccs = (const int*)d_in[6];
    const float* W1   = (const float*)d_in[7];
    const float* b1   = (const float*)d_in[8];
    const float* W2   = (const float*)d_in[9];
    const float* b2   = (const float*)d_in[10];
    const float* Wr   = (const float*)d_in[11];
    const float* br   = (const float*)d_in[12];
    const float* f1w  = (const float*)d_in[13];
    const float* f1b  = (const float*)d_in[14];
    const float* f2w  = (const float*)d_in[15];
    const float* f2b  = (const float*)d_in[16];
    const float* f3w  = (const float*)d_in[17];
    const float* f3b  = (const float*)d_in[18];
    float* dout = (float*)d_out;

    char* ws = (char*)d_ws;
    size_t off = 0;
    auto alloc = [&](size_t bytes) -> char* {
        char* p = ws + off;
        off = (off + bytes + 255) & ~(size_t)255;
        return p;
    };
    float* outF = (float*)alloc((size_t)N4 * CC * 4);
    float* T1   = (float*)alloc((size_t)N4 * CC * 4);
    float* accC = (float*)alloc((size_t)N4 * CC * 4);
    float* Sb   = (float*)alloc((size_t)CHUNK * N4 * 4);
    unsigned short* Abf = (unsigned short*)alloc((size_t)N4 * KP * 2);
    unsigned short* Bbf = (unsigned short*)alloc((size_t)N4 * KP * 2);
    unsigned short* W2T = (unsigned short*)Sb;  // alias: Sb dead after last topk
    float* xhat = (float*)alloc((size_t)N4 * 18 * 4);
    float* sq1  = (float*)alloc(N4 * 4);
    float* sq2  = (float*)alloc(N4 * 4);
    float* di1  = (float*)alloc(N4 * 4);
    float* di2  = (float*)alloc(N4 * 4);
    float* wv1  = (float*)alloc((size_t)N4 * KNN * 4);
    float* wv2  = (float*)alloc((size_t)N4 * KNN * 4);
    int*   ix1  = (int*)alloc((size_t)N4 * KNN * 4);
    int*   ix2  = (int*)alloc((size_t)N4 * KNN * 4);
    float* t2x  = (float*)alloc((size_t)N4 * FDIM * 4);
    float* vfr  = (float*)alloc((size_t)NRB * CC * 4);
    float* tr1  = (float*)alloc((size_t)NRB * CC * 4);
    float* tr2  = (float*)alloc((size_t)NRB * CC * 4);
    float* rpre = (float*)alloc((size_t)NRB * CC * 4);
    float* Mb   = (float*)alloc(6 * CC * 4);
    float* rbm  = (float*)alloc(CC * 4);
    float* otm  = (float*)alloc(CC * 4);
    float* h1p  = (float*)alloc(512 * 4);
    float* racc = (float*)alloc(64 * 4);
    if (off > ws_size) return;

    hipMemsetAsync(accC, 0, (size_t)N4 * CC * 4, stream);
    hipMemsetAsync(Mb,   0, 6 * CC * 4, stream);
    hipMemsetAsync(rbm,  0, CC * 4, stream);
    hipMemsetAsync(otm,  0, CC * 4, stream);
    hipMemsetAsync(h1p,  0, 512 * 4, stream);
    hipMemsetAsync(racc, 0, 64 * 4, stream);
    hipMemsetAsync(rpre, 0, (size_t)NRB * CC * 4, stream);

    // ---- graph 1 (on x) ----
    sqx_kernel<<<(N4 + 255) / 256, 256, 0, stream>>>(x, sq1, xhat);
    for (int cb = 0; cb < N4; cb += CHUNK) {
        gram1_kernel<<<dim3(N4 / 256, CHUNK), 256, 0, stream>>>(x, sq1, Sb, cb);
        topk_radix<<<CHUNK, 256, 0, stream>>>(Sb, cb, ix1, wv1, di1);
    }
    dinv_kernel<<<N4 / 256, 256, 0, stream>>>(di1);
    wnorm_kernel<<<(N4 * KNN + 255) / 256, 256, 0, stream>>>(wv1, ix1, di1);

    // ---- cheb conv 1 ----
    spmv_cheb<<<N4, 64, 0, stream>>>(xhat, xhat, xhat + 6, ix1, wv1, FDIM, 18, 18, 18, 1.f, 0.f);
    spmv_cheb<<<N4, 64, 0, stream>>>(xhat + 6, xhat, xhat + 12, ix1, wv1, FDIM, 18, 18, 18, 2.f, 1.f);
    cheb1_out_kernel<<<N4 / 16, 256, 0, stream>>>(xhat, W1, b1, outF);

    matT6_partial<<<dim3(4, 8), 256, 0, stream>>>(outF, xhat + 6, 18, Mb);
    fro_kernel<<<24, 256, 0, stream>>>(Mb, racc + 0);

    vfr_kernel<<<dim3(4, NRB), 256, 0, stream>>>(outF, sccs, vfr);

    // ---- graph 2 (on outF), bf16 MFMA gram ----
    sq2_kernel<<<N4 / 4, 256, 0, stream>>>(outF, sq2);
    cvt_bf16_kernel<<<N4 * 128 / 256, 256, 0, stream>>>(outF, Abf);
    for (int cb = 0; cb < N4; cb += CHUNK) {
        gram2_mfma<<<dim3(N4 / 128, CHUNK / 128), 256, 0, stream>>>(Abf, sq2, Sb, cb);
        topk_radix<<<CHUNK, 256, 0, stream>>>(Sb, cb, ix2, wv2, di2);
    }
    dinv_kernel<<<N4 / 256, 256, 0, stream>>>(di2);
    wnorm_kernel<<<(N4 * KNN + 255) / 256, 256, 0, stream>>>(wv2, ix2, di2);

    // Sb dead -> build W2T in its space
    w2t_kernel<<<dim3(16, 16, 6), 256, 0, stream>>>(W2, W2T);

    spmv_cheb<<<N4, 64, 0, stream>>>(x, x, t2x, ix2, wv2, FDIM, FDIM, FDIM, FDIM, 1.f, 0.f);

    // ---- cheb conv 2 (K=6) ----
    gemm_mfma_acc<<<dim3(8, 32), 256, 0, stream>>>(Abf, W2T + (size_t)0 * KP * KP, accC);
    spmv_cheb_f4<<<N4, 256, 0, stream>>>(outF, outF, T1, ix2, wv2, 1.f, 0.f);
    cvt_bf16_kernel<<<N4 * 128 / 256, 256, 0, stream>>>(T1, Bbf);
    gemm_mfma_acc<<<dim3(8, 32), 256, 0, stream>>>(Bbf, W2T + (size_t)1 * KP * KP, accC);
    spmv_cheb_f4<<<N4, 256, 0, stream>>>(T1, outF, outF, ix2, wv2, 2.f, 1.f);
    cvt_bf16_kernel<<<N4 * 128 / 256, 256, 0, stream>>>(outF, Abf);
    gemm_mfma_acc<<<dim3(8, 32), 256, 0, stream>>>(Abf, W2T + (size_t)2 * KP * KP, accC);
    spmv_cheb_f4<<<N4, 256, 0, stream>>>(outF, T1, T1, ix2, wv2, 2.f, 1.f);
    cvt_bf16_kernel<<<N4 * 128 / 256, 256, 0, stream>>>(T1, Bbf);
    gemm_mfma_acc<<<dim3(8, 32), 256, 0, stream>>>(Bbf, W2T + (size_t)3 * KP * KP, accC);
    spmv_cheb_f4<<<N4, 256, 0, stream>>>(T1, outF, outF, ix2, wv2, 2.f, 1.f);
    cvt_bf16_kernel<<<N4 * 128 / 256, 256, 0, stream>>>(outF, Abf);
    gemm_mfma_acc<<<dim3(8, 32), 256, 0, stream>>>(Abf, W2T + (size_t)4 * KP * KP, accC);
    spmv_cheb_f4<<<N4, 256, 0, stream>>>(outF, T1, T1, ix2, wv2, 2.f, 1.f);
    cvt_bf16_kernel<<<N4 * 128 / 256, 256, 0, stream>>>(T1, Bbf);
    gemm_mfma_acc<<<dim3(8, 32), 256, 0, stream>>>(Bbf, W2T + (size_t)5 * KP * KP, accC);
    bias_relu_kernel<<<(int)(((size_t)N4 * CC + 255) / 256), 256, 0, stream>>>(accC, b2);

    hipMemsetAsync(Mb, 0, 6 * CC * 4, stream);
    matT6_partial<<<dim3(4, 8), 256, 0, stream>>>(accC, t2x, FDIM, Mb);
    fro_kernel<<<24, 256, 0, stream>>>(Mb, racc + 1);

    colmax_kernel<<<dim3(4, 16), 256, 0, stream>>>(accC, otm);

    // ---- reeb cheb conv (K=3) ----
    reeb_mm_kernel<<<dim3(4, NRB), 256, 0, stream>>>(Lr, vfr, nullptr, tr1, 1.f);
    reeb_mm_kernel<<<dim3(4, NRB), 256, 0, stream>>>(Lr, tr1, vfr, tr2, 2.f);
    reeb_conv_splitk<<<dim3(4, 24), 256, 0, stream>>>(vfr, tr1, tr2, Wr, rpre);
    reeb_max_kernel<<<4, 256, 0, stream>>>(rpre, br, rbm);

    // ---- FC head ----
    fc1_kernel<<<dim3(2, 8), 256, 0, stream>>>(rbm, otm, f1w, h1p);
    fc23_kernel<<<1, 512, 0, stream>>>(h1p, f1b, f2w, f2b, f3w, f3b, dout);
    finalize_kernel<<<1, 256, 0, stream>>>(racc, f1w, f1b, f2w, f2b, f3w, f3b, dout);
}

// Round 5
// 1034.800 us; speedup vs baseline: 3.3629x; 1.3465x over previous
//
#include <hip/hip_runtime.h>
#include <math.h>

#define N4    4096
#define FDIM  6
#define CC    1000
#define KP    1024   // padded K for bf16 GEMMs
#define KNN   40
#define CHUNK 1024
#define NRB   20
#define SSC   205

typedef __attribute__((ext_vector_type(8))) short bf16x8;
typedef __attribute__((ext_vector_type(4))) float f32x4;

__device__ __forceinline__ unsigned short f2bf(float f) {
    unsigned u = __float_as_uint(f);
    u = (u + 0x7fffu + ((u >> 16) & 1u)) >> 16;
    return (unsigned short)u;
}
__device__ __forceinline__ float bf2f(short s) {
    return __uint_as_float(((unsigned)(unsigned short)s) << 16);
}

// ---------------- graph build ----------------

__global__ __launch_bounds__(256) void sqx_kernel(const float* __restrict__ x,
                                                  float* __restrict__ sq1,
                                                  float* __restrict__ xhat) {
    int n = blockIdx.x * blockDim.x + threadIdx.x;
    if (n >= N4) return;
    float s = 0.f;
#pragma unroll
    for (int f = 0; f < FDIM; ++f) {
        float v = x[n * FDIM + f];
        s += v * v;
        xhat[n * 18 + f] = v;
    }
    sq1[n] = s;
}

__global__ __launch_bounds__(256) void gram1_kernel(const float* __restrict__ x,
                                                    const float* __restrict__ sq1,
                                                    float* __restrict__ S, int base) {
    __shared__ float xn[FDIM];
    __shared__ float sn;
    int r = blockIdx.y;
    int n = base + r;
    int m = blockIdx.x * 256 + threadIdx.x;
    if (threadIdx.x < FDIM) xn[threadIdx.x] = x[n * FDIM + threadIdx.x];
    if (threadIdx.x == FDIM) sn = sq1[n];
    __syncthreads();
    float d = 0.f;
#pragma unroll
    for (int f = 0; f < FDIM; ++f) d += xn[f] * x[m * FDIM + f];
    float e = sn + sq1[m] - 2.f * d;
    S[(size_t)r * N4 + m] = __expf(-e);
}

// radix-select top-40 per row (exact; parallel suffix-scan bucket pick;
// ==T ties in ascending index order to match lax.top_k)
__global__ __launch_bounds__(256) void topk_radix(const float* __restrict__ S, int base,
                                                  int* __restrict__ idx, float* __restrict__ val,
                                                  float* __restrict__ rowsum) {
    __shared__ unsigned sv[N4];
    __shared__ int hist[4 * 256];
    __shared__ int sc[256];
    __shared__ float red[256];
    __shared__ unsigned s_pfx;
    __shared__ int s_need;
    __shared__ int s_cnt;
    int t = threadIdx.x;
    int r = blockIdx.x;
    int n = base + r;
    const float* row = S + (size_t)r * N4;
    for (int i = t; i < N4; i += 256) sv[i] = __float_as_uint(row[i]);
    if (t == 0) { s_pfx = 0u; s_need = KNN; s_cnt = 0; }
    __syncthreads();

    int* hw = &hist[(t >> 6) * 256];
#pragma unroll
    for (int level = 24; level >= 0; level -= 8) {
        hist[t] = 0; hist[256 + t] = 0; hist[512 + t] = 0; hist[768 + t] = 0;
        __syncthreads();
        unsigned pfx = s_pfx;
        int need = s_need;
        for (int i = t; i < N4; i += 256) {
            unsigned u = sv[i];
            bool m = (level == 24) || ((u >> (level + 8)) == (pfx >> (level + 8)));
            if (m) atomicAdd(&hw[(u >> level) & 255], 1);
        }
        __syncthreads();
        int cnt = hist[t] + hist[256 + t] + hist[512 + t] + hist[768 + t];
        sc[t] = cnt;
        __syncthreads();
#pragma unroll
        for (int off = 1; off < 256; off <<= 1) {
            int v = sc[t] + ((t + off < 256) ? sc[t + off] : 0);
            __syncthreads();
            sc[t] = v;
            __syncthreads();
        }
        int incl = sc[t];
        int excl = incl - cnt;
        if (incl >= need && excl < need) {
            s_need = need - excl;
            s_pfx = pfx | ((unsigned)t << level);
        }
        __syncthreads();
    }
    unsigned Tbits = s_pfx;
    float Tf = __uint_as_float(Tbits);
    int needEq = s_need;

    float psum = 0.f;
    for (int i = t; i < N4; i += 256) {
        unsigned u = sv[i];
        if (u > Tbits) {
            int p = atomicAdd(&s_cnt, 1);
            idx[(size_t)n * KNN + p] = i;
            float v = __uint_as_float(u);
            val[(size_t)n * KNN + p] = v;
            psum += v;
        }
    }
    red[t] = psum;
    __syncthreads();
    for (int o = 128; o; o >>= 1) { if (t < o) red[t] += red[t + o]; __syncthreads(); }
    if (t == 0) rowsum[n] = red[0] + (float)needEq * Tf;

    if (t < 64) {
        int filled = KNN - needEq;
        for (int ib = 0; ib < N4 && filled < KNN; ib += 64) {
            bool eq = (sv[ib + t] == Tbits);
            unsigned long long m = __ballot(eq);
            int pre = __popcll(m & ((1ull << t) - 1ull));
            if (eq && (filled + pre) < KNN) {
                idx[(size_t)n * KNN + filled + pre] = ib + t;
                val[(size_t)n * KNN + filled + pre] = Tf;
            }
            filled += __popcll(m);
        }
    }
}

__global__ __launch_bounds__(256) void dinv_kernel(float* __restrict__ rs) {
    int n = blockIdx.x * 256 + threadIdx.x;
    if (n < N4) rs[n] = rsqrtf(rs[n]);
}

__global__ __launch_bounds__(256) void wnorm_kernel(float* __restrict__ wv,
                                                    const int* __restrict__ idx,
                                                    const float* __restrict__ dinv) {
    int i = blockIdx.x * 256 + threadIdx.x;
    if (i >= N4 * KNN) return;
    int n = i / KNN;
    wv[i] = wv[i] * dinv[n] * dinv[idx[i]];
}

// Tn[n,:] = a*(Tc[n,:] - sum_j wv[n,j]*Tc[idx[n,j],:]) - b*Tp[n,:]   (F small)
__global__ __launch_bounds__(64) void spmv_cheb(const float* __restrict__ Tc,
                                                const float* __restrict__ Tp,
                                                float* __restrict__ Tn,
                                                const int* __restrict__ idx,
                                                const float* __restrict__ wv,
                                                int F, int sC, int sP, int sN,
                                                float a, float b) {
    __shared__ int   si[KNN];
    __shared__ float sw[KNN];
    int n = blockIdx.x;
    if (threadIdx.x < KNN) {
        si[threadIdx.x] = idx[(size_t)n * KNN + threadIdx.x];
        sw[threadIdx.x] = wv[(size_t)n * KNN + threadIdx.x];
    }
    __syncthreads();
    for (int c = threadIdx.x; c < F; c += blockDim.x) {
        float s = 0.f;
#pragma unroll 8
        for (int j = 0; j < KNN; ++j) s += sw[j] * Tc[(size_t)si[j] * sC + c];
        float v = a * (Tc[(size_t)n * sC + c] - s);
        if (b != 0.f) v -= b * Tp[(size_t)n * sP + c];
        Tn[(size_t)n * sN + c] = v;
    }
}

// CC-wide variant: gathers neighbor rows from the bf16 mirror (2 KB/row, half
// the traffic), own-row/Tp fp32; writes fp32 Tn AND its bf16 mirror (fused cvt).
// block=128: lane t covers cols 8t..8t+7 (125 real lanes, 3 pad lanes).
__global__ __launch_bounds__(128) void spmv_cheb_bf(const unsigned short* __restrict__ Tcbf,
                                                    const float* __restrict__ Tc,
                                                    const float* __restrict__ Tp,
                                                    float* __restrict__ Tn,
                                                    unsigned short* __restrict__ Tnbf,
                                                    const int* __restrict__ idx,
                                                    const float* __restrict__ wv,
                                                    float a, float b) {
    __shared__ int   si[KNN];
    __shared__ float sw[KNN];
    int n = blockIdx.x;
    int t = threadIdx.x;
    if (t < KNN) {
        si[t] = idx[(size_t)n * KNN + t];
        sw[t] = wv[(size_t)n * KNN + t];
    }
    __syncthreads();
    int c = t * 8;
    float acc0 = 0, acc1 = 0, acc2 = 0, acc3 = 0, acc4 = 0, acc5 = 0, acc6 = 0, acc7 = 0;
#pragma unroll 4
    for (int j = 0; j < KNN; ++j) {
        bf16x8 v = *(const bf16x8*)(Tcbf + (size_t)si[j] * KP + c);
        float wj = sw[j];
        acc0 += wj * bf2f(v[0]); acc1 += wj * bf2f(v[1]);
        acc2 += wj * bf2f(v[2]); acc3 += wj * bf2f(v[3]);
        acc4 += wj * bf2f(v[4]); acc5 += wj * bf2f(v[5]);
        acc6 += wj * bf2f(v[6]); acc7 += wj * bf2f(v[7]);
    }
    bf16x8 ob;
    if (t < 125) {
        float4 tc0 = *(const float4*)(Tc + (size_t)n * CC + c);
        float4 tc1 = *(const float4*)(Tc + (size_t)n * CC + c + 4);
        float o0 = a * (tc0.x - acc0), o1 = a * (tc0.y - acc1);
        float o2 = a * (tc0.z - acc2), o3 = a * (tc0.w - acc3);
        float o4 = a * (tc1.x - acc4), o5 = a * (tc1.y - acc5);
        float o6 = a * (tc1.z - acc6), o7 = a * (tc1.w - acc7);
        if (b != 0.f) {
            float4 tp0 = *(const float4*)(Tp + (size_t)n * CC + c);
            float4 tp1 = *(const float4*)(Tp + (size_t)n * CC + c + 4);
            o0 -= b * tp0.x; o1 -= b * tp0.y; o2 -= b * tp0.z; o3 -= b * tp0.w;
            o4 -= b * tp1.x; o5 -= b * tp1.y; o6 -= b * tp1.z; o7 -= b * tp1.w;
        }
        float4 w0 = make_float4(o0, o1, o2, o3);
        float4 w1 = make_float4(o4, o5, o6, o7);
        *(float4*)(Tn + (size_t)n * CC + c) = w0;
        *(float4*)(Tn + (size_t)n * CC + c + 4) = w1;
        ob[0] = (short)f2bf(o0); ob[1] = (short)f2bf(o1);
        ob[2] = (short)f2bf(o2); ob[3] = (short)f2bf(o3);
        ob[4] = (short)f2bf(o4); ob[5] = (short)f2bf(o5);
        ob[6] = (short)f2bf(o6); ob[7] = (short)f2bf(o7);
    } else {
#pragma unroll
        for (int q = 0; q < 8; ++q) ob[q] = 0;
    }
    *(bf16x8*)(Tnbf + (size_t)n * KP + c) = ob;
}

// ---------------- bf16 conversion / transpose ----------------

__global__ __launch_bounds__(256) void cvt_bf16_kernel(const float* __restrict__ in,
                                                       unsigned short* __restrict__ out) {
    int i = blockIdx.x * 256 + threadIdx.x;     // N4*128 total
    int r = i >> 7, g = i & 127;
    bf16x8 v;
    if (g < 125) {
        float4 a = *(const float4*)(in + (size_t)r * CC + g * 8);
        float4 b = *(const float4*)(in + (size_t)r * CC + g * 8 + 4);
        v[0] = (short)f2bf(a.x); v[1] = (short)f2bf(a.y);
        v[2] = (short)f2bf(a.z); v[3] = (short)f2bf(a.w);
        v[4] = (short)f2bf(b.x); v[5] = (short)f2bf(b.y);
        v[6] = (short)f2bf(b.z); v[7] = (short)f2bf(b.w);
    } else {
#pragma unroll
        for (int q = 0; q < 8; ++q) v[q] = 0;
    }
    *(bf16x8*)(out + (size_t)r * KP + g * 8) = v;
}

// W2 [6*CC x CC] fp32 -> W2T [6][KP(n) x KP(k)] bf16, W2T[s][n][k] = W2[s*CC+k][n]
__global__ __launch_bounds__(256) void w2t_kernel(const float* __restrict__ W2,
                                                  unsigned short* __restrict__ out) {
    __shared__ unsigned short tile[64][65];
    int t = threadIdx.x;
    int k0 = blockIdx.x * 64, n0 = blockIdx.y * 64, s = blockIdx.z;
#pragma unroll
    for (int p = 0; p < 16; ++p) {
        int i = p * 256 + t;
        int kk = i >> 6, nn = i & 63;
        int k = k0 + kk, n = n0 + nn;
        float v = (k < CC && n < CC) ? W2[((size_t)s * CC + k) * CC + n] : 0.f;
        tile[kk][nn] = f2bf(v);
    }
    __syncthreads();
#pragma unroll
    for (int p = 0; p < 16; ++p) {
        int i = p * 256 + t;
        int nn = i >> 6, kk = i & 63;
        out[((size_t)s * KP + n0 + nn) * KP + k0 + kk] = tile[kk][nn];
    }
}

// ---------------- MFMA GEMMs (128x128 tile, BK=32, bf16 in / fp32 acc) ----------------

#define LDP 40

__device__ __forceinline__ void gemm_core(const unsigned short* __restrict__ Ag,
                                          const unsigned short* __restrict__ Bg,
                                          short* As, short* Bs, int t,
                                          f32x4 (&acc)[4][4]) {
    int l = t & 63, w = t >> 6;
    int wm = (w >> 1) * 64, wn = (w & 1) * 64;
    int ar0 = t >> 2, ak0 = (t & 3) * 8;
    int ar1 = (t + 256) >> 2, ak1 = ((t + 256) & 3) * 8;
    int lr = l & 15, lq8 = (l >> 4) * 8;
    for (int k0 = 0; k0 < KP; k0 += 32) {
        bf16x8 a0 = *(const bf16x8*)(Ag + (size_t)ar0 * KP + k0 + ak0);
        bf16x8 a1 = *(const bf16x8*)(Ag + (size_t)ar1 * KP + k0 + ak1);
        bf16x8 b0 = *(const bf16x8*)(Bg + (size_t)ar0 * KP + k0 + ak0);
        bf16x8 b1 = *(const bf16x8*)(Bg + (size_t)ar1 * KP + k0 + ak1);
        __syncthreads();
        *(bf16x8*)&As[ar0 * LDP + ak0] = a0;
        *(bf16x8*)&As[ar1 * LDP + ak1] = a1;
        *(bf16x8*)&Bs[ar0 * LDP + ak0] = b0;
        *(bf16x8*)&Bs[ar1 * LDP + ak1] = b1;
        __syncthreads();
        bf16x8 af[4], bfr[4];
#pragma unroll
        for (int mi = 0; mi < 4; ++mi)
            af[mi] = *(const bf16x8*)&As[(wm + mi * 16 + lr) * LDP + lq8];
#pragma unroll
        for (int ni = 0; ni < 4; ++ni)
            bfr[ni] = *(const bf16x8*)&Bs[(wn + ni * 16 + lr) * LDP + lq8];
#pragma unroll
        for (int mi = 0; mi < 4; ++mi)
#pragma unroll
            for (int ni = 0; ni < 4; ++ni)
                acc[mi][ni] = __builtin_amdgcn_mfma_f32_16x16x32_bf16(af[mi], bfr[ni], acc[mi][ni], 0, 0, 0);
    }
}

__global__ __launch_bounds__(256) void gemm_mfma_acc(const unsigned short* __restrict__ A,
                                                     const unsigned short* __restrict__ B,
                                                     float* __restrict__ C) {
    __shared__ short As[128 * LDP];
    __shared__ short Bs[128 * LDP];
    int t = threadIdx.x;
    int n0 = blockIdx.x * 128, m0 = blockIdx.y * 128;
    f32x4 acc[4][4] = {};
    gemm_core(A + (size_t)m0 * KP, B + (size_t)n0 * KP, As, Bs, t, acc);
    int l = t & 63, w = t >> 6;
    int wm = (w >> 1) * 64, wn = (w & 1) * 64;
    int lr = l & 15, lq4 = (l >> 4) * 4;
#pragma unroll
    for (int ni = 0; ni < 4; ++ni) {
        int n = n0 + wn + ni * 16 + lr;
        if (n >= CC) continue;
#pragma unroll
        for (int mi = 0; mi < 4; ++mi) {
            int m = m0 + wm + mi * 16 + lq4;
            f32x4 v = acc[mi][ni];
#pragma unroll
            for (int r = 0; r < 4; ++r) C[(size_t)(m + r) * CC + n] += v[r];
        }
    }
}

// final Cheb GEMM: fused += acc + bias then relu
__global__ __launch_bounds__(256) void gemm_mfma_final(const unsigned short* __restrict__ A,
                                                       const unsigned short* __restrict__ B,
                                                       float* __restrict__ C,
                                                       const float* __restrict__ b2) {
    __shared__ short As[128 * LDP];
    __shared__ short Bs[128 * LDP];
    int t = threadIdx.x;
    int n0 = blockIdx.x * 128, m0 = blockIdx.y * 128;
    f32x4 acc[4][4] = {};
    gemm_core(A + (size_t)m0 * KP, B + (size_t)n0 * KP, As, Bs, t, acc);
    int l = t & 63, w = t >> 6;
    int wm = (w >> 1) * 64, wn = (w & 1) * 64;
    int lr = l & 15, lq4 = (l >> 4) * 4;
#pragma unroll
    for (int ni = 0; ni < 4; ++ni) {
        int n = n0 + wn + ni * 16 + lr;
        if (n >= CC) continue;
        float bb = b2[n];
#pragma unroll
        for (int mi = 0; mi < 4; ++mi) {
            int m = m0 + wm + mi * 16 + lq4;
            f32x4 v = acc[mi][ni];
#pragma unroll
            for (int r = 0; r < 4; ++r) {
                float* p = &C[(size_t)(m + r) * CC + n];
                *p = fmaxf(*p + v[r] + bb, 0.f);
            }
        }
    }
}

__global__ __launch_bounds__(256) void gram2_mfma(const unsigned short* __restrict__ Abf,
                                                  const float* __restrict__ sq2,
                                                  float* __restrict__ S, int base) {
    __shared__ short As[128 * LDP];
    __shared__ short Bs[128 * LDP];
    int t = threadIdx.x;
    int n0 = blockIdx.x * 128, m0 = blockIdx.y * 128;
    f32x4 acc[4][4] = {};
    gemm_core(Abf + (size_t)(base + m0) * KP, Abf + (size_t)n0 * KP, As, Bs, t, acc);
    int l = t & 63, w = t >> 6;
    int wm = (w >> 1) * 64, wn = (w & 1) * 64;
    int lr = l & 15, lq4 = (l >> 4) * 4;
#pragma unroll
    for (int ni = 0; ni < 4; ++ni) {
        int n = n0 + wn + ni * 16 + lr;
        float sn = sq2[n];
#pragma unroll
        for (int mi = 0; mi < 4; ++mi) {
            int mrow = m0 + wm + mi * 16 + lq4;
            f32x4 v = acc[mi][ni];
#pragma unroll
            for (int r = 0; r < 4; ++r) {
                float d = sq2[base + mrow + r] + sn - 2.f * v[r];
                S[(size_t)(mrow + r) * N4 + n] = __expf(-d);
            }
        }
    }
}

// ---------------- cheb conv 1 ----------------

__global__ __launch_bounds__(256) void cheb1_out_kernel(const float* __restrict__ xhat,
                                                        const float* __restrict__ W1,
                                                        const float* __restrict__ b1,
                                                        float* __restrict__ outF) {
    __shared__ float xh[16][18];
    int n0 = blockIdx.x * 16;
    int tid = threadIdx.x;
    for (int i = tid; i < 16 * 18; i += 256) xh[i / 18][i % 18] = xhat[(size_t)n0 * 18 + i];
    __syncthreads();
    for (int c0 = 0; c0 < CC; c0 += 256) {
        int c = c0 + tid;
        if (c < CC) {
            float acc[16];
#pragma unroll
            for (int r = 0; r < 16; ++r) acc[r] = 0.f;
            for (int f = 0; f < 18; ++f) {
                float wv = W1[(size_t)f * CC + c];
#pragma unroll
                for (int r = 0; r < 16; ++r) acc[r] += xh[r][f] * wv;
            }
            float bb = b1[c];
#pragma unroll
            for (int r = 0; r < 16; ++r)
                outF[(size_t)(n0 + r) * CC + c] = fmaxf(acc[r] + bb, 0.f);
        }
    }
}

// ---------------- regs (frobenius of O^T @ T) ----------------

__global__ __launch_bounds__(256) void matT6_partial(const float* __restrict__ O,
                                                     const float* __restrict__ T, int ts,
                                                     float* __restrict__ M) {
    __shared__ float sT[128][6];
    int t = threadIdx.x;
    int c = blockIdx.x * 256 + t;
    int n0 = blockIdx.y * 128;
    for (int i = t; i < 128 * 6; i += 256) {
        int nn = i / 6, f = i % 6;
        sT[nn][f] = T[(size_t)(n0 + nn) * ts + f];
    }
    __syncthreads();
    if (c >= CC) return;
    float a0 = 0, a1 = 0, a2 = 0, a3 = 0, a4 = 0, a5 = 0;
    for (int nn = 0; nn < 128; ++nn) {
        float o = O[(size_t)(n0 + nn) * CC + c];
        a0 += o * sT[nn][0]; a1 += o * sT[nn][1]; a2 += o * sT[nn][2];
        a3 += o * sT[nn][3]; a4 += o * sT[nn][4]; a5 += o * sT[nn][5];
    }
    atomicAdd(&M[0 * CC + c], a0);
    atomicAdd(&M[1 * CC + c], a1);
    atomicAdd(&M[2 * CC + c], a2);
    atomicAdd(&M[3 * CC + c], a3);
    atomicAdd(&M[4 * CC + c], a4);
    atomicAdd(&M[5 * CC + c], a5);
}

__global__ __launch_bounds__(256) void fro_kernel(const float* __restrict__ M, float* __restrict__ dst) {
    __shared__ float red[256];
    int t = threadIdx.x;
    int i = blockIdx.x * 256 + t;
    float v = (i < 6 * CC) ? M[i] : 0.f;
    red[t] = v * v;
    __syncthreads();
    for (int o = 128; o; o >>= 1) { if (t < o) red[t] += red[t + o]; __syncthreads(); }
    if (t == 0) atomicAdd(dst, red[0]);
}

// ---------------- pooling ----------------

__global__ __launch_bounds__(256) void vfr_kernel(const float* __restrict__ outF,
                                                  const int* __restrict__ sccs,
                                                  float* __restrict__ vfr) {
    int r = blockIdx.y;
    int c = blockIdx.x * 256 + threadIdx.x;
    if (c >= CC) return;
    float m = 0.f;
    for (int s = 0; s < SSC; ++s) {
        int n = sccs[r * SSC + s];
        m = fmaxf(m, outF[(size_t)n * CC + c]);
    }
    vfr[(size_t)r * CC + c] = m;
}

__global__ __launch_bounds__(256) void sq2_kernel(const float* __restrict__ outF,
                                                  float* __restrict__ sq2) {
    int lane = threadIdx.x & 63, w = threadIdx.x >> 6;
    int n = blockIdx.x * 4 + w;
    const float* row = outF + (size_t)n * CC;
    float s = 0.f;
    for (int i = lane; i < CC; i += 64) { float v = row[i]; s += v * v; }
#pragma unroll
    for (int o = 32; o; o >>= 1) s += __shfl_down(s, o);
    if (lane == 0) sq2[n] = s;
}

__global__ __launch_bounds__(256) void colmax_kernel(const float* __restrict__ O,
                                                     float* __restrict__ dst) {
    int c = blockIdx.x * 256 + threadIdx.x;
    if (c >= CC) return;
    int n0 = blockIdx.y * 256;
    float m = 0.f;
    for (int n = n0; n < n0 + 256; ++n) m = fmaxf(m, O[(size_t)n * CC + c]);
    atomicMax((int*)&dst[c], __float_as_int(m));
}

// ---------------- reeb branch ----------------

__global__ __launch_bounds__(256) void reeb_mm_kernel(const float* __restrict__ Lr,
                                                      const float* __restrict__ Vin,
                                                      const float* __restrict__ Vsub,
                                                      float* __restrict__ Vout, float a2) {
    int c = blockIdx.x * 256 + threadIdx.x;
    if (c >= CC) return;
    int r = blockIdx.y;
    float s = 0.f;
#pragma unroll
    for (int j = 0; j < NRB; ++j) s += Lr[r * NRB + j] * Vin[(size_t)j * CC + c];
    float v = a2 * s;
    if (Vsub) v -= Vsub[(size_t)r * CC + c];
    Vout[(size_t)r * CC + c] = v;
}

#define RKC 125
__global__ __launch_bounds__(256) void reeb_conv_splitk(const float* __restrict__ vfr,
                                                        const float* __restrict__ tr1,
                                                        const float* __restrict__ tr2,
                                                        const float* __restrict__ Wr,
                                                        float* __restrict__ rpre) {
    __shared__ float sA[NRB][RKC];
    int t = threadIdx.x;
    int kbase = blockIdx.y * RKC;
    for (int i = t; i < NRB * RKC; i += 256) {
        int r = i / RKC, kk = i % RKC;
        int kg = kbase + kk;
        float v;
        if (kg < CC)           v = vfr[(size_t)r * CC + kg];
        else if (kg < 2 * CC)  v = tr1[(size_t)r * CC + kg - CC];
        else                   v = tr2[(size_t)r * CC + kg - 2 * CC];
        sA[r][kk] = v;
    }
    __syncthreads();
    int c = blockIdx.x * 256 + t;
    if (c >= CC) return;
    float acc[NRB];
#pragma unroll
    for (int r = 0; r < NRB; ++r) acc[r] = 0.f;
    for (int kk = 0; kk < RKC; ++kk) {
        float wv = Wr[(size_t)(kbase + kk) * CC + c];
#pragma unroll
        for (int r = 0; r < NRB; ++r) acc[r] += sA[r][kk] * wv;
    }
#pragma unroll
    for (int r = 0; r < NRB; ++r) atomicAdd(&rpre[(size_t)r * CC + c], acc[r]);
}

__global__ __launch_bounds__(256) void reeb_max_kernel(const float* __restrict__ pre,
                                                       const float* __restrict__ br,
                                                       float* __restrict__ rbm) {
    int c = blockIdx.x * 256 + threadIdx.x;
    if (c >= CC) return;
    float bb = br[c];
    float m = 0.f;
    for (int r = 0; r < NRB; ++r) m = fmaxf(m, fmaxf(pre[(size_t)r * CC + c] + bb, 0.f));
    rbm[c] = m;
}

// ---------------- FC head ----------------

__global__ __launch_bounds__(256) void fc1_kernel(const float* __restrict__ rbm,
                                                  const float* __restrict__ otm,
                                                  const float* __restrict__ w,
                                                  float* __restrict__ h1pre) {
    int j = blockIdx.x * 256 + threadIdx.x;
    if (j >= 512) return;
    int i0 = blockIdx.y * 250;
    float s = 0.f;
    for (int i = i0; i < i0 + 250; ++i) {
        float v = (i < CC) ? rbm[i] : otm[i - CC];
        s += v * w[(size_t)i * 512 + j];
    }
    atomicAdd(&h1pre[j], s);
}

__global__ __launch_bounds__(512) void fc23_kernel(const float* __restrict__ h1pre,
                                                   const float* __restrict__ b1f,
                                                   const float* __restrict__ w2,
                                                   const float* __restrict__ b2f,
                                                   const float* __restrict__ w3,
                                                   const float* __restrict__ b3f,
                                                   float* __restrict__ dout) {
    __shared__ float h1[512];
    __shared__ float h2[128];
    int t = threadIdx.x;
    h1[t] = fmaxf(h1pre[t] + b1f[t], 0.f);
    __syncthreads();
    if (t < 128) {
        float s = b2f[t];
        for (int i = 0; i < 512; ++i) s += h1[i] * w2[(size_t)i * 128 + t];
        h2[t] = fmaxf(s, 0.f);
    }
    __syncthreads();
    if (t < 40) {
        float s = b3f[t];
        for (int i = 0; i < 128; ++i) s += h2[i] * w3[(size_t)i * 40 + t];
        dout[t] = s;
    }
}

__global__ __launch_bounds__(256) void finalize_kernel(const float* __restrict__ racc,
                                                       const float* __restrict__ f1w,
                                                       const float* __restrict__ f1b,
                                                       const float* __restrict__ f2w,
                                                       const float* __restrict__ f2b,
                                                       const float* __restrict__ f3w,
                                                       const float* __restrict__ f3b,
                                                       float* __restrict__ dout) {
    __shared__ float red[256];
    __shared__ float res[3];
    int t = threadIdx.x;
    float s1 = 0.f, s2 = 0.f, s3 = 0.f;
    for (int i = t; i < 2000; i += 256) { float v = f1w[(size_t)i * 512]; s1 += v * v; }
    for (int i = t; i < 512; i += 256) { float v = f2w[(size_t)i * 128]; s2 += v * v; }
    if (t < 128) { float v = f3w[(size_t)t * 40]; s3 = v * v; }

    red[t] = s1; __syncthreads();
    for (int o = 128; o; o >>= 1) { if (t < o) red[t] += red[t + o]; __syncthreads(); }
    if (t == 0) res[0] = red[0];
    __syncthreads();
    red[t] = s2; __syncthreads();
    for (int o = 128; o; o >>= 1) { if (t < o) red[t] += red[t + o]; __syncthreads(); }
    if (t == 0) res[1] = red[0];
    __syncthreads();
    red[t] = s3; __syncthreads();
    for (int o = 128; o; o >>= 1) { if (t < o) red[t] += red[t + o]; __syncthreads(); }
    if (t == 0) res[2] = red[0];
    __syncthreads();

    if (t == 0) {
        dout[40] = sqrtf(racc[0]);
        dout[41] = sqrtf(racc[1]);
        dout[42] = res[0];
        dout[43] = f1b[0] * f1b[0];
        dout[44] = res[1];
        dout[45] = f2b[0] * f2b[0];
        dout[46] = res[2];
        dout[47] = f3b[0] * f3b[0];
    }
}

// ---------------- host ----------------

extern "C" void kernel_launch(void* const* d_in, const int* in_sizes, int n_in,
                              void* d_out, int out_size, void* d_ws, size_t ws_size,
                              hipStream_t stream) {
    const float* x    = (const float*)d_in[0];
    const float* Lr   = (const float*)d_in[5];
    const int*   sccs = (const int*)d_in[6];
    const float* W1   = (const float*)d_in[7];
    const float* b1   = (const float*)d_in[8];
    const float* W2   = (const float*)d_in[9];
    const float* b2   = (const float*)d_in[10];
    const float* Wr   = (const float*)d_in[11];
    const float* br   = (const float*)d_in[12];
    const float* f1w  = (const float*)d_in[13];
    const float* f1b  = (const float*)d_in[14];
    const float* f2w  = (const float*)d_in[15];
    const float* f2b  = (const float*)d_in[16];
    const float* f3w  = (const float*)d_in[17];
    const float* f3b  = (const float*)d_in[18];
    float* dout = (float*)d_out;

    char* ws = (char*)d_ws;
    size_t off = 0;
    auto alloc = [&](size_t bytes) -> char* {
        char* p = ws + off;
        off = (off + bytes + 255) & ~(size_t)255;
        return p;
    };
    float* outF = (float*)alloc((size_t)N4 * CC * 4);
    float* T1   = (float*)alloc((size_t)N4 * CC * 4);
    float* accC = (float*)alloc((size_t)N4 * CC * 4);
    float* Sb   = (float*)alloc((size_t)CHUNK * N4 * 4);
    unsigned short* Abf = (unsigned short*)alloc((size_t)N4 * KP * 2);
    unsigned short* Bbf = (unsigned short*)alloc((size_t)N4 * KP * 2);
    unsigned short* W2T = (unsigned short*)Sb;  // alias: Sb dead after last topk
    float* xhat = (float*)alloc((size_t)N4 * 18 * 4);
    float* sq1  = (float*)alloc(N4 * 4);
    float* sq2  = (float*)alloc(N4 * 4);
    float* di1  = (float*)alloc(N4 * 4);
    float* di2  = (float*)alloc(N4 * 4);
    float* wv1  = (float*)alloc((size_t)N4 * KNN * 4);
    float* wv2  = (float*)alloc((size_t)N4 * KNN * 4);
    int*   ix1  = (int*)alloc((size_t)N4 * KNN * 4);
    int*   ix2  = (int*)alloc((size_t)N4 * KNN * 4);
    float* t2x  = (float*)alloc((size_t)N4 * FDIM * 4);
    float* vfr  = (float*)alloc((size_t)NRB * CC * 4);
    float* tr1  = (float*)alloc((size_t)NRB * CC * 4);
    float* tr2  = (float*)alloc((size_t)NRB * CC * 4);
    float* rpre = (float*)alloc((size_t)NRB * CC * 4);
    float* Mb   = (float*)alloc(6 * CC * 4);
    float* rbm  = (float*)alloc(CC * 4);
    float* otm  = (float*)alloc(CC * 4);
    float* h1p  = (float*)alloc(512 * 4);
    float* racc = (float*)alloc(64 * 4);
    if (off > ws_size) return;

    hipMemsetAsync(accC, 0, (size_t)N4 * CC * 4, stream);
    hipMemsetAsync(Mb,   0, 6 * CC * 4, stream);
    hipMemsetAsync(rbm,  0, CC * 4, stream);
    hipMemsetAsync(otm,  0, CC * 4, stream);
    hipMemsetAsync(h1p,  0, 512 * 4, stream);
    hipMemsetAsync(racc, 0, 64 * 4, stream);
    hipMemsetAsync(rpre, 0, (size_t)NRB * CC * 4, stream);

    // ---- graph 1 (on x) ----
    sqx_kernel<<<(N4 + 255) / 256, 256, 0, stream>>>(x, sq1, xhat);
    for (int cb = 0; cb < N4; cb += CHUNK) {
        gram1_kernel<<<dim3(N4 / 256, CHUNK), 256, 0, stream>>>(x, sq1, Sb, cb);
        topk_radix<<<CHUNK, 256, 0, stream>>>(Sb, cb, ix1, wv1, di1);
    }
    dinv_kernel<<<N4 / 256, 256, 0, stream>>>(di1);
    wnorm_kernel<<<(N4 * KNN + 255) / 256, 256, 0, stream>>>(wv1, ix1, di1);

    // ---- cheb conv 1 ----
    spmv_cheb<<<N4, 64, 0, stream>>>(xhat, xhat, xhat + 6, ix1, wv1, FDIM, 18, 18, 18, 1.f, 0.f);
    spmv_cheb<<<N4, 64, 0, stream>>>(xhat + 6, xhat, xhat + 12, ix1, wv1, FDIM, 18, 18, 18, 2.f, 1.f);
    cheb1_out_kernel<<<N4 / 16, 256, 0, stream>>>(xhat, W1, b1, outF);

    matT6_partial<<<dim3(4, 32), 256, 0, stream>>>(outF, xhat + 6, 18, Mb);
    fro_kernel<<<24, 256, 0, stream>>>(Mb, racc + 0);

    vfr_kernel<<<dim3(4, NRB), 256, 0, stream>>>(outF, sccs, vfr);

    // ---- graph 2 (on outF), bf16 MFMA gram ----
    sq2_kernel<<<N4 / 4, 256, 0, stream>>>(outF, sq2);
    cvt_bf16_kernel<<<N4 * 128 / 256, 256, 0, stream>>>(outF, Abf);
    for (int cb = 0; cb < N4; cb += CHUNK) {
        gram2_mfma<<<dim3(N4 / 128, CHUNK / 128), 256, 0, stream>>>(Abf, sq2, Sb, cb);
        topk_radix<<<CHUNK, 256, 0, stream>>>(Sb, cb, ix2, wv2, di2);
    }
    dinv_kernel<<<N4 / 256, 256, 0, stream>>>(di2);
    wnorm_kernel<<<(N4 * KNN + 255) / 256, 256, 0, stream>>>(wv2, ix2, di2);

    // Sb dead -> build W2T in its space
    w2t_kernel<<<dim3(16, 16, 6), 256, 0, stream>>>(W2, W2T);

    spmv_cheb<<<N4, 64, 0, stream>>>(x, x, t2x, ix2, wv2, FDIM, FDIM, FDIM, FDIM, 1.f, 0.f);

    // ---- cheb conv 2 (K=6): T0=outF/Abf, gathers from bf16 mirror, fused cvt ----
    gemm_mfma_acc<<<dim3(8, 32), 256, 0, stream>>>(Abf, W2T + (size_t)0 * KP * KP, accC);
    spmv_cheb_bf<<<N4, 128, 0, stream>>>(Abf, outF, outF, T1, Bbf, ix2, wv2, 1.f, 0.f);       // T1
    gemm_mfma_acc<<<dim3(8, 32), 256, 0, stream>>>(Bbf, W2T + (size_t)1 * KP * KP, accC);
    spmv_cheb_bf<<<N4, 128, 0, stream>>>(Bbf, T1, outF, outF, Abf, ix2, wv2, 2.f, 1.f);       // T2
    gemm_mfma_acc<<<dim3(8, 32), 256, 0, stream>>>(Abf, W2T + (size_t)2 * KP * KP, accC);
    spmv_cheb_bf<<<N4, 128, 0, stream>>>(Abf, outF, T1, T1, Bbf, ix2, wv2, 2.f, 1.f);         // T3
    gemm_mfma_acc<<<dim3(8, 32), 256, 0, stream>>>(Bbf, W2T + (size_t)3 * KP * KP, accC);
    spmv_cheb_bf<<<N4, 128, 0, stream>>>(Bbf, T1, outF, outF, Abf, ix2, wv2, 2.f, 1.f);       // T4
    gemm_mfma_acc<<<dim3(8, 32), 256, 0, stream>>>(Abf, W2T + (size_t)4 * KP * KP, accC);
    spmv_cheb_bf<<<N4, 128, 0, stream>>>(Abf, outF, T1, T1, Bbf, ix2, wv2, 2.f, 1.f);         // T5
    gemm_mfma_final<<<dim3(8, 32), 256, 0, stream>>>(Bbf, W2T + (size_t)5 * KP * KP, accC, b2);

    hipMemsetAsync(Mb, 0, 6 * CC * 4, stream);
    matT6_partial<<<dim3(4, 32), 256, 0, stream>>>(accC, t2x, FDIM, Mb);
    fro_kernel<<<24, 256, 0, stream>>>(Mb, racc + 1);

    colmax_kernel<<<dim3(4, 16), 256, 0, stream>>>(accC, otm);

    // ---- reeb cheb conv (K=3) ----
    reeb_mm_kernel<<<dim3(4, NRB), 256, 0, stream>>>(Lr, vfr, nullptr, tr1, 1.f);
    reeb_mm_kernel<<<dim3(4, NRB), 256, 0, stream>>>(Lr, tr1, vfr, tr2, 2.f);
    reeb_conv_splitk<<<dim3(4, 24), 256, 0, stream>>>(vfr, tr1, tr2, Wr, rpre);
    reeb_max_kernel<<<4, 256, 0, stream>>>(rpre, br, rbm);

    // ---- FC head ----
    fc1_kernel<<<dim3(2, 8), 256, 0, stream>>>(rbm, otm, f1w, h1p);
    fc23_kernel<<<1, 512, 0, stream>>>(h1p, f1b, f2w, f2b, f3w, f3b, dout);
    finalize_kernel<<<1, 256, 0, stream>>>(racc, f1w, f1b, f2w, f2b, f3w, f3b, dout);
}

// Round 6
// 1006.190 us; speedup vs baseline: 3.4586x; 1.0284x over previous
//
#include <hip/hip_runtime.h>
#include <math.h>

#define N4    4096
#define FDIM  6
#define CC    1000
#define KP    1024   // padded K for bf16 GEMMs
#define KNN   40
#define CHUNK 1024
#define NRB   20
#define SSC   205

typedef __attribute__((ext_vector_type(8))) short bf16x8;
typedef __attribute__((ext_vector_type(4))) float f32x4;

__device__ __forceinline__ unsigned short f2bf(float f) {
    unsigned u = __float_as_uint(f);
    u = (u + 0x7fffu + ((u >> 16) & 1u)) >> 16;
    return (unsigned short)u;
}
__device__ __forceinline__ float bf2f(short s) {
    return __uint_as_float(((unsigned)(unsigned short)s) << 16);
}

// ---------------- graph build ----------------

__global__ __launch_bounds__(256) void sqx_kernel(const float* __restrict__ x,
                                                  float* __restrict__ sq1,
                                                  float* __restrict__ xhat) {
    int n = blockIdx.x * blockDim.x + threadIdx.x;
    if (n >= N4) return;
    float s = 0.f;
#pragma unroll
    for (int f = 0; f < FDIM; ++f) {
        float v = x[n * FDIM + f];
        s += v * v;
        xhat[n * 18 + f] = v;
    }
    sq1[n] = s;
}

__global__ __launch_bounds__(256) void gram1_kernel(const float* __restrict__ x,
                                                    const float* __restrict__ sq1,
                                                    float* __restrict__ S, int base) {
    __shared__ float xn[FDIM];
    __shared__ float sn;
    int r = blockIdx.y;
    int n = base + r;
    int m = blockIdx.x * 256 + threadIdx.x;
    if (threadIdx.x < FDIM) xn[threadIdx.x] = x[n * FDIM + threadIdx.x];
    if (threadIdx.x == FDIM) sn = sq1[n];
    __syncthreads();
    float d = 0.f;
#pragma unroll
    for (int f = 0; f < FDIM; ++f) d += xn[f] * x[m * FDIM + f];
    float e = sn + sq1[m] - 2.f * d;
    S[(size_t)r * N4 + m] = __expf(-e);
}

// radix-select top-40 per row (exact; parallel suffix-scan bucket pick;
// ==T ties in ascending index order to match lax.top_k). 512 threads.
__global__ __launch_bounds__(512) void topk_radix(const float* __restrict__ S, int base,
                                                  int* __restrict__ idx, float* __restrict__ val,
                                                  float* __restrict__ rowsum) {
    __shared__ unsigned sv[N4];
    __shared__ int hist[8 * 256];
    __shared__ int sc[256];
    __shared__ float red[512];
    __shared__ unsigned s_pfx;
    __shared__ int s_need;
    __shared__ int s_cnt;
    int t = threadIdx.x;
    int r = blockIdx.x;
    int n = base + r;
    const float* row = S + (size_t)r * N4;
    for (int i = t; i < N4; i += 512) sv[i] = __float_as_uint(row[i]);
    if (t == 0) { s_pfx = 0u; s_need = KNN; s_cnt = 0; }
    __syncthreads();

    int* hw = &hist[(t >> 6) * 256];   // per-wave histogram copy (8 waves)
#pragma unroll
    for (int level = 24; level >= 0; level -= 8) {
        hist[t] = 0; hist[512 + t] = 0; hist[1024 + t] = 0; hist[1536 + t] = 0;
        __syncthreads();
        unsigned pfx = s_pfx;
        int need = s_need;
        for (int i = t; i < N4; i += 512) {
            unsigned u = sv[i];
            bool m = (level == 24) || ((u >> (level + 8)) == (pfx >> (level + 8)));
            if (m) atomicAdd(&hw[(u >> level) & 255], 1);
        }
        __syncthreads();
        int cnt = 0;
        if (t < 256) {
#pragma unroll
            for (int wq = 0; wq < 8; ++wq) cnt += hist[wq * 256 + t];
            sc[t] = cnt;
        }
        __syncthreads();
        // inclusive suffix sum over 256 buckets (Hillis-Steele, 8 steps)
#pragma unroll
        for (int off = 1; off < 256; off <<= 1) {
            int v = 0;
            if (t < 256) v = sc[t] + ((t + off < 256) ? sc[t + off] : 0);
            __syncthreads();
            if (t < 256) sc[t] = v;
            __syncthreads();
        }
        if (t < 256) {
            int incl = sc[t];
            int excl = incl - cnt;
            if (incl >= need && excl < need) {   // unique winner bucket
                s_need = need - excl;
                s_pfx = pfx | ((unsigned)t << level);
            }
        }
        __syncthreads();
    }
    unsigned Tbits = s_pfx;
    float Tf = __uint_as_float(Tbits);
    int needEq = s_need;

    // collect strictly-greater (count = KNN - needEq), accumulate their sum
    float psum = 0.f;
    for (int i = t; i < N4; i += 512) {
        unsigned u = sv[i];
        if (u > Tbits) {
            int p = atomicAdd(&s_cnt, 1);
            idx[(size_t)n * KNN + p] = i;
            float v = __uint_as_float(u);
            val[(size_t)n * KNN + p] = v;
            psum += v;
        }
    }
    red[t] = psum;
    __syncthreads();
    for (int o = 256; o; o >>= 1) { if (t < o) red[t] += red[t + o]; __syncthreads(); }
    if (t == 0) rowsum[n] = red[0] + (float)needEq * Tf;

    // equals: earliest indices first (wave 0 ballot scan)
    if (t < 64) {
        int filled = KNN - needEq;
        for (int ib = 0; ib < N4 && filled < KNN; ib += 64) {
            bool eq = (sv[ib + t] == Tbits);
            unsigned long long m = __ballot(eq);
            int pre = __popcll(m & ((1ull << t) - 1ull));
            if (eq && (filled + pre) < KNN) {
                idx[(size_t)n * KNN + filled + pre] = ib + t;
                val[(size_t)n * KNN + filled + pre] = Tf;
            }
            filled += __popcll(m);
        }
    }
}

__global__ __launch_bounds__(256) void dinv_kernel(float* __restrict__ rs) {
    int n = blockIdx.x * 256 + threadIdx.x;
    if (n < N4) rs[n] = rsqrtf(rs[n]);
}

__global__ __launch_bounds__(256) void wnorm_kernel(float* __restrict__ wv,
                                                    const int* __restrict__ idx,
                                                    const float* __restrict__ dinv) {
    int i = blockIdx.x * 256 + threadIdx.x;
    if (i >= N4 * KNN) return;
    int n = i / KNN;
    wv[i] = wv[i] * dinv[n] * dinv[idx[i]];
}

// Tn[n,:] = a*(Tc[n,:] - sum_j wv[n,j]*Tc[idx[n,j],:]) - b*Tp[n,:]   (F small)
__global__ __launch_bounds__(64) void spmv_cheb(const float* __restrict__ Tc,
                                                const float* __restrict__ Tp,
                                                float* __restrict__ Tn,
                                                const int* __restrict__ idx,
                                                const float* __restrict__ wv,
                                                int F, int sC, int sP, int sN,
                                                float a, float b) {
    __shared__ int   si[KNN];
    __shared__ float sw[KNN];
    int n = blockIdx.x;
    if (threadIdx.x < KNN) {
        si[threadIdx.x] = idx[(size_t)n * KNN + threadIdx.x];
        sw[threadIdx.x] = wv[(size_t)n * KNN + threadIdx.x];
    }
    __syncthreads();
    for (int c = threadIdx.x; c < F; c += blockDim.x) {
        float s = 0.f;
#pragma unroll 8
        for (int j = 0; j < KNN; ++j) s += sw[j] * Tc[(size_t)si[j] * sC + c];
        float v = a * (Tc[(size_t)n * sC + c] - s);
        if (b != 0.f) v -= b * Tp[(size_t)n * sP + c];
        Tn[(size_t)n * sN + c] = v;
    }
}

// CC-wide variant: gathers neighbor rows from the bf16 mirror (2 KB/row),
// own-row/Tp fp32; writes fp32 Tn AND its bf16 mirror (fused cvt).
__global__ __launch_bounds__(128) void spmv_cheb_bf(const unsigned short* __restrict__ Tcbf,
                                                    const float* __restrict__ Tc,
                                                    const float* __restrict__ Tp,
                                                    float* __restrict__ Tn,
                                                    unsigned short* __restrict__ Tnbf,
                                                    const int* __restrict__ idx,
                                                    const float* __restrict__ wv,
                                                    float a, float b) {
    __shared__ int   si[KNN];
    __shared__ float sw[KNN];
    int n = blockIdx.x;
    int t = threadIdx.x;
    if (t < KNN) {
        si[t] = idx[(size_t)n * KNN + t];
        sw[t] = wv[(size_t)n * KNN + t];
    }
    __syncthreads();
    int c = t * 8;
    float acc0 = 0, acc1 = 0, acc2 = 0, acc3 = 0, acc4 = 0, acc5 = 0, acc6 = 0, acc7 = 0;
#pragma unroll 4
    for (int j = 0; j < KNN; ++j) {
        bf16x8 v = *(const bf16x8*)(Tcbf + (size_t)si[j] * KP + c);
        float wj = sw[j];
        acc0 += wj * bf2f(v[0]); acc1 += wj * bf2f(v[1]);
        acc2 += wj * bf2f(v[2]); acc3 += wj * bf2f(v[3]);
        acc4 += wj * bf2f(v[4]); acc5 += wj * bf2f(v[5]);
        acc6 += wj * bf2f(v[6]); acc7 += wj * bf2f(v[7]);
    }
    bf16x8 ob;
    if (t < 125) {
        float4 tc0 = *(const float4*)(Tc + (size_t)n * CC + c);
        float4 tc1 = *(const float4*)(Tc + (size_t)n * CC + c + 4);
        float o0 = a * (tc0.x - acc0), o1 = a * (tc0.y - acc1);
        float o2 = a * (tc0.z - acc2), o3 = a * (tc0.w - acc3);
        float o4 = a * (tc1.x - acc4), o5 = a * (tc1.y - acc5);
        float o6 = a * (tc1.z - acc6), o7 = a * (tc1.w - acc7);
        if (b != 0.f) {
            float4 tp0 = *(const float4*)(Tp + (size_t)n * CC + c);
            float4 tp1 = *(const float4*)(Tp + (size_t)n * CC + c + 4);
            o0 -= b * tp0.x; o1 -= b * tp0.y; o2 -= b * tp0.z; o3 -= b * tp0.w;
            o4 -= b * tp1.x; o5 -= b * tp1.y; o6 -= b * tp1.z; o7 -= b * tp1.w;
        }
        float4 w0 = make_float4(o0, o1, o2, o3);
        float4 w1 = make_float4(o4, o5, o6, o7);
        *(float4*)(Tn + (size_t)n * CC + c) = w0;
        *(float4*)(Tn + (size_t)n * CC + c + 4) = w1;
        ob[0] = (short)f2bf(o0); ob[1] = (short)f2bf(o1);
        ob[2] = (short)f2bf(o2); ob[3] = (short)f2bf(o3);
        ob[4] = (short)f2bf(o4); ob[5] = (short)f2bf(o5);
        ob[6] = (short)f2bf(o6); ob[7] = (short)f2bf(o7);
    } else {
#pragma unroll
        for (int q = 0; q < 8; ++q) ob[q] = 0;
    }
    *(bf16x8*)(Tnbf + (size_t)n * KP + c) = ob;
}

// ---------------- bf16 conversion / transpose ----------------

__global__ __launch_bounds__(256) void cvt_bf16_kernel(const float* __restrict__ in,
                                                       unsigned short* __restrict__ out) {
    int i = blockIdx.x * 256 + threadIdx.x;     // N4*128 total
    int r = i >> 7, g = i & 127;
    bf16x8 v;
    if (g < 125) {
        float4 a = *(const float4*)(in + (size_t)r * CC + g * 8);
        float4 b = *(const float4*)(in + (size_t)r * CC + g * 8 + 4);
        v[0] = (short)f2bf(a.x); v[1] = (short)f2bf(a.y);
        v[2] = (short)f2bf(a.z); v[3] = (short)f2bf(a.w);
        v[4] = (short)f2bf(b.x); v[5] = (short)f2bf(b.y);
        v[6] = (short)f2bf(b.z); v[7] = (short)f2bf(b.w);
    } else {
#pragma unroll
        for (int q = 0; q < 8; ++q) v[q] = 0;
    }
    *(bf16x8*)(out + (size_t)r * KP + g * 8) = v;
}

// W2 [6*CC x CC] fp32 -> W2T [6][KP(n) x KP(k)] bf16
__global__ __launch_bounds__(256) void w2t_kernel(const float* __restrict__ W2,
                                                  unsigned short* __restrict__ out) {
    __shared__ unsigned short tile[64][65];
    int t = threadIdx.x;
    int k0 = blockIdx.x * 64, n0 = blockIdx.y * 64, s = blockIdx.z;
#pragma unroll
    for (int p = 0; p < 16; ++p) {
        int i = p * 256 + t;
        int kk = i >> 6, nn = i & 63;
        int k = k0 + kk, n = n0 + nn;
        float v = (k < CC && n < CC) ? W2[((size_t)s * CC + k) * CC + n] : 0.f;
        tile[kk][nn] = f2bf(v);
    }
    __syncthreads();
#pragma unroll
    for (int p = 0; p < 16; ++p) {
        int i = p * 256 + t;
        int nn = i >> 6, kk = i & 63;
        out[((size_t)s * KP + n0 + nn) * KP + k0 + kk] = tile[kk][nn];
    }
}

// ---------------- MFMA GEMMs (128x128 tile, BK=32, bf16 in / fp32 acc) ----------------

#define LDP 40

__device__ __forceinline__ void gemm_core(const unsigned short* __restrict__ Ag,
                                          const unsigned short* __restrict__ Bg,
                                          short* As, short* Bs, int t,
                                          f32x4 (&acc)[4][4]) {
    int l = t & 63, w = t >> 6;
    int wm = (w >> 1) * 64, wn = (w & 1) * 64;
    int ar0 = t >> 2, ak0 = (t & 3) * 8;
    int ar1 = (t + 256) >> 2, ak1 = ((t + 256) & 3) * 8;
    int lr = l & 15, lq8 = (l >> 4) * 8;
    for (int k0 = 0; k0 < KP; k0 += 32) {
        bf16x8 a0 = *(const bf16x8*)(Ag + (size_t)ar0 * KP + k0 + ak0);
        bf16x8 a1 = *(const bf16x8*)(Ag + (size_t)ar1 * KP + k0 + ak1);
        bf16x8 b0 = *(const bf16x8*)(Bg + (size_t)ar0 * KP + k0 + ak0);
        bf16x8 b1 = *(const bf16x8*)(Bg + (size_t)ar1 * KP + k0 + ak1);
        __syncthreads();
        *(bf16x8*)&As[ar0 * LDP + ak0] = a0;
        *(bf16x8*)&As[ar1 * LDP + ak1] = a1;
        *(bf16x8*)&Bs[ar0 * LDP + ak0] = b0;
        *(bf16x8*)&Bs[ar1 * LDP + ak1] = b1;
        __syncthreads();
        bf16x8 af[4], bfr[4];
#pragma unroll
        for (int mi = 0; mi < 4; ++mi)
            af[mi] = *(const bf16x8*)&As[(wm + mi * 16 + lr) * LDP + lq8];
#pragma unroll
        for (int ni = 0; ni < 4; ++ni)
            bfr[ni] = *(const bf16x8*)&Bs[(wn + ni * 16 + lr) * LDP + lq8];
#pragma unroll
        for (int mi = 0; mi < 4; ++mi)
#pragma unroll
            for (int ni = 0; ni < 4; ++ni)
                acc[mi][ni] = __builtin_amdgcn_mfma_f32_16x16x32_bf16(af[mi], bfr[ni], acc[mi][ni], 0, 0, 0);
    }
}

__global__ __launch_bounds__(256) void gemm_mfma_acc(const unsigned short* __restrict__ A,
                                                     const unsigned short* __restrict__ B,
                                                     float* __restrict__ C) {
    __shared__ short As[128 * LDP];
    __shared__ short Bs[128 * LDP];
    int t = threadIdx.x;
    int n0 = blockIdx.x * 128, m0 = blockIdx.y * 128;
    f32x4 acc[4][4] = {};
    gemm_core(A + (size_t)m0 * KP, B + (size_t)n0 * KP, As, Bs, t, acc);
    int l = t & 63, w = t >> 6;
    int wm = (w >> 1) * 64, wn = (w & 1) * 64;
    int lr = l & 15, lq4 = (l >> 4) * 4;
#pragma unroll
    for (int ni = 0; ni < 4; ++ni) {
        int n = n0 + wn + ni * 16 + lr;
        if (n >= CC) continue;
#pragma unroll
        for (int mi = 0; mi < 4; ++mi) {
            int m = m0 + wm + mi * 16 + lq4;
            f32x4 v = acc[mi][ni];
#pragma unroll
            for (int r = 0; r < 4; ++r) C[(size_t)(m + r) * CC + n] += v[r];
        }
    }
}

__global__ __launch_bounds__(256) void gemm_mfma_final(const unsigned short* __restrict__ A,
                                                       const unsigned short* __restrict__ B,
                                                       float* __restrict__ C,
                                                       const float* __restrict__ b2) {
    __shared__ short As[128 * LDP];
    __shared__ short Bs[128 * LDP];
    int t = threadIdx.x;
    int n0 = blockIdx.x * 128, m0 = blockIdx.y * 128;
    f32x4 acc[4][4] = {};
    gemm_core(A + (size_t)m0 * KP, B + (size_t)n0 * KP, As, Bs, t, acc);
    int l = t & 63, w = t >> 6;
    int wm = (w >> 1) * 64, wn = (w & 1) * 64;
    int lr = l & 15, lq4 = (l >> 4) * 4;
#pragma unroll
    for (int ni = 0; ni < 4; ++ni) {
        int n = n0 + wn + ni * 16 + lr;
        if (n >= CC) continue;
        float bb = b2[n];
#pragma unroll
        for (int mi = 0; mi < 4; ++mi) {
            int m = m0 + wm + mi * 16 + lq4;
            f32x4 v = acc[mi][ni];
#pragma unroll
            for (int r = 0; r < 4; ++r) {
                float* p = &C[(size_t)(m + r) * CC + n];
                *p = fmaxf(*p + v[r] + bb, 0.f);
            }
        }
    }
}

__global__ __launch_bounds__(256) void gram2_mfma(const unsigned short* __restrict__ Abf,
                                                  const float* __restrict__ sq2,
                                                  float* __restrict__ S, int base) {
    __shared__ short As[128 * LDP];
    __shared__ short Bs[128 * LDP];
    int t = threadIdx.x;
    int n0 = blockIdx.x * 128, m0 = blockIdx.y * 128;
    f32x4 acc[4][4] = {};
    gemm_core(Abf + (size_t)(base + m0) * KP, Abf + (size_t)n0 * KP, As, Bs, t, acc);
    int l = t & 63, w = t >> 6;
    int wm = (w >> 1) * 64, wn = (w & 1) * 64;
    int lr = l & 15, lq4 = (l >> 4) * 4;
#pragma unroll
    for (int ni = 0; ni < 4; ++ni) {
        int n = n0 + wn + ni * 16 + lr;
        float sn = sq2[n];
#pragma unroll
        for (int mi = 0; mi < 4; ++mi) {
            int mrow = m0 + wm + mi * 16 + lq4;
            f32x4 v = acc[mi][ni];
#pragma unroll
            for (int r = 0; r < 4; ++r) {
                float d = sq2[base + mrow + r] + sn - 2.f * v[r];
                S[(size_t)(mrow + r) * N4 + n] = __expf(-d);
            }
        }
    }
}

// ---------------- cheb conv 1 ----------------

__global__ __launch_bounds__(256) void cheb1_out_kernel(const float* __restrict__ xhat,
                                                        const float* __restrict__ W1,
                                                        const float* __restrict__ b1,
                                                        float* __restrict__ outF) {
    __shared__ float xh[16][18];
    int n0 = blockIdx.x * 16;
    int tid = threadIdx.x;
    for (int i = tid; i < 16 * 18; i += 256) xh[i / 18][i % 18] = xhat[(size_t)n0 * 18 + i];
    __syncthreads();
    for (int c0 = 0; c0 < CC; c0 += 256) {
        int c = c0 + tid;
        if (c < CC) {
            float acc[16];
#pragma unroll
            for (int r = 0; r < 16; ++r) acc[r] = 0.f;
            for (int f = 0; f < 18; ++f) {
                float wv = W1[(size_t)f * CC + c];
#pragma unroll
                for (int r = 0; r < 16; ++r) acc[r] += xh[r][f] * wv;
            }
            float bb = b1[c];
#pragma unroll
            for (int r = 0; r < 16; ++r)
                outF[(size_t)(n0 + r) * CC + c] = fmaxf(acc[r] + bb, 0.f);
        }
    }
}

// ---------------- regs (frobenius of O^T @ T) ----------------

__global__ __launch_bounds__(256) void matT6_partial(const float* __restrict__ O,
                                                     const float* __restrict__ T, int ts,
                                                     float* __restrict__ M) {
    __shared__ float sT[128][6];
    int t = threadIdx.x;
    int c = blockIdx.x * 256 + t;
    int n0 = blockIdx.y * 128;
    for (int i = t; i < 128 * 6; i += 256) {
        int nn = i / 6, f = i % 6;
        sT[nn][f] = T[(size_t)(n0 + nn) * ts + f];
    }
    __syncthreads();
    if (c >= CC) return;
    float a0 = 0, a1 = 0, a2 = 0, a3 = 0, a4 = 0, a5 = 0;
    for (int nn = 0; nn < 128; ++nn) {
        float o = O[(size_t)(n0 + nn) * CC + c];
        a0 += o * sT[nn][0]; a1 += o * sT[nn][1]; a2 += o * sT[nn][2];
        a3 += o * sT[nn][3]; a4 += o * sT[nn][4]; a5 += o * sT[nn][5];
    }
    atomicAdd(&M[0 * CC + c], a0);
    atomicAdd(&M[1 * CC + c], a1);
    atomicAdd(&M[2 * CC + c], a2);
    atomicAdd(&M[3 * CC + c], a3);
    atomicAdd(&M[4 * CC + c], a4);
    atomicAdd(&M[5 * CC + c], a5);
}

__global__ __launch_bounds__(256) void fro_kernel(const float* __restrict__ M, float* __restrict__ dst) {
    __shared__ float red[256];
    int t = threadIdx.x;
    int i = blockIdx.x * 256 + t;
    float v = (i < 6 * CC) ? M[i] : 0.f;
    red[t] = v * v;
    __syncthreads();
    for (int o = 128; o; o >>= 1) { if (t < o) red[t] += red[t + o]; __syncthreads(); }
    if (t == 0) atomicAdd(dst, red[0]);
}

// ---------------- pooling ----------------

// z-split scc max-pool; vfr must be zeroed (outF >= 0 so int-max trick valid)
__global__ __launch_bounds__(256) void vfr_kernel(const float* __restrict__ outF,
                                                  const int* __restrict__ sccs,
                                                  float* __restrict__ vfr) {
    int r = blockIdx.y;
    int c = blockIdx.x * 256 + threadIdx.x;
    if (c >= CC) return;
    int s0 = blockIdx.z * 41;
    float m = 0.f;
    for (int s = s0; s < s0 + 41; ++s) {
        int n = sccs[r * SSC + s];
        m = fmaxf(m, outF[(size_t)n * CC + c]);
    }
    atomicMax((int*)&vfr[(size_t)r * CC + c], __float_as_int(m));
}

__global__ __launch_bounds__(256) void sq2_kernel(const float* __restrict__ outF,
                                                  float* __restrict__ sq2) {
    int lane = threadIdx.x & 63, w = threadIdx.x >> 6;
    int n = blockIdx.x * 4 + w;
    const float* row = outF + (size_t)n * CC;
    float s = 0.f;
    for (int i = lane; i < CC; i += 64) { float v = row[i]; s += v * v; }
#pragma unroll
    for (int o = 32; o; o >>= 1) s += __shfl_down(s, o);
    if (lane == 0) sq2[n] = s;
}

__global__ __launch_bounds__(256) void colmax_kernel(const float* __restrict__ O,
                                                     float* __restrict__ dst) {
    int c = blockIdx.x * 256 + threadIdx.x;
    if (c >= CC) return;
    int n0 = blockIdx.y * 256;
    float m = 0.f;
    for (int n = n0; n < n0 + 256; ++n) m = fmaxf(m, O[(size_t)n * CC + c]);
    atomicMax((int*)&dst[c], __float_as_int(m));
}

// ---------------- reeb branch ----------------

__global__ __launch_bounds__(256) void reeb_mm_kernel(const float* __restrict__ Lr,
                                                      const float* __restrict__ Vin,
                                                      const float* __restrict__ Vsub,
                                                      float* __restrict__ Vout, float a2) {
    int c = blockIdx.x * 256 + threadIdx.x;
    if (c >= CC) return;
    int r = blockIdx.y;
    float s = 0.f;
#pragma unroll
    for (int j = 0; j < NRB; ++j) s += Lr[r * NRB + j] * Vin[(size_t)j * CC + c];
    float v = a2 * s;
    if (Vsub) v -= Vsub[(size_t)r * CC + c];
    Vout[(size_t)r * CC + c] = v;
}

#define RKC 25
__global__ __launch_bounds__(256) void reeb_conv_splitk(const float* __restrict__ vfr,
                                                        const float* __restrict__ tr1,
                                                        const float* __restrict__ tr2,
                                                        const float* __restrict__ Wr,
                                                        float* __restrict__ rpre) {
    __shared__ float sA[NRB][RKC];
    int t = threadIdx.x;
    int kbase = blockIdx.y * RKC;
    for (int i = t; i < NRB * RKC; i += 256) {
        int r = i / RKC, kk = i % RKC;
        int kg = kbase + kk;
        float v;
        if (kg < CC)           v = vfr[(size_t)r * CC + kg];
        else if (kg < 2 * CC)  v = tr1[(size_t)r * CC + kg - CC];
        else                   v = tr2[(size_t)r * CC + kg - 2 * CC];
        sA[r][kk] = v;
    }
    __syncthreads();
    int c = blockIdx.x * 256 + t;
    if (c >= CC) return;
    float acc[NRB];
#pragma unroll
    for (int r = 0; r < NRB; ++r) acc[r] = 0.f;
    for (int kk = 0; kk < RKC; ++kk) {
        float wv = Wr[(size_t)(kbase + kk) * CC + c];
#pragma unroll
        for (int r = 0; r < NRB; ++r) acc[r] += sA[r][kk] * wv;
    }
#pragma unroll
    for (int r = 0; r < NRB; ++r) atomicAdd(&rpre[(size_t)r * CC + c], acc[r]);
}

__global__ __launch_bounds__(256) void reeb_max_kernel(const float* __restrict__ pre,
                                                       const float* __restrict__ br,
                                                       float* __restrict__ rbm) {
    int c = blockIdx.x * 256 + threadIdx.x;
    if (c >= CC) return;
    float bb = br[c];
    float m = 0.f;
    for (int r = 0; r < NRB; ++r) m = fmaxf(m, fmaxf(pre[(size_t)r * CC + c] + bb, 0.f));
    rbm[c] = m;
}

// ---------------- FC head ----------------

__global__ __launch_bounds__(256) void fc1_kernel(const float* __restrict__ rbm,
                                                  const float* __restrict__ otm,
                                                  const float* __restrict__ w,
                                                  float* __restrict__ h1pre) {
    int j = blockIdx.x * 256 + threadIdx.x;
    if (j >= 512) return;
    int i0 = blockIdx.y * 250;
    float s = 0.f;
    for (int i = i0; i < i0 + 250; ++i) {
        float v = (i < CC) ? rbm[i] : otm[i - CC];
        s += v * w[(size_t)i * 512 + j];
    }
    atomicAdd(&h1pre[j], s);
}

__global__ __launch_bounds__(512) void fc23_kernel(const float* __restrict__ h1pre,
                                                   const float* __restrict__ b1f,
                                                   const float* __restrict__ w2,
                                                   const float* __restrict__ b2f,
                                                   const float* __restrict__ w3,
                                                   const float* __restrict__ b3f,
                                                   float* __restrict__ dout) {
    __shared__ float h1[512];
    __shared__ float h2[128];
    int t = threadIdx.x;
    h1[t] = fmaxf(h1pre[t] + b1f[t], 0.f);
    __syncthreads();
    if (t < 128) {
        float s = b2f[t];
        for (int i = 0; i < 512; ++i) s += h1[i] * w2[(size_t)i * 128 + t];
        h2[t] = fmaxf(s, 0.f);
    }
    __syncthreads();
    if (t < 40) {
        float s = b3f[t];
        for (int i = 0; i < 128; ++i) s += h2[i] * w3[(size_t)i * 40 + t];
        dout[t] = s;
    }
}

__global__ __launch_bounds__(256) void finalize_kernel(const float* __restrict__ racc,
                                                       const float* __restrict__ f1w,
                                                       const float* __restrict__ f1b,
                                                       const float* __restrict__ f2w,
                                                       const float* __restrict__ f2b,
                                                       const float* __restrict__ f3w,
                                                       const float* __restrict__ f3b,
                                                       float* __restrict__ dout) {
    __shared__ float red[256];
    __shared__ float res[3];
    int t = threadIdx.x;
    float s1 = 0.f, s2 = 0.f, s3 = 0.f;
    for (int i = t; i < 2000; i += 256) { float v = f1w[(size_t)i * 512]; s1 += v * v; }
    for (int i = t; i < 512; i += 256) { float v = f2w[(size_t)i * 128]; s2 += v * v; }
    if (t < 128) { float v = f3w[(size_t)t * 40]; s3 = v * v; }

    red[t] = s1; __syncthreads();
    for (int o = 128; o; o >>= 1) { if (t < o) red[t] += red[t + o]; __syncthreads(); }
    if (t == 0) res[0] = red[0];
    __syncthreads();
    red[t] = s2; __syncthreads();
    for (int o = 128; o; o >>= 1) { if (t < o) red[t] += red[t + o]; __syncthreads(); }
    if (t == 0) res[1] = red[0];
    __syncthreads();
    red[t] = s3; __syncthreads();
    for (int o = 128; o; o >>= 1) { if (t < o) red[t] += red[t + o]; __syncthreads(); }
    if (t == 0) res[2] = red[0];
    __syncthreads();

    if (t == 0) {
        dout[40] = sqrtf(racc[0]);
        dout[41] = sqrtf(racc[1]);
        dout[42] = res[0];
        dout[43] = f1b[0] * f1b[0];
        dout[44] = res[1];
        dout[45] = f2b[0] * f2b[0];
        dout[46] = res[2];
        dout[47] = f3b[0] * f3b[0];
    }
}

// ---------------- host ----------------

extern "C" void kernel_launch(void* const* d_in, const int* in_sizes, int n_in,
                              void* d_out, int out_size, void* d_ws, size_t ws_size,
                              hipStream_t stream) {
    const float* x    = (const float*)d_in[0];
    const float* Lr   = (const float*)d_in[5];
    const int*   sccs = (const int*)d_in[6];
    const float* W1   = (const float*)d_in[7];
    const float* b1   = (const float*)d_in[8];
    const float* W2   = (const float*)d_in[9];
    const float* b2   = (const float*)d_in[10];
    const float* Wr   = (const float*)d_in[11];
    const float* br   = (const float*)d_in[12];
    const float* f1w  = (const float*)d_in[13];
    const float* f1b  = (const float*)d_in[14];
    const float* f2w  = (const float*)d_in[15];
    const float* f2b  = (const float*)d_in[16];
    const float* f3w  = (const float*)d_in[17];
    const float* f3b  = (const float*)d_in[18];
    float* dout = (float*)d_out;

    char* ws = (char*)d_ws;
    size_t off = 0;
    auto alloc = [&](size_t bytes) -> char* {
        char* p = ws + off;
        off = (off + bytes + 255) & ~(size_t)255;
        return p;
    };
    float* outF = (float*)alloc((size_t)N4 * CC * 4);
    float* T1   = (float*)alloc((size_t)N4 * CC * 4);
    float* accC = (float*)alloc((size_t)N4 * CC * 4);
    float* Sb   = (float*)alloc((size_t)CHUNK * N4 * 4);
    unsigned short* Abf = (unsigned short*)alloc((size_t)N4 * KP * 2);
    unsigned short* Bbf = (unsigned short*)alloc((size_t)N4 * KP * 2);
    unsigned short* W2T = (unsigned short*)Sb;  // alias: Sb dead after last topk
    float* xhat = (float*)alloc((size_t)N4 * 18 * 4);
    float* sq1  = (float*)alloc(N4 * 4);
    float* sq2  = (float*)alloc(N4 * 4);
    float* di1  = (float*)alloc(N4 * 4);
    float* di2  = (float*)alloc(N4 * 4);
    float* wv1  = (float*)alloc((size_t)N4 * KNN * 4);
    float* wv2  = (float*)alloc((size_t)N4 * KNN * 4);
    int*   ix1  = (int*)alloc((size_t)N4 * KNN * 4);
    int*   ix2  = (int*)alloc((size_t)N4 * KNN * 4);
    float* t2x  = (float*)alloc((size_t)N4 * FDIM * 4);
    float* vfr  = (float*)alloc((size_t)NRB * CC * 4);
    float* tr1  = (float*)alloc((size_t)NRB * CC * 4);
    float* tr2  = (float*)alloc((size_t)NRB * CC * 4);
    float* rpre = (float*)alloc((size_t)NRB * CC * 4);
    float* Mb   = (float*)alloc(6 * CC * 4);
    float* rbm  = (float*)alloc(CC * 4);
    float* otm  = (float*)alloc(CC * 4);
    float* h1p  = (float*)alloc(512 * 4);
    float* racc = (float*)alloc(64 * 4);
    if (off > ws_size) return;

    hipMemsetAsync(accC, 0, (size_t)N4 * CC * 4, stream);
    hipMemsetAsync(Mb,   0, 6 * CC * 4, stream);
    hipMemsetAsync(rbm,  0, CC * 4, stream);
    hipMemsetAsync(otm,  0, CC * 4, stream);
    hipMemsetAsync(h1p,  0, 512 * 4, stream);
    hipMemsetAsync(racc, 0, 64 * 4, stream);
    hipMemsetAsync(rpre, 0, (size_t)NRB * CC * 4, stream);
    hipMemsetAsync(vfr,  0, (size_t)NRB * CC * 4, stream);

    // ---- graph 1 (on x) ----
    sqx_kernel<<<(N4 + 255) / 256, 256, 0, stream>>>(x, sq1, xhat);
    for (int cb = 0; cb < N4; cb += CHUNK) {
        gram1_kernel<<<dim3(N4 / 256, CHUNK), 256, 0, stream>>>(x, sq1, Sb, cb);
        topk_radix<<<CHUNK, 512, 0, stream>>>(Sb, cb, ix1, wv1, di1);
    }
    dinv_kernel<<<N4 / 256, 256, 0, stream>>>(di1);
    wnorm_kernel<<<(N4 * KNN + 255) / 256, 256, 0, stream>>>(wv1, ix1, di1);

    // ---- cheb conv 1 ----
    spmv_cheb<<<N4, 64, 0, stream>>>(xhat, xhat, xhat + 6, ix1, wv1, FDIM, 18, 18, 18, 1.f, 0.f);
    spmv_cheb<<<N4, 64, 0, stream>>>(xhat + 6, xhat, xhat + 12, ix1, wv1, FDIM, 18, 18, 18, 2.f, 1.f);
    cheb1_out_kernel<<<N4 / 16, 256, 0, stream>>>(xhat, W1, b1, outF);

    matT6_partial<<<dim3(4, 32), 256, 0, stream>>>(outF, xhat + 6, 18, Mb);
    fro_kernel<<<24, 256, 0, stream>>>(Mb, racc + 0);

    vfr_kernel<<<dim3(4, NRB, 5), 256, 0, stream>>>(outF, sccs, vfr);

    // ---- graph 2 (on outF), bf16 MFMA gram ----
    sq2_kernel<<<N4 / 4, 256, 0, stream>>>(outF, sq2);
    cvt_bf16_kernel<<<N4 * 128 / 256, 256, 0, stream>>>(outF, Abf);
    for (int cb = 0; cb < N4; cb += CHUNK) {
        gram2_mfma<<<dim3(N4 / 128, CHUNK / 128), 256, 0, stream>>>(Abf, sq2, Sb, cb);
        topk_radix<<<CHUNK, 512, 0, stream>>>(Sb, cb, ix2, wv2, di2);
    }
    dinv_kernel<<<N4 / 256, 256, 0, stream>>>(di2);
    wnorm_kernel<<<(N4 * KNN + 255) / 256, 256, 0, stream>>>(wv2, ix2, di2);

    // Sb dead -> build W2T in its space
    w2t_kernel<<<dim3(16, 16, 6), 256, 0, stream>>>(W2, W2T);

    spmv_cheb<<<N4, 64, 0, stream>>>(x, x, t2x, ix2, wv2, FDIM, FDIM, FDIM, FDIM, 1.f, 0.f);

    // ---- cheb conv 2 (K=6): T0=outF/Abf, gathers from bf16 mirror, fused cvt ----
    gemm_mfma_acc<<<dim3(8, 32), 256, 0, stream>>>(Abf, W2T + (size_t)0 * KP * KP, accC);
    spmv_cheb_bf<<<N4, 128, 0, stream>>>(Abf, outF, outF, T1, Bbf, ix2, wv2, 1.f, 0.f);       // T1
    gemm_mfma_acc<<<dim3(8, 32), 256, 0, stream>>>(Bbf, W2T + (size_t)1 * KP * KP, accC);
    spmv_cheb_bf<<<N4, 128, 0, stream>>>(Bbf, T1, outF, outF, Abf, ix2, wv2, 2.f, 1.f);       // T2
    gemm_mfma_acc<<<dim3(8, 32), 256, 0, stream>>>(Abf, W2T + (size_t)2 * KP * KP, accC);
    spmv_cheb_bf<<<N4, 128, 0, stream>>>(Abf, outF, T1, T1, Bbf, ix2, wv2, 2.f, 1.f);         // T3
    gemm_mfma_acc<<<dim3(8, 32), 256, 0, stream>>>(Bbf, W2T + (size_t)3 * KP * KP, accC);
    spmv_cheb_bf<<<N4, 128, 0, stream>>>(Bbf, T1, outF, outF, Abf, ix2, wv2, 2.f, 1.f);       // T4
    gemm_mfma_acc<<<dim3(8, 32), 256, 0, stream>>>(Abf, W2T + (size_t)4 * KP * KP, accC);
    spmv_cheb_bf<<<N4, 128, 0, stream>>>(Abf, outF, T1, T1, Bbf, ix2, wv2, 2.f, 1.f);         // T5
    gemm_mfma_final<<<dim3(8, 32), 256, 0, stream>>>(Bbf, W2T + (size_t)5 * KP * KP, accC, b2);

    hipMemsetAsync(Mb, 0, 6 * CC * 4, stream);
    matT6_partial<<<dim3(4, 32), 256, 0, stream>>>(accC, t2x, FDIM, Mb);
    fro_kernel<<<24, 256, 0, stream>>>(Mb, racc + 1);

    colmax_kernel<<<dim3(4, 16), 256, 0, stream>>>(accC, otm);

    // ---- reeb cheb conv (K=3) ----
    reeb_mm_kernel<<<dim3(4, NRB), 256, 0, stream>>>(Lr, vfr, nullptr, tr1, 1.f);
    reeb_mm_kernel<<<dim3(4, NRB), 256, 0, stream>>>(Lr, tr1, vfr, tr2, 2.f);
    reeb_conv_splitk<<<dim3(4, 120), 256, 0, stream>>>(vfr, tr1, tr2, Wr, rpre);
    reeb_max_kernel<<<4, 256, 0, stream>>>(rpre, br, rbm);

    // ---- FC head ----
    fc1_kernel<<<dim3(2, 8), 256, 0, stream>>>(rbm, otm, f1w, h1p);
    fc23_kernel<<<1, 512, 0, stream>>>(h1p, f1b, f2w, f2b, f3w, f3b, dout);
    finalize_kernel<<<1, 256, 0, stream>>>(racc, f1w, f1b, f2w, f2b, f3w, f3b, dout);
}

// Round 7
// 999.298 us; speedup vs baseline: 3.4824x; 1.0069x over previous
//
#include <hip/hip_runtime.h>
#include <math.h>

#define N4    4096
#define FDIM  6
#define CC    1000
#define KP    1024   // padded K for bf16 GEMMs
#define KNN   40
#define CHUNK 1024
#define NRB   20
#define SSC   205

typedef __attribute__((ext_vector_type(8))) short bf16x8;
typedef __attribute__((ext_vector_type(4))) float f32x4;

__device__ __forceinline__ unsigned short f2bf(float f) {
    unsigned u = __float_as_uint(f);
    u = (u + 0x7fffu + ((u >> 16) & 1u)) >> 16;
    return (unsigned short)u;
}
__device__ __forceinline__ float bf2f(short s) {
    return __uint_as_float(((unsigned)(unsigned short)s) << 16);
}

// ---------------- graph build ----------------

__global__ __launch_bounds__(256) void sqx_kernel(const float* __restrict__ x,
                                                  float* __restrict__ sq1,
                                                  float* __restrict__ xhat) {
    int n = blockIdx.x * blockDim.x + threadIdx.x;
    if (n >= N4) return;
    float s = 0.f;
#pragma unroll
    for (int f = 0; f < FDIM; ++f) {
        float v = x[n * FDIM + f];
        s += v * v;
        xhat[n * 18 + f] = v;
    }
    sq1[n] = s;
}

__global__ __launch_bounds__(256) void gram1_kernel(const float* __restrict__ x,
                                                    const float* __restrict__ sq1,
                                                    float* __restrict__ S, int base) {
    __shared__ float xn[FDIM];
    __shared__ float sn;
    int r = blockIdx.y;
    int n = base + r;
    int m = blockIdx.x * 256 + threadIdx.x;
    if (threadIdx.x < FDIM) xn[threadIdx.x] = x[n * FDIM + threadIdx.x];
    if (threadIdx.x == FDIM) sn = sq1[n];
    __syncthreads();
    float d = 0.f;
#pragma unroll
    for (int f = 0; f < FDIM; ++f) d += xn[f] * x[m * FDIM + f];
    float e = sn + sq1[m] - 2.f * d;
    S[(size_t)r * N4 + m] = __expf(-e);
}

// radix-select top-40 per row (exact). Bucket pick: wave-0 shuffle suffix
// scan (4 buckets/lane, no barriers inside scan). ==T ties taken ascending
// to match lax.top_k.
__global__ __launch_bounds__(512) void topk_radix(const float* __restrict__ S, int base,
                                                  int* __restrict__ idx, float* __restrict__ val,
                                                  float* __restrict__ rowsum) {
    __shared__ unsigned sv[N4];
    __shared__ int hist[8 * 256];
    __shared__ int sc[256];
    __shared__ float red[512];
    __shared__ unsigned s_pfx;
    __shared__ int s_need;
    __shared__ int s_cnt;
    int t = threadIdx.x;
    int lane = t & 63, w = t >> 6;
    int r = blockIdx.x;
    int n = base + r;
    const float* row = S + (size_t)r * N4;
    for (int i = t; i < N4; i += 512) sv[i] = __float_as_uint(row[i]);
    if (t == 0) { s_pfx = 0u; s_need = KNN; s_cnt = 0; }
    __syncthreads();

    int* hw = &hist[w * 256];   // per-wave histogram copy (8 waves)
#pragma unroll
    for (int level = 24; level >= 0; level -= 8) {
        hist[t] = 0; hist[512 + t] = 0; hist[1024 + t] = 0; hist[1536 + t] = 0;
        __syncthreads();
        unsigned pfx = s_pfx;
        int need = s_need;
        for (int i = t; i < N4; i += 512) {
            unsigned u = sv[i];
            bool m = (level == 24) || ((u >> (level + 8)) == (pfx >> (level + 8)));
            if (m) atomicAdd(&hw[(u >> level) & 255], 1);
        }
        __syncthreads();
        if (t < 256) {
            int cnt = 0;
#pragma unroll
            for (int wq = 0; wq < 8; ++wq) cnt += hist[wq * 256 + t];
            sc[t] = cnt;
        }
        __syncthreads();
        if (w == 0) {   // wave 0: suffix scan over 256 buckets, 4/lane
            int c0 = sc[4 * lane + 0], c1 = sc[4 * lane + 1];
            int c2 = sc[4 * lane + 2], c3 = sc[4 * lane + 3];
            int s = c0 + c1 + c2 + c3;
            int suf = s;
#pragma unroll
            for (int off = 1; off < 64; off <<= 1) {
                int ov = __shfl_down(suf, off, 64);
                if (lane + off < 64) suf += ov;
            }
            int above = suf - s;              // exclusive suffix from higher lanes
            int i3 = above + c3;
            int i2 = i3 + c2;
            int i1 = i2 + c1;
            int i0 = i1 + c0;
            if (i3 >= need && i3 - c3 < need) { s_need = need - (i3 - c3); s_pfx = pfx | ((unsigned)(4 * lane + 3) << level); }
            if (i2 >= need && i2 - c2 < need) { s_need = need - (i2 - c2); s_pfx = pfx | ((unsigned)(4 * lane + 2) << level); }
            if (i1 >= need && i1 - c1 < need) { s_need = need - (i1 - c1); s_pfx = pfx | ((unsigned)(4 * lane + 1) << level); }
            if (i0 >= need && i0 - c0 < need) { s_need = need - (i0 - c0); s_pfx = pfx | ((unsigned)(4 * lane + 0) << level); }
        }
        __syncthreads();
    }
    unsigned Tbits = s_pfx;
    float Tf = __uint_as_float(Tbits);
    int needEq = s_need;

    // collect strictly-greater (count = KNN - needEq), accumulate their sum
    float psum = 0.f;
    for (int i = t; i < N4; i += 512) {
        unsigned u = sv[i];
        if (u > Tbits) {
            int p = atomicAdd(&s_cnt, 1);
            idx[(size_t)n * KNN + p] = i;
            float v = __uint_as_float(u);
            val[(size_t)n * KNN + p] = v;
            psum += v;
        }
    }
    red[t] = psum;
    __syncthreads();
    for (int o = 256; o; o >>= 1) { if (t < o) red[t] += red[t + o]; __syncthreads(); }
    if (t == 0) rowsum[n] = red[0] + (float)needEq * Tf;

    // equals: earliest indices first (wave 0 ballot scan)
    if (t < 64) {
        int filled = KNN - needEq;
        for (int ib = 0; ib < N4 && filled < KNN; ib += 64) {
            bool eq = (sv[ib + t] == Tbits);
            unsigned long long m = __ballot(eq);
            int pre = __popcll(m & ((1ull << t) - 1ull));
            if (eq && (filled + pre) < KNN) {
                idx[(size_t)n * KNN + filled + pre] = ib + t;
                val[(size_t)n * KNN + filled + pre] = Tf;
            }
            filled += __popcll(m);
        }
    }
}

__global__ __launch_bounds__(256) void dinv_kernel(float* __restrict__ rs) {
    int n = blockIdx.x * 256 + threadIdx.x;
    if (n < N4) rs[n] = rsqrtf(rs[n]);
}

__global__ __launch_bounds__(256) void wnorm_kernel(float* __restrict__ wv,
                                                    const int* __restrict__ idx,
                                                    const float* __restrict__ dinv) {
    int i = blockIdx.x * 256 + threadIdx.x;
    if (i >= N4 * KNN) return;
    int n = i / KNN;
    wv[i] = wv[i] * dinv[n] * dinv[idx[i]];
}

// Tn[n,:] = a*(Tc[n,:] - sum_j wv[n,j]*Tc[idx[n,j],:]) - b*Tp[n,:]   (F small)
__global__ __launch_bounds__(64) void spmv_cheb(const float* __restrict__ Tc,
                                                const float* __restrict__ Tp,
                                                float* __restrict__ Tn,
                                                const int* __restrict__ idx,
                                                const float* __restrict__ wv,
                                                int F, int sC, int sP, int sN,
                                                float a, float b) {
    __shared__ int   si[KNN];
    __shared__ float sw[KNN];
    int n = blockIdx.x;
    if (threadIdx.x < KNN) {
        si[threadIdx.x] = idx[(size_t)n * KNN + threadIdx.x];
        sw[threadIdx.x] = wv[(size_t)n * KNN + threadIdx.x];
    }
    __syncthreads();
    for (int c = threadIdx.x; c < F; c += blockDim.x) {
        float s = 0.f;
#pragma unroll 8
        for (int j = 0; j < KNN; ++j) s += sw[j] * Tc[(size_t)si[j] * sC + c];
        float v = a * (Tc[(size_t)n * sC + c] - s);
        if (b != 0.f) v -= b * Tp[(size_t)n * sP + c];
        Tn[(size_t)n * sN + c] = v;
    }
}

// CC-wide: 256 threads, two half-blocks each gather 20 of 40 neighbors from
// the bf16 mirror; merge via LDS; fused fp32+bf16 write.
__global__ __launch_bounds__(256) void spmv_cheb_bf(const unsigned short* __restrict__ Tcbf,
                                                    const float* __restrict__ Tc,
                                                    const float* __restrict__ Tp,
                                                    float* __restrict__ Tn,
                                                    unsigned short* __restrict__ Tnbf,
                                                    const int* __restrict__ idx,
                                                    const float* __restrict__ wv,
                                                    float a, float b) {
    __shared__ int   si[KNN];
    __shared__ float sw[KNN];
    __shared__ float part[128][8];
    int n = blockIdx.x;
    int t = threadIdx.x;
    int tt = t & 127, h = t >> 7;
    if (t < KNN) {
        si[t] = idx[(size_t)n * KNN + t];
        sw[t] = wv[(size_t)n * KNN + t];
    }
    __syncthreads();
    int c = tt * 8;
    float acc0 = 0, acc1 = 0, acc2 = 0, acc3 = 0, acc4 = 0, acc5 = 0, acc6 = 0, acc7 = 0;
    int j0 = h * 20;
#pragma unroll 4
    for (int j = j0; j < j0 + 20; ++j) {
        bf16x8 v = *(const bf16x8*)(Tcbf + (size_t)si[j] * KP + c);
        float wj = sw[j];
        acc0 += wj * bf2f(v[0]); acc1 += wj * bf2f(v[1]);
        acc2 += wj * bf2f(v[2]); acc3 += wj * bf2f(v[3]);
        acc4 += wj * bf2f(v[4]); acc5 += wj * bf2f(v[5]);
        acc6 += wj * bf2f(v[6]); acc7 += wj * bf2f(v[7]);
    }
    if (h == 1) {
        part[tt][0] = acc0; part[tt][1] = acc1; part[tt][2] = acc2; part[tt][3] = acc3;
        part[tt][4] = acc4; part[tt][5] = acc5; part[tt][6] = acc6; part[tt][7] = acc7;
    }
    __syncthreads();
    if (h == 0) {
        acc0 += part[tt][0]; acc1 += part[tt][1]; acc2 += part[tt][2]; acc3 += part[tt][3];
        acc4 += part[tt][4]; acc5 += part[tt][5]; acc6 += part[tt][6]; acc7 += part[tt][7];
        bf16x8 ob;
        if (tt < 125) {
            float4 tc0 = *(const float4*)(Tc + (size_t)n * CC + c);
            float4 tc1 = *(const float4*)(Tc + (size_t)n * CC + c + 4);
            float o0 = a * (tc0.x - acc0), o1 = a * (tc0.y - acc1);
            float o2 = a * (tc0.z - acc2), o3 = a * (tc0.w - acc3);
            float o4 = a * (tc1.x - acc4), o5 = a * (tc1.y - acc5);
            float o6 = a * (tc1.z - acc6), o7 = a * (tc1.w - acc7);
            if (b != 0.f) {
                float4 tp0 = *(const float4*)(Tp + (size_t)n * CC + c);
                float4 tp1 = *(const float4*)(Tp + (size_t)n * CC + c + 4);
                o0 -= b * tp0.x; o1 -= b * tp0.y; o2 -= b * tp0.z; o3 -= b * tp0.w;
                o4 -= b * tp1.x; o5 -= b * tp1.y; o6 -= b * tp1.z; o7 -= b * tp1.w;
            }
            *(float4*)(Tn + (size_t)n * CC + c) = make_float4(o0, o1, o2, o3);
            *(float4*)(Tn + (size_t)n * CC + c + 4) = make_float4(o4, o5, o6, o7);
            ob[0] = (short)f2bf(o0); ob[1] = (short)f2bf(o1);
            ob[2] = (short)f2bf(o2); ob[3] = (short)f2bf(o3);
            ob[4] = (short)f2bf(o4); ob[5] = (short)f2bf(o5);
            ob[6] = (short)f2bf(o6); ob[7] = (short)f2bf(o7);
        } else {
#pragma unroll
            for (int q = 0; q < 8; ++q) ob[q] = 0;
        }
        *(bf16x8*)(Tnbf + (size_t)n * KP + c) = ob;
    }
}

// ---------------- bf16 conversion / transpose ----------------

__global__ __launch_bounds__(256) void cvt_bf16_kernel(const float* __restrict__ in,
                                                       unsigned short* __restrict__ out) {
    int i = blockIdx.x * 256 + threadIdx.x;     // N4*128 total
    int r = i >> 7, g = i & 127;
    bf16x8 v;
    if (g < 125) {
        float4 a = *(const float4*)(in + (size_t)r * CC + g * 8);
        float4 b = *(const float4*)(in + (size_t)r * CC + g * 8 + 4);
        v[0] = (short)f2bf(a.x); v[1] = (short)f2bf(a.y);
        v[2] = (short)f2bf(a.z); v[3] = (short)f2bf(a.w);
        v[4] = (short)f2bf(b.x); v[5] = (short)f2bf(b.y);
        v[6] = (short)f2bf(b.z); v[7] = (short)f2bf(b.w);
    } else {
#pragma unroll
        for (int q = 0; q < 8; ++q) v[q] = 0;
    }
    *(bf16x8*)(out + (size_t)r * KP + g * 8) = v;
}

// W2 [6*CC x CC] fp32 -> W2T [6][KP(n) x KP(k)] bf16
__global__ __launch_bounds__(256) void w2t_kernel(const float* __restrict__ W2,
                                                  unsigned short* __restrict__ out) {
    __shared__ unsigned short tile[64][65];
    int t = threadIdx.x;
    int k0 = blockIdx.x * 64, n0 = blockIdx.y * 64, s = blockIdx.z;
#pragma unroll
    for (int p = 0; p < 16; ++p) {
        int i = p * 256 + t;
        int kk = i >> 6, nn = i & 63;
        int k = k0 + kk, n = n0 + nn;
        float v = (k < CC && n < CC) ? W2[((size_t)s * CC + k) * CC + n] : 0.f;
        tile[kk][nn] = f2bf(v);
    }
    __syncthreads();
#pragma unroll
    for (int p = 0; p < 16; ++p) {
        int i = p * 256 + t;
        int nn = i >> 6, kk = i & 63;
        out[((size_t)s * KP + n0 + nn) * KP + k0 + kk] = tile[kk][nn];
    }
}

// ---------------- MFMA GEMMs (128x128 tile, BK=32, bf16 in / fp32 acc) ----------------

#define LDP 40

__device__ __forceinline__ void gemm_core(const unsigned short* __restrict__ Ag,
                                          const unsigned short* __restrict__ Bg,
                                          short* As, short* Bs, int t,
                                          f32x4 (&acc)[4][4]) {
    int l = t & 63, w = t >> 6;
    int wm = (w >> 1) * 64, wn = (w & 1) * 64;
    int ar0 = t >> 2, ak0 = (t & 3) * 8;
    int ar1 = (t + 256) >> 2, ak1 = ((t + 256) & 3) * 8;
    int lr = l & 15, lq8 = (l >> 4) * 8;
    for (int k0 = 0; k0 < KP; k0 += 32) {
        bf16x8 a0 = *(const bf16x8*)(Ag + (size_t)ar0 * KP + k0 + ak0);
        bf16x8 a1 = *(const bf16x8*)(Ag + (size_t)ar1 * KP + k0 + ak1);
        bf16x8 b0 = *(const bf16x8*)(Bg + (size_t)ar0 * KP + k0 + ak0);
        bf16x8 b1 = *(const bf16x8*)(Bg + (size_t)ar1 * KP + k0 + ak1);
        __syncthreads();
        *(bf16x8*)&As[ar0 * LDP + ak0] = a0;
        *(bf16x8*)&As[ar1 * LDP + ak1] = a1;
        *(bf16x8*)&Bs[ar0 * LDP + ak0] = b0;
        *(bf16x8*)&Bs[ar1 * LDP + ak1] = b1;
        __syncthreads();
        bf16x8 af[4], bfr[4];
#pragma unroll
        for (int mi = 0; mi < 4; ++mi)
            af[mi] = *(const bf16x8*)&As[(wm + mi * 16 + lr) * LDP + lq8];
#pragma unroll
        for (int ni = 0; ni < 4; ++ni)
            bfr[ni] = *(const bf16x8*)&Bs[(wn + ni * 16 + lr) * LDP + lq8];
#pragma unroll
        for (int mi = 0; mi < 4; ++mi)
#pragma unroll
            for (int ni = 0; ni < 4; ++ni)
                acc[mi][ni] = __builtin_amdgcn_mfma_f32_16x16x32_bf16(af[mi], bfr[ni], acc[mi][ni], 0, 0, 0);
    }
}

__global__ __launch_bounds__(256) void gemm_mfma_acc(const unsigned short* __restrict__ A,
                                                     const unsigned short* __restrict__ B,
                                                     float* __restrict__ C) {
    __shared__ short As[128 * LDP];
    __shared__ short Bs[128 * LDP];
    int t = threadIdx.x;
    int n0 = blockIdx.x * 128, m0 = blockIdx.y * 128;
    f32x4 acc[4][4] = {};
    gemm_core(A + (size_t)m0 * KP, B + (size_t)n0 * KP, As, Bs, t, acc);
    int l = t & 63, w = t >> 6;
    int wm = (w >> 1) * 64, wn = (w & 1) * 64;
    int lr = l & 15, lq4 = (l >> 4) * 4;
#pragma unroll
    for (int ni = 0; ni < 4; ++ni) {
        int n = n0 + wn + ni * 16 + lr;
        if (n >= CC) continue;
#pragma unroll
        for (int mi = 0; mi < 4; ++mi) {
            int m = m0 + wm + mi * 16 + lq4;
            f32x4 v = acc[mi][ni];
#pragma unroll
            for (int r = 0; r < 4; ++r) C[(size_t)(m + r) * CC + n] += v[r];
        }
    }
}

__global__ __launch_bounds__(256) void gemm_mfma_final(const unsigned short* __restrict__ A,
                                                       const unsigned short* __restrict__ B,
                                                       float* __restrict__ C,
                                                       const float* __restrict__ b2) {
    __shared__ short As[128 * LDP];
    __shared__ short Bs[128 * LDP];
    int t = threadIdx.x;
    int n0 = blockIdx.x * 128, m0 = blockIdx.y * 128;
    f32x4 acc[4][4] = {};
    gemm_core(A + (size_t)m0 * KP, B + (size_t)n0 * KP, As, Bs, t, acc);
    int l = t & 63, w = t >> 6;
    int wm = (w >> 1) * 64, wn = (w & 1) * 64;
    int lr = l & 15, lq4 = (l >> 4) * 4;
#pragma unroll
    for (int ni = 0; ni < 4; ++ni) {
        int n = n0 + wn + ni * 16 + lr;
        if (n >= CC) continue;
        float bb = b2[n];
#pragma unroll
        for (int mi = 0; mi < 4; ++mi) {
            int m = m0 + wm + mi * 16 + lq4;
            f32x4 v = acc[mi][ni];
#pragma unroll
            for (int r = 0; r < 4; ++r) {
                float* p = &C[(size_t)(m + r) * CC + n];
                *p = fmaxf(*p + v[r] + bb, 0.f);
            }
        }
    }
}

__global__ __launch_bounds__(256) void gram2_mfma(const unsigned short* __restrict__ Abf,
                                                  const float* __restrict__ sq2,
                                                  float* __restrict__ S, int base) {
    __shared__ short As[128 * LDP];
    __shared__ short Bs[128 * LDP];
    int t = threadIdx.x;
    int n0 = blockIdx.x * 128, m0 = blockIdx.y * 128;
    f32x4 acc[4][4] = {};
    gemm_core(Abf + (size_t)(base + m0) * KP, Abf + (size_t)n0 * KP, As, Bs, t, acc);
    int l = t & 63, w = t >> 6;
    int wm = (w >> 1) * 64, wn = (w & 1) * 64;
    int lr = l & 15, lq4 = (l >> 4) * 4;
#pragma unroll
    for (int ni = 0; ni < 4; ++ni) {
        int n = n0 + wn + ni * 16 + lr;
        float sn = sq2[n];
#pragma unroll
        for (int mi = 0; mi < 4; ++mi) {
            int mrow = m0 + wm + mi * 16 + lq4;
            f32x4 v = acc[mi][ni];
#pragma unroll
            for (int r = 0; r < 4; ++r) {
                float d = sq2[base + mrow + r] + sn - 2.f * v[r];
                S[(size_t)(mrow + r) * N4 + n] = __expf(-d);
            }
        }
    }
}

// ---------------- cheb conv 1 ----------------

__global__ __launch_bounds__(256) void cheb1_out_kernel(const float* __restrict__ xhat,
                                                        const float* __restrict__ W1,
                                                        const float* __restrict__ b1,
                                                        float* __restrict__ outF) {
    __shared__ float xh[16][18];
    int n0 = blockIdx.x * 16;
    int tid = threadIdx.x;
    for (int i = tid; i < 16 * 18; i += 256) xh[i / 18][i % 18] = xhat[(size_t)n0 * 18 + i];
    __syncthreads();
    for (int c0 = 0; c0 < CC; c0 += 256) {
        int c = c0 + tid;
        if (c < CC) {
            float acc[16];
#pragma unroll
            for (int r = 0; r < 16; ++r) acc[r] = 0.f;
            for (int f = 0; f < 18; ++f) {
                float wv = W1[(size_t)f * CC + c];
#pragma unroll
                for (int r = 0; r < 16; ++r) acc[r] += xh[r][f] * wv;
            }
            float bb = b1[c];
#pragma unroll
            for (int r = 0; r < 16; ++r)
                outF[(size_t)(n0 + r) * CC + c] = fmaxf(acc[r] + bb, 0.f);
        }
    }
}

// ---------------- regs (frobenius of O^T @ T) ----------------

__global__ __launch_bounds__(256) void matT6_partial(const float* __restrict__ O,
                                                     const float* __restrict__ T, int ts,
                                                     float* __restrict__ M) {
    __shared__ float sT[128][6];
    int t = threadIdx.x;
    int c = blockIdx.x * 256 + t;
    int n0 = blockIdx.y * 128;
    for (int i = t; i < 128 * 6; i += 256) {
        int nn = i / 6, f = i % 6;
        sT[nn][f] = T[(size_t)(n0 + nn) * ts + f];
    }
    __syncthreads();
    if (c >= CC) return;
    float a0 = 0, a1 = 0, a2 = 0, a3 = 0, a4 = 0, a5 = 0;
    for (int nn = 0; nn < 128; ++nn) {
        float o = O[(size_t)(n0 + nn) * CC + c];
        a0 += o * sT[nn][0]; a1 += o * sT[nn][1]; a2 += o * sT[nn][2];
        a3 += o * sT[nn][3]; a4 += o * sT[nn][4]; a5 += o * sT[nn][5];
    }
    atomicAdd(&M[0 * CC + c], a0);
    atomicAdd(&M[1 * CC + c], a1);
    atomicAdd(&M[2 * CC + c], a2);
    atomicAdd(&M[3 * CC + c], a3);
    atomicAdd(&M[4 * CC + c], a4);
    atomicAdd(&M[5 * CC + c], a5);
}

__global__ __launch_bounds__(256) void fro_kernel(const float* __restrict__ M, float* __restrict__ dst) {
    __shared__ float red[256];
    int t = threadIdx.x;
    int i = blockIdx.x * 256 + t;
    float v = (i < 6 * CC) ? M[i] : 0.f;
    red[t] = v * v;
    __syncthreads();
    for (int o = 128; o; o >>= 1) { if (t < o) red[t] += red[t + o]; __syncthreads(); }
    if (t == 0) atomicAdd(dst, red[0]);
}

// ---------------- pooling ----------------

__global__ __launch_bounds__(256) void vfr_kernel(const float* __restrict__ outF,
                                                  const int* __restrict__ sccs,
                                                  float* __restrict__ vfr) {
    int r = blockIdx.y;
    int c = blockIdx.x * 256 + threadIdx.x;
    if (c >= CC) return;
    int s0 = blockIdx.z * 41;
    float m = 0.f;
    for (int s = s0; s < s0 + 41; ++s) {
        int n = sccs[r * SSC + s];
        m = fmaxf(m, outF[(size_t)n * CC + c]);
    }
    atomicMax((int*)&vfr[(size_t)r * CC + c], __float_as_int(m));
}

__global__ __launch_bounds__(256) void sq2_kernel(const float* __restrict__ outF,
                                                  float* __restrict__ sq2) {
    int lane = threadIdx.x & 63, w = threadIdx.x >> 6;
    int n = blockIdx.x * 4 + w;
    const float* row = outF + (size_t)n * CC;
    float s = 0.f;
    for (int i = lane; i < CC; i += 64) { float v = row[i]; s += v * v; }
#pragma unroll
    for (int o = 32; o; o >>= 1) s += __shfl_down(s, o);
    if (lane == 0) sq2[n] = s;
}

// row-split column max; dst must be zeroed (values >= 0)
__global__ __launch_bounds__(256) void colmax_kernel(const float* __restrict__ O,
                                                     float* __restrict__ dst) {
    int c = blockIdx.x * 256 + threadIdx.x;
    if (c >= CC) return;
    int n0 = blockIdx.y * 64;
    float m = 0.f;
    for (int n = n0; n < n0 + 64; ++n) m = fmaxf(m, O[(size_t)n * CC + c]);
    atomicMax((int*)&dst[c], __float_as_int(m));
}

// ---------------- reeb branch ----------------

__global__ __launch_bounds__(256) void reeb_mm_kernel(const float* __restrict__ Lr,
                                                      const float* __restrict__ Vin,
                                                      const float* __restrict__ Vsub,
                                                      float* __restrict__ Vout, float a2) {
    int c = blockIdx.x * 256 + threadIdx.x;
    if (c >= CC) return;
    int r = blockIdx.y;
    float s = 0.f;
#pragma unroll
    for (int j = 0; j < NRB; ++j) s += Lr[r * NRB + j] * Vin[(size_t)j * CC + c];
    float v = a2 * s;
    if (Vsub) v -= Vsub[(size_t)r * CC + c];
    Vout[(size_t)r * CC + c] = v;
}

#define RKC 25
__global__ __launch_bounds__(256) void reeb_conv_splitk(const float* __restrict__ vfr,
                                                        const float* __restrict__ tr1,
                                                        const float* __restrict__ tr2,
                                                        const float* __restrict__ Wr,
                                                        float* __restrict__ rpre) {
    __shared__ float sA[NRB][RKC];
    int t = threadIdx.x;
    int kbase = blockIdx.y * RKC;
    for (int i = t; i < NRB * RKC; i += 256) {
        int r = i / RKC, kk = i % RKC;
        int kg = kbase + kk;
        float v;
        if (kg < CC)           v = vfr[(size_t)r * CC + kg];
        else if (kg < 2 * CC)  v = tr1[(size_t)r * CC + kg - CC];
        else                   v = tr2[(size_t)r * CC + kg - 2 * CC];
        sA[r][kk] = v;
    }
    __syncthreads();
    int c = blockIdx.x * 256 + t;
    if (c >= CC) return;
    float acc[NRB];
#pragma unroll
    for (int r = 0; r < NRB; ++r) acc[r] = 0.f;
    for (int kk = 0; kk < RKC; ++kk) {
        float wv = Wr[(size_t)(kbase + kk) * CC + c];
#pragma unroll
        for (int r = 0; r < NRB; ++r) acc[r] += sA[r][kk] * wv;
    }
#pragma unroll
    for (int r = 0; r < NRB; ++r) atomicAdd(&rpre[(size_t)r * CC + c], acc[r]);
}

__global__ __launch_bounds__(256) void reeb_max_kernel(const float* __restrict__ pre,
                                                       const float* __restrict__ br,
                                                       float* __restrict__ rbm) {
    int c = blockIdx.x * 256 + threadIdx.x;
    if (c >= CC) return;
    float bb = br[c];
    float m = 0.f;
    for (int r = 0; r < NRB; ++r) m = fmaxf(m, fmaxf(pre[(size_t)r * CC + c] + bb, 0.f));
    rbm[c] = m;
}

// ---------------- FC head ----------------

__global__ __launch_bounds__(256) void fc1_kernel(const float* __restrict__ rbm,
                                                  const float* __restrict__ otm,
                                                  const float* __restrict__ w,
                                                  float* __restrict__ h1pre) {
    int j = blockIdx.x * 256 + threadIdx.x;
    if (j >= 512) return;
    int i0 = blockIdx.y * 250;
    float s = 0.f;
    for (int i = i0; i < i0 + 250; ++i) {
        float v = (i < CC) ? rbm[i] : otm[i - CC];
        s += v * w[(size_t)i * 512 + j];
    }
    atomicAdd(&h1pre[j], s);
}

__global__ __launch_bounds__(512) void fc23_kernel(const float* __restrict__ h1pre,
                                                   const float* __restrict__ b1f,
                                                   const float* __restrict__ w2,
                                                   const float* __restrict__ b2f,
                                                   const float* __restrict__ w3,
                                                   const float* __restrict__ b3f,
                                                   float* __restrict__ dout) {
    __shared__ float h1[512];
    __shared__ float h2[128];
    int t = threadIdx.x;
    h1[t] = fmaxf(h1pre[t] + b1f[t], 0.f);
    __syncthreads();
    if (t < 128) {
        float s = b2f[t];
        for (int i = 0; i < 512; ++i) s += h1[i] * w2[(size_t)i * 128 + t];
        h2[t] = fmaxf(s, 0.f);
    }
    __syncthreads();
    if (t < 40) {
        float s = b3f[t];
        for (int i = 0; i < 128; ++i) s += h2[i] * w3[(size_t)i * 40 + t];
        dout[t] = s;
    }
}

__global__ __launch_bounds__(256) void finalize_kernel(const float* __restrict__ racc,
                                                       const float* __restrict__ f1w,
                                                       const float* __restrict__ f1b,
                                                       const float* __restrict__ f2w,
                                                       const float* __restrict__ f2b,
                                                       const float* __restrict__ f3w,
                                                       const float* __restrict__ f3b,
                                                       float* __restrict__ dout) {
    __shared__ float red[256];
    __shared__ float res[3];
    int t = threadIdx.x;
    float s1 = 0.f, s2 = 0.f, s3 = 0.f;
    for (int i = t; i < 2000; i += 256) { float v = f1w[(size_t)i * 512]; s1 += v * v; }
    for (int i = t; i < 512; i += 256) { float v = f2w[(size_t)i * 128]; s2 += v * v; }
    if (t < 128) { float v = f3w[(size_t)t * 40]; s3 = v * v; }

    red[t] = s1; __syncthreads();
    for (int o = 128; o; o >>= 1) { if (t < o) red[t] += red[t + o]; __syncthreads(); }
    if (t == 0) res[0] = red[0];
    __syncthreads();
    red[t] = s2; __syncthreads();
    for (int o = 128; o; o >>= 1) { if (t < o) red[t] += red[t + o]; __syncthreads(); }
    if (t == 0) res[1] = red[0];
    __syncthreads();
    red[t] = s3; __syncthreads();
    for (int o = 128; o; o >>= 1) { if (t < o) red[t] += red[t + o]; __syncthreads(); }
    if (t == 0) res[2] = red[0];
    __syncthreads();

    if (t == 0) {
        dout[40] = sqrtf(racc[0]);
        dout[41] = sqrtf(racc[1]);
        dout[42] = res[0];
        dout[43] = f1b[0] * f1b[0];
        dout[44] = res[1];
        dout[45] = f2b[0] * f2b[0];
        dout[46] = res[2];
        dout[47] = f3b[0] * f3b[0];
    }
}

// ---------------- host ----------------

extern "C" void kernel_launch(void* const* d_in, const int* in_sizes, int n_in,
                              void* d_out, int out_size, void* d_ws, size_t ws_size,
                              hipStream_t stream) {
    const float* x    = (const float*)d_in[0];
    const float* Lr   = (const float*)d_in[5];
    const int*   sccs = (const int*)d_in[6];
    const float* W1   = (const float*)d_in[7];
    const float* b1   = (const float*)d_in[8];
    const float* W2   = (const float*)d_in[9];
    const float* b2   = (const float*)d_in[10];
    const float* Wr   = (const float*)d_in[11];
    const float* br   = (const float*)d_in[12];
    const float* f1w  = (const float*)d_in[13];
    const float* f1b  = (const float*)d_in[14];
    const float* f2w  = (const float*)d_in[15];
    const float* f2b  = (const float*)d_in[16];
    const float* f3w  = (const float*)d_in[17];
    const float* f3b  = (const float*)d_in[18];
    float* dout = (float*)d_out;

    char* ws = (char*)d_ws;
    size_t off = 0;
    auto alloc = [&](size_t bytes) -> char* {
        char* p = ws + off;
        off = (off + bytes + 255) & ~(size_t)255;
        return p;
    };
    float* outF = (float*)alloc((size_t)N4 * CC * 4);
    float* T1   = (float*)alloc((size_t)N4 * CC * 4);
    float* accC = (float*)alloc((size_t)N4 * CC * 4);
    float* Sb   = (float*)alloc((size_t)CHUNK * N4 * 4);
    unsigned short* Abf = (unsigned short*)alloc((size_t)N4 * KP * 2);
    unsigned short* Bbf = (unsigned short*)alloc((size_t)N4 * KP * 2);
    unsigned short* W2T = (unsigned short*)Sb;  // alias: Sb dead after last topk
    float* xhat = (float*)alloc((size_t)N4 * 18 * 4);
    float* sq1  = (float*)alloc(N4 * 4);
    float* sq2  = (float*)alloc(N4 * 4);
    float* di1  = (float*)alloc(N4 * 4);
    float* di2  = (float*)alloc(N4 * 4);
    float* wv1  = (float*)alloc((size_t)N4 * KNN * 4);
    float* wv2  = (float*)alloc((size_t)N4 * KNN * 4);
    int*   ix1  = (int*)alloc((size_t)N4 * KNN * 4);
    int*   ix2  = (int*)alloc((size_t)N4 * KNN * 4);
    float* t2x  = (float*)alloc((size_t)N4 * FDIM * 4);
    float* vfr  = (float*)alloc((size_t)NRB * CC * 4);
    float* tr1  = (float*)alloc((size_t)NRB * CC * 4);
    float* tr2  = (float*)alloc((size_t)NRB * CC * 4);
    float* rpre = (float*)alloc((size_t)NRB * CC * 4);
    float* Mb   = (float*)alloc(6 * CC * 4);
    float* rbm  = (float*)alloc(CC * 4);
    float* otm  = (float*)alloc(CC * 4);
    float* h1p  = (float*)alloc(512 * 4);
    float* racc = (float*)alloc(64 * 4);
    if (off > ws_size) return;

    hipMemsetAsync(accC, 0, (size_t)N4 * CC * 4, stream);
    hipMemsetAsync(Mb,   0, 6 * CC * 4, stream);
    hipMemsetAsync(rbm,  0, CC * 4, stream);
    hipMemsetAsync(otm,  0, CC * 4, stream);
    hipMemsetAsync(h1p,  0, 512 * 4, stream);
    hipMemsetAsync(racc, 0, 64 * 4, stream);
    hipMemsetAsync(rpre, 0, (size_t)NRB * CC * 4, stream);
    hipMemsetAsync(vfr,  0, (size_t)NRB * CC * 4, stream);

    // ---- graph 1 (on x) ----
    sqx_kernel<<<(N4 + 255) / 256, 256, 0, stream>>>(x, sq1, xhat);
    for (int cb = 0; cb < N4; cb += CHUNK) {
        gram1_kernel<<<dim3(N4 / 256, CHUNK), 256, 0, stream>>>(x, sq1, Sb, cb);
        topk_radix<<<CHUNK, 512, 0, stream>>>(Sb, cb, ix1, wv1, di1);
    }
    dinv_kernel<<<N4 / 256, 256, 0, stream>>>(di1);
    wnorm_kernel<<<(N4 * KNN + 255) / 256, 256, 0, stream>>>(wv1, ix1, di1);

    // ---- cheb conv 1 ----
    spmv_cheb<<<N4, 64, 0, stream>>>(xhat, xhat, xhat + 6, ix1, wv1, FDIM, 18, 18, 18, 1.f, 0.f);
    spmv_cheb<<<N4, 64, 0, stream>>>(xhat + 6, xhat, xhat + 12, ix1, wv1, FDIM, 18, 18, 18, 2.f, 1.f);
    cheb1_out_kernel<<<N4 / 16, 256, 0, stream>>>(xhat, W1, b1, outF);

    matT6_partial<<<dim3(4, 32), 256, 0, stream>>>(outF, xhat + 6, 18, Mb);
    fro_kernel<<<24, 256, 0, stream>>>(Mb, racc + 0);

    vfr_kernel<<<dim3(4, NRB, 5), 256, 0, stream>>>(outF, sccs, vfr);

    // ---- graph 2 (on outF), bf16 MFMA gram ----
    sq2_kernel<<<N4 / 4, 256, 0, stream>>>(outF, sq2);
    cvt_bf16_kernel<<<N4 * 128 / 256, 256, 0, stream>>>(outF, Abf);
    for (int cb = 0; cb < N4; cb += CHUNK) {
        gram2_mfma<<<dim3(N4 / 128, CHUNK / 128), 256, 0, stream>>>(Abf, sq2, Sb, cb);
        topk_radix<<<CHUNK, 512, 0, stream>>>(Sb, cb, ix2, wv2, di2);
    }
    dinv_kernel<<<N4 / 256, 256, 0, stream>>>(di2);
    wnorm_kernel<<<(N4 * KNN + 255) / 256, 256, 0, stream>>>(wv2, ix2, di2);

    // Sb dead -> build W2T in its space
    w2t_kernel<<<dim3(16, 16, 6), 256, 0, stream>>>(W2, W2T);

    spmv_cheb<<<N4, 64, 0, stream>>>(x, x, t2x, ix2, wv2, FDIM, FDIM, FDIM, FDIM, 1.f, 0.f);

    // ---- cheb conv 2 (K=6): T0=outF/Abf, gathers from bf16 mirror, fused cvt ----
    gemm_mfma_acc<<<dim3(8, 32), 256, 0, stream>>>(Abf, W2T + (size_t)0 * KP * KP, accC);
    spmv_cheb_bf<<<N4, 256, 0, stream>>>(Abf, outF, outF, T1, Bbf, ix2, wv2, 1.f, 0.f);       // T1
    gemm_mfma_acc<<<dim3(8, 32), 256, 0, stream>>>(Bbf, W2T + (size_t)1 * KP * KP, accC);
    spmv_cheb_bf<<<N4, 256, 0, stream>>>(Bbf, T1, outF, outF, Abf, ix2, wv2, 2.f, 1.f);       // T2
    gemm_mfma_acc<<<dim3(8, 32), 256, 0, stream>>>(Abf, W2T + (size_t)2 * KP * KP, accC);
    spmv_cheb_bf<<<N4, 256, 0, stream>>>(Abf, outF, T1, T1, Bbf, ix2, wv2, 2.f, 1.f);         // T3
    gemm_mfma_acc<<<dim3(8, 32), 256, 0, stream>>>(Bbf, W2T + (size_t)3 * KP * KP, accC);
    spmv_cheb_bf<<<N4, 256, 0, stream>>>(Bbf, T1, outF, outF, Abf, ix2, wv2, 2.f, 1.f);       // T4
    gemm_mfma_acc<<<dim3(8, 32), 256, 0, stream>>>(Abf, W2T + (size_t)4 * KP * KP, accC);
    spmv_cheb_bf<<<N4, 256, 0, stream>>>(Abf, outF, T1, T1, Bbf, ix2, wv2, 2.f, 1.f);         // T5
    gemm_mfma_final<<<dim3(8, 32), 256, 0, stream>>>(Bbf, W2T + (size_t)5 * KP * KP, accC, b2);

    hipMemsetAsync(Mb, 0, 6 * CC * 4, stream);
    matT6_partial<<<dim3(4, 32), 256, 0, stream>>>(accC, t2x, FDIM, Mb);
    fro_kernel<<<24, 256, 0, stream>>>(Mb, racc + 1);

    colmax_kernel<<<dim3(4, 64), 256, 0, stream>>>(accC, otm);

    // ---- reeb cheb conv (K=3) ----
    reeb_mm_kernel<<<dim3(4, NRB), 256, 0, stream>>>(Lr, vfr, nullptr, tr1, 1.f);
    reeb_mm_kernel<<<dim3(4, NRB), 256, 0, stream>>>(Lr, tr1, vfr, tr2, 2.f);
    reeb_conv_splitk<<<dim3(4, 120), 256, 0, stream>>>(vfr, tr1, tr2, Wr, rpre);
    reeb_max_kernel<<<4, 256, 0, stream>>>(rpre, br, rbm);

    // ---- FC head ----
    fc1_kernel<<<dim3(2, 8), 256, 0, stream>>>(rbm, otm, f1w, h1p);
    fc23_kernel<<<1, 512, 0, stream>>>(h1p, f1b, f2w, f2b, f3w, f3b, dout);
    finalize_kernel<<<1, 256, 0, stream>>>(racc, f1w, f1b, f2w, f2b, f3w, f3b, dout);
}

// Round 8
// 855.115 us; speedup vs baseline: 4.0696x; 1.1686x over previous
//
#include <hip/hip_runtime.h>
#include <math.h>

#define N4    4096
#define FDIM  6
#define CC    1000
#define KP    1024   // padded K for bf16 GEMMs
#define KNN   40
#define NRB   20
#define SSC   205

typedef __attribute__((ext_vector_type(8))) short bf16x8;
typedef __attribute__((ext_vector_type(4))) float f32x4;

__device__ __forceinline__ unsigned short f2bf(float f) {
    unsigned u = __float_as_uint(f);
    u = (u + 0x7fffu + ((u >> 16) & 1u)) >> 16;
    return (unsigned short)u;
}
__device__ __forceinline__ float bf2f(short s) {
    return __uint_as_float(((unsigned)(unsigned short)s) << 16);
}

// ---------------- graph build ----------------

__global__ __launch_bounds__(256) void sqx_kernel(const float* __restrict__ x,
                                                  float* __restrict__ sq1,
                                                  float* __restrict__ xhat) {
    int n = blockIdx.x * blockDim.x + threadIdx.x;
    if (n >= N4) return;
    float s = 0.f;
#pragma unroll
    for (int f = 0; f < FDIM; ++f) {
        float v = x[n * FDIM + f];
        s += v * v;
        xhat[n * 18 + f] = v;
    }
    sq1[n] = s;
}

__global__ __launch_bounds__(256) void gram1_kernel(const float* __restrict__ x,
                                                    const float* __restrict__ sq1,
                                                    float* __restrict__ S) {
    __shared__ float xn[FDIM];
    __shared__ float sn;
    int r = blockIdx.y;
    int m = blockIdx.x * 256 + threadIdx.x;
    if (threadIdx.x < FDIM) xn[threadIdx.x] = x[r * FDIM + threadIdx.x];
    if (threadIdx.x == FDIM) sn = sq1[r];
    __syncthreads();
    float d = 0.f;
#pragma unroll
    for (int f = 0; f < FDIM; ++f) d += xn[f] * x[m * FDIM + f];
    float e = sn + sq1[m] - 2.f * d;
    S[(size_t)r * N4 + m] = __expf(-e);
}

// radix-select top-40 per row (exact). Wave-0 shuffle suffix scan for bucket
// pick; histogram copies indexed by (t&7) so a wave's 64 lanes spread over 8
// copies (cuts same-bucket LDS-atomic serialization). ==T ties ascending.
__global__ __launch_bounds__(512) void topk_radix(const float* __restrict__ S,
                                                  int* __restrict__ idx, float* __restrict__ val,
                                                  float* __restrict__ rowsum) {
    __shared__ unsigned sv[N4];
    __shared__ int hist[8 * 256];
    __shared__ int sc[256];
    __shared__ float red[512];
    __shared__ unsigned s_pfx;
    __shared__ int s_need;
    __shared__ int s_cnt;
    int t = threadIdx.x;
    int lane = t & 63, w = t >> 6;
    int n = blockIdx.x;
    const float* row = S + (size_t)n * N4;
    for (int i = t; i < N4; i += 512) sv[i] = __float_as_uint(row[i]);
    if (t == 0) { s_pfx = 0u; s_need = KNN; s_cnt = 0; }
    __syncthreads();

    int* hw = &hist[(t & 7) * 256];   // lane-spread histogram copy
#pragma unroll
    for (int level = 24; level >= 0; level -= 8) {
        hist[t] = 0; hist[512 + t] = 0; hist[1024 + t] = 0; hist[1536 + t] = 0;
        __syncthreads();
        unsigned pfx = s_pfx;
        int need = s_need;
        for (int i = t; i < N4; i += 512) {
            unsigned u = sv[i];
            bool m = (level == 24) || ((u >> (level + 8)) == (pfx >> (level + 8)));
            if (m) atomicAdd(&hw[(u >> level) & 255], 1);
        }
        __syncthreads();
        if (t < 256) {
            int cnt = 0;
#pragma unroll
            for (int wq = 0; wq < 8; ++wq) cnt += hist[wq * 256 + t];
            sc[t] = cnt;
        }
        __syncthreads();
        if (w == 0) {   // wave 0: suffix scan over 256 buckets, 4/lane
            int c0 = sc[4 * lane + 0], c1 = sc[4 * lane + 1];
            int c2 = sc[4 * lane + 2], c3 = sc[4 * lane + 3];
            int s = c0 + c1 + c2 + c3;
            int suf = s;
#pragma unroll
            for (int off = 1; off < 64; off <<= 1) {
                int ov = __shfl_down(suf, off, 64);
                if (lane + off < 64) suf += ov;
            }
            int above = suf - s;
            int i3 = above + c3;
            int i2 = i3 + c2;
            int i1 = i2 + c1;
            int i0 = i1 + c0;
            if (i3 >= need && i3 - c3 < need) { s_need = need - (i3 - c3); s_pfx = pfx | ((unsigned)(4 * lane + 3) << level); }
            if (i2 >= need && i2 - c2 < need) { s_need = need - (i2 - c2); s_pfx = pfx | ((unsigned)(4 * lane + 2) << level); }
            if (i1 >= need && i1 - c1 < need) { s_need = need - (i1 - c1); s_pfx = pfx | ((unsigned)(4 * lane + 1) << level); }
            if (i0 >= need && i0 - c0 < need) { s_need = need - (i0 - c0); s_pfx = pfx | ((unsigned)(4 * lane + 0) << level); }
        }
        __syncthreads();
    }
    unsigned Tbits = s_pfx;
    float Tf = __uint_as_float(Tbits);
    int needEq = s_need;

    float psum = 0.f;
    for (int i = t; i < N4; i += 512) {
        unsigned u = sv[i];
        if (u > Tbits) {
            int p = atomicAdd(&s_cnt, 1);
            idx[(size_t)n * KNN + p] = i;
            float v = __uint_as_float(u);
            val[(size_t)n * KNN + p] = v;
            psum += v;
        }
    }
    red[t] = psum;
    __syncthreads();
    for (int o = 256; o; o >>= 1) { if (t < o) red[t] += red[t + o]; __syncthreads(); }
    if (t == 0) rowsum[n] = red[0] + (float)needEq * Tf;

    if (t < 64) {
        int filled = KNN - needEq;
        for (int ib = 0; ib < N4 && filled < KNN; ib += 64) {
            bool eq = (sv[ib + t] == Tbits);
            unsigned long long m = __ballot(eq);
            int pre = __popcll(m & ((1ull << t) - 1ull));
            if (eq && (filled + pre) < KNN) {
                idx[(size_t)n * KNN + filled + pre] = ib + t;
                val[(size_t)n * KNN + filled + pre] = Tf;
            }
            filled += __popcll(m);
        }
    }
}

__global__ __launch_bounds__(256) void dinv_kernel(float* __restrict__ rs) {
    int n = blockIdx.x * 256 + threadIdx.x;
    if (n < N4) rs[n] = rsqrtf(rs[n]);
}

__global__ __launch_bounds__(256) void wnorm_kernel(float* __restrict__ wv,
                                                    const int* __restrict__ idx,
                                                    const float* __restrict__ dinv) {
    int i = blockIdx.x * 256 + threadIdx.x;
    if (i >= N4 * KNN) return;
    int n = i / KNN;
    wv[i] = wv[i] * dinv[n] * dinv[idx[i]];
}

// Tn[n,:] = a*(Tc[n,:] - sum_j wv[n,j]*Tc[idx[n,j],:]) - b*Tp[n,:]   (F small)
__global__ __launch_bounds__(64) void spmv_cheb(const float* __restrict__ Tc,
                                                const float* __restrict__ Tp,
                                                float* __restrict__ Tn,
                                                const int* __restrict__ idx,
                                                const float* __restrict__ wv,
                                                int F, int sC, int sP, int sN,
                                                float a, float b) {
    __shared__ int   si[KNN];
    __shared__ float sw[KNN];
    int n = blockIdx.x;
    if (threadIdx.x < KNN) {
        si[threadIdx.x] = idx[(size_t)n * KNN + threadIdx.x];
        sw[threadIdx.x] = wv[(size_t)n * KNN + threadIdx.x];
    }
    __syncthreads();
    for (int c = threadIdx.x; c < F; c += blockDim.x) {
        float s = 0.f;
#pragma unroll 8
        for (int j = 0; j < KNN; ++j) s += sw[j] * Tc[(size_t)si[j] * sC + c];
        float v = a * (Tc[(size_t)n * sC + c] - s);
        if (b != 0.f) v -= b * Tp[(size_t)n * sP + c];
        Tn[(size_t)n * sN + c] = v;
    }
}

// CC-wide: 256 threads, two half-blocks each gather 20 of 40 neighbors from
// the bf16 mirror; merge via LDS; fused fp32+bf16 write.
__global__ __launch_bounds__(256) void spmv_cheb_bf(const unsigned short* __restrict__ Tcbf,
                                                    const float* __restrict__ Tc,
                                                    const float* __restrict__ Tp,
                                                    float* __restrict__ Tn,
                                                    unsigned short* __restrict__ Tnbf,
                                                    const int* __restrict__ idx,
                                                    const float* __restrict__ wv,
                                                    float a, float b) {
    __shared__ int   si[KNN];
    __shared__ float sw[KNN];
    __shared__ float part[128][8];
    int n = blockIdx.x;
    int t = threadIdx.x;
    int tt = t & 127, h = t >> 7;
    if (t < KNN) {
        si[t] = idx[(size_t)n * KNN + t];
        sw[t] = wv[(size_t)n * KNN + t];
    }
    __syncthreads();
    int c = tt * 8;
    float acc0 = 0, acc1 = 0, acc2 = 0, acc3 = 0, acc4 = 0, acc5 = 0, acc6 = 0, acc7 = 0;
    int j0 = h * 20;
#pragma unroll 4
    for (int j = j0; j < j0 + 20; ++j) {
        bf16x8 v = *(const bf16x8*)(Tcbf + (size_t)si[j] * KP + c);
        float wj = sw[j];
        acc0 += wj * bf2f(v[0]); acc1 += wj * bf2f(v[1]);
        acc2 += wj * bf2f(v[2]); acc3 += wj * bf2f(v[3]);
        acc4 += wj * bf2f(v[4]); acc5 += wj * bf2f(v[5]);
        acc6 += wj * bf2f(v[6]); acc7 += wj * bf2f(v[7]);
    }
    if (h == 1) {
        part[tt][0] = acc0; part[tt][1] = acc1; part[tt][2] = acc2; part[tt][3] = acc3;
        part[tt][4] = acc4; part[tt][5] = acc5; part[tt][6] = acc6; part[tt][7] = acc7;
    }
    __syncthreads();
    if (h == 0) {
        acc0 += part[tt][0]; acc1 += part[tt][1]; acc2 += part[tt][2]; acc3 += part[tt][3];
        acc4 += part[tt][4]; acc5 += part[tt][5]; acc6 += part[tt][6]; acc7 += part[tt][7];
        bf16x8 ob;
        if (tt < 125) {
            float4 tc0 = *(const float4*)(Tc + (size_t)n * CC + c);
            float4 tc1 = *(const float4*)(Tc + (size_t)n * CC + c + 4);
            float o0 = a * (tc0.x - acc0), o1 = a * (tc0.y - acc1);
            float o2 = a * (tc0.z - acc2), o3 = a * (tc0.w - acc3);
            float o4 = a * (tc1.x - acc4), o5 = a * (tc1.y - acc5);
            float o6 = a * (tc1.z - acc6), o7 = a * (tc1.w - acc7);
            if (b != 0.f) {
                float4 tp0 = *(const float4*)(Tp + (size_t)n * CC + c);
                float4 tp1 = *(const float4*)(Tp + (size_t)n * CC + c + 4);
                o0 -= b * tp0.x; o1 -= b * tp0.y; o2 -= b * tp0.z; o3 -= b * tp0.w;
                o4 -= b * tp1.x; o5 -= b * tp1.y; o6 -= b * tp1.z; o7 -= b * tp1.w;
            }
            *(float4*)(Tn + (size_t)n * CC + c) = make_float4(o0, o1, o2, o3);
            *(float4*)(Tn + (size_t)n * CC + c + 4) = make_float4(o4, o5, o6, o7);
            ob[0] = (short)f2bf(o0); ob[1] = (short)f2bf(o1);
            ob[2] = (short)f2bf(o2); ob[3] = (short)f2bf(o3);
            ob[4] = (short)f2bf(o4); ob[5] = (short)f2bf(o5);
            ob[6] = (short)f2bf(o6); ob[7] = (short)f2bf(o7);
        } else {
#pragma unroll
            for (int q = 0; q < 8; ++q) ob[q] = 0;
        }
        *(bf16x8*)(Tnbf + (size_t)n * KP + c) = ob;
    }
}

// ---------------- bf16 conversion / transpose ----------------

__global__ __launch_bounds__(256) void cvt_bf16_kernel(const float* __restrict__ in,
                                                       unsigned short* __restrict__ out) {
    int i = blockIdx.x * 256 + threadIdx.x;     // N4*128 total
    int r = i >> 7, g = i & 127;
    bf16x8 v;
    if (g < 125) {
        float4 a = *(const float4*)(in + (size_t)r * CC + g * 8);
        float4 b = *(const float4*)(in + (size_t)r * CC + g * 8 + 4);
        v[0] = (short)f2bf(a.x); v[1] = (short)f2bf(a.y);
        v[2] = (short)f2bf(a.z); v[3] = (short)f2bf(a.w);
        v[4] = (short)f2bf(b.x); v[5] = (short)f2bf(b.y);
        v[6] = (short)f2bf(b.z); v[7] = (short)f2bf(b.w);
    } else {
#pragma unroll
        for (int q = 0; q < 8; ++q) v[q] = 0;
    }
    *(bf16x8*)(out + (size_t)r * KP + g * 8) = v;
}

// W2 [6*CC x CC] fp32 -> W2T [6][KP(n) x KP(k)] bf16
__global__ __launch_bounds__(256) void w2t_kernel(const float* __restrict__ W2,
                                                  unsigned short* __restrict__ out) {
    __shared__ unsigned short tile[64][65];
    int t = threadIdx.x;
    int k0 = blockIdx.x * 64, n0 = blockIdx.y * 64, s = blockIdx.z;
#pragma unroll
    for (int p = 0; p < 16; ++p) {
        int i = p * 256 + t;
        int kk = i >> 6, nn = i & 63;
        int k = k0 + kk, n = n0 + nn;
        float v = (k < CC && n < CC) ? W2[((size_t)s * CC + k) * CC + n] : 0.f;
        tile[kk][nn] = f2bf(v);
    }
    __syncthreads();
#pragma unroll
    for (int p = 0; p < 16; ++p) {
        int i = p * 256 + t;
        int nn = i >> 6, kk = i & 63;
        out[((size_t)s * KP + n0 + nn) * KP + k0 + kk] = tile[kk][nn];
    }
}

// ---------------- MFMA GEMMs (128x128 tile, BK=32, bf16 in / fp32 acc) ----------------

#define LDP 40

__device__ __forceinline__ void gemm_core(const unsigned short* __restrict__ Ag,
                                          const unsigned short* __restrict__ Bg,
                                          short* As, short* Bs, int t,
                                          f32x4 (&acc)[4][4]) {
    int l = t & 63, w = t >> 6;
    int wm = (w >> 1) * 64, wn = (w & 1) * 64;
    int ar0 = t >> 2, ak0 = (t & 3) * 8;
    int ar1 = (t + 256) >> 2, ak1 = ((t + 256) & 3) * 8;
    int lr = l & 15, lq8 = (l >> 4) * 8;
    for (int k0 = 0; k0 < KP; k0 += 32) {
        bf16x8 a0 = *(const bf16x8*)(Ag + (size_t)ar0 * KP + k0 + ak0);
        bf16x8 a1 = *(const bf16x8*)(Ag + (size_t)ar1 * KP + k0 + ak1);
        bf16x8 b0 = *(const bf16x8*)(Bg + (size_t)ar0 * KP + k0 + ak0);
        bf16x8 b1 = *(const bf16x8*)(Bg + (size_t)ar1 * KP + k0 + ak1);
        __syncthreads();
        *(bf16x8*)&As[ar0 * LDP + ak0] = a0;
        *(bf16x8*)&As[ar1 * LDP + ak1] = a1;
        *(bf16x8*)&Bs[ar0 * LDP + ak0] = b0;
        *(bf16x8*)&Bs[ar1 * LDP + ak1] = b1;
        __syncthreads();
        bf16x8 af[4], bfr[4];
#pragma unroll
        for (int mi = 0; mi < 4; ++mi)
            af[mi] = *(const bf16x8*)&As[(wm + mi * 16 + lr) * LDP + lq8];
#pragma unroll
        for (int ni = 0; ni < 4; ++ni)
            bfr[ni] = *(const bf16x8*)&Bs[(wn + ni * 16 + lr) * LDP + lq8];
#pragma unroll
        for (int mi = 0; mi < 4; ++mi)
#pragma unroll
            for (int ni = 0; ni < 4; ++ni)
                acc[mi][ni] = __builtin_amdgcn_mfma_f32_16x16x32_bf16(af[mi], bfr[ni], acc[mi][ni], 0, 0, 0);
    }
}

__global__ __launch_bounds__(256) void gemm_mfma_acc(const unsigned short* __restrict__ A,
                                                     const unsigned short* __restrict__ B,
                                                     float* __restrict__ C) {
    __shared__ short As[128 * LDP];
    __shared__ short Bs[128 * LDP];
    int t = threadIdx.x;
    int n0 = blockIdx.x * 128, m0 = blockIdx.y * 128;
    f32x4 acc[4][4] = {};
    gemm_core(A + (size_t)m0 * KP, B + (size_t)n0 * KP, As, Bs, t, acc);
    int l = t & 63, w = t >> 6;
    int wm = (w >> 1) * 64, wn = (w & 1) * 64;
    int lr = l & 15, lq4 = (l >> 4) * 4;
#pragma unroll
    for (int ni = 0; ni < 4; ++ni) {
        int n = n0 + wn + ni * 16 + lr;
        if (n >= CC) continue;
#pragma unroll
        for (int mi = 0; mi < 4; ++mi) {
            int m = m0 + wm + mi * 16 + lq4;
            f32x4 v = acc[mi][ni];
#pragma unroll
            for (int r = 0; r < 4; ++r) C[(size_t)(m + r) * CC + n] += v[r];
        }
    }
}

__global__ __launch_bounds__(256) void gemm_mfma_final(const unsigned short* __restrict__ A,
                                                       const unsigned short* __restrict__ B,
                                                       float* __restrict__ C,
                                                       const float* __restrict__ b2) {
    __shared__ short As[128 * LDP];
    __shared__ short Bs[128 * LDP];
    int t = threadIdx.x;
    int n0 = blockIdx.x * 128, m0 = blockIdx.y * 128;
    f32x4 acc[4][4] = {};
    gemm_core(A + (size_t)m0 * KP, B + (size_t)n0 * KP, As, Bs, t, acc);
    int l = t & 63, w = t >> 6;
    int wm = (w >> 1) * 64, wn = (w & 1) * 64;
    int lr = l & 15, lq4 = (l >> 4) * 4;
#pragma unroll
    for (int ni = 0; ni < 4; ++ni) {
        int n = n0 + wn + ni * 16 + lr;
        if (n >= CC) continue;
        float bb = b2[n];
#pragma unroll
        for (int mi = 0; mi < 4; ++mi) {
            int m = m0 + wm + mi * 16 + lq4;
            f32x4 v = acc[mi][ni];
#pragma unroll
            for (int r = 0; r < 4; ++r) {
                float* p = &C[(size_t)(m + r) * CC + n];
                *p = fmaxf(*p + v[r] + bb, 0.f);
            }
        }
    }
}

__global__ __launch_bounds__(256) void gram2_mfma(const unsigned short* __restrict__ Abf,
                                                  const float* __restrict__ sq2,
                                                  float* __restrict__ S) {
    __shared__ short As[128 * LDP];
    __shared__ short Bs[128 * LDP];
    int t = threadIdx.x;
    int n0 = blockIdx.x * 128, m0 = blockIdx.y * 128;
    f32x4 acc[4][4] = {};
    gemm_core(Abf + (size_t)m0 * KP, Abf + (size_t)n0 * KP, As, Bs, t, acc);
    int l = t & 63, w = t >> 6;
    int wm = (w >> 1) * 64, wn = (w & 1) * 64;
    int lr = l & 15, lq4 = (l >> 4) * 4;
#pragma unroll
    for (int ni = 0; ni < 4; ++ni) {
        int n = n0 + wn + ni * 16 + lr;
        float sn = sq2[n];
#pragma unroll
        for (int mi = 0; mi < 4; ++mi) {
            int mrow = m0 + wm + mi * 16 + lq4;
            f32x4 v = acc[mi][ni];
#pragma unroll
            for (int r = 0; r < 4; ++r) {
                float d = sq2[mrow + r] + sn - 2.f * v[r];
                S[(size_t)(mrow + r) * N4 + n] = __expf(-d);
            }
        }
    }
}

// ---------------- cheb conv 1 ----------------

__global__ __launch_bounds__(256) void cheb1_out_kernel(const float* __restrict__ xhat,
                                                        const float* __restrict__ W1,
                                                        const float* __restrict__ b1,
                                                        float* __restrict__ outF) {
    __shared__ float xh[16][18];
    int n0 = blockIdx.x * 16;
    int tid = threadIdx.x;
    for (int i = tid; i < 16 * 18; i += 256) xh[i / 18][i % 18] = xhat[(size_t)n0 * 18 + i];
    __syncthreads();
    for (int c0 = 0; c0 < CC; c0 += 256) {
        int c = c0 + tid;
        if (c < CC) {
            float acc[16];
#pragma unroll
            for (int r = 0; r < 16; ++r) acc[r] = 0.f;
            for (int f = 0; f < 18; ++f) {
                float wv = W1[(size_t)f * CC + c];
#pragma unroll
                for (int r = 0; r < 16; ++r) acc[r] += xh[r][f] * wv;
            }
            float bb = b1[c];
#pragma unroll
            for (int r = 0; r < 16; ++r)
                outF[(size_t)(n0 + r) * CC + c] = fmaxf(acc[r] + bb, 0.f);
        }
    }
}

// ---------------- regs (frobenius of O^T @ T) ----------------

__global__ __launch_bounds__(256) void matT6_partial(const float* __restrict__ O,
                                                     const float* __restrict__ T, int ts,
                                                     float* __restrict__ M) {
    __shared__ float sT[128][6];
    int t = threadIdx.x;
    int c = blockIdx.x * 256 + t;
    int n0 = blockIdx.y * 128;
    for (int i = t; i < 128 * 6; i += 256) {
        int nn = i / 6, f = i % 6;
        sT[nn][f] = T[(size_t)(n0 + nn) * ts + f];
    }
    __syncthreads();
    if (c >= CC) return;
    float a0 = 0, a1 = 0, a2 = 0, a3 = 0, a4 = 0, a5 = 0;
    for (int nn = 0; nn < 128; ++nn) {
        float o = O[(size_t)(n0 + nn) * CC + c];
        a0 += o * sT[nn][0]; a1 += o * sT[nn][1]; a2 += o * sT[nn][2];
        a3 += o * sT[nn][3]; a4 += o * sT[nn][4]; a5 += o * sT[nn][5];
    }
    atomicAdd(&M[0 * CC + c], a0);
    atomicAdd(&M[1 * CC + c], a1);
    atomicAdd(&M[2 * CC + c], a2);
    atomicAdd(&M[3 * CC + c], a3);
    atomicAdd(&M[4 * CC + c], a4);
    atomicAdd(&M[5 * CC + c], a5);
}

__global__ __launch_bounds__(256) void fro_kernel(const float* __restrict__ M, float* __restrict__ dst) {
    __shared__ float red[256];
    int t = threadIdx.x;
    int i = blockIdx.x * 256 + t;
    float v = (i < 6 * CC) ? M[i] : 0.f;
    red[t] = v * v;
    __syncthreads();
    for (int o = 128; o; o >>= 1) { if (t < o) red[t] += red[t + o]; __syncthreads(); }
    if (t == 0) atomicAdd(dst, red[0]);
}

// ---------------- pooling ----------------

__global__ __launch_bounds__(256) void vfr_kernel(const float* __restrict__ outF,
                                                  const int* __restrict__ sccs,
                                                  float* __restrict__ vfr) {
    int r = blockIdx.y;
    int c = blockIdx.x * 256 + threadIdx.x;
    if (c >= CC) return;
    int s0 = blockIdx.z * 41;
    float m = 0.f;
    for (int s = s0; s < s0 + 41; ++s) {
        int n = sccs[r * SSC + s];
        m = fmaxf(m, outF[(size_t)n * CC + c]);
    }
    atomicMax((int*)&vfr[(size_t)r * CC + c], __float_as_int(m));
}

__global__ __launch_bounds__(256) void sq2_kernel(const float* __restrict__ outF,
                                                  float* __restrict__ sq2) {
    int lane = threadIdx.x & 63, w = threadIdx.x >> 6;
    int n = blockIdx.x * 4 + w;
    const float* row = outF + (size_t)n * CC;
    float s = 0.f;
    for (int i = lane; i < CC; i += 64) { float v = row[i]; s += v * v; }
#pragma unroll
    for (int o = 32; o; o >>= 1) s += __shfl_down(s, o);
    if (lane == 0) sq2[n] = s;
}

// row-split column max; dst must be zeroed (values >= 0)
__global__ __launch_bounds__(256) void colmax_kernel(const float* __restrict__ O,
                                                     float* __restrict__ dst) {
    int c = blockIdx.x * 256 + threadIdx.x;
    if (c >= CC) return;
    int n0 = blockIdx.y * 64;
    float m = 0.f;
    for (int n = n0; n < n0 + 64; ++n) m = fmaxf(m, O[(size_t)n * CC + c]);
    atomicMax((int*)&dst[c], __float_as_int(m));
}

// ---------------- reeb branch ----------------

__global__ __launch_bounds__(256) void reeb_mm_kernel(const float* __restrict__ Lr,
                                                      const float* __restrict__ Vin,
                                                      const float* __restrict__ Vsub,
                                                      float* __restrict__ Vout, float a2) {
    int c = blockIdx.x * 256 + threadIdx.x;
    if (c >= CC) return;
    int r = blockIdx.y;
    float s = 0.f;
#pragma unroll
    for (int j = 0; j < NRB; ++j) s += Lr[r * NRB + j] * Vin[(size_t)j * CC + c];
    float v = a2 * s;
    if (Vsub) v -= Vsub[(size_t)r * CC + c];
    Vout[(size_t)r * CC + c] = v;
}

#define RKC 25
__global__ __launch_bounds__(256) void reeb_conv_splitk(const float* __restrict__ vfr,
                                                        const float* __restrict__ tr1,
                                                        const float* __restrict__ tr2,
                                                        const float* __restrict__ Wr,
                                                        float* __restrict__ rpre) {
    __shared__ float sA[NRB][RKC];
    int t = threadIdx.x;
    int kbase = blockIdx.y * RKC;
    for (int i = t; i < NRB * RKC; i += 256) {
        int r = i / RKC, kk = i % RKC;
        int kg = kbase + kk;
        float v;
        if (kg < CC)           v = vfr[(size_t)r * CC + kg];
        else if (kg < 2 * CC)  v = tr1[(size_t)r * CC + kg - CC];
        else                   v = tr2[(size_t)r * CC + kg - 2 * CC];
        sA[r][kk] = v;
    }
    __syncthreads();
    int c = blockIdx.x * 256 + t;
    if (c >= CC) return;
    float acc[NRB];
#pragma unroll
    for (int r = 0; r < NRB; ++r) acc[r] = 0.f;
    for (int kk = 0; kk < RKC; ++kk) {
        float wv = Wr[(size_t)(kbase + kk) * CC + c];
#pragma unroll
        for (int r = 0; r < NRB; ++r) acc[r] += sA[r][kk] * wv;
    }
#pragma unroll
    for (int r = 0; r < NRB; ++r) atomicAdd(&rpre[(size_t)r * CC + c], acc[r]);
}

__global__ __launch_bounds__(256) void reeb_max_kernel(const float* __restrict__ pre,
                                                       const float* __restrict__ br,
                                                       float* __restrict__ rbm) {
    int c = blockIdx.x * 256 + threadIdx.x;
    if (c >= CC) return;
    float bb = br[c];
    float m = 0.f;
    for (int r = 0; r < NRB; ++r) m = fmaxf(m, fmaxf(pre[(size_t)r * CC + c] + bb, 0.f));
    rbm[c] = m;
}

// ---------------- FC head ----------------

__global__ __launch_bounds__(256) void fc1_kernel(const float* __restrict__ rbm,
                                                  const float* __restrict__ otm,
                                                  const float* __restrict__ w,
                                                  float* __restrict__ h1pre) {
    int j = blockIdx.x * 256 + threadIdx.x;
    if (j >= 512) return;
    int i0 = blockIdx.y * 250;
    float s = 0.f;
    for (int i = i0; i < i0 + 250; ++i) {
        float v = (i < CC) ? rbm[i] : otm[i - CC];
        s += v * w[(size_t)i * 512 + j];
    }
    atomicAdd(&h1pre[j], s);
}

__global__ __launch_bounds__(512) void fc23_kernel(const float* __restrict__ h1pre,
                                                   const float* __restrict__ b1f,
                                                   const float* __restrict__ w2,
                                                   const float* __restrict__ b2f,
                                                   const float* __restrict__ w3,
                                                   const float* __restrict__ b3f,
                                                   float* __restrict__ dout) {
    __shared__ float h1[512];
    __shared__ float h2[128];
    int t = threadIdx.x;
    h1[t] = fmaxf(h1pre[t] + b1f[t], 0.f);
    __syncthreads();
    if (t < 128) {
        float s = b2f[t];
        for (int i = 0; i < 512; ++i) s += h1[i] * w2[(size_t)i * 128 + t];
        h2[t] = fmaxf(s, 0.f);
    }
    __syncthreads();
    if (t < 40) {
        float s = b3f[t];
        for (int i = 0; i < 128; ++i) s += h2[i] * w3[(size_t)i * 40 + t];
        dout[t] = s;
    }
}

__global__ __launch_bounds__(256) void finalize_kernel(const float* __restrict__ racc,
                                                       const float* __restrict__ f1w,
                                                       const float* __restrict__ f1b,
                                                       const float* __restrict__ f2w,
                                                       const float* __restrict__ f2b,
                                                       const float* __restrict__ f3w,
                                                       const float* __restrict__ f3b,
                                                       float* __restrict__ dout) {
    __shared__ float red[256];
    __shared__ float res[3];
    int t = threadIdx.x;
    float s1 = 0.f, s2 = 0.f, s3 = 0.f;
    for (int i = t; i < 2000; i += 256) { float v = f1w[(size_t)i * 512]; s1 += v * v; }
    for (int i = t; i < 512; i += 256) { float v = f2w[(size_t)i * 128]; s2 += v * v; }
    if (t < 128) { float v = f3w[(size_t)t * 40]; s3 = v * v; }

    red[t] = s1; __syncthreads();
    for (int o = 128; o; o >>= 1) { if (t < o) red[t] += red[t + o]; __syncthreads(); }
    if (t == 0) res[0] = red[0];
    __syncthreads();
    red[t] = s2; __syncthreads();
    for (int o = 128; o; o >>= 1) { if (t < o) red[t] += red[t + o]; __syncthreads(); }
    if (t == 0) res[1] = red[0];
    __syncthreads();
    red[t] = s3; __syncthreads();
    for (int o = 128; o; o >>= 1) { if (t < o) red[t] += red[t + o]; __syncthreads(); }
    if (t == 0) res[2] = red[0];
    __syncthreads();

    if (t == 0) {
        dout[40] = sqrtf(racc[0]);
        dout[41] = sqrtf(racc[1]);
        dout[42] = res[0];
        dout[43] = f1b[0] * f1b[0];
        dout[44] = res[1];
        dout[45] = f2b[0] * f2b[0];
        dout[46] = res[2];
        dout[47] = f3b[0] * f3b[0];
    }
}

// ---------------- host ----------------

extern "C" void kernel_launch(void* const* d_in, const int* in_sizes, int n_in,
                              void* d_out, int out_size, void* d_ws, size_t ws_size,
                              hipStream_t stream) {
    const float* x    = (const float*)d_in[0];
    const float* Lr   = (const float*)d_in[5];
    const int*   sccs = (const int*)d_in[6];
    const float* W1   = (const float*)d_in[7];
    const float* b1   = (const float*)d_in[8];
    const float* W2   = (const float*)d_in[9];
    const float* b2   = (const float*)d_in[10];
    const float* Wr   = (const float*)d_in[11];
    const float* br   = (const float*)d_in[12];
    const float* f1w  = (const float*)d_in[13];
    const float* f1b  = (const float*)d_in[14];
    const float* f2w  = (const float*)d_in[15];
    const float* f2b  = (const float*)d_in[16];
    const float* f3w  = (const float*)d_in[17];
    const float* f3b  = (const float*)d_in[18];
    float* dout = (float*)d_out;

    char* ws = (char*)d_ws;
    size_t off = 0;
    auto alloc = [&](size_t bytes) -> char* {
        char* p = ws + off;
        off = (off + bytes + 255) & ~(size_t)255;
        return p;
    };
    float* outF = (float*)alloc((size_t)N4 * CC * 4);
    float* T1   = (float*)alloc((size_t)N4 * CC * 4);
    float* accC = (float*)alloc((size_t)N4 * CC * 4);
    float* Sb   = (float*)alloc((size_t)N4 * N4 * 4);   // full 4096x4096 similarity
    unsigned short* Abf = (unsigned short*)alloc((size_t)N4 * KP * 2);
    unsigned short* Bbf = (unsigned short*)alloc((size_t)N4 * KP * 2);
    unsigned short* W2T = (unsigned short*)Sb;  // alias: Sb dead after last topk
    float* xhat = (float*)alloc((size_t)N4 * 18 * 4);
    float* sq1  = (float*)alloc(N4 * 4);
    float* sq2  = (float*)alloc(N4 * 4);
    float* di1  = (float*)alloc(N4 * 4);
    float* di2  = (float*)alloc(N4 * 4);
    float* wv1  = (float*)alloc((size_t)N4 * KNN * 4);
    float* wv2  = (float*)alloc((size_t)N4 * KNN * 4);
    int*   ix1  = (int*)alloc((size_t)N4 * KNN * 4);
    int*   ix2  = (int*)alloc((size_t)N4 * KNN * 4);
    float* t2x  = (float*)alloc((size_t)N4 * FDIM * 4);
    float* tr1  = (float*)alloc((size_t)NRB * CC * 4);
    float* tr2  = (float*)alloc((size_t)NRB * CC * 4);
    // zero-zone: one memset covers [Mb, Mb2, rbm, otm, h1p, racc, rpre, vfr]
    char*  zbase = ws + off;
    float* Mb   = (float*)alloc(6 * CC * 4);
    float* Mb2  = (float*)alloc(6 * CC * 4);
    float* rbm  = (float*)alloc(CC * 4);
    float* otm  = (float*)alloc(CC * 4);
    float* h1p  = (float*)alloc(512 * 4);
    float* racc = (float*)alloc(64 * 4);
    float* rpre = (float*)alloc((size_t)NRB * CC * 4);
    float* vfr  = (float*)alloc((size_t)NRB * CC * 4);
    size_t zlen = (size_t)((ws + off) - zbase);
    if (off > ws_size) return;

    hipMemsetAsync(accC, 0, (size_t)N4 * CC * 4, stream);
    hipMemsetAsync(zbase, 0, zlen, stream);

    // ---- graph 1 (on x) ----
    sqx_kernel<<<(N4 + 255) / 256, 256, 0, stream>>>(x, sq1, xhat);
    gram1_kernel<<<dim3(N4 / 256, N4), 256, 0, stream>>>(x, sq1, Sb);
    topk_radix<<<N4, 512, 0, stream>>>(Sb, ix1, wv1, di1);
    dinv_kernel<<<N4 / 256, 256, 0, stream>>>(di1);
    wnorm_kernel<<<(N4 * KNN + 255) / 256, 256, 0, stream>>>(wv1, ix1, di1);

    // ---- cheb conv 1 ----
    spmv_cheb<<<N4, 64, 0, stream>>>(xhat, xhat, xhat + 6, ix1, wv1, FDIM, 18, 18, 18, 1.f, 0.f);
    spmv_cheb<<<N4, 64, 0, stream>>>(xhat + 6, xhat, xhat + 12, ix1, wv1, FDIM, 18, 18, 18, 2.f, 1.f);
    cheb1_out_kernel<<<N4 / 16, 256, 0, stream>>>(xhat, W1, b1, outF);

    matT6_partial<<<dim3(4, 32), 256, 0, stream>>>(outF, xhat + 6, 18, Mb);
    fro_kernel<<<24, 256, 0, stream>>>(Mb, racc + 0);

    vfr_kernel<<<dim3(4, NRB, 5), 256, 0, stream>>>(outF, sccs, vfr);

    // ---- graph 2 (on outF), bf16 MFMA gram ----
    sq2_kernel<<<N4 / 4, 256, 0, stream>>>(outF, sq2);
    cvt_bf16_kernel<<<N4 * 128 / 256, 256, 0, stream>>>(outF, Abf);
    gram2_mfma<<<dim3(N4 / 128, N4 / 128), 256, 0, stream>>>(Abf, sq2, Sb);
    topk_radix<<<N4, 512, 0, stream>>>(Sb, ix2, wv2, di2);
    dinv_kernel<<<N4 / 256, 256, 0, stream>>>(di2);
    wnorm_kernel<<<(N4 * KNN + 255) / 256, 256, 0, stream>>>(wv2, ix2, di2);

    // Sb dead -> build W2T in its space
    w2t_kernel<<<dim3(16, 16, 6), 256, 0, stream>>>(W2, W2T);

    spmv_cheb<<<N4, 64, 0, stream>>>(x, x, t2x, ix2, wv2, FDIM, FDIM, FDIM, FDIM, 1.f, 0.f);

    // ---- cheb conv 2 (K=6): T0=outF/Abf, gathers from bf16 mirror, fused cvt ----
    gemm_mfma_acc<<<dim3(8, 32), 256, 0, stream>>>(Abf, W2T + (size_t)0 * KP * KP, accC);
    spmv_cheb_bf<<<N4, 256, 0, stream>>>(Abf, outF, outF, T1, Bbf, ix2, wv2, 1.f, 0.f);       // T1
    gemm_mfma_acc<<<dim3(8, 32), 256, 0, stream>>>(Bbf, W2T + (size_t)1 * KP * KP, accC);
    spmv_cheb_bf<<<N4, 256, 0, stream>>>(Bbf, T1, outF, outF, Abf, ix2, wv2, 2.f, 1.f);       // T2
    gemm_mfma_acc<<<dim3(8, 32), 256, 0, stream>>>(Abf, W2T + (size_t)2 * KP * KP, accC);
    spmv_cheb_bf<<<N4, 256, 0, stream>>>(Abf, outF, T1, T1, Bbf, ix2, wv2, 2.f, 1.f);         // T3
    gemm_mfma_acc<<<dim3(8, 32), 256, 0, stream>>>(Bbf, W2T + (size_t)3 * KP * KP, accC);
    spmv_cheb_bf<<<N4, 256, 0, stream>>>(Bbf, T1, outF, outF, Abf, ix2, wv2, 2.f, 1.f);       // T4
    gemm_mfma_acc<<<dim3(8, 32), 256, 0, stream>>>(Abf, W2T + (size_t)4 * KP * KP, accC);
    spmv_cheb_bf<<<N4, 256, 0, stream>>>(Abf, outF, T1, T1, Bbf, ix2, wv2, 2.f, 1.f);         // T5
    gemm_mfma_final<<<dim3(8, 32), 256, 0, stream>>>(Bbf, W2T + (size_t)5 * KP * KP, accC, b2);

    matT6_partial<<<dim3(4, 32), 256, 0, stream>>>(accC, t2x, FDIM, Mb2);
    fro_kernel<<<24, 256, 0, stream>>>(Mb2, racc + 1);

    colmax_kernel<<<dim3(4, 64), 256, 0, stream>>>(accC, otm);

    // ---- reeb cheb conv (K=3) ----
    reeb_mm_kernel<<<dim3(4, NRB), 256, 0, stream>>>(Lr, vfr, nullptr, tr1, 1.f);
    reeb_mm_kernel<<<dim3(4, NRB), 256, 0, stream>>>(Lr, tr1, vfr, tr2, 2.f);
    reeb_conv_splitk<<<dim3(4, 120), 256, 0, stream>>>(vfr, tr1, tr2, Wr, rpre);
    reeb_max_kernel<<<4, 256, 0, stream>>>(rpre, br, rbm);

    // ---- FC head ----
    fc1_kernel<<<dim3(2, 8), 256, 0, stream>>>(rbm, otm, f1w, h1p);
    fc23_kernel<<<1, 512, 0, stream>>>(h1p, f1b, f2w, f2b, f3w, f3b, dout);
    finalize_kernel<<<1, 256, 0, stream>>>(racc, f1w, f1b, f2w, f2b, f3w, f3b, dout);
}

// Round 9
// 844.675 us; speedup vs baseline: 4.1199x; 1.0124x over previous
//
#include <hip/hip_runtime.h>
#include <math.h>

#define N4    4096
#define FDIM  6
#define CC    1000
#define KP    1024   // padded K for bf16 GEMMs
#define KNN   40
#define NRB   20
#define SSC   205

typedef __attribute__((ext_vector_type(8))) short bf16x8;
typedef __attribute__((ext_vector_type(4))) float f32x4;

__device__ __forceinline__ unsigned short f2bf(float f) {
    unsigned u = __float_as_uint(f);
    u = (u + 0x7fffu + ((u >> 16) & 1u)) >> 16;
    return (unsigned short)u;
}
__device__ __forceinline__ float bf2f(short s) {
    return __uint_as_float(((unsigned)(unsigned short)s) << 16);
}

// ---------------- graph build ----------------

__global__ __launch_bounds__(256) void sqx_kernel(const float* __restrict__ x,
                                                  float* __restrict__ sq1,
                                                  float* __restrict__ xhat) {
    int n = blockIdx.x * blockDim.x + threadIdx.x;
    if (n >= N4) return;
    float s = 0.f;
#pragma unroll
    for (int f = 0; f < FDIM; ++f) {
        float v = x[n * FDIM + f];
        s += v * v;
        xhat[n * 18 + f] = v;
    }
    sq1[n] = s;
}

// ---------------- radix top-40 (exact, with candidate compaction) ----------------
// float >= 0 -> uint order == float order. After the level-24 pass, elements
// with top byte > b1 are provably in the top-40 (emitted directly); ==b1
// candidates are compacted to a ushort index list so levels 16/8/0 and the
// >T collect scan only the (typically tiny) list. ==T ties taken in
// ascending index order (matches lax.top_k).

#define NHC 8
#define HSTRIDE 257   // 257 % 32 == 1: copy c bucket b -> bank (c+b)%32, de-aliased

struct TopkSh {
    unsigned sv[N4];
    int hist[NHC * HSTRIDE];
    int sc[256];
    float red[512];
    unsigned short cidx[N4];
    unsigned s_pfx;
    int s_need, s_cnt, s_m;
};

__device__ __forceinline__ void hist_pick(TopkSh& sh, int level, int t, int lane, int w) {
    if (t < 256) {
        int cnt = 0;
#pragma unroll
        for (int c = 0; c < NHC; ++c) cnt += sh.hist[c * HSTRIDE + t];
        sh.sc[t] = cnt;
    }
    __syncthreads();
    if (w == 0) {   // wave 0: suffix scan over 256 buckets, 4/lane, no barriers
        int need = sh.s_need;
        unsigned pfx = sh.s_pfx;
        int c0 = sh.sc[4 * lane + 0], c1 = sh.sc[4 * lane + 1];
        int c2 = sh.sc[4 * lane + 2], c3 = sh.sc[4 * lane + 3];
        int s = c0 + c1 + c2 + c3;
        int suf = s;
#pragma unroll
        for (int off = 1; off < 64; off <<= 1) {
            int ov = __shfl_down(suf, off, 64);
            if (lane + off < 64) suf += ov;
        }
        int above = suf - s;
        int i3 = above + c3, i2 = i3 + c2, i1 = i2 + c1, i0 = i1 + c0;
        if (i3 >= need && i3 - c3 < need) { sh.s_need = need - (i3 - c3); sh.s_pfx = pfx | ((unsigned)(4 * lane + 3) << level); }
        if (i2 >= need && i2 - c2 < need) { sh.s_need = need - (i2 - c2); sh.s_pfx = pfx | ((unsigned)(4 * lane + 2) << level); }
        if (i1 >= need && i1 - c1 < need) { sh.s_need = need - (i1 - c1); sh.s_pfx = pfx | ((unsigned)(4 * lane + 1) << level); }
        if (i0 >= need && i0 - c0 < need) { sh.s_need = need - (i0 - c0); sh.s_pfx = pfx | ((unsigned)(4 * lane + 0) << level); }
    }
    __syncthreads();
}

__device__ void topk_select(TopkSh& sh, int n, int* __restrict__ idx,
                            float* __restrict__ val, float* __restrict__ rowsum) {
    int t = threadIdx.x, lane = t & 63, w = t >> 6;
    if (t == 0) { sh.s_pfx = 0u; sh.s_need = KNN; sh.s_cnt = 0; sh.s_m = 0; }
    for (int q = t; q < NHC * HSTRIDE; q += 512) sh.hist[q] = 0;
    __syncthreads();
    int* hw = &sh.hist[(t & 7) * HSTRIDE];

    // pass 1: full scan, top byte
    for (int i = t; i < N4; i += 512) atomicAdd(&hw[sh.sv[i] >> 24], 1);
    __syncthreads();
    hist_pick(sh, 24, t, lane, w);
    unsigned b1 = sh.s_pfx >> 24;

    // compact ==b1 candidates; emit >b1 directly (provably top-40)
    float psum = 0.f;
    for (int i = t; i < N4; i += 512) {
        unsigned u = sh.sv[i];
        unsigned tb = u >> 24;
        if (tb == b1) {
            int p = atomicAdd(&sh.s_m, 1);
            sh.cidx[p] = (unsigned short)i;
        } else if (tb > b1) {
            int p = atomicAdd(&sh.s_cnt, 1);
            float v = __uint_as_float(u);
            idx[(size_t)n * KNN + p] = i;
            val[(size_t)n * KNN + p] = v;
            psum += v;
        }
    }
    __syncthreads();
    int mcnt = sh.s_m;

    // levels 16, 8, 0 over the compacted list
    for (int level = 16; level >= 0; level -= 8) {
        for (int q = t; q < NHC * HSTRIDE; q += 512) sh.hist[q] = 0;
        __syncthreads();
        unsigned pfx = sh.s_pfx;
        for (int j = t; j < mcnt; j += 512) {
            unsigned u = sh.sv[sh.cidx[j]];
            if ((u >> (level + 8)) == (pfx >> (level + 8)))
                atomicAdd(&hw[(u >> level) & 255], 1);
        }
        __syncthreads();
        hist_pick(sh, level, t, lane, w);
    }
    unsigned Tbits = sh.s_pfx;
    float Tf = __uint_as_float(Tbits);
    int needEq = sh.s_need;

    // collect >T within the compacted list
    for (int j = t; j < mcnt; j += 512) {
        unsigned u = sh.sv[sh.cidx[j]];
        if (u > Tbits) {
            int p = atomicAdd(&sh.s_cnt, 1);
            float v = __uint_as_float(u);
            idx[(size_t)n * KNN + p] = (int)sh.cidx[j];
            val[(size_t)n * KNN + p] = v;
            psum += v;
        }
    }
    sh.red[t] = psum;
    __syncthreads();
    for (int o = 256; o; o >>= 1) { if (t < o) sh.red[t] += sh.red[t + o]; __syncthreads(); }
    if (t == 0) rowsum[n] = sh.red[0] + (float)needEq * Tf;

    // equals: earliest indices first (wave 0 ballot scan over full array)
    if (t < 64) {
        int filled = KNN - needEq;
        for (int ib = 0; ib < N4 && filled < KNN; ib += 64) {
            bool eq = (sh.sv[ib + t] == Tbits);
            unsigned long long m = __ballot(eq);
            int pre = __popcll(m & ((1ull << t) - 1ull));
            if (eq && (filled + pre) < KNN) {
                idx[(size_t)n * KNN + filled + pre] = ib + t;
                val[(size_t)n * KNN + filled + pre] = Tf;
            }
            filled += __popcll(m);
        }
    }
}

// graph-1: similarities computed in-kernel (6-dim dot), no Sb round-trip
__global__ __launch_bounds__(512) void topk_fused1(const float* __restrict__ x,
                                                   const float* __restrict__ sq1,
                                                   int* __restrict__ idx, float* __restrict__ val,
                                                   float* __restrict__ rowsum) {
    __shared__ TopkSh sh;
    __shared__ float xn[FDIM];
    __shared__ float sns;
    int n = blockIdx.x;
    int t = threadIdx.x;
    if (t < FDIM) xn[t] = x[n * FDIM + t];
    if (t == FDIM) sns = sq1[n];
    __syncthreads();
    float x0 = xn[0], x1 = xn[1], x2 = xn[2], x3 = xn[3], x4 = xn[4], x5 = xn[5];
    float sn = sns;
    for (int i = t; i < N4; i += 512) {
        const float* xi = x + i * FDIM;
        float d = x0 * xi[0] + x1 * xi[1] + x2 * xi[2] + x3 * xi[3] + x4 * xi[4] + x5 * xi[5];
        float e = sn + sq1[i] - 2.f * d;
        sh.sv[i] = __float_as_uint(__expf(-e));
    }
    topk_select(sh, n, idx, val, rowsum);
}

// graph-2: reads a precomputed Sb row (vectorized)
__global__ __launch_bounds__(512) void topk_radix(const float* __restrict__ S,
                                                  int* __restrict__ idx, float* __restrict__ val,
                                                  float* __restrict__ rowsum) {
    __shared__ TopkSh sh;
    int n = blockIdx.x;
    int t = threadIdx.x;
    const unsigned* row = (const unsigned*)(S + (size_t)n * N4);
    uint4 a = *(const uint4*)(row + 8 * t);
    uint4 b = *(const uint4*)(row + 8 * t + 4);
    *(uint4*)&sh.sv[8 * t] = a;
    *(uint4*)&sh.sv[8 * t + 4] = b;
    topk_select(sh, n, idx, val, rowsum);
}

__global__ __launch_bounds__(256) void dinv_kernel(float* __restrict__ rs) {
    int n = blockIdx.x * 256 + threadIdx.x;
    if (n < N4) rs[n] = rsqrtf(rs[n]);
}

__global__ __launch_bounds__(256) void wnorm_kernel(float* __restrict__ wv,
                                                    const int* __restrict__ idx,
                                                    const float* __restrict__ dinv) {
    int i = blockIdx.x * 256 + threadIdx.x;
    if (i >= N4 * KNN) return;
    int n = i / KNN;
    wv[i] = wv[i] * dinv[n] * dinv[idx[i]];
}

// Tn[n,:] = a*(Tc[n,:] - sum_j wv[n,j]*Tc[idx[n,j],:]) - b*Tp[n,:]   (F small)
__global__ __launch_bounds__(64) void spmv_cheb(const float* __restrict__ Tc,
                                                const float* __restrict__ Tp,
                                                float* __restrict__ Tn,
                                                const int* __restrict__ idx,
                                                const float* __restrict__ wv,
                                                int F, int sC, int sP, int sN,
                                                float a, float b) {
    __shared__ int   si[KNN];
    __shared__ float sw[KNN];
    int n = blockIdx.x;
    if (threadIdx.x < KNN) {
        si[threadIdx.x] = idx[(size_t)n * KNN + threadIdx.x];
        sw[threadIdx.x] = wv[(size_t)n * KNN + threadIdx.x];
    }
    __syncthreads();
    for (int c = threadIdx.x; c < F; c += blockDim.x) {
        float s = 0.f;
#pragma unroll 8
        for (int j = 0; j < KNN; ++j) s += sw[j] * Tc[(size_t)si[j] * sC + c];
        float v = a * (Tc[(size_t)n * sC + c] - s);
        if (b != 0.f) v -= b * Tp[(size_t)n * sP + c];
        Tn[(size_t)n * sN + c] = v;
    }
}

// CC-wide: 256 threads, two half-blocks each gather 20 of 40 neighbors from
// the bf16 mirror; merge via LDS; fused fp32+bf16 write.
__global__ __launch_bounds__(256) void spmv_cheb_bf(const unsigned short* __restrict__ Tcbf,
                                                    const float* __restrict__ Tc,
                                                    const float* __restrict__ Tp,
                                                    float* __restrict__ Tn,
                                                    unsigned short* __restrict__ Tnbf,
                                                    const int* __restrict__ idx,
                                                    const float* __restrict__ wv,
                                                    float a, float b) {
    __shared__ int   si[KNN];
    __shared__ float sw[KNN];
    __shared__ float part[128][8];
    int n = blockIdx.x;
    int t = threadIdx.x;
    int tt = t & 127, h = t >> 7;
    if (t < KNN) {
        si[t] = idx[(size_t)n * KNN + t];
        sw[t] = wv[(size_t)n * KNN + t];
    }
    __syncthreads();
    int c = tt * 8;
    float acc0 = 0, acc1 = 0, acc2 = 0, acc3 = 0, acc4 = 0, acc5 = 0, acc6 = 0, acc7 = 0;
    int j0 = h * 20;
#pragma unroll 4
    for (int j = j0; j < j0 + 20; ++j) {
        bf16x8 v = *(const bf16x8*)(Tcbf + (size_t)si[j] * KP + c);
        float wj = sw[j];
        acc0 += wj * bf2f(v[0]); acc1 += wj * bf2f(v[1]);
        acc2 += wj * bf2f(v[2]); acc3 += wj * bf2f(v[3]);
        acc4 += wj * bf2f(v[4]); acc5 += wj * bf2f(v[5]);
        acc6 += wj * bf2f(v[6]); acc7 += wj * bf2f(v[7]);
    }
    if (h == 1) {
        part[tt][0] = acc0; part[tt][1] = acc1; part[tt][2] = acc2; part[tt][3] = acc3;
        part[tt][4] = acc4; part[tt][5] = acc5; part[tt][6] = acc6; part[tt][7] = acc7;
    }
    __syncthreads();
    if (h == 0) {
        acc0 += part[tt][0]; acc1 += part[tt][1]; acc2 += part[tt][2]; acc3 += part[tt][3];
        acc4 += part[tt][4]; acc5 += part[tt][5]; acc6 += part[tt][6]; acc7 += part[tt][7];
        bf16x8 ob;
        if (tt < 125) {
            float4 tc0 = *(const float4*)(Tc + (size_t)n * CC + c);
            float4 tc1 = *(const float4*)(Tc + (size_t)n * CC + c + 4);
            float o0 = a * (tc0.x - acc0), o1 = a * (tc0.y - acc1);
            float o2 = a * (tc0.z - acc2), o3 = a * (tc0.w - acc3);
            float o4 = a * (tc1.x - acc4), o5 = a * (tc1.y - acc5);
            float o6 = a * (tc1.z - acc6), o7 = a * (tc1.w - acc7);
            if (b != 0.f) {
                float4 tp0 = *(const float4*)(Tp + (size_t)n * CC + c);
                float4 tp1 = *(const float4*)(Tp + (size_t)n * CC + c + 4);
                o0 -= b * tp0.x; o1 -= b * tp0.y; o2 -= b * tp0.z; o3 -= b * tp0.w;
                o4 -= b * tp1.x; o5 -= b * tp1.y; o6 -= b * tp1.z; o7 -= b * tp1.w;
            }
            *(float4*)(Tn + (size_t)n * CC + c) = make_float4(o0, o1, o2, o3);
            *(float4*)(Tn + (size_t)n * CC + c + 4) = make_float4(o4, o5, o6, o7);
            ob[0] = (short)f2bf(o0); ob[1] = (short)f2bf(o1);
            ob[2] = (short)f2bf(o2); ob[3] = (short)f2bf(o3);
            ob[4] = (short)f2bf(o4); ob[5] = (short)f2bf(o5);
            ob[6] = (short)f2bf(o6); ob[7] = (short)f2bf(o7);
        } else {
#pragma unroll
            for (int q = 0; q < 8; ++q) ob[q] = 0;
        }
        *(bf16x8*)(Tnbf + (size_t)n * KP + c) = ob;
    }
}

// ---------------- bf16 conversion / transpose ----------------

__global__ __launch_bounds__(256) void cvt_bf16_kernel(const float* __restrict__ in,
                                                       unsigned short* __restrict__ out) {
    int i = blockIdx.x * 256 + threadIdx.x;     // N4*128 total
    int r = i >> 7, g = i & 127;
    bf16x8 v;
    if (g < 125) {
        float4 a = *(const float4*)(in + (size_t)r * CC + g * 8);
        float4 b = *(const float4*)(in + (size_t)r * CC + g * 8 + 4);
        v[0] = (short)f2bf(a.x); v[1] = (short)f2bf(a.y);
        v[2] = (short)f2bf(a.z); v[3] = (short)f2bf(a.w);
        v[4] = (short)f2bf(b.x); v[5] = (short)f2bf(b.y);
        v[6] = (short)f2bf(b.z); v[7] = (short)f2bf(b.w);
    } else {
#pragma unroll
        for (int q = 0; q < 8; ++q) v[q] = 0;
    }
    *(bf16x8*)(out + (size_t)r * KP + g * 8) = v;
}

// W2 [6*CC x CC] fp32 -> W2T [6][KP(n) x KP(k)] bf16
__global__ __launch_bounds__(256) void w2t_kernel(const float* __restrict__ W2,
                                                  unsigned short* __restrict__ out) {
    __shared__ unsigned short tile[64][65];
    int t = threadIdx.x;
    int k0 = blockIdx.x * 64, n0 = blockIdx.y * 64, s = blockIdx.z;
#pragma unroll
    for (int p = 0; p < 16; ++p) {
        int i = p * 256 + t;
        int kk = i >> 6, nn = i & 63;
        int k = k0 + kk, n = n0 + nn;
        float v = (k < CC && n < CC) ? W2[((size_t)s * CC + k) * CC + n] : 0.f;
        tile[kk][nn] = f2bf(v);
    }
    __syncthreads();
#pragma unroll
    for (int p = 0; p < 16; ++p) {
        int i = p * 256 + t;
        int nn = i >> 6, kk = i & 63;
        out[((size_t)s * KP + n0 + nn) * KP + k0 + kk] = tile[kk][nn];
    }
}

// ---------------- MFMA GEMMs (128x128 tile, BK=32, bf16 in / fp32 acc) ----------------

#define LDP 40

__device__ __forceinline__ void gemm_core(const unsigned short* __restrict__ Ag,
                                          const unsigned short* __restrict__ Bg,
                                          short* As, short* Bs, int t,
                                          f32x4 (&acc)[4][4]) {
    int l = t & 63, w = t >> 6;
    int wm = (w >> 1) * 64, wn = (w & 1) * 64;
    int ar0 = t >> 2, ak0 = (t & 3) * 8;
    int ar1 = (t + 256) >> 2, ak1 = ((t + 256) & 3) * 8;
    int lr = l & 15, lq8 = (l >> 4) * 8;
    for (int k0 = 0; k0 < KP; k0 += 32) {
        bf16x8 a0 = *(const bf16x8*)(Ag + (size_t)ar0 * KP + k0 + ak0);
        bf16x8 a1 = *(const bf16x8*)(Ag + (size_t)ar1 * KP + k0 + ak1);
        bf16x8 b0 = *(const bf16x8*)(Bg + (size_t)ar0 * KP + k0 + ak0);
        bf16x8 b1 = *(const bf16x8*)(Bg + (size_t)ar1 * KP + k0 + ak1);
        __syncthreads();
        *(bf16x8*)&As[ar0 * LDP + ak0] = a0;
        *(bf16x8*)&As[ar1 * LDP + ak1] = a1;
        *(bf16x8*)&Bs[ar0 * LDP + ak0] = b0;
        *(bf16x8*)&Bs[ar1 * LDP + ak1] = b1;
        __syncthreads();
        bf16x8 af[4], bfr[4];
#pragma unroll
        for (int mi = 0; mi < 4; ++mi)
            af[mi] = *(const bf16x8*)&As[(wm + mi * 16 + lr) * LDP + lq8];
#pragma unroll
        for (int ni = 0; ni < 4; ++ni)
            bfr[ni] = *(const bf16x8*)&Bs[(wn + ni * 16 + lr) * LDP + lq8];
#pragma unroll
        for (int mi = 0; mi < 4; ++mi)
#pragma unroll
            for (int ni = 0; ni < 4; ++ni)
                acc[mi][ni] = __builtin_amdgcn_mfma_f32_16x16x32_bf16(af[mi], bfr[ni], acc[mi][ni], 0, 0, 0);
    }
}

__global__ __launch_bounds__(256) void gemm_mfma_acc(const unsigned short* __restrict__ A,
                                                     const unsigned short* __restrict__ B,
                                                     float* __restrict__ C) {
    __shared__ short As[128 * LDP];
    __shared__ short Bs[128 * LDP];
    int t = threadIdx.x;
    int n0 = blockIdx.x * 128, m0 = blockIdx.y * 128;
    f32x4 acc[4][4] = {};
    gemm_core(A + (size_t)m0 * KP, B + (size_t)n0 * KP, As, Bs, t, acc);
    int l = t & 63, w = t >> 6;
    int wm = (w >> 1) * 64, wn = (w & 1) * 64;
    int lr = l & 15, lq4 = (l >> 4) * 4;
#pragma unroll
    for (int ni = 0; ni < 4; ++ni) {
        int n = n0 + wn + ni * 16 + lr;
        if (n >= CC) continue;
#pragma unroll
        for (int mi = 0; mi < 4; ++mi) {
            int m = m0 + wm + mi * 16 + lq4;
            f32x4 v = acc[mi][ni];
#pragma unroll
            for (int r = 0; r < 4; ++r) C[(size_t)(m + r) * CC + n] += v[r];
        }
    }
}

__global__ __launch_bounds__(256) void gemm_mfma_final(const unsigned short* __restrict__ A,
                                                       const unsigned short* __restrict__ B,
                                                       float* __restrict__ C,
                                                       const float* __restrict__ b2) {
    __shared__ short As[128 * LDP];
    __shared__ short Bs[128 * LDP];
    int t = threadIdx.x;
    int n0 = blockIdx.x * 128, m0 = blockIdx.y * 128;
    f32x4 acc[4][4] = {};
    gemm_core(A + (size_t)m0 * KP, B + (size_t)n0 * KP, As, Bs, t, acc);
    int l = t & 63, w = t >> 6;
    int wm = (w >> 1) * 64, wn = (w & 1) * 64;
    int lr = l & 15, lq4 = (l >> 4) * 4;
#pragma unroll
    for (int ni = 0; ni < 4; ++ni) {
        int n = n0 + wn + ni * 16 + lr;
        if (n >= CC) continue;
        float bb = b2[n];
#pragma unroll
        for (int mi = 0; mi < 4; ++mi) {
            int m = m0 + wm + mi * 16 + lq4;
            f32x4 v = acc[mi][ni];
#pragma unroll
            for (int r = 0; r < 4; ++r) {
                float* p = &C[(size_t)(m + r) * CC + n];
                *p = fmaxf(*p + v[r] + bb, 0.f);
            }
        }
    }
}

__global__ __launch_bounds__(256) void gram2_mfma(const unsigned short* __restrict__ Abf,
                                                  const float* __restrict__ sq2,
                                                  float* __restrict__ S) {
    __shared__ short As[128 * LDP];
    __shared__ short Bs[128 * LDP];
    int t = threadIdx.x;
    int n0 = blockIdx.x * 128, m0 = blockIdx.y * 128;
    f32x4 acc[4][4] = {};
    gemm_core(Abf + (size_t)m0 * KP, Abf + (size_t)n0 * KP, As, Bs, t, acc);
    int l = t & 63, w = t >> 6;
    int wm = (w >> 1) * 64, wn = (w & 1) * 64;
    int lr = l & 15, lq4 = (l >> 4) * 4;
#pragma unroll
    for (int ni = 0; ni < 4; ++ni) {
        int n = n0 + wn + ni * 16 + lr;
        float sn = sq2[n];
#pragma unroll
        for (int mi = 0; mi < 4; ++mi) {
            int mrow = m0 + wm + mi * 16 + lq4;
            f32x4 v = acc[mi][ni];
#pragma unroll
            for (int r = 0; r < 4; ++r) {
                float d = sq2[mrow + r] + sn - 2.f * v[r];
                S[(size_t)(mrow + r) * N4 + n] = __expf(-d);
            }
        }
    }
}

// ---------------- cheb conv 1 ----------------

__global__ __launch_bounds__(256) void cheb1_out_kernel(const float* __restrict__ xhat,
                                                        const float* __restrict__ W1,
                                                        const float* __restrict__ b1,
                                                        float* __restrict__ outF) {
    __shared__ float xh[16][18];
    int n0 = blockIdx.x * 16;
    int tid = threadIdx.x;
    for (int i = tid; i < 16 * 18; i += 256) xh[i / 18][i % 18] = xhat[(size_t)n0 * 18 + i];
    __syncthreads();
    for (int c0 = 0; c0 < CC; c0 += 256) {
        int c = c0 + tid;
        if (c < CC) {
            float acc[16];
#pragma unroll
            for (int r = 0; r < 16; ++r) acc[r] = 0.f;
            for (int f = 0; f < 18; ++f) {
                float wv = W1[(size_t)f * CC + c];
#pragma unroll
                for (int r = 0; r < 16; ++r) acc[r] += xh[r][f] * wv;
            }
            float bb = b1[c];
#pragma unroll
            for (int r = 0; r < 16; ++r)
                outF[(size_t)(n0 + r) * CC + c] = fmaxf(acc[r] + bb, 0.f);
        }
    }
}

// ---------------- regs (frobenius of O^T @ T) ----------------

__global__ __launch_bounds__(256) void matT6_partial(const float* __restrict__ O,
                                                     const float* __restrict__ T, int ts,
                                                     float* __restrict__ M) {
    __shared__ float sT[128][6];
    int t = threadIdx.x;
    int c = blockIdx.x * 256 + t;
    int n0 = blockIdx.y * 128;
    for (int i = t; i < 128 * 6; i += 256) {
        int nn = i / 6, f = i % 6;
        sT[nn][f] = T[(size_t)(n0 + nn) * ts + f];
    }
    __syncthreads();
    if (c >= CC) return;
    float a0 = 0, a1 = 0, a2 = 0, a3 = 0, a4 = 0, a5 = 0;
    for (int nn = 0; nn < 128; ++nn) {
        float o = O[(size_t)(n0 + nn) * CC + c];
        a0 += o * sT[nn][0]; a1 += o * sT[nn][1]; a2 += o * sT[nn][2];
        a3 += o * sT[nn][3]; a4 += o * sT[nn][4]; a5 += o * sT[nn][5];
    }
    atomicAdd(&M[0 * CC + c], a0);
    atomicAdd(&M[1 * CC + c], a1);
    atomicAdd(&M[2 * CC + c], a2);
    atomicAdd(&M[3 * CC + c], a3);
    atomicAdd(&M[4 * CC + c], a4);
    atomicAdd(&M[5 * CC + c], a5);
}

__global__ __launch_bounds__(256) void fro_kernel(const float* __restrict__ M, float* __restrict__ dst) {
    __shared__ float red[256];
    int t = threadIdx.x;
    int i = blockIdx.x * 256 + t;
    float v = (i < 6 * CC) ? M[i] : 0.f;
    red[t] = v * v;
    __syncthreads();
    for (int o = 128; o; o >>= 1) { if (t < o) red[t] += red[t + o]; __syncthreads(); }
    if (t == 0) atomicAdd(dst, red[0]);
}

// ---------------- pooling ----------------

__global__ __launch_bounds__(256) void vfr_kernel(const float* __restrict__ outF,
                                                  const int* __restrict__ sccs,
                                                  float* __restrict__ vfr) {
    int r = blockIdx.y;
    int c = blockIdx.x * 256 + threadIdx.x;
    if (c >= CC) return;
    int s0 = blockIdx.z * 41;
    float m = 0.f;
    for (int s = s0; s < s0 + 41; ++s) {
        int n = sccs[r * SSC + s];
        m = fmaxf(m, outF[(size_t)n * CC + c]);
    }
    atomicMax((int*)&vfr[(size_t)r * CC + c], __float_as_int(m));
}

__global__ __launch_bounds__(256) void sq2_kernel(const float* __restrict__ outF,
                                                  float* __restrict__ sq2) {
    int lane = threadIdx.x & 63, w = threadIdx.x >> 6;
    int n = blockIdx.x * 4 + w;
    const float* row = outF + (size_t)n * CC;
    float s = 0.f;
    for (int i = lane; i < CC; i += 64) { float v = row[i]; s += v * v; }
#pragma unroll
    for (int o = 32; o; o >>= 1) s += __shfl_down(s, o);
    if (lane == 0) sq2[n] = s;
}

// row-split column max; dst must be zeroed (values >= 0)
__global__ __launch_bounds__(256) void colmax_kernel(const float* __restrict__ O,
                                                     float* __restrict__ dst) {
    int c = blockIdx.x * 256 + threadIdx.x;
    if (c >= CC) return;
    int n0 = blockIdx.y * 64;
    float m = 0.f;
    for (int n = n0; n < n0 + 64; ++n) m = fmaxf(m, O[(size_t)n * CC + c]);
    atomicMax((int*)&dst[c], __float_as_int(m));
}

// ---------------- reeb branch ----------------

__global__ __launch_bounds__(256) void reeb_mm_kernel(const float* __restrict__ Lr,
                                                      const float* __restrict__ Vin,
                                                      const float* __restrict__ Vsub,
                                                      float* __restrict__ Vout, float a2) {
    int c = blockIdx.x * 256 + threadIdx.x;
    if (c >= CC) return;
    int r = blockIdx.y;
    float s = 0.f;
#pragma unroll
    for (int j = 0; j < NRB; ++j) s += Lr[r * NRB + j] * Vin[(size_t)j * CC + c];
    float v = a2 * s;
    if (Vsub) v -= Vsub[(size_t)r * CC + c];
    Vout[(size_t)r * CC + c] = v;
}

#define RKC 25
__global__ __launch_bounds__(256) void reeb_conv_splitk(const float* __restrict__ vfr,
                                                        const float* __restrict__ tr1,
                                                        const float* __restrict__ tr2,
                                                        const float* __restrict__ Wr,
                                                        float* __restrict__ rpre) {
    __shared__ float sA[NRB][RKC];
    int t = threadIdx.x;
    int kbase = blockIdx.y * RKC;
    for (int i = t; i < NRB * RKC; i += 256) {
        int r = i / RKC, kk = i % RKC;
        int kg = kbase + kk;
        float v;
        if (kg < CC)           v = vfr[(size_t)r * CC + kg];
        else if (kg < 2 * CC)  v = tr1[(size_t)r * CC + kg - CC];
        else                   v = tr2[(size_t)r * CC + kg - 2 * CC];
        sA[r][kk] = v;
    }
    __syncthreads();
    int c = blockIdx.x * 256 + t;
    if (c >= CC) return;
    float acc[NRB];
#pragma unroll
    for (int r = 0; r < NRB; ++r) acc[r] = 0.f;
    for (int kk = 0; kk < RKC; ++kk) {
        float wv = Wr[(size_t)(kbase + kk) * CC + c];
#pragma unroll
        for (int r = 0; r < NRB; ++r) acc[r] += sA[r][kk] * wv;
    }
#pragma unroll
    for (int r = 0; r < NRB; ++r) atomicAdd(&rpre[(size_t)r * CC + c], acc[r]);
}

__global__ __launch_bounds__(256) void reeb_max_kernel(const float* __restrict__ pre,
                                                       const float* __restrict__ br,
                                                       float* __restrict__ rbm) {
    int c = blockIdx.x * 256 + threadIdx.x;
    if (c >= CC) return;
    float bb = br[c];
    float m = 0.f;
    for (int r = 0; r < NRB; ++r) m = fmaxf(m, fmaxf(pre[(size_t)r * CC + c] + bb, 0.f));
    rbm[c] = m;
}

// ---------------- FC head ----------------

__global__ __launch_bounds__(256) void fc1_kernel(const float* __restrict__ rbm,
                                                  const float* __restrict__ otm,
                                                  const float* __restrict__ w,
                                                  float* __restrict__ h1pre) {
    int j = blockIdx.x * 256 + threadIdx.x;
    if (j >= 512) return;
    int i0 = blockIdx.y * 250;
    float s = 0.f;
    for (int i = i0; i < i0 + 250; ++i) {
        float v = (i < CC) ? rbm[i] : otm[i - CC];
        s += v * w[(size_t)i * 512 + j];
    }
    atomicAdd(&h1pre[j], s);
}

__global__ __launch_bounds__(512) void fc23_kernel(const float* __restrict__ h1pre,
                                                   const float* __restrict__ b1f,
                                                   const float* __restrict__ w2,
                                                   const float* __restrict__ b2f,
                                                   const float* __restrict__ w3,
                                                   const float* __restrict__ b3f,
                                                   float* __restrict__ dout) {
    __shared__ float h1[512];
    __shared__ float h2[128];
    int t = threadIdx.x;
    h1[t] = fmaxf(h1pre[t] + b1f[t], 0.f);
    __syncthreads();
    if (t < 128) {
        float s = b2f[t];
        for (int i = 0; i < 512; ++i) s += h1[i] * w2[(size_t)i * 128 + t];
        h2[t] = fmaxf(s, 0.f);
    }
    __syncthreads();
    if (t < 40) {
        float s = b3f[t];
        for (int i = 0; i < 128; ++i) s += h2[i] * w3[(size_t)i * 40 + t];
        dout[t] = s;
    }
}

__global__ __launch_bounds__(256) void finalize_kernel(const float* __restrict__ racc,
                                                       const float* __restrict__ f1w,
                                                       const float* __restrict__ f1b,
                                                       const float* __restrict__ f2w,
                                                       const float* __restrict__ f2b,
                                                       const float* __restrict__ f3w,
                                                       const float* __restrict__ f3b,
                                                       float* __restrict__ dout) {
    __shared__ float red[256];
    __shared__ float res[3];
    int t = threadIdx.x;
    float s1 = 0.f, s2 = 0.f, s3 = 0.f;
    for (int i = t; i < 2000; i += 256) { float v = f1w[(size_t)i * 512]; s1 += v * v; }
    for (int i = t; i < 512; i += 256) { float v = f2w[(size_t)i * 128]; s2 += v * v; }
    if (t < 128) { float v = f3w[(size_t)t * 40]; s3 = v * v; }

    red[t] = s1; __syncthreads();
    for (int o = 128; o; o >>= 1) { if (t < o) red[t] += red[t + o]; __syncthreads(); }
    if (t == 0) res[0] = red[0];
    __syncthreads();
    red[t] = s2; __syncthreads();
    for (int o = 128; o; o >>= 1) { if (t < o) red[t] += red[t + o]; __syncthreads(); }
    if (t == 0) res[1] = red[0];
    __syncthreads();
    red[t] = s3; __syncthreads();
    for (int o = 128; o; o >>= 1) { if (t < o) red[t] += red[t + o]; __syncthreads(); }
    if (t == 0) res[2] = red[0];
    __syncthreads();

    if (t == 0) {
        dout[40] = sqrtf(racc[0]);
        dout[41] = sqrtf(racc[1]);
        dout[42] = res[0];
        dout[43] = f1b[0] * f1b[0];
        dout[44] = res[1];
        dout[45] = f2b[0] * f2b[0];
        dout[46] = res[2];
        dout[47] = f3b[0] * f3b[0];
    }
}

// ---------------- host ----------------

extern "C" void kernel_launch(void* const* d_in, const int* in_sizes, int n_in,
                              void* d_out, int out_size, void* d_ws, size_t ws_size,
                              hipStream_t stream) {
    const float* x    = (const float*)d_in[0];
    const float* Lr   = (const float*)d_in[5];
    const int*   sccs = (const int*)d_in[6];
    const float* W1   = (const float*)d_in[7];
    const float* b1   = (const float*)d_in[8];
    const float* W2   = (const float*)d_in[9];
    const float* b2   = (const float*)d_in[10];
    const float* Wr   = (const float*)d_in[11];
    const float* br   = (const float*)d_in[12];
    const float* f1w  = (const float*)d_in[13];
    const float* f1b  = (const float*)d_in[14];
    const float* f2w  = (const float*)d_in[15];
    const float* f2b  = (const float*)d_in[16];
    const float* f3w  = (const float*)d_in[17];
    const float* f3b  = (const float*)d_in[18];
    float* dout = (float*)d_out;

    char* ws = (char*)d_ws;
    size_t off = 0;
    auto alloc = [&](size_t bytes) -> char* {
        char* p = ws + off;
        off = (off + bytes + 255) & ~(size_t)255;
        return p;
    };
    float* outF = (float*)alloc((size_t)N4 * CC * 4);
    float* T1   = (float*)alloc((size_t)N4 * CC * 4);
    float* accC = (float*)alloc((size_t)N4 * CC * 4);
    float* Sb   = (float*)alloc((size_t)N4 * N4 * 4);   // full 4096x4096 similarity
    unsigned short* Abf = (unsigned short*)alloc((size_t)N4 * KP * 2);
    unsigned short* Bbf = (unsigned short*)alloc((size_t)N4 * KP * 2);
    unsigned short* W2T = (unsigned short*)Sb;  // alias: Sb dead after topk2
    float* xhat = (float*)alloc((size_t)N4 * 18 * 4);
    float* sq1  = (float*)alloc(N4 * 4);
    float* sq2  = (float*)alloc(N4 * 4);
    float* di1  = (float*)alloc(N4 * 4);
    float* di2  = (float*)alloc(N4 * 4);
    float* wv1  = (float*)alloc((size_t)N4 * KNN * 4);
    float* wv2  = (float*)alloc((size_t)N4 * KNN * 4);
    int*   ix1  = (int*)alloc((size_t)N4 * KNN * 4);
    int*   ix2  = (int*)alloc((size_t)N4 * KNN * 4);
    float* t2x  = (float*)alloc((size_t)N4 * FDIM * 4);
    float* tr1  = (float*)alloc((size_t)NRB * CC * 4);
    float* tr2  = (float*)alloc((size_t)NRB * CC * 4);
    // zero-zone: one memset covers [Mb, Mb2, rbm, otm, h1p, racc, rpre, vfr]
    char*  zbase = ws + off;
    float* Mb   = (float*)alloc(6 * CC * 4);
    float* Mb2  = (float*)alloc(6 * CC * 4);
    float* rbm  = (float*)alloc(CC * 4);
    float* otm  = (float*)alloc(CC * 4);
    float* h1p  = (float*)alloc(512 * 4);
    float* racc = (float*)alloc(64 * 4);
    float* rpre = (float*)alloc((size_t)NRB * CC * 4);
    float* vfr  = (float*)alloc((size_t)NRB * CC * 4);
    size_t zlen = (size_t)((ws + off) - zbase);
    if (off > ws_size) return;

    hipMemsetAsync(accC, 0, (size_t)N4 * CC * 4, stream);
    hipMemsetAsync(zbase, 0, zlen, stream);

    // ---- graph 1 (on x): fused similarity + top-40 ----
    sqx_kernel<<<(N4 + 255) / 256, 256, 0, stream>>>(x, sq1, xhat);
    topk_fused1<<<N4, 512, 0, stream>>>(x, sq1, ix1, wv1, di1);
    dinv_kernel<<<N4 / 256, 256, 0, stream>>>(di1);
    wnorm_kernel<<<(N4 * KNN + 255) / 256, 256, 0, stream>>>(wv1, ix1, di1);

    // ---- cheb conv 1 ----
    spmv_cheb<<<N4, 64, 0, stream>>>(xhat, xhat, xhat + 6, ix1, wv1, FDIM, 18, 18, 18, 1.f, 0.f);
    spmv_cheb<<<N4, 64, 0, stream>>>(xhat + 6, xhat, xhat + 12, ix1, wv1, FDIM, 18, 18, 18, 2.f, 1.f);
    cheb1_out_kernel<<<N4 / 16, 256, 0, stream>>>(xhat, W1, b1, outF);

    matT6_partial<<<dim3(4, 32), 256, 0, stream>>>(outF, xhat + 6, 18, Mb);
    fro_kernel<<<24, 256, 0, stream>>>(Mb, racc + 0);

    vfr_kernel<<<dim3(4, NRB, 5), 256, 0, stream>>>(outF, sccs, vfr);

    // ---- graph 2 (on outF), bf16 MFMA gram ----
    sq2_kernel<<<N4 / 4, 256, 0, stream>>>(outF, sq2);
    cvt_bf16_kernel<<<N4 * 128 / 256, 256, 0, stream>>>(outF, Abf);
    gram2_mfma<<<dim3(N4 / 128, N4 / 128), 256, 0, stream>>>(Abf, sq2, Sb);
    topk_radix<<<N4, 512, 0, stream>>>(Sb, ix2, wv2, di2);
    dinv_kernel<<<N4 / 256, 256, 0, stream>>>(di2);
    wnorm_kernel<<<(N4 * KNN + 255) / 256, 256, 0, stream>>>(wv2, ix2, di2);

    // Sb dead -> build W2T in its space
    w2t_kernel<<<dim3(16, 16, 6), 256, 0, stream>>>(W2, W2T);

    spmv_cheb<<<N4, 64, 0, stream>>>(x, x, t2x, ix2, wv2, FDIM, FDIM, FDIM, FDIM, 1.f, 0.f);

    // ---- cheb conv 2 (K=6): T0=outF/Abf, gathers from bf16 mirror, fused cvt ----
    gemm_mfma_acc<<<dim3(8, 32), 256, 0, stream>>>(Abf, W2T + (size_t)0 * KP * KP, accC);
    spmv_cheb_bf<<<N4, 256, 0, stream>>>(Abf, outF, outF, T1, Bbf, ix2, wv2, 1.f, 0.f);       // T1
    gemm_mfma_acc<<<dim3(8, 32), 256, 0, stream>>>(Bbf, W2T + (size_t)1 * KP * KP, accC);
    spmv_cheb_bf<<<N4, 256, 0, stream>>>(Bbf, T1, outF, outF, Abf, ix2, wv2, 2.f, 1.f);       // T2
    gemm_mfma_acc<<<dim3(8, 32), 256, 0, stream>>>(Abf, W2T + (size_t)2 * KP * KP, accC);
    spmv_cheb_bf<<<N4, 256, 0, stream>>>(Abf, outF, T1, T1, Bbf, ix2, wv2, 2.f, 1.f);         // T3
    gemm_mfma_acc<<<dim3(8, 32), 256, 0, stream>>>(Bbf, W2T + (size_t)3 * KP * KP, accC);
    spmv_cheb_bf<<<N4, 256, 0, stream>>>(Bbf, T1, outF, outF, Abf, ix2, wv2, 2.f, 1.f);       // T4
    gemm_mfma_acc<<<dim3(8, 32), 256, 0, stream>>>(Abf, W2T + (size_t)4 * KP * KP, accC);
    spmv_cheb_bf<<<N4, 256, 0, stream>>>(Abf, outF, T1, T1, Bbf, ix2, wv2, 2.f, 1.f);         // T5
    gemm_mfma_final<<<dim3(8, 32), 256, 0, stream>>>(Bbf, W2T + (size_t)5 * KP * KP, accC, b2);

    matT6_partial<<<dim3(4, 32), 256, 0, stream>>>(accC, t2x, FDIM, Mb2);
    fro_kernel<<<24, 256, 0, stream>>>(Mb2, racc + 1);

    colmax_kernel<<<dim3(4, 64), 256, 0, stream>>>(accC, otm);

    // ---- reeb cheb conv (K=3) ----
    reeb_mm_kernel<<<dim3(4, NRB), 256, 0, stream>>>(Lr, vfr, nullptr, tr1, 1.f);
    reeb_mm_kernel<<<dim3(4, NRB), 256, 0, stream>>>(Lr, tr1, vfr, tr2, 2.f);
    reeb_conv_splitk<<<dim3(4, 120), 256, 0, stream>>>(vfr, tr1, tr2, Wr, rpre);
    reeb_max_kernel<<<4, 256, 0, stream>>>(rpre, br, rbm);

    // ---- FC head ----
    fc1_kernel<<<dim3(2, 8), 256, 0, stream>>>(rbm, otm, f1w, h1p);
    fc23_kernel<<<1, 512, 0, stream>>>(h1p, f1b, f2w, f2b, f3w, f3b, dout);
    finalize_kernel<<<1, 256, 0, stream>>>(racc, f1w, f1b, f2w, f2b, f3w, f3b, dout);
}

// Round 10
// 803.781 us; speedup vs baseline: 4.3295x; 1.0509x over previous
//
#include <hip/hip_runtime.h>
#include <math.h>

#define N4    4096
#define FDIM  6
#define CC    1000
#define KP    1024   // padded K for bf16 GEMMs
#define KNN   40
#define NRB   20
#define SSC   205

typedef __attribute__((ext_vector_type(8))) short bf16x8;
typedef __attribute__((ext_vector_type(4))) float f32x4;

__device__ __forceinline__ unsigned short f2bf(float f) {
    unsigned u = __float_as_uint(f);
    u = (u + 0x7fffu + ((u >> 16) & 1u)) >> 16;
    return (unsigned short)u;
}
__device__ __forceinline__ float bf2f(short s) {
    return __uint_as_float(((unsigned)(unsigned short)s) << 16);
}

// distance -> descending-sortable key (smaller d == larger key), sign-correct
__device__ __forceinline__ unsigned d2key(float d) {
    unsigned u = __float_as_uint(d);
    return ((int)u < 0) ? u : (~u) ^ 0x80000000u;
}
__device__ __forceinline__ float key2d(unsigned k) {
    unsigned u = (k >> 31) ? k : (~k) ^ 0x80000000u;
    return __uint_as_float(u);
}

// ---------------- graph build ----------------

__global__ __launch_bounds__(256) void sqx_kernel(const float* __restrict__ x,
                                                  float* __restrict__ sq1,
                                                  float* __restrict__ xhat) {
    int n = blockIdx.x * blockDim.x + threadIdx.x;
    if (n >= N4) return;
    float s = 0.f;
#pragma unroll
    for (int f = 0; f < FDIM; ++f) {
        float v = x[n * FDIM + f];
        s += v * v;
        xhat[n * 18 + f] = v;
    }
    sq1[n] = s;
}

// ---------------- radix top-40 on distance keys (exact) ----------------
// Selection on d-bits (no exp); exp(-d) computed only for the ~40 winners.
// ==T ties in ascending index order (matches lax.top_k on the exp values).

#define NHC 8
#define HSTRIDE 257   // 257 % 32 == 1: histogram copies de-aliased across banks

struct TopkSh {
    unsigned sv[N4];
    int hist[NHC * HSTRIDE];
    int sc[256];
    float red[512];
    unsigned short cidx[N4];
    unsigned s_pfx;
    int s_need, s_cnt, s_m;
};

__device__ __forceinline__ void hist_pick(TopkSh& sh, int level, int t, int lane, int w) {
    if (t < 256) {
        int cnt = 0;
#pragma unroll
        for (int c = 0; c < NHC; ++c) cnt += sh.hist[c * HSTRIDE + t];
        sh.sc[t] = cnt;
    }
    __syncthreads();
    if (w == 0) {   // wave 0: suffix scan over 256 buckets, 4/lane, no barriers
        int need = sh.s_need;
        unsigned pfx = sh.s_pfx;
        int c0 = sh.sc[4 * lane + 0], c1 = sh.sc[4 * lane + 1];
        int c2 = sh.sc[4 * lane + 2], c3 = sh.sc[4 * lane + 3];
        int s = c0 + c1 + c2 + c3;
        int suf = s;
#pragma unroll
        for (int off = 1; off < 64; off <<= 1) {
            int ov = __shfl_down(suf, off, 64);
            if (lane + off < 64) suf += ov;
        }
        int above = suf - s;
        int i3 = above + c3, i2 = i3 + c2, i1 = i2 + c1, i0 = i1 + c0;
        if (i3 >= need && i3 - c3 < need) { sh.s_need = need - (i3 - c3); sh.s_pfx = pfx | ((unsigned)(4 * lane + 3) << level); }
        if (i2 >= need && i2 - c2 < need) { sh.s_need = need - (i2 - c2); sh.s_pfx = pfx | ((unsigned)(4 * lane + 2) << level); }
        if (i1 >= need && i1 - c1 < need) { sh.s_need = need - (i1 - c1); sh.s_pfx = pfx | ((unsigned)(4 * lane + 1) << level); }
        if (i0 >= need && i0 - c0 < need) { sh.s_need = need - (i0 - c0); sh.s_pfx = pfx | ((unsigned)(4 * lane + 0) << level); }
    }
    __syncthreads();
}

__device__ void topk_select(TopkSh& sh, int n, int* __restrict__ idx,
                            float* __restrict__ val, float* __restrict__ rowsum) {
    int t = threadIdx.x, lane = t & 63, w = t >> 6;
    if (t == 0) { sh.s_pfx = 0u; sh.s_need = KNN; sh.s_cnt = 0; sh.s_m = 0; }
    for (int q = t; q < NHC * HSTRIDE; q += 512) sh.hist[q] = 0;
    __syncthreads();
    int* hw = &sh.hist[(t & 7) * HSTRIDE];

    // pass 1: full scan, top byte
    for (int i = t; i < N4; i += 512) atomicAdd(&hw[sh.sv[i] >> 24], 1);
    __syncthreads();
    hist_pick(sh, 24, t, lane, w);
    unsigned b1 = sh.s_pfx >> 24;

    // compact ==b1 candidates; emit >b1 directly (provably top-40)
    float psum = 0.f;
    for (int i = t; i < N4; i += 512) {
        unsigned u = sh.sv[i];
        unsigned tb = u >> 24;
        if (tb == b1) {
            int p = atomicAdd(&sh.s_m, 1);
            sh.cidx[p] = (unsigned short)i;
        } else if (tb > b1) {
            int p = atomicAdd(&sh.s_cnt, 1);
            float v = __expf(-key2d(u));
            idx[(size_t)n * KNN + p] = i;
            val[(size_t)n * KNN + p] = v;
            psum += v;
        }
    }
    __syncthreads();
    int mcnt = sh.s_m;

    // levels 16, 8, 0 over the compacted list
    for (int level = 16; level >= 0; level -= 8) {
        for (int q = t; q < NHC * HSTRIDE; q += 512) sh.hist[q] = 0;
        __syncthreads();
        unsigned pfx = sh.s_pfx;
        for (int j = t; j < mcnt; j += 512) {
            unsigned u = sh.sv[sh.cidx[j]];
            if ((u >> (level + 8)) == (pfx >> (level + 8)))
                atomicAdd(&hw[(u >> level) & 255], 1);
        }
        __syncthreads();
        hist_pick(sh, level, t, lane, w);
    }
    unsigned Tbits = sh.s_pfx;
    float Tf = __expf(-key2d(Tbits));
    int needEq = sh.s_need;

    // collect >T within the compacted list
    for (int j = t; j < mcnt; j += 512) {
        unsigned u = sh.sv[sh.cidx[j]];
        if (u > Tbits) {
            int p = atomicAdd(&sh.s_cnt, 1);
            float v = __expf(-key2d(u));
            idx[(size_t)n * KNN + p] = (int)sh.cidx[j];
            val[(size_t)n * KNN + p] = v;
            psum += v;
        }
    }
    sh.red[t] = psum;
    __syncthreads();
    for (int o = 256; o; o >>= 1) { if (t < o) sh.red[t] += sh.red[t + o]; __syncthreads(); }
    if (t == 0) rowsum[n] = sh.red[0] + (float)needEq * Tf;

    // equals: earliest indices first (wave 0 ballot scan over full array)
    if (t < 64) {
        int filled = KNN - needEq;
        for (int ib = 0; ib < N4 && filled < KNN; ib += 64) {
            bool eq = (sh.sv[ib + t] == Tbits);
            unsigned long long m = __ballot(eq);
            int pre = __popcll(m & ((1ull << t) - 1ull));
            if (eq && (filled + pre) < KNN) {
                idx[(size_t)n * KNN + filled + pre] = ib + t;
                val[(size_t)n * KNN + filled + pre] = Tf;
            }
            filled += __popcll(m);
        }
    }
}

// graph-1: distances computed in-kernel (6-dim dot, float2 loads), no Sb round-trip
__global__ __launch_bounds__(512) void topk_fused1(const float* __restrict__ x,
                                                   const float* __restrict__ sq1,
                                                   int* __restrict__ idx, float* __restrict__ val,
                                                   float* __restrict__ rowsum) {
    __shared__ TopkSh sh;
    __shared__ float xn[FDIM];
    __shared__ float sns;
    int n = blockIdx.x;
    int t = threadIdx.x;
    if (t < FDIM) xn[t] = x[n * FDIM + t];
    if (t == FDIM) sns = sq1[n];
    __syncthreads();
    float x0 = xn[0], x1 = xn[1], x2 = xn[2], x3 = xn[3], x4 = xn[4], x5 = xn[5];
    float sn = sns;
    for (int i = t; i < N4; i += 512) {
        const float2* xi = (const float2*)(x + i * FDIM);
        float2 p0 = xi[0], p1 = xi[1], p2 = xi[2];
        float d = x0 * p0.x + x1 * p0.y + x2 * p1.x + x3 * p1.y + x4 * p2.x + x5 * p2.y;
        float e = sn + sq1[i] - 2.f * d;
        sh.sv[i] = d2key(e);
    }
    topk_select(sh, n, idx, val, rowsum);
}

// graph-2: reads a precomputed distance row (vectorized), keys on the fly
__global__ __launch_bounds__(512) void topk_radix(const float* __restrict__ S,
                                                  int* __restrict__ idx, float* __restrict__ val,
                                                  float* __restrict__ rowsum) {
    __shared__ TopkSh sh;
    int n = blockIdx.x;
    int t = threadIdx.x;
    const float* row = S + (size_t)n * N4;
    float4 a = *(const float4*)(row + 8 * t);
    float4 b = *(const float4*)(row + 8 * t + 4);
    sh.sv[8 * t + 0] = d2key(a.x); sh.sv[8 * t + 1] = d2key(a.y);
    sh.sv[8 * t + 2] = d2key(a.z); sh.sv[8 * t + 3] = d2key(a.w);
    sh.sv[8 * t + 4] = d2key(b.x); sh.sv[8 * t + 5] = d2key(b.y);
    sh.sv[8 * t + 6] = d2key(b.z); sh.sv[8 * t + 7] = d2key(b.w);
    topk_select(sh, n, idx, val, rowsum);
}

__global__ __launch_bounds__(256) void dinv_kernel(float* __restrict__ rs) {
    int n = blockIdx.x * 256 + threadIdx.x;
    if (n < N4) rs[n] = rsqrtf(rs[n]);
}

__global__ __launch_bounds__(256) void wnorm_kernel(float* __restrict__ wv,
                                                    const int* __restrict__ idx,
                                                    const float* __restrict__ dinv) {
    int i = blockIdx.x * 256 + threadIdx.x;
    if (i >= N4 * KNN) return;
    int n = i / KNN;
    wv[i] = wv[i] * dinv[n] * dinv[idx[i]];
}

// Tn[n,:] = a*(Tc[n,:] - sum_j wv[n,j]*Tc[idx[n,j],:]) - b*Tp[n,:]   (F small, fp32)
__global__ __launch_bounds__(64) void spmv_cheb(const float* __restrict__ Tc,
                                                const float* __restrict__ Tp,
                                                float* __restrict__ Tn,
                                                const int* __restrict__ idx,
                                                const float* __restrict__ wv,
                                                int F, int sC, int sP, int sN,
                                                float a, float b) {
    __shared__ int   si[KNN];
    __shared__ float sw[KNN];
    int n = blockIdx.x;
    if (threadIdx.x < KNN) {
        si[threadIdx.x] = idx[(size_t)n * KNN + threadIdx.x];
        sw[threadIdx.x] = wv[(size_t)n * KNN + threadIdx.x];
    }
    __syncthreads();
    for (int c = threadIdx.x; c < F; c += blockDim.x) {
        float s = 0.f;
#pragma unroll 8
        for (int j = 0; j < KNN; ++j) s += sw[j] * Tc[(size_t)si[j] * sC + c];
        float v = a * (Tc[(size_t)n * sC + c] - s);
        if (b != 0.f) v -= b * Tp[(size_t)n * sP + c];
        Tn[(size_t)n * sN + c] = v;
    }
}

// CC-wide, fully bf16-resident recursion: reads Tc/Tp mirrors, writes Tn mirror.
// Two half-blocks each gather 20 of 40 neighbors; merge via LDS. Pad cols are
// zero in all mirrors, so all 128 lanes compute/write unconditionally.
__global__ __launch_bounds__(256) void spmv_cheb_bf(const unsigned short* __restrict__ Tcbf,
                                                    const unsigned short* __restrict__ Tpbf,
                                                    unsigned short* __restrict__ Tnbf,
                                                    const int* __restrict__ idx,
                                                    const float* __restrict__ wv,
                                                    float a, float b) {
    __shared__ int   si[KNN];
    __shared__ float sw[KNN];
    __shared__ float part[128][8];
    int n = blockIdx.x;
    int t = threadIdx.x;
    int tt = t & 127, h = t >> 7;
    if (t < KNN) {
        si[t] = idx[(size_t)n * KNN + t];
        sw[t] = wv[(size_t)n * KNN + t];
    }
    __syncthreads();
    int c = tt * 8;
    float acc0 = 0, acc1 = 0, acc2 = 0, acc3 = 0, acc4 = 0, acc5 = 0, acc6 = 0, acc7 = 0;
    int j0 = h * 20;
#pragma unroll 4
    for (int j = j0; j < j0 + 20; ++j) {
        bf16x8 v = *(const bf16x8*)(Tcbf + (size_t)si[j] * KP + c);
        float wj = sw[j];
        acc0 += wj * bf2f(v[0]); acc1 += wj * bf2f(v[1]);
        acc2 += wj * bf2f(v[2]); acc3 += wj * bf2f(v[3]);
        acc4 += wj * bf2f(v[4]); acc5 += wj * bf2f(v[5]);
        acc6 += wj * bf2f(v[6]); acc7 += wj * bf2f(v[7]);
    }
    if (h == 1) {
        part[tt][0] = acc0; part[tt][1] = acc1; part[tt][2] = acc2; part[tt][3] = acc3;
        part[tt][4] = acc4; part[tt][5] = acc5; part[tt][6] = acc6; part[tt][7] = acc7;
    }
    __syncthreads();
    if (h == 0) {
        acc0 += part[tt][0]; acc1 += part[tt][1]; acc2 += part[tt][2]; acc3 += part[tt][3];
        acc4 += part[tt][4]; acc5 += part[tt][5]; acc6 += part[tt][6]; acc7 += part[tt][7];
        bf16x8 tc = *(const bf16x8*)(Tcbf + (size_t)n * KP + c);
        float o0 = a * (bf2f(tc[0]) - acc0), o1 = a * (bf2f(tc[1]) - acc1);
        float o2 = a * (bf2f(tc[2]) - acc2), o3 = a * (bf2f(tc[3]) - acc3);
        float o4 = a * (bf2f(tc[4]) - acc4), o5 = a * (bf2f(tc[5]) - acc5);
        float o6 = a * (bf2f(tc[6]) - acc6), o7 = a * (bf2f(tc[7]) - acc7);
        if (b != 0.f) {
            bf16x8 tp = *(const bf16x8*)(Tpbf + (size_t)n * KP + c);
            o0 -= b * bf2f(tp[0]); o1 -= b * bf2f(tp[1]);
            o2 -= b * bf2f(tp[2]); o3 -= b * bf2f(tp[3]);
            o4 -= b * bf2f(tp[4]); o5 -= b * bf2f(tp[5]);
            o6 -= b * bf2f(tp[6]); o7 -= b * bf2f(tp[7]);
        }
        bf16x8 ob;
        ob[0] = (short)f2bf(o0); ob[1] = (short)f2bf(o1);
        ob[2] = (short)f2bf(o2); ob[3] = (short)f2bf(o3);
        ob[4] = (short)f2bf(o4); ob[5] = (short)f2bf(o5);
        ob[6] = (short)f2bf(o6); ob[7] = (short)f2bf(o7);
        *(bf16x8*)(Tnbf + (size_t)n * KP + c) = ob;
    }
}

// ---------------- bf16 conversion / transpose ----------------

__global__ __launch_bounds__(256) void cvt_bf16_kernel(const float* __restrict__ in,
                                                       unsigned short* __restrict__ out) {
    int i = blockIdx.x * 256 + threadIdx.x;     // N4*128 total
    int r = i >> 7, g = i & 127;
    bf16x8 v;
    if (g < 125) {
        float4 a = *(const float4*)(in + (size_t)r * CC + g * 8);
        float4 b = *(const float4*)(in + (size_t)r * CC + g * 8 + 4);
        v[0] = (short)f2bf(a.x); v[1] = (short)f2bf(a.y);
        v[2] = (short)f2bf(a.z); v[3] = (short)f2bf(a.w);
        v[4] = (short)f2bf(b.x); v[5] = (short)f2bf(b.y);
        v[6] = (short)f2bf(b.z); v[7] = (short)f2bf(b.w);
    } else {
#pragma unroll
        for (int q = 0; q < 8; ++q) v[q] = 0;
    }
    *(bf16x8*)(out + (size_t)r * KP + g * 8) = v;
}

// W2 [6*CC x CC] fp32 -> W2T [6][KP(n) x KP(k)] bf16
__global__ __launch_bounds__(256) void w2t_kernel(const float* __restrict__ W2,
                                                  unsigned short* __restrict__ out) {
    __shared__ unsigned short tile[64][65];
    int t = threadIdx.x;
    int k0 = blockIdx.x * 64, n0 = blockIdx.y * 64, s = blockIdx.z;
#pragma unroll
    for (int p = 0; p < 16; ++p) {
        int i = p * 256 + t;
        int kk = i >> 6, nn = i & 63;
        int k = k0 + kk, n = n0 + nn;
        float v = (k < CC && n < CC) ? W2[((size_t)s * CC + k) * CC + n] : 0.f;
        tile[kk][nn] = f2bf(v);
    }
    __syncthreads();
#pragma unroll
    for (int p = 0; p < 16; ++p) {
        int i = p * 256 + t;
        int nn = i >> 6, kk = i & 63;
        out[((size_t)s * KP + n0 + nn) * KP + k0 + kk] = tile[kk][nn];
    }
}

// ---------------- MFMA GEMMs (128x128 tile, BK=32, bf16 in / fp32 acc) ----------------

#define LDP 40

__device__ __forceinline__ void gemm_core(const unsigned short* __restrict__ Ag,
                                          const unsigned short* __restrict__ Bg,
                                          short* As, short* Bs, int t,
                                          f32x4 (&acc)[4][4]) {
    int l = t & 63, w = t >> 6;
    int wm = (w >> 1) * 64, wn = (w & 1) * 64;
    int ar0 = t >> 2, ak0 = (t & 3) * 8;
    int ar1 = (t + 256) >> 2, ak1 = ((t + 256) & 3) * 8;
    int lr = l & 15, lq8 = (l >> 4) * 8;
    for (int k0 = 0; k0 < KP; k0 += 32) {
        bf16x8 a0 = *(const bf16x8*)(Ag + (size_t)ar0 * KP + k0 + ak0);
        bf16x8 a1 = *(const bf16x8*)(Ag + (size_t)ar1 * KP + k0 + ak1);
        bf16x8 b0 = *(const bf16x8*)(Bg + (size_t)ar0 * KP + k0 + ak0);
        bf16x8 b1 = *(const bf16x8*)(Bg + (size_t)ar1 * KP + k0 + ak1);
        __syncthreads();
        *(bf16x8*)&As[ar0 * LDP + ak0] = a0;
        *(bf16x8*)&As[ar1 * LDP + ak1] = a1;
        *(bf16x8*)&Bs[ar0 * LDP + ak0] = b0;
        *(bf16x8*)&Bs[ar1 * LDP + ak1] = b1;
        __syncthreads();
        bf16x8 af[4], bfr[4];
#pragma unroll
        for (int mi = 0; mi < 4; ++mi)
            af[mi] = *(const bf16x8*)&As[(wm + mi * 16 + lr) * LDP + lq8];
#pragma unroll
        for (int ni = 0; ni < 4; ++ni)
            bfr[ni] = *(const bf16x8*)&Bs[(wn + ni * 16 + lr) * LDP + lq8];
#pragma unroll
        for (int mi = 0; mi < 4; ++mi)
#pragma unroll
            for (int ni = 0; ni < 4; ++ni)
                acc[mi][ni] = __builtin_amdgcn_mfma_f32_16x16x32_bf16(af[mi], bfr[ni], acc[mi][ni], 0, 0, 0);
    }
}

__global__ __launch_bounds__(256) void gemm_mfma_acc(const unsigned short* __restrict__ A,
                                                     const unsigned short* __restrict__ B,
                                                     float* __restrict__ C) {
    __shared__ short As[128 * LDP];
    __shared__ short Bs[128 * LDP];
    int t = threadIdx.x;
    int n0 = blockIdx.x * 128, m0 = blockIdx.y * 128;
    f32x4 acc[4][4] = {};
    gemm_core(A + (size_t)m0 * KP, B + (size_t)n0 * KP, As, Bs, t, acc);
    int l = t & 63, w = t >> 6;
    int wm = (w >> 1) * 64, wn = (w & 1) * 64;
    int lr = l & 15, lq4 = (l >> 4) * 4;
#pragma unroll
    for (int ni = 0; ni < 4; ++ni) {
        int n = n0 + wn + ni * 16 + lr;
        if (n >= CC) continue;
#pragma unroll
        for (int mi = 0; mi < 4; ++mi) {
            int m = m0 + wm + mi * 16 + lq4;
            f32x4 v = acc[mi][ni];
#pragma unroll
            for (int r = 0; r < 4; ++r) C[(size_t)(m + r) * CC + n] += v[r];
        }
    }
}

__global__ __launch_bounds__(256) void gemm_mfma_final(const unsigned short* __restrict__ A,
                                                       const unsigned short* __restrict__ B,
                                                       float* __restrict__ C,
                                                       const float* __restrict__ b2) {
    __shared__ short As[128 * LDP];
    __shared__ short Bs[128 * LDP];
    int t = threadIdx.x;
    int n0 = blockIdx.x * 128, m0 = blockIdx.y * 128;
    f32x4 acc[4][4] = {};
    gemm_core(A + (size_t)m0 * KP, B + (size_t)n0 * KP, As, Bs, t, acc);
    int l = t & 63, w = t >> 6;
    int wm = (w >> 1) * 64, wn = (w & 1) * 64;
    int lr = l & 15, lq4 = (l >> 4) * 4;
#pragma unroll
    for (int ni = 0; ni < 4; ++ni) {
        int n = n0 + wn + ni * 16 + lr;
        if (n >= CC) continue;
        float bb = b2[n];
#pragma unroll
        for (int mi = 0; mi < 4; ++mi) {
            int m = m0 + wm + mi * 16 + lq4;
            f32x4 v = acc[mi][ni];
#pragma unroll
            for (int r = 0; r < 4; ++r) {
                float* p = &C[(size_t)(m + r) * CC + n];
                *p = fmaxf(*p + v[r] + bb, 0.f);
            }
        }
    }
}

// writes raw distance d (exp deferred to topk emit)
__global__ __launch_bounds__(256) void gram2_mfma(const unsigned short* __restrict__ Abf,
                                                  const float* __restrict__ sq2,
                                                  float* __restrict__ S) {
    __shared__ short As[128 * LDP];
    __shared__ short Bs[128 * LDP];
    int t = threadIdx.x;
    int n0 = blockIdx.x * 128, m0 = blockIdx.y * 128;
    f32x4 acc[4][4] = {};
    gemm_core(Abf + (size_t)m0 * KP, Abf + (size_t)n0 * KP, As, Bs, t, acc);
    int l = t & 63, w = t >> 6;
    int wm = (w >> 1) * 64, wn = (w & 1) * 64;
    int lr = l & 15, lq4 = (l >> 4) * 4;
#pragma unroll
    for (int ni = 0; ni < 4; ++ni) {
        int n = n0 + wn + ni * 16 + lr;
        float sn = sq2[n];
#pragma unroll
        for (int mi = 0; mi < 4; ++mi) {
            int mrow = m0 + wm + mi * 16 + lq4;
            f32x4 v = acc[mi][ni];
#pragma unroll
            for (int r = 0; r < 4; ++r) {
                S[(size_t)(mrow + r) * N4 + n] = sq2[mrow + r] + sn - 2.f * v[r];
            }
        }
    }
}

// ---------------- cheb conv 1 ----------------

__global__ __launch_bounds__(256) void cheb1_out_kernel(const float* __restrict__ xhat,
                                                        const float* __restrict__ W1,
                                                        const float* __restrict__ b1,
                                                        float* __restrict__ outF) {
    __shared__ float xh[16][18];
    int n0 = blockIdx.x * 16;
    int tid = threadIdx.x;
    for (int i = tid; i < 16 * 18; i += 256) xh[i / 18][i % 18] = xhat[(size_t)n0 * 18 + i];
    __syncthreads();
    for (int c0 = 0; c0 < CC; c0 += 256) {
        int c = c0 + tid;
        if (c < CC) {
            float acc[16];
#pragma unroll
            for (int r = 0; r < 16; ++r) acc[r] = 0.f;
            for (int f = 0; f < 18; ++f) {
                float wv = W1[(size_t)f * CC + c];
#pragma unroll
                for (int r = 0; r < 16; ++r) acc[r] += xh[r][f] * wv;
            }
            float bb = b1[c];
#pragma unroll
            for (int r = 0; r < 16; ++r)
                outF[(size_t)(n0 + r) * CC + c] = fmaxf(acc[r] + bb, 0.f);
        }
    }
}

// ---------------- regs (frobenius of O^T @ T) ----------------

__global__ __launch_bounds__(256) void matT6_partial(const float* __restrict__ O,
                                                     const float* __restrict__ T, int ts,
                                                     float* __restrict__ M) {
    __shared__ float sT[128][6];
    int t = threadIdx.x;
    int c = blockIdx.x * 256 + t;
    int n0 = blockIdx.y * 128;
    for (int i = t; i < 128 * 6; i += 256) {
        int nn = i / 6, f = i % 6;
        sT[nn][f] = T[(size_t)(n0 + nn) * ts + f];
    }
    __syncthreads();
    if (c >= CC) return;
    float a0 = 0, a1 = 0, a2 = 0, a3 = 0, a4 = 0, a5 = 0;
    for (int nn = 0; nn < 128; ++nn) {
        float o = O[(size_t)(n0 + nn) * CC + c];
        a0 += o * sT[nn][0]; a1 += o * sT[nn][1]; a2 += o * sT[nn][2];
        a3 += o * sT[nn][3]; a4 += o * sT[nn][4]; a5 += o * sT[nn][5];
    }
    atomicAdd(&M[0 * CC + c], a0);
    atomicAdd(&M[1 * CC + c], a1);
    atomicAdd(&M[2 * CC + c], a2);
    atomicAdd(&M[3 * CC + c], a3);
    atomicAdd(&M[4 * CC + c], a4);
    atomicAdd(&M[5 * CC + c], a5);
}

__global__ __launch_bounds__(256) void fro_kernel(const float* __restrict__ M, float* __restrict__ dst) {
    __shared__ float red[256];
    int t = threadIdx.x;
    int i = blockIdx.x * 256 + t;
    float v = (i < 6 * CC) ? M[i] : 0.f;
    red[t] = v * v;
    __syncthreads();
    for (int o = 128; o; o >>= 1) { if (t < o) red[t] += red[t + o]; __syncthreads(); }
    if (t == 0) atomicAdd(dst, red[0]);
}

// ---------------- pooling ----------------

__global__ __launch_bounds__(256) void vfr_kernel(const float* __restrict__ outF,
                                                  const int* __restrict__ sccs,
                                                  float* __restrict__ vfr) {
    int r = blockIdx.y;
    int c = blockIdx.x * 256 + threadIdx.x;
    if (c >= CC) return;
    int s0 = blockIdx.z * 41;
    float m = 0.f;
    for (int s = s0; s < s0 + 41; ++s) {
        int n = sccs[r * SSC + s];
        m = fmaxf(m, outF[(size_t)n * CC + c]);
    }
    atomicMax((int*)&vfr[(size_t)r * CC + c], __float_as_int(m));
}

__global__ __launch_bounds__(256) void sq2_kernel(const float* __restrict__ outF,
                                                  float* __restrict__ sq2) {
    int lane = threadIdx.x & 63, w = threadIdx.x >> 6;
    int n = blockIdx.x * 4 + w;
    const float* row = outF + (size_t)n * CC;
    float s = 0.f;
    for (int i = lane; i < CC; i += 64) { float v = row[i]; s += v * v; }
#pragma unroll
    for (int o = 32; o; o >>= 1) s += __shfl_down(s, o);
    if (lane == 0) sq2[n] = s;
}

// row-split column max; dst must be zeroed (values >= 0)
__global__ __launch_bounds__(256) void colmax_kernel(const float* __restrict__ O,
                                                     float* __restrict__ dst) {
    int c = blockIdx.x * 256 + threadIdx.x;
    if (c >= CC) return;
    int n0 = blockIdx.y * 64;
    float m = 0.f;
    for (int n = n0; n < n0 + 64; ++n) m = fmaxf(m, O[(size_t)n * CC + c]);
    atomicMax((int*)&dst[c], __float_as_int(m));
}

// ---------------- reeb branch ----------------

__global__ __launch_bounds__(256) void reeb_mm_kernel(const float* __restrict__ Lr,
                                                      const float* __restrict__ Vin,
                                                      const float* __restrict__ Vsub,
                                                      float* __restrict__ Vout, float a2) {
    int c = blockIdx.x * 256 + threadIdx.x;
    if (c >= CC) return;
    int r = blockIdx.y;
    float s = 0.f;
#pragma unroll
    for (int j = 0; j < NRB; ++j) s += Lr[r * NRB + j] * Vin[(size_t)j * CC + c];
    float v = a2 * s;
    if (Vsub) v -= Vsub[(size_t)r * CC + c];
    Vout[(size_t)r * CC + c] = v;
}

#define RKC 25
__global__ __launch_bounds__(256) void reeb_conv_splitk(const float* __restrict__ vfr,
                                                        const float* __restrict__ tr1,
                                                        const float* __restrict__ tr2,
                                                        const float* __restrict__ Wr,
                                                        float* __restrict__ rpre) {
    __shared__ float sA[NRB][RKC];
    int t = threadIdx.x;
    int kbase = blockIdx.y * RKC;
    for (int i = t; i < NRB * RKC; i += 256) {
        int r = i / RKC, kk = i % RKC;
        int kg = kbase + kk;
        float v;
        if (kg < CC)           v = vfr[(size_t)r * CC + kg];
        else if (kg < 2 * CC)  v = tr1[(size_t)r * CC + kg - CC];
        else                   v = tr2[(size_t)r * CC + kg - 2 * CC];
        sA[r][kk] = v;
    }
    __syncthreads();
    int c = blockIdx.x * 256 + t;
    if (c >= CC) return;
    float acc[NRB];
#pragma unroll
    for (int r = 0; r < NRB; ++r) acc[r] = 0.f;
    for (int kk = 0; kk < RKC; ++kk) {
        float wv = Wr[(size_t)(kbase + kk) * CC + c];
#pragma unroll
        for (int r = 0; r < NRB; ++r) acc[r] += sA[r][kk] * wv;
    }
#pragma unroll
    for (int r = 0; r < NRB; ++r) atomicAdd(&rpre[(size_t)r * CC + c], acc[r]);
}

__global__ __launch_bounds__(256) void reeb_max_kernel(const float* __restrict__ pre,
                                                       const float* __restrict__ br,
                                                       float* __restrict__ rbm) {
    int c = blockIdx.x * 256 + threadIdx.x;
    if (c >= CC) return;
    float bb = br[c];
    float m = 0.f;
    for (int r = 0; r < NRB; ++r) m = fmaxf(m, fmaxf(pre[(size_t)r * CC + c] + bb, 0.f));
    rbm[c] = m;
}

// ---------------- FC head ----------------

__global__ __launch_bounds__(256) void fc1_kernel(const float* __restrict__ rbm,
                                                  const float* __restrict__ otm,
                                                  const float* __restrict__ w,
                                                  float* __restrict__ h1pre) {
    int j = blockIdx.x * 256 + threadIdx.x;
    if (j >= 512) return;
    int i0 = blockIdx.y * 250;
    float s = 0.f;
    for (int i = i0; i < i0 + 250; ++i) {
        float v = (i < CC) ? rbm[i] : otm[i - CC];
        s += v * w[(size_t)i * 512 + j];
    }
    atomicAdd(&h1pre[j], s);
}

__global__ __launch_bounds__(512) void fc23_kernel(const float* __restrict__ h1pre,
                                                   const float* __restrict__ b1f,
                                                   const float* __restrict__ w2,
                                                   const float* __restrict__ b2f,
                                                   const float* __restrict__ w3,
                                                   const float* __restrict__ b3f,
                                                   float* __restrict__ dout) {
    __shared__ float h1[512];
    __shared__ float h2[128];
    int t = threadIdx.x;
    h1[t] = fmaxf(h1pre[t] + b1f[t], 0.f);
    __syncthreads();
    if (t < 128) {
        float s = b2f[t];
        for (int i = 0; i < 512; ++i) s += h1[i] * w2[(size_t)i * 128 + t];
        h2[t] = fmaxf(s, 0.f);
    }
    __syncthreads();
    if (t < 40) {
        float s = b3f[t];
        for (int i = 0; i < 128; ++i) s += h2[i] * w3[(size_t)i * 40 + t];
        dout[t] = s;
    }
}

__global__ __launch_bounds__(256) void finalize_kernel(const float* __restrict__ racc,
                                                       const float* __restrict__ f1w,
                                                       const float* __restrict__ f1b,
                                                       const float* __restrict__ f2w,
                                                       const float* __restrict__ f2b,
                                                       const float* __restrict__ f3w,
                                                       const float* __restrict__ f3b,
                                                       float* __restrict__ dout) {
    __shared__ float red[256];
    __shared__ float res[3];
    int t = threadIdx.x;
    float s1 = 0.f, s2 = 0.f, s3 = 0.f;
    for (int i = t; i < 2000; i += 256) { float v = f1w[(size_t)i * 512]; s1 += v * v; }
    for (int i = t; i < 512; i += 256) { float v = f2w[(size_t)i * 128]; s2 += v * v; }
    if (t < 128) { float v = f3w[(size_t)t * 40]; s3 = v * v; }

    red[t] = s1; __syncthreads();
    for (int o = 128; o; o >>= 1) { if (t < o) red[t] += red[t + o]; __syncthreads(); }
    if (t == 0) res[0] = red[0];
    __syncthreads();
    red[t] = s2; __syncthreads();
    for (int o = 128; o; o >>= 1) { if (t < o) red[t] += red[t + o]; __syncthreads(); }
    if (t == 0) res[1] = red[0];
    __syncthreads();
    red[t] = s3; __syncthreads();
    for (int o = 128; o; o >>= 1) { if (t < o) red[t] += red[t + o]; __syncthreads(); }
    if (t == 0) res[2] = red[0];
    __syncthreads();

    if (t == 0) {
        dout[40] = sqrtf(racc[0]);
        dout[41] = sqrtf(racc[1]);
        dout[42] = res[0];
        dout[43] = f1b[0] * f1b[0];
        dout[44] = res[1];
        dout[45] = f2b[0] * f2b[0];
        dout[46] = res[2];
        dout[47] = f3b[0] * f3b[0];
    }
}

// ---------------- host ----------------

extern "C" void kernel_launch(void* const* d_in, const int* in_sizes, int n_in,
                              void* d_out, int out_size, void* d_ws, size_t ws_size,
                              hipStream_t stream) {
    const float* x    = (const float*)d_in[0];
    const float* Lr   = (const float*)d_in[5];
    const int*   sccs = (const int*)d_in[6];
    const float* W1   = (const float*)d_in[7];
    const float* b1   = (const float*)d_in[8];
    const float* W2   = (const float*)d_in[9];
    const float* b2   = (const float*)d_in[10];
    const float* Wr   = (const float*)d_in[11];
    const float* br   = (const float*)d_in[12];
    const float* f1w  = (const float*)d_in[13];
    const float* f1b  = (const float*)d_in[14];
    const float* f2w  = (const float*)d_in[15];
    const float* f2b  = (const float*)d_in[16];
    const float* f3w  = (const float*)d_in[17];
    const float* f3b  = (const float*)d_in[18];
    float* dout = (float*)d_out;

    char* ws = (char*)d_ws;
    size_t off = 0;
    auto alloc = [&](size_t bytes) -> char* {
        char* p = ws + off;
        off = (off + bytes + 255) & ~(size_t)255;
        return p;
    };
    float* outF = (float*)alloc((size_t)N4 * CC * 4);
    float* accC = (float*)alloc((size_t)N4 * CC * 4);
    float* Sb   = (float*)alloc((size_t)N4 * N4 * 4);   // full 4096x4096 distances
    unsigned short* Abf = (unsigned short*)alloc((size_t)N4 * KP * 2);
    unsigned short* Bbf = (unsigned short*)alloc((size_t)N4 * KP * 2);
    unsigned short* Cbf = (unsigned short*)alloc((size_t)N4 * KP * 2);
    unsigned short* W2T = (unsigned short*)Sb;  // alias: Sb dead after topk2
    float* xhat = (float*)alloc((size_t)N4 * 18 * 4);
    float* sq1  = (float*)alloc(N4 * 4);
    float* sq2  = (float*)alloc(N4 * 4);
    float* di1  = (float*)alloc(N4 * 4);
    float* di2  = (float*)alloc(N4 * 4);
    float* wv1  = (float*)alloc((size_t)N4 * KNN * 4);
    float* wv2  = (float*)alloc((size_t)N4 * KNN * 4);
    int*   ix1  = (int*)alloc((size_t)N4 * KNN * 4);
    int*   ix2  = (int*)alloc((size_t)N4 * KNN * 4);
    float* t2x  = (float*)alloc((size_t)N4 * FDIM * 4);
    float* tr1  = (float*)alloc((size_t)NRB * CC * 4);
    float* tr2  = (float*)alloc((size_t)NRB * CC * 4);
    // zero-zone: one memset covers [Mb, Mb2, rbm, otm, h1p, racc, rpre, vfr]
    char*  zbase = ws + off;
    float* Mb   = (float*)alloc(6 * CC * 4);
    float* Mb2  = (float*)alloc(6 * CC * 4);
    float* rbm  = (float*)alloc(CC * 4);
    float* otm  = (float*)alloc(CC * 4);
    float* h1p  = (float*)alloc(512 * 4);
    float* racc = (float*)alloc(64 * 4);
    float* rpre = (float*)alloc((size_t)NRB * CC * 4);
    float* vfr  = (float*)alloc((size_t)NRB * CC * 4);
    size_t zlen = (size_t)((ws + off) - zbase);
    if (off > ws_size) return;

    hipMemsetAsync(accC, 0, (size_t)N4 * CC * 4, stream);
    hipMemsetAsync(zbase, 0, zlen, stream);

    // ---- graph 1 (on x): fused distance + top-40 (exp only for winners) ----
    sqx_kernel<<<(N4 + 255) / 256, 256, 0, stream>>>(x, sq1, xhat);
    topk_fused1<<<N4, 512, 0, stream>>>(x, sq1, ix1, wv1, di1);
    dinv_kernel<<<N4 / 256, 256, 0, stream>>>(di1);
    wnorm_kernel<<<(N4 * KNN + 255) / 256, 256, 0, stream>>>(wv1, ix1, di1);

    // ---- cheb conv 1 ----
    spmv_cheb<<<N4, 64, 0, stream>>>(xhat, xhat, xhat + 6, ix1, wv1, FDIM, 18, 18, 18, 1.f, 0.f);
    spmv_cheb<<<N4, 64, 0, stream>>>(xhat + 6, xhat, xhat + 12, ix1, wv1, FDIM, 18, 18, 18, 2.f, 1.f);
    cheb1_out_kernel<<<N4 / 16, 256, 0, stream>>>(xhat, W1, b1, outF);

    matT6_partial<<<dim3(4, 32), 256, 0, stream>>>(outF, xhat + 6, 18, Mb);
    fro_kernel<<<24, 256, 0, stream>>>(Mb, racc + 0);

    vfr_kernel<<<dim3(4, NRB, 5), 256, 0, stream>>>(outF, sccs, vfr);

    // ---- graph 2 (on outF), bf16 MFMA gram writing raw distances ----
    sq2_kernel<<<N4 / 4, 256, 0, stream>>>(outF, sq2);
    cvt_bf16_kernel<<<N4 * 128 / 256, 256, 0, stream>>>(outF, Abf);
    gram2_mfma<<<dim3(N4 / 128, N4 / 128), 256, 0, stream>>>(Abf, sq2, Sb);
    topk_radix<<<N4, 512, 0, stream>>>(Sb, ix2, wv2, di2);
    dinv_kernel<<<N4 / 256, 256, 0, stream>>>(di2);
    wnorm_kernel<<<(N4 * KNN + 255) / 256, 256, 0, stream>>>(wv2, ix2, di2);

    // Sb dead -> build W2T in its space
    w2t_kernel<<<dim3(16, 16, 6), 256, 0, stream>>>(W2, W2T);

    spmv_cheb<<<N4, 64, 0, stream>>>(x, x, t2x, ix2, wv2, FDIM, FDIM, FDIM, FDIM, 1.f, 0.f);

    // ---- cheb conv 2 (K=6): bf16-resident recursion, mirrors rotate A->B->C ----
    gemm_mfma_acc<<<dim3(8, 32), 256, 0, stream>>>(Abf, W2T + (size_t)0 * KP * KP, accC);
    spmv_cheb_bf<<<N4, 256, 0, stream>>>(Abf, Abf, Bbf, ix2, wv2, 1.f, 0.f);   // T1 = L T0
    gemm_mfma_acc<<<dim3(8, 32), 256, 0, stream>>>(Bbf, W2T + (size_t)1 * KP * KP, accC);
    spmv_cheb_bf<<<N4, 256, 0, stream>>>(Bbf, Abf, Cbf, ix2, wv2, 2.f, 1.f);   // T2
    gemm_mfma_acc<<<dim3(8, 32), 256, 0, stream>>>(Cbf, W2T + (size_t)2 * KP * KP, accC);
    spmv_cheb_bf<<<N4, 256, 0, stream>>>(Cbf, Bbf, Abf, ix2, wv2, 2.f, 1.f);   // T3
    gemm_mfma_acc<<<dim3(8, 32), 256, 0, stream>>>(Abf, W2T + (size_t)3 * KP * KP, accC);
    spmv_cheb_bf<<<N4, 256, 0, stream>>>(Abf, Cbf, Bbf, ix2, wv2, 2.f, 1.f);   // T4
    gemm_mfma_acc<<<dim3(8, 32), 256, 0, stream>>>(Bbf, W2T + (size_t)4 * KP * KP, accC);
    spmv_cheb_bf<<<N4, 256, 0, stream>>>(Bbf, Abf, Cbf, ix2, wv2, 2.f, 1.f);   // T5
    gemm_mfma_final<<<dim3(8, 32), 256, 0, stream>>>(Cbf, W2T + (size_t)5 * KP * KP, accC, b2);

    matT6_partial<<<dim3(4, 32), 256, 0, stream>>>(accC, t2x, FDIM, Mb2);
    fro_kernel<<<24, 256, 0, stream>>>(Mb2, racc + 1);

    colmax_kernel<<<dim3(4, 64), 256, 0, stream>>>(accC, otm);

    // ---- reeb cheb conv (K=3) ----
    reeb_mm_kernel<<<dim3(4, NRB), 256, 0, stream>>>(Lr, vfr, nullptr, tr1, 1.f);
    reeb_mm_kernel<<<dim3(4, NRB), 256, 0, stream>>>(Lr, tr1, vfr, tr2, 2.f);
    reeb_conv_splitk<<<dim3(4, 120), 256, 0, stream>>>(vfr, tr1, tr2, Wr, rpre);
    reeb_max_kernel<<<4, 256, 0, stream>>>(rpre, br, rbm);

    // ---- FC head ----
    fc1_kernel<<<dim3(2, 8), 256, 0, stream>>>(rbm, otm, f1w, h1p);
    fc23_kernel<<<1, 512, 0, stream>>>(h1p, f1b, f2w, f2b, f3w, f3b, dout);
    finalize_kernel<<<1, 256, 0, stream>>>(racc, f1w, f1b, f2w, f2b, f3w, f3b, dout);
}

// Round 11
// 760.855 us; speedup vs baseline: 4.5738x; 1.0564x over previous
//
#include <hip/hip_runtime.h>
#include <math.h>

#define N4    4096
#define FDIM  6
#define CC    1000
#define KP    1024
#define KP6   (6 * KP)
#define KNN   40
#define NRB   20
#define SSC   205

typedef __attribute__((ext_vector_type(8))) short bf16x8;
typedef __attribute__((ext_vector_type(4))) float f32x4;

__device__ __forceinline__ unsigned short f2bf(float f) {
    unsigned u = __float_as_uint(f);
    u = (u + 0x7fffu + ((u >> 16) & 1u)) >> 16;
    return (unsigned short)u;
}
__device__ __forceinline__ float bf2f(short s) {
    return __uint_as_float(((unsigned)(unsigned short)s) << 16);
}

// distance -> descending-sortable key (smaller d == larger key)
__device__ __forceinline__ unsigned d2key(float d) {
    unsigned u = __float_as_uint(d);
    return ((int)u < 0) ? u : (~u) ^ 0x80000000u;
}
__device__ __forceinline__ float key2d(unsigned k) {
    unsigned u = (k >> 31) ? k : (~k) ^ 0x80000000u;
    return __uint_as_float(u);
}

// ---------------- graph build ----------------

__global__ __launch_bounds__(256) void sqx_kernel(const float* __restrict__ x,
                                                  float* __restrict__ sq1,
                                                  float* __restrict__ xhat) {
    int n = blockIdx.x * blockDim.x + threadIdx.x;
    if (n >= N4) return;
    float s = 0.f;
#pragma unroll
    for (int f = 0; f < FDIM; ++f) {
        float v = x[n * FDIM + f];
        s += v * v;
        xhat[n * 18 + f] = v;
    }
    sq1[n] = s;
}

// ---------------- radix top-40 on distance keys (exact) ----------------

#define NHC 8
#define HSTRIDE 257

struct TopkSh {
    unsigned sv[N4];
    int hist[NHC * HSTRIDE];
    int sc[256];
    float red[512];
    unsigned short cidx[N4];
    unsigned s_pfx;
    int s_need, s_cnt, s_m;
};

__device__ __forceinline__ void hist_pick(TopkSh& sh, int level, int t, int lane, int w) {
    if (t < 256) {
        int cnt = 0;
#pragma unroll
        for (int c = 0; c < NHC; ++c) cnt += sh.hist[c * HSTRIDE + t];
        sh.sc[t] = cnt;
    }
    __syncthreads();
    if (w == 0) {
        int need = sh.s_need;
        unsigned pfx = sh.s_pfx;
        int c0 = sh.sc[4 * lane + 0], c1 = sh.sc[4 * lane + 1];
        int c2 = sh.sc[4 * lane + 2], c3 = sh.sc[4 * lane + 3];
        int s = c0 + c1 + c2 + c3;
        int suf = s;
#pragma unroll
        for (int off = 1; off < 64; off <<= 1) {
            int ov = __shfl_down(suf, off, 64);
            if (lane + off < 64) suf += ov;
        }
        int above = suf - s;
        int i3 = above + c3, i2 = i3 + c2, i1 = i2 + c1, i0 = i1 + c0;
        if (i3 >= need && i3 - c3 < need) { sh.s_need = need - (i3 - c3); sh.s_pfx = pfx | ((unsigned)(4 * lane + 3) << level); }
        if (i2 >= need && i2 - c2 < need) { sh.s_need = need - (i2 - c2); sh.s_pfx = pfx | ((unsigned)(4 * lane + 2) << level); }
        if (i1 >= need && i1 - c1 < need) { sh.s_need = need - (i1 - c1); sh.s_pfx = pfx | ((unsigned)(4 * lane + 1) << level); }
        if (i0 >= need && i0 - c0 < need) { sh.s_need = need - (i0 - c0); sh.s_pfx = pfx | ((unsigned)(4 * lane + 0) << level); }
    }
    __syncthreads();
}

__device__ void topk_select(TopkSh& sh, int n, int* __restrict__ idx,
                            float* __restrict__ val, float* __restrict__ rowsum) {
    int t = threadIdx.x, lane = t & 63, w = t >> 6;
    if (t == 0) { sh.s_pfx = 0u; sh.s_need = KNN; sh.s_cnt = 0; sh.s_m = 0; }
    for (int q = t; q < NHC * HSTRIDE; q += 512) sh.hist[q] = 0;
    __syncthreads();
    int* hw = &sh.hist[(t & 7) * HSTRIDE];

    // pass 1: full scan, top byte, run-length flushed (keys cluster by exponent)
    {
        unsigned prevb = 0xFFFFFFFFu; int rl = 0;
        for (int i = t; i < N4; i += 512) {
            unsigned b = sh.sv[i] >> 24;
            if (b == prevb) ++rl;
            else { if (rl) atomicAdd(&hw[prevb], rl); prevb = b; rl = 1; }
        }
        if (rl) atomicAdd(&hw[prevb], rl);
    }
    __syncthreads();
    hist_pick(sh, 24, t, lane, w);
    unsigned b1 = sh.s_pfx >> 24;

    // compact ==b1 (ballot-aggregated), emit >b1 directly (provably top-40)
    float psum = 0.f;
    for (int i = t; i < N4; i += 512) {
        unsigned u = sh.sv[i];
        unsigned tb = u >> 24;
        bool isc = (tb == b1);
        unsigned long long mm = __ballot(isc);
        int cw = __popcll(mm);
        int base = 0;
        if (lane == 0 && cw) base = atomicAdd(&sh.s_m, cw);
        base = __shfl(base, 0);
        if (isc) sh.cidx[base + __popcll(mm & ((1ull << lane) - 1ull))] = (unsigned short)i;

        bool isg = (tb > b1);
        unsigned long long mg = __ballot(isg);
        int gw = __popcll(mg);
        int gbase = 0;
        if (lane == 0 && gw) gbase = atomicAdd(&sh.s_cnt, gw);
        gbase = __shfl(gbase, 0);
        if (isg) {
            int p = gbase + __popcll(mg & ((1ull << lane) - 1ull));
            float v = __expf(-key2d(u));
            idx[(size_t)n * KNN + p] = i;
            val[(size_t)n * KNN + p] = v;
            psum += v;
        }
    }
    __syncthreads();
    int mcnt = sh.s_m;

    // levels 16, 8, 0 over the compacted list
    for (int level = 16; level >= 0; level -= 8) {
        for (int q = t; q < NHC * HSTRIDE; q += 512) sh.hist[q] = 0;
        __syncthreads();
        unsigned pfx = sh.s_pfx;
        for (int j = t; j < mcnt; j += 512) {
            unsigned u = sh.sv[sh.cidx[j]];
            if ((u >> (level + 8)) == (pfx >> (level + 8)))
                atomicAdd(&hw[(u >> level) & 255], 1);
        }
        __syncthreads();
        hist_pick(sh, level, t, lane, w);
    }
    unsigned Tbits = sh.s_pfx;
    float Tf = __expf(-key2d(Tbits));
    int needEq = sh.s_need;

    // collect >T within the compacted list
    for (int j = t; j < mcnt; j += 512) {
        unsigned u = sh.sv[sh.cidx[j]];
        if (u > Tbits) {
            int p = atomicAdd(&sh.s_cnt, 1);
            float v = __expf(-key2d(u));
            idx[(size_t)n * KNN + p] = (int)sh.cidx[j];
            val[(size_t)n * KNN + p] = v;
            psum += v;
        }
    }
    sh.red[t] = psum;
    __syncthreads();
    for (int o = 256; o; o >>= 1) { if (t < o) sh.red[t] += sh.red[t + o]; __syncthreads(); }
    if (t == 0) rowsum[n] = sh.red[0] + (float)needEq * Tf;

    // equals: earliest indices first (wave 0 ballot scan)
    if (t < 64) {
        int filled = KNN - needEq;
        for (int ib = 0; ib < N4 && filled < KNN; ib += 64) {
            bool eq = (sh.sv[ib + t] == Tbits);
            unsigned long long m = __ballot(eq);
            int pre = __popcll(m & ((1ull << t) - 1ull));
            if (eq && (filled + pre) < KNN) {
                idx[(size_t)n * KNN + filled + pre] = ib + t;
                val[(size_t)n * KNN + filled + pre] = Tf;
            }
            filled += __popcll(m);
        }
    }
}

// graph-1: distances computed in-kernel
__global__ __launch_bounds__(512) void topk_fused1(const float* __restrict__ x,
                                                   const float* __restrict__ sq1,
                                                   int* __restrict__ idx, float* __restrict__ val,
                                                   float* __restrict__ rowsum) {
    __shared__ TopkSh sh;
    __shared__ float xn[FDIM];
    __shared__ float sns;
    int n = blockIdx.x;
    int t = threadIdx.x;
    if (t < FDIM) xn[t] = x[n * FDIM + t];
    if (t == FDIM) sns = sq1[n];
    __syncthreads();
    float x0 = xn[0], x1 = xn[1], x2 = xn[2], x3 = xn[3], x4 = xn[4], x5 = xn[5];
    float sn = sns;
    for (int i = t; i < N4; i += 512) {
        const float2* xi = (const float2*)(x + i * FDIM);
        float2 p0 = xi[0], p1 = xi[1], p2 = xi[2];
        float d = x0 * p0.x + x1 * p0.y + x2 * p1.x + x3 * p1.y + x4 * p2.x + x5 * p2.y;
        float e = sn + sq1[i] - 2.f * d;
        sh.sv[i] = d2key(e);
    }
    topk_select(sh, n, idx, val, rowsum);
}

// graph-2: reads precomputed distance row
__global__ __launch_bounds__(512) void topk_radix(const float* __restrict__ S,
                                                  int* __restrict__ idx, float* __restrict__ val,
                                                  float* __restrict__ rowsum) {
    __shared__ TopkSh sh;
    int n = blockIdx.x;
    int t = threadIdx.x;
    const float* row = S + (size_t)n * N4;
    float4 a = *(const float4*)(row + 8 * t);
    float4 b = *(const float4*)(row + 8 * t + 4);
    sh.sv[8 * t + 0] = d2key(a.x); sh.sv[8 * t + 1] = d2key(a.y);
    sh.sv[8 * t + 2] = d2key(a.z); sh.sv[8 * t + 3] = d2key(a.w);
    sh.sv[8 * t + 4] = d2key(b.x); sh.sv[8 * t + 5] = d2key(b.y);
    sh.sv[8 * t + 6] = d2key(b.z); sh.sv[8 * t + 7] = d2key(b.w);
    topk_select(sh, n, idx, val, rowsum);
}

__global__ __launch_bounds__(256) void dinv_kernel(float* __restrict__ rs) {
    int n = blockIdx.x * 256 + threadIdx.x;
    if (n < N4) rs[n] = rsqrtf(rs[n]);
}

__global__ __launch_bounds__(256) void wnorm_kernel(float* __restrict__ wv,
                                                    const int* __restrict__ idx,
                                                    const float* __restrict__ dinv) {
    int i = blockIdx.x * 256 + threadIdx.x;
    if (i >= N4 * KNN) return;
    int n = i / KNN;
    wv[i] = wv[i] * dinv[n] * dinv[idx[i]];
}

// Tn[n,:] = a*(Tc[n,:] - sum_j wv[n,j]*Tc[idx[n,j],:]) - b*Tp[n,:]   (F small, fp32)
__global__ __launch_bounds__(64) void spmv_cheb(const float* __restrict__ Tc,
                                                const float* __restrict__ Tp,
                                                float* __restrict__ Tn,
                                                const int* __restrict__ idx,
                                                const float* __restrict__ wv,
                                                int F, int sC, int sP, int sN,
                                                float a, float b) {
    __shared__ int   si[KNN];
    __shared__ float sw[KNN];
    int n = blockIdx.x;
    if (threadIdx.x < KNN) {
        si[threadIdx.x] = idx[(size_t)n * KNN + threadIdx.x];
        sw[threadIdx.x] = wv[(size_t)n * KNN + threadIdx.x];
    }
    __syncthreads();
    for (int c = threadIdx.x; c < F; c += blockDim.x) {
        float s = 0.f;
#pragma unroll 8
        for (int j = 0; j < KNN; ++j) s += sw[j] * Tc[(size_t)si[j] * sC + c];
        float v = a * (Tc[(size_t)n * sC + c] - s);
        if (b != 0.f) v -= b * Tp[(size_t)n * sP + c];
        Tn[(size_t)n * sN + c] = v;
    }
}

// bf16-resident recursion over Tall slices (row stride KP6)
__global__ __launch_bounds__(256) void spmv_cheb_bf(const unsigned short* __restrict__ Tcbf,
                                                    const unsigned short* __restrict__ Tpbf,
                                                    unsigned short* __restrict__ Tnbf,
                                                    const int* __restrict__ idx,
                                                    const float* __restrict__ wv,
                                                    float a, float b) {
    __shared__ int   si[KNN];
    __shared__ float sw[KNN];
    __shared__ float part[128][8];
    int n = blockIdx.x;
    int t = threadIdx.x;
    int tt = t & 127, h = t >> 7;
    if (t < KNN) {
        si[t] = idx[(size_t)n * KNN + t];
        sw[t] = wv[(size_t)n * KNN + t];
    }
    __syncthreads();
    int c = tt * 8;
    float acc0 = 0, acc1 = 0, acc2 = 0, acc3 = 0, acc4 = 0, acc5 = 0, acc6 = 0, acc7 = 0;
    int j0 = h * 20;
#pragma unroll 4
    for (int j = j0; j < j0 + 20; ++j) {
        bf16x8 v = *(const bf16x8*)(Tcbf + (size_t)si[j] * KP6 + c);
        float wj = sw[j];
        acc0 += wj * bf2f(v[0]); acc1 += wj * bf2f(v[1]);
        acc2 += wj * bf2f(v[2]); acc3 += wj * bf2f(v[3]);
        acc4 += wj * bf2f(v[4]); acc5 += wj * bf2f(v[5]);
        acc6 += wj * bf2f(v[6]); acc7 += wj * bf2f(v[7]);
    }
    if (h == 1) {
        part[tt][0] = acc0; part[tt][1] = acc1; part[tt][2] = acc2; part[tt][3] = acc3;
        part[tt][4] = acc4; part[tt][5] = acc5; part[tt][6] = acc6; part[tt][7] = acc7;
    }
    __syncthreads();
    if (h == 0) {
        acc0 += part[tt][0]; acc1 += part[tt][1]; acc2 += part[tt][2]; acc3 += part[tt][3];
        acc4 += part[tt][4]; acc5 += part[tt][5]; acc6 += part[tt][6]; acc7 += part[tt][7];
        bf16x8 tc = *(const bf16x8*)(Tcbf + (size_t)n * KP6 + c);
        float o0 = a * (bf2f(tc[0]) - acc0), o1 = a * (bf2f(tc[1]) - acc1);
        float o2 = a * (bf2f(tc[2]) - acc2), o3 = a * (bf2f(tc[3]) - acc3);
        float o4 = a * (bf2f(tc[4]) - acc4), o5 = a * (bf2f(tc[5]) - acc5);
        float o6 = a * (bf2f(tc[6]) - acc6), o7 = a * (bf2f(tc[7]) - acc7);
        if (b != 0.f) {
            bf16x8 tp = *(const bf16x8*)(Tpbf + (size_t)n * KP6 + c);
            o0 -= b * bf2f(tp[0]); o1 -= b * bf2f(tp[1]);
            o2 -= b * bf2f(tp[2]); o3 -= b * bf2f(tp[3]);
            o4 -= b * bf2f(tp[4]); o5 -= b * bf2f(tp[5]);
            o6 -= b * bf2f(tp[6]); o7 -= b * bf2f(tp[7]);
        }
        bf16x8 ob;
        ob[0] = (short)f2bf(o0); ob[1] = (short)f2bf(o1);
        ob[2] = (short)f2bf(o2); ob[3] = (short)f2bf(o3);
        ob[4] = (short)f2bf(o4); ob[5] = (short)f2bf(o5);
        ob[6] = (short)f2bf(o6); ob[7] = (short)f2bf(o7);
        *(bf16x8*)(Tnbf + (size_t)n * KP6 + c) = ob;
    }
}

// ---------------- bf16 conversion / transpose ----------------

// fp32 [N4 x CC] -> Tall slice 0 (bf16, row stride KP6, zero-padded)
__global__ __launch_bounds__(256) void cvt_bf16_kernel(const float* __restrict__ in,
                                                       unsigned short* __restrict__ out) {
    int i = blockIdx.x * 256 + threadIdx.x;
    int r = i >> 7, g = i & 127;
    bf16x8 v;
    if (g < 125) {
        float4 a = *(const float4*)(in + (size_t)r * CC + g * 8);
        float4 b = *(const float4*)(in + (size_t)r * CC + g * 8 + 4);
        v[0] = (short)f2bf(a.x); v[1] = (short)f2bf(a.y);
        v[2] = (short)f2bf(a.z); v[3] = (short)f2bf(a.w);
        v[4] = (short)f2bf(b.x); v[5] = (short)f2bf(b.y);
        v[6] = (short)f2bf(b.z); v[7] = (short)f2bf(b.w);
    } else {
#pragma unroll
        for (int q = 0; q < 8; ++q) v[q] = 0;
    }
    *(bf16x8*)(out + (size_t)r * KP6 + g * 8) = v;
}

// W2 [6*CC x CC] fp32 -> W2T6 [1024 rows(n)][KP6 cols(k)] bf16
__global__ __launch_bounds__(256) void w2t_kernel(const float* __restrict__ W2,
                                                  unsigned short* __restrict__ out) {
    __shared__ unsigned short tile[64][65];
    int t = threadIdx.x;
    int k0 = blockIdx.x * 64, n0 = blockIdx.y * 64, s = blockIdx.z;
#pragma unroll
    for (int p = 0; p < 16; ++p) {
        int i = p * 256 + t;
        int kk = i >> 6, nn = i & 63;
        int k = k0 + kk, n = n0 + nn;
        float v = (k < CC && n < CC) ? W2[((size_t)s * CC + k) * CC + n] : 0.f;
        tile[kk][nn] = f2bf(v);
    }
    __syncthreads();
#pragma unroll
    for (int p = 0; p < 16; ++p) {
        int i = p * 256 + t;
        int nn = i >> 6, kk = i & 63;
        out[(size_t)(n0 + nn) * KP6 + (size_t)s * KP + k0 + kk] = tile[kk][nn];
    }
}

// ---------------- MFMA GEMMs (128x128 tile, BK=32, bf16 in / fp32 acc) ----------------

#define LDP 40

template<int STR>
__device__ __forceinline__ void gemm_core(const unsigned short* __restrict__ Ag,
                                          const unsigned short* __restrict__ Bg,
                                          short* As, short* Bs, int t,
                                          int kbeg, int kend,
                                          f32x4 (&acc)[4][4]) {
    int l = t & 63, w = t >> 6;
    int wm = (w >> 1) * 64, wn = (w & 1) * 64;
    int ar0 = t >> 2, ak0 = (t & 3) * 8;
    int ar1 = (t + 256) >> 2, ak1 = ((t + 256) & 3) * 8;
    int lr = l & 15, lq8 = (l >> 4) * 8;
    for (int k0 = kbeg; k0 < kend; k0 += 32) {
        bf16x8 a0 = *(const bf16x8*)(Ag + (size_t)ar0 * STR + k0 + ak0);
        bf16x8 a1 = *(const bf16x8*)(Ag + (size_t)ar1 * STR + k0 + ak1);
        bf16x8 b0 = *(const bf16x8*)(Bg + (size_t)ar0 * STR + k0 + ak0);
        bf16x8 b1 = *(const bf16x8*)(Bg + (size_t)ar1 * STR + k0 + ak1);
        __syncthreads();
        *(bf16x8*)&As[ar0 * LDP + ak0] = a0;
        *(bf16x8*)&As[ar1 * LDP + ak1] = a1;
        *(bf16x8*)&Bs[ar0 * LDP + ak0] = b0;
        *(bf16x8*)&Bs[ar1 * LDP + ak1] = b1;
        __syncthreads();
        bf16x8 af[4], bfr[4];
#pragma unroll
        for (int mi = 0; mi < 4; ++mi)
            af[mi] = *(const bf16x8*)&As[(wm + mi * 16 + lr) * LDP + lq8];
#pragma unroll
        for (int ni = 0; ni < 4; ++ni)
            bfr[ni] = *(const bf16x8*)&Bs[(wn + ni * 16 + lr) * LDP + lq8];
#pragma unroll
        for (int mi = 0; mi < 4; ++mi)
#pragma unroll
            for (int ni = 0; ni < 4; ++ni)
                acc[mi][ni] = __builtin_amdgcn_mfma_f32_16x16x32_bf16(af[mi], bfr[ni], acc[mi][ni], 0, 0, 0);
    }
}

// batched cheb2 GEMM: C_part[z] = Tall[:, z*2048:(z+1)*2048] @ W2T6[:, same]^T
__global__ __launch_bounds__(256) void gemm_mfma_big(const unsigned short* __restrict__ A,
                                                     const unsigned short* __restrict__ B,
                                                     float* __restrict__ Cp) {
    __shared__ short As[128 * LDP];
    __shared__ short Bs[128 * LDP];
    int t = threadIdx.x;
    int n0 = blockIdx.x * 128, m0 = blockIdx.y * 128;
    int kz = blockIdx.z;
    float* C = Cp + (size_t)kz * N4 * CC;
    f32x4 acc[4][4] = {};
    gemm_core<KP6>(A + (size_t)m0 * KP6, B + (size_t)n0 * KP6, As, Bs, t,
                   kz * 2048, kz * 2048 + 2048, acc);
    int l = t & 63, w = t >> 6;
    int wm = (w >> 1) * 64, wn = (w & 1) * 64;
    int lr = l & 15, lq4 = (l >> 4) * 4;
#pragma unroll
    for (int ni = 0; ni < 4; ++ni) {
        int n = n0 + wn + ni * 16 + lr;
        if (n >= CC) continue;
#pragma unroll
        for (int mi = 0; mi < 4; ++mi) {
            int m = m0 + wm + mi * 16 + lq4;
            f32x4 v = acc[mi][ni];
#pragma unroll
            for (int r = 0; r < 4; ++r) C[(size_t)(m + r) * CC + n] = v[r];
        }
    }
}

// out2 = relu(C0 + C1 + C2 + b2)   (in place into C0)
__global__ __launch_bounds__(256) void bias_relu_merge(float* __restrict__ C,
                                                       const float* __restrict__ b2) {
    size_t i = (size_t)blockIdx.x * 256 + threadIdx.x;
    if (i >= (size_t)N4 * CC) return;
    int c = (int)(i % CC);
    C[i] = fmaxf(C[i] + C[i + (size_t)N4 * CC] + C[i + 2 * (size_t)N4 * CC] + b2[c], 0.f);
}

// gram over Tall slice 0 -> raw distances
__global__ __launch_bounds__(256) void gram2_mfma(const unsigned short* __restrict__ Tall,
                                                  const float* __restrict__ sq2,
                                                  float* __restrict__ S) {
    __shared__ short As[128 * LDP];
    __shared__ short Bs[128 * LDP];
    int t = threadIdx.x;
    int n0 = blockIdx.x * 128, m0 = blockIdx.y * 128;
    f32x4 acc[4][4] = {};
    gemm_core<KP6>(Tall + (size_t)m0 * KP6, Tall + (size_t)n0 * KP6, As, Bs, t, 0, KP, acc);
    int l = t & 63, w = t >> 6;
    int wm = (w >> 1) * 64, wn = (w & 1) * 64;
    int lr = l & 15, lq4 = (l >> 4) * 4;
#pragma unroll
    for (int ni = 0; ni < 4; ++ni) {
        int n = n0 + wn + ni * 16 + lr;
        float sn = sq2[n];
#pragma unroll
        for (int mi = 0; mi < 4; ++mi) {
            int mrow = m0 + wm + mi * 16 + lq4;
            f32x4 v = acc[mi][ni];
#pragma unroll
            for (int r = 0; r < 4; ++r) {
                S[(size_t)(mrow + r) * N4 + n] = sq2[mrow + r] + sn - 2.f * v[r];
            }
        }
    }
}

// ---------------- cheb conv 1 ----------------

__global__ __launch_bounds__(256) void cheb1_out_kernel(const float* __restrict__ xhat,
                                                        const float* __restrict__ W1,
                                                        const float* __restrict__ b1,
                                                        float* __restrict__ outF) {
    __shared__ float xh[16][18];
    int n0 = blockIdx.x * 16;
    int tid = threadIdx.x;
    for (int i = tid; i < 16 * 18; i += 256) xh[i / 18][i % 18] = xhat[(size_t)n0 * 18 + i];
    __syncthreads();
    for (int c0 = 0; c0 < CC; c0 += 256) {
        int c = c0 + tid;
        if (c < CC) {
            float acc[16];
#pragma unroll
            for (int r = 0; r < 16; ++r) acc[r] = 0.f;
            for (int f = 0; f < 18; ++f) {
                float wv = W1[(size_t)f * CC + c];
#pragma unroll
                for (int r = 0; r < 16; ++r) acc[r] += xh[r][f] * wv;
            }
            float bb = b1[c];
#pragma unroll
            for (int r = 0; r < 16; ++r)
                outF[(size_t)(n0 + r) * CC + c] = fmaxf(acc[r] + bb, 0.f);
        }
    }
}

// ---------------- regs (frobenius of O^T @ T) ----------------

__global__ __launch_bounds__(256) void matT6_partial(const float* __restrict__ O,
                                                     const float* __restrict__ T, int ts,
                                                     float* __restrict__ M) {
    __shared__ float sT[128][6];
    int t = threadIdx.x;
    int c = blockIdx.x * 256 + t;
    int n0 = blockIdx.y * 128;
    for (int i = t; i < 128 * 6; i += 256) {
        int nn = i / 6, f = i % 6;
        sT[nn][f] = T[(size_t)(n0 + nn) * ts + f];
    }
    __syncthreads();
    if (c >= CC) return;
    float a0 = 0, a1 = 0, a2 = 0, a3 = 0, a4 = 0, a5 = 0;
    for (int nn = 0; nn < 128; ++nn) {
        float o = O[(size_t)(n0 + nn) * CC + c];
        a0 += o * sT[nn][0]; a1 += o * sT[nn][1]; a2 += o * sT[nn][2];
        a3 += o * sT[nn][3]; a4 += o * sT[nn][4]; a5 += o * sT[nn][5];
    }
    atomicAdd(&M[0 * CC + c], a0);
    atomicAdd(&M[1 * CC + c], a1);
    atomicAdd(&M[2 * CC + c], a2);
    atomicAdd(&M[3 * CC + c], a3);
    atomicAdd(&M[4 * CC + c], a4);
    atomicAdd(&M[5 * CC + c], a5);
}

__global__ __launch_bounds__(256) void fro_kernel(const float* __restrict__ M, float* __restrict__ dst) {
    __shared__ float red[256];
    int t = threadIdx.x;
    int i = blockIdx.x * 256 + t;
    float v = (i < 6 * CC) ? M[i] : 0.f;
    red[t] = v * v;
    __syncthreads();
    for (int o = 128; o; o >>= 1) { if (t < o) red[t] += red[t + o]; __syncthreads(); }
    if (t == 0) atomicAdd(dst, red[0]);
}

// ---------------- pooling ----------------

__global__ __launch_bounds__(256) void vfr_kernel(const float* __restrict__ outF,
                                                  const int* __restrict__ sccs,
                                                  float* __restrict__ vfr) {
    int r = blockIdx.y;
    int c = blockIdx.x * 256 + threadIdx.x;
    if (c >= CC) return;
    int s0 = blockIdx.z * 41;
    float m = 0.f;
    for (int s = s0; s < s0 + 41; ++s) {
        int n = sccs[r * SSC + s];
        m = fmaxf(m, outF[(size_t)n * CC + c]);
    }
    atomicMax((int*)&vfr[(size_t)r * CC + c], __float_as_int(m));
}

__global__ __launch_bounds__(256) void sq2_kernel(const float* __restrict__ outF,
                                                  float* __restrict__ sq2) {
    int lane = threadIdx.x & 63, w = threadIdx.x >> 6;
    int n = blockIdx.x * 4 + w;
    const float* row = outF + (size_t)n * CC;
    float s = 0.f;
    for (int i = lane; i < CC; i += 64) { float v = row[i]; s += v * v; }
#pragma unroll
    for (int o = 32; o; o >>= 1) s += __shfl_down(s, o);
    if (lane == 0) sq2[n] = s;
}

// row-split column max; dst must be zeroed (values >= 0)
__global__ __launch_bounds__(256) void colmax_kernel(const float* __restrict__ O,
                                                     float* __restrict__ dst) {
    int c = blockIdx.x * 256 + threadIdx.x;
    if (c >= CC) return;
    int n0 = blockIdx.y * 64;
    float m = 0.f;
    for (int n = n0; n < n0 + 64; ++n) m = fmaxf(m, O[(size_t)n * CC + c]);
    atomicMax((int*)&dst[c], __float_as_int(m));
}

// ---------------- reeb branch ----------------

__global__ __launch_bounds__(256) void reeb_mm_kernel(const float* __restrict__ Lr,
                                                      const float* __restrict__ Vin,
                                                      const float* __restrict__ Vsub,
                                                      float* __restrict__ Vout, float a2) {
    int c = blockIdx.x * 256 + threadIdx.x;
    if (c >= CC) return;
    int r = blockIdx.y;
    float s = 0.f;
#pragma unroll
    for (int j = 0; j < NRB; ++j) s += Lr[r * NRB + j] * Vin[(size_t)j * CC + c];
    float v = a2 * s;
    if (Vsub) v -= Vsub[(size_t)r * CC + c];
    Vout[(size_t)r * CC + c] = v;
}

#define RKC 25
__global__ __launch_bounds__(256) void reeb_conv_splitk(const float* __restrict__ vfr,
                                                        const float* __restrict__ tr1,
                                                        const float* __restrict__ tr2,
                                                        const float* __restrict__ Wr,
                                                        float* __restrict__ rpre) {
    __shared__ float sA[NRB][RKC];
    int t = threadIdx.x;
    int kbase = blockIdx.y * RKC;
    for (int i = t; i < NRB * RKC; i += 256) {
        int r = i / RKC, kk = i % RKC;
        int kg = kbase + kk;
        float v;
        if (kg < CC)           v = vfr[(size_t)r * CC + kg];
        else if (kg < 2 * CC)  v = tr1[(size_t)r * CC + kg - CC];
        else                   v = tr2[(size_t)r * CC + kg - 2 * CC];
        sA[r][kk] = v;
    }
    __syncthreads();
    int c = blockIdx.x * 256 + t;
    if (c >= CC) return;
    float acc[NRB];
#pragma unroll
    for (int r = 0; r < NRB; ++r) acc[r] = 0.f;
    for (int kk = 0; kk < RKC; ++kk) {
        float wv = Wr[(size_t)(kbase + kk) * CC + c];
#pragma unroll
        for (int r = 0; r < NRB; ++r) acc[r] += sA[r][kk] * wv;
    }
#pragma unroll
    for (int r = 0; r < NRB; ++r) atomicAdd(&rpre[(size_t)r * CC + c], acc[r]);
}

__global__ __launch_bounds__(256) void reeb_max_kernel(const float* __restrict__ pre,
                                                       const float* __restrict__ br,
                                                       float* __restrict__ rbm) {
    int c = blockIdx.x * 256 + threadIdx.x;
    if (c >= CC) return;
    float bb = br[c];
    float m = 0.f;
    for (int r = 0; r < NRB; ++r) m = fmaxf(m, fmaxf(pre[(size_t)r * CC + c] + bb, 0.f));
    rbm[c] = m;
}

// ---------------- FC head ----------------

__global__ __launch_bounds__(256) void fc1_kernel(const float* __restrict__ rbm,
                                                  const float* __restrict__ otm,
                                                  const float* __restrict__ w,
                                                  float* __restrict__ h1pre) {
    int j = blockIdx.x * 256 + threadIdx.x;
    if (j >= 512) return;
    int i0 = blockIdx.y * 250;
    float s = 0.f;
    for (int i = i0; i < i0 + 250; ++i) {
        float v = (i < CC) ? rbm[i] : otm[i - CC];
        s += v * w[(size_t)i * 512 + j];
    }
    atomicAdd(&h1pre[j], s);
}

__global__ __launch_bounds__(512) void fc23_kernel(const float* __restrict__ h1pre,
                                                   const float* __restrict__ b1f,
                                                   const float* __restrict__ w2,
                                                   const float* __restrict__ b2f,
                                                   const float* __restrict__ w3,
                                                   const float* __restrict__ b3f,
                                                   float* __restrict__ dout) {
    __shared__ float h1[512];
    __shared__ float h2[128];
    int t = threadIdx.x;
    h1[t] = fmaxf(h1pre[t] + b1f[t], 0.f);
    __syncthreads();
    if (t < 128) {
        float s = b2f[t];
        for (int i = 0; i < 512; ++i) s += h1[i] * w2[(size_t)i * 128 + t];
        h2[t] = fmaxf(s, 0.f);
    }
    __syncthreads();
    if (t < 40) {
        float s = b3f[t];
        for (int i = 0; i < 128; ++i) s += h2[i] * w3[(size_t)i * 40 + t];
        dout[t] = s;
    }
}

__global__ __launch_bounds__(256) void finalize_kernel(const float* __restrict__ racc,
                                                       const float* __restrict__ f1w,
                                                       const float* __restrict__ f1b,
                                                       const float* __restrict__ f2w,
                                                       const float* __restrict__ f2b,
                                                       const float* __restrict__ f3w,
                                                       const float* __restrict__ f3b,
                                                       float* __restrict__ dout) {
    __shared__ float red[256];
    __shared__ float res[3];
    int t = threadIdx.x;
    float s1 = 0.f, s2 = 0.f, s3 = 0.f;
    for (int i = t; i < 2000; i += 256) { float v = f1w[(size_t)i * 512]; s1 += v * v; }
    for (int i = t; i < 512; i += 256) { float v = f2w[(size_t)i * 128]; s2 += v * v; }
    if (t < 128) { float v = f3w[(size_t)t * 40]; s3 = v * v; }

    red[t] = s1; __syncthreads();
    for (int o = 128; o; o >>= 1) { if (t < o) red[t] += red[t + o]; __syncthreads(); }
    if (t == 0) res[0] = red[0];
    __syncthreads();
    red[t] = s2; __syncthreads();
    for (int o = 128; o; o >>= 1) { if (t < o) red[t] += red[t + o]; __syncthreads(); }
    if (t == 0) res[1] = red[0];
    __syncthreads();
    red[t] = s3; __syncthreads();
    for (int o = 128; o; o >>= 1) { if (t < o) red[t] += red[t + o]; __syncthreads(); }
    if (t == 0) res[2] = red[0];
    __syncthreads();

    if (t == 0) {
        dout[40] = sqrtf(racc[0]);
        dout[41] = sqrtf(racc[1]);
        dout[42] = res[0];
        dout[43] = f1b[0] * f1b[0];
        dout[44] = res[1];
        dout[45] = f2b[0] * f2b[0];
        dout[46] = res[2];
        dout[47] = f3b[0] * f3b[0];
    }
}

// ---------------- host ----------------

extern "C" void kernel_launch(void* const* d_in, const int* in_sizes, int n_in,
                              void* d_out, int out_size, void* d_ws, size_t ws_size,
                              hipStream_t stream) {
    const float* x    = (const float*)d_in[0];
    const float* Lr   = (const float*)d_in[5];
    const int*   sccs = (const int*)d_in[6];
    const float* W1   = (const float*)d_in[7];
    const float* b1   = (const float*)d_in[8];
    const float* W2   = (const float*)d_in[9];
    const float* b2   = (const float*)d_in[10];
    const float* Wr   = (const float*)d_in[11];
    const float* br   = (const float*)d_in[12];
    const float* f1w  = (const float*)d_in[13];
    const float* f1b  = (const float*)d_in[14];
    const float* f2w  = (const float*)d_in[15];
    const float* f2b  = (const float*)d_in[16];
    const float* f3w  = (const float*)d_in[17];
    const float* f3b  = (const float*)d_in[18];
    float* dout = (float*)d_out;

    char* ws = (char*)d_ws;
    size_t off = 0;
    auto alloc = [&](size_t bytes) -> char* {
        char* p = ws + off;
        off = (off + bytes + 255) & ~(size_t)255;
        return p;
    };
    float* outF = (float*)alloc((size_t)N4 * CC * 4);
    float* Cp   = (float*)alloc((size_t)3 * N4 * CC * 4);   // split-K partials; Cp[0] becomes out2
    float* Sb   = (float*)alloc((size_t)N4 * N4 * 4);       // full 4096x4096 distances
    unsigned short* Tall = (unsigned short*)alloc((size_t)N4 * KP6 * 2);  // T0..T5 bf16
    unsigned short* W2T6 = (unsigned short*)Sb;             // alias: Sb dead after topk2
    float* xhat = (float*)alloc((size_t)N4 * 18 * 4);
    float* sq1  = (float*)alloc(N4 * 4);
    float* sq2  = (float*)alloc(N4 * 4);
    float* di1  = (float*)alloc(N4 * 4);
    float* di2  = (float*)alloc(N4 * 4);
    float* wv1  = (float*)alloc((size_t)N4 * KNN * 4);
    float* wv2  = (float*)alloc((size_t)N4 * KNN * 4);
    int*   ix1  = (int*)alloc((size_t)N4 * KNN * 4);
    int*   ix2  = (int*)alloc((size_t)N4 * KNN * 4);
    float* t2x  = (float*)alloc((size_t)N4 * FDIM * 4);
    float* tr1  = (float*)alloc((size_t)NRB * CC * 4);
    float* tr2  = (float*)alloc((size_t)NRB * CC * 4);
    char*  zbase = ws + off;
    float* Mb   = (float*)alloc(6 * CC * 4);
    float* Mb2  = (float*)alloc(6 * CC * 4);
    float* rbm  = (float*)alloc(CC * 4);
    float* otm  = (float*)alloc(CC * 4);
    float* h1p  = (float*)alloc(512 * 4);
    float* racc = (float*)alloc(64 * 4);
    float* rpre = (float*)alloc((size_t)NRB * CC * 4);
    float* vfr  = (float*)alloc((size_t)NRB * CC * 4);
    size_t zlen = (size_t)((ws + off) - zbase);
    if (off > ws_size) return;

    hipMemsetAsync(zbase, 0, zlen, stream);

    // ---- graph 1 (on x): fused distance + top-40 ----
    sqx_kernel<<<(N4 + 255) / 256, 256, 0, stream>>>(x, sq1, xhat);
    topk_fused1<<<N4, 512, 0, stream>>>(x, sq1, ix1, wv1, di1);
    dinv_kernel<<<N4 / 256, 256, 0, stream>>>(di1);
    wnorm_kernel<<<(N4 * KNN + 255) / 256, 256, 0, stream>>>(wv1, ix1, di1);

    // ---- cheb conv 1 ----
    spmv_cheb<<<N4, 64, 0, stream>>>(xhat, xhat, xhat + 6, ix1, wv1, FDIM, 18, 18, 18, 1.f, 0.f);
    spmv_cheb<<<N4, 64, 0, stream>>>(xhat + 6, xhat, xhat + 12, ix1, wv1, FDIM, 18, 18, 18, 2.f, 1.f);
    cheb1_out_kernel<<<N4 / 16, 256, 0, stream>>>(xhat, W1, b1, outF);

    matT6_partial<<<dim3(4, 32), 256, 0, stream>>>(outF, xhat + 6, 18, Mb);
    fro_kernel<<<24, 256, 0, stream>>>(Mb, racc + 0);

    vfr_kernel<<<dim3(4, NRB, 5), 256, 0, stream>>>(outF, sccs, vfr);

    // ---- graph 2 (on outF) ----
    sq2_kernel<<<N4 / 4, 256, 0, stream>>>(outF, sq2);
    cvt_bf16_kernel<<<N4 * 128 / 256, 256, 0, stream>>>(outF, Tall);  // slice 0
    gram2_mfma<<<dim3(N4 / 128, N4 / 128), 256, 0, stream>>>(Tall, sq2, Sb);
    topk_radix<<<N4, 512, 0, stream>>>(Sb, ix2, wv2, di2);
    dinv_kernel<<<N4 / 256, 256, 0, stream>>>(di2);
    wnorm_kernel<<<(N4 * KNN + 255) / 256, 256, 0, stream>>>(wv2, ix2, di2);

    // Sb dead -> build W2T6 in its space
    w2t_kernel<<<dim3(16, 16, 6), 256, 0, stream>>>(W2, W2T6);

    spmv_cheb<<<N4, 64, 0, stream>>>(x, x, t2x, ix2, wv2, FDIM, FDIM, FDIM, FDIM, 1.f, 0.f);

    // ---- cheb recursion (bf16, into Tall slices 1..5) ----
    spmv_cheb_bf<<<N4, 256, 0, stream>>>(Tall + 0 * KP, Tall + 0 * KP, Tall + 1 * KP, ix2, wv2, 1.f, 0.f);
    spmv_cheb_bf<<<N4, 256, 0, stream>>>(Tall + 1 * KP, Tall + 0 * KP, Tall + 2 * KP, ix2, wv2, 2.f, 1.f);
    spmv_cheb_bf<<<N4, 256, 0, stream>>>(Tall + 2 * KP, Tall + 1 * KP, Tall + 3 * KP, ix2, wv2, 2.f, 1.f);
    spmv_cheb_bf<<<N4, 256, 0, stream>>>(Tall + 3 * KP, Tall + 2 * KP, Tall + 4 * KP, ix2, wv2, 2.f, 1.f);
    spmv_cheb_bf<<<N4, 256, 0, stream>>>(Tall + 4 * KP, Tall + 3 * KP, Tall + 5 * KP, ix2, wv2, 2.f, 1.f);

    // ---- one batched K=6144 GEMM (split-K=3, plain stores) + merge ----
    gemm_mfma_big<<<dim3(8, 32, 3), 256, 0, stream>>>(Tall, W2T6, Cp);
    bias_relu_merge<<<(int)(((size_t)N4 * CC + 255) / 256), 256, 0, stream>>>(Cp, b2);

    matT6_partial<<<dim3(4, 32), 256, 0, stream>>>(Cp, t2x, FDIM, Mb2);
    fro_kernel<<<24, 256, 0, stream>>>(Mb2, racc + 1);

    colmax_kernel<<<dim3(4, 64), 256, 0, stream>>>(Cp, otm);

    // ---- reeb cheb conv (K=3) ----
    reeb_mm_kernel<<<dim3(4, NRB), 256, 0, stream>>>(Lr, vfr, nullptr, tr1, 1.f);
    reeb_mm_kernel<<<dim3(4, NRB), 256, 0, stream>>>(Lr, tr1, vfr, tr2, 2.f);
    reeb_conv_splitk<<<dim3(4, 120), 256, 0, stream>>>(vfr, tr1, tr2, Wr, rpre);
    reeb_max_kernel<<<4, 256, 0, stream>>>(rpre, br, rbm);

    // ---- FC head ----
    fc1_kernel<<<dim3(2, 8), 256, 0, stream>>>(rbm, otm, f1w, h1p);
    fc23_kernel<<<1, 512, 0, stream>>>(h1p, f1b, f2w, f2b, f3w, f3b, dout);
    finalize_kernel<<<1, 256, 0, stream>>>(racc, f1w, f1b, f2w, f2b, f3w, f3b, dout);
}

// Round 12
// 745.577 us; speedup vs baseline: 4.6675x; 1.0205x over previous
//
#include <hip/hip_runtime.h>
#include <math.h>

#define N4    4096
#define FDIM  6
#define CC    1000
#define KP    1024
#define KP6   (6 * KP)
#define KNN   40
#define NRB   20
#define SSC   205

typedef __attribute__((ext_vector_type(8))) short bf16x8;
typedef __attribute__((ext_vector_type(4))) float f32x4;

__device__ __forceinline__ unsigned short f2bf(float f) {
    unsigned u = __float_as_uint(f);
    u = (u + 0x7fffu + ((u >> 16) & 1u)) >> 16;
    return (unsigned short)u;
}
__device__ __forceinline__ float bf2f(short s) {
    return __uint_as_float(((unsigned)(unsigned short)s) << 16);
}

// distance -> descending-sortable key (smaller d == larger key)
__device__ __forceinline__ unsigned d2key(float d) {
    unsigned u = __float_as_uint(d);
    return ((int)u < 0) ? u : (~u) ^ 0x80000000u;
}
__device__ __forceinline__ float key2d(unsigned k) {
    unsigned u = (k >> 31) ? k : (~k) ^ 0x80000000u;
    return __uint_as_float(u);
}

// ---------------- graph build ----------------

__global__ __launch_bounds__(256) void sqx_kernel(const float* __restrict__ x,
                                                  float* __restrict__ sq1,
                                                  float* __restrict__ xhat) {
    int n = blockIdx.x * blockDim.x + threadIdx.x;
    if (n >= N4) return;
    float s = 0.f;
#pragma unroll
    for (int f = 0; f < FDIM; ++f) {
        float v = x[n * FDIM + f];
        s += v * v;
        xhat[n * 18 + f] = v;
    }
    sq1[n] = s;
}

// ---------------- radix top-40 on distance keys (exact) ----------------

#define NHC 8
#define HSTRIDE 257

struct TopkSh {
    unsigned sv[N4];
    int hist[NHC * HSTRIDE];
    int sc[256];
    float red[512];
    unsigned short cidx[N4];
    unsigned s_pfx;
    int s_need, s_cnt, s_m;
};

__device__ __forceinline__ void hist_pick(TopkSh& sh, int level, int t, int lane, int w) {
    if (t < 256) {
        int cnt = 0;
#pragma unroll
        for (int c = 0; c < NHC; ++c) cnt += sh.hist[c * HSTRIDE + t];
        sh.sc[t] = cnt;
    }
    __syncthreads();
    if (w == 0) {
        int need = sh.s_need;
        unsigned pfx = sh.s_pfx;
        int c0 = sh.sc[4 * lane + 0], c1 = sh.sc[4 * lane + 1];
        int c2 = sh.sc[4 * lane + 2], c3 = sh.sc[4 * lane + 3];
        int s = c0 + c1 + c2 + c3;
        int suf = s;
#pragma unroll
        for (int off = 1; off < 64; off <<= 1) {
            int ov = __shfl_down(suf, off, 64);
            if (lane + off < 64) suf += ov;
        }
        int above = suf - s;
        int i3 = above + c3, i2 = i3 + c2, i1 = i2 + c1, i0 = i1 + c0;
        if (i3 >= need && i3 - c3 < need) { sh.s_need = need - (i3 - c3); sh.s_pfx = pfx | ((unsigned)(4 * lane + 3) << level); }
        if (i2 >= need && i2 - c2 < need) { sh.s_need = need - (i2 - c2); sh.s_pfx = pfx | ((unsigned)(4 * lane + 2) << level); }
        if (i1 >= need && i1 - c1 < need) { sh.s_need = need - (i1 - c1); sh.s_pfx = pfx | ((unsigned)(4 * lane + 1) << level); }
        if (i0 >= need && i0 - c0 < need) { sh.s_need = need - (i0 - c0); sh.s_pfx = pfx | ((unsigned)(4 * lane + 0) << level); }
    }
    __syncthreads();
}

__device__ void topk_select(TopkSh& sh, int n, int* __restrict__ idx,
                            float* __restrict__ val, float* __restrict__ rowsum) {
    int t = threadIdx.x, lane = t & 63, w = t >> 6;
    if (t == 0) { sh.s_pfx = 0u; sh.s_need = KNN; sh.s_cnt = 0; sh.s_m = 0; }
    for (int q = t; q < NHC * HSTRIDE; q += 512) sh.hist[q] = 0;
    __syncthreads();
    int* hw = &sh.hist[(t & 7) * HSTRIDE];

    // pass 1: full scan, top byte, run-length flushed
    {
        unsigned prevb = 0xFFFFFFFFu; int rl = 0;
        for (int i = t; i < N4; i += 512) {
            unsigned b = sh.sv[i] >> 24;
            if (b == prevb) ++rl;
            else { if (rl) atomicAdd(&hw[prevb], rl); prevb = b; rl = 1; }
        }
        if (rl) atomicAdd(&hw[prevb], rl);
    }
    __syncthreads();
    hist_pick(sh, 24, t, lane, w);
    unsigned b1 = sh.s_pfx >> 24;

    // compact ==b1 (ballot-aggregated), emit >b1 directly
    float psum = 0.f;
    for (int i = t; i < N4; i += 512) {
        unsigned u = sh.sv[i];
        unsigned tb = u >> 24;
        bool isc = (tb == b1);
        unsigned long long mm = __ballot(isc);
        int cw = __popcll(mm);
        int base = 0;
        if (lane == 0 && cw) base = atomicAdd(&sh.s_m, cw);
        base = __shfl(base, 0);
        if (isc) sh.cidx[base + __popcll(mm & ((1ull << lane) - 1ull))] = (unsigned short)i;

        bool isg = (tb > b1);
        unsigned long long mg = __ballot(isg);
        int gw = __popcll(mg);
        int gbase = 0;
        if (lane == 0 && gw) gbase = atomicAdd(&sh.s_cnt, gw);
        gbase = __shfl(gbase, 0);
        if (isg) {
            int p = gbase + __popcll(mg & ((1ull << lane) - 1ull));
            float v = __expf(-key2d(u));
            idx[(size_t)n * KNN + p] = i;
            val[(size_t)n * KNN + p] = v;
            psum += v;
        }
    }
    __syncthreads();
    int mcnt = sh.s_m;

    // levels 16, 8, 0 over the compacted list
    for (int level = 16; level >= 0; level -= 8) {
        for (int q = t; q < NHC * HSTRIDE; q += 512) sh.hist[q] = 0;
        __syncthreads();
        unsigned pfx = sh.s_pfx;
        for (int j = t; j < mcnt; j += 512) {
            unsigned u = sh.sv[sh.cidx[j]];
            if ((u >> (level + 8)) == (pfx >> (level + 8)))
                atomicAdd(&hw[(u >> level) & 255], 1);
        }
        __syncthreads();
        hist_pick(sh, level, t, lane, w);
    }
    unsigned Tbits = sh.s_pfx;
    float Tf = __expf(-key2d(Tbits));
    int needEq = sh.s_need;

    // collect >T within the compacted list
    for (int j = t; j < mcnt; j += 512) {
        unsigned u = sh.sv[sh.cidx[j]];
        if (u > Tbits) {
            int p = atomicAdd(&sh.s_cnt, 1);
            float v = __expf(-key2d(u));
            idx[(size_t)n * KNN + p] = (int)sh.cidx[j];
            val[(size_t)n * KNN + p] = v;
            psum += v;
        }
    }
    sh.red[t] = psum;
    __syncthreads();
    for (int o = 256; o; o >>= 1) { if (t < o) sh.red[t] += sh.red[t + o]; __syncthreads(); }
    if (t == 0) rowsum[n] = sh.red[0] + (float)needEq * Tf;

    // equals: earliest indices first (wave 0 ballot scan)
    if (t < 64) {
        int filled = KNN - needEq;
        for (int ib = 0; ib < N4 && filled < KNN; ib += 64) {
            bool eq = (sh.sv[ib + t] == Tbits);
            unsigned long long m = __ballot(eq);
            int pre = __popcll(m & ((1ull << t) - 1ull));
            if (eq && (filled + pre) < KNN) {
                idx[(size_t)n * KNN + filled + pre] = ib + t;
                val[(size_t)n * KNN + filled + pre] = Tf;
            }
            filled += __popcll(m);
        }
    }
}

__global__ __launch_bounds__(512) void topk_fused1(const float* __restrict__ x,
                                                   const float* __restrict__ sq1,
                                                   int* __restrict__ idx, float* __restrict__ val,
                                                   float* __restrict__ rowsum) {
    __shared__ TopkSh sh;
    __shared__ float xn[FDIM];
    __shared__ float sns;
    int n = blockIdx.x;
    int t = threadIdx.x;
    if (t < FDIM) xn[t] = x[n * FDIM + t];
    if (t == FDIM) sns = sq1[n];
    __syncthreads();
    float x0 = xn[0], x1 = xn[1], x2 = xn[2], x3 = xn[3], x4 = xn[4], x5 = xn[5];
    float sn = sns;
    for (int i = t; i < N4; i += 512) {
        const float2* xi = (const float2*)(x + i * FDIM);
        float2 p0 = xi[0], p1 = xi[1], p2 = xi[2];
        float d = x0 * p0.x + x1 * p0.y + x2 * p1.x + x3 * p1.y + x4 * p2.x + x5 * p2.y;
        float e = sn + sq1[i] - 2.f * d;
        sh.sv[i] = d2key(e);
    }
    topk_select(sh, n, idx, val, rowsum);
}

__global__ __launch_bounds__(512) void topk_radix(const float* __restrict__ S,
                                                  int* __restrict__ idx, float* __restrict__ val,
                                                  float* __restrict__ rowsum) {
    __shared__ TopkSh sh;
    int n = blockIdx.x;
    int t = threadIdx.x;
    const float* row = S + (size_t)n * N4;
    float4 a = *(const float4*)(row + 8 * t);
    float4 b = *(const float4*)(row + 8 * t + 4);
    sh.sv[8 * t + 0] = d2key(a.x); sh.sv[8 * t + 1] = d2key(a.y);
    sh.sv[8 * t + 2] = d2key(a.z); sh.sv[8 * t + 3] = d2key(a.w);
    sh.sv[8 * t + 4] = d2key(b.x); sh.sv[8 * t + 5] = d2key(b.y);
    sh.sv[8 * t + 6] = d2key(b.z); sh.sv[8 * t + 7] = d2key(b.w);
    topk_select(sh, n, idx, val, rowsum);
}

// wnorm with inline rsqrt (no separate dinv pass); rs = row sums
__global__ __launch_bounds__(256) void wnorm_kernel(float* __restrict__ wv,
                                                    const int* __restrict__ idx,
                                                    const float* __restrict__ rs) {
    int i = blockIdx.x * 256 + threadIdx.x;
    if (i >= N4 * KNN) return;
    int n = i / KNN;
    wv[i] = wv[i] * rsqrtf(rs[n]) * rsqrtf(rs[idx[i]]);
}

// Tn[n,:] = a*(Tc[n,:] - sum_j wv[n,j]*Tc[idx[n,j],:]) - b*Tp[n,:]   (F small, fp32)
__global__ __launch_bounds__(64) void spmv_cheb(const float* __restrict__ Tc,
                                                const float* __restrict__ Tp,
                                                float* __restrict__ Tn,
                                                const int* __restrict__ idx,
                                                const float* __restrict__ wv,
                                                int F, int sC, int sP, int sN,
                                                float a, float b) {
    __shared__ int   si[KNN];
    __shared__ float sw[KNN];
    int n = blockIdx.x;
    if (threadIdx.x < KNN) {
        si[threadIdx.x] = idx[(size_t)n * KNN + threadIdx.x];
        sw[threadIdx.x] = wv[(size_t)n * KNN + threadIdx.x];
    }
    __syncthreads();
    for (int c = threadIdx.x; c < F; c += blockDim.x) {
        float s = 0.f;
#pragma unroll 8
        for (int j = 0; j < KNN; ++j) s += sw[j] * Tc[(size_t)si[j] * sC + c];
        float v = a * (Tc[(size_t)n * sC + c] - s);
        if (b != 0.f) v -= b * Tp[(size_t)n * sP + c];
        Tn[(size_t)n * sN + c] = v;
    }
}

// bf16-resident recursion over Tall slices (row stride KP6)
__global__ __launch_bounds__(256) void spmv_cheb_bf(const unsigned short* __restrict__ Tcbf,
                                                    const unsigned short* __restrict__ Tpbf,
                                                    unsigned short* __restrict__ Tnbf,
                                                    const int* __restrict__ idx,
                                                    const float* __restrict__ wv,
                                                    float a, float b) {
    __shared__ int   si[KNN];
    __shared__ float sw[KNN];
    __shared__ float part[128][8];
    int n = blockIdx.x;
    int t = threadIdx.x;
    int tt = t & 127, h = t >> 7;
    if (t < KNN) {
        si[t] = idx[(size_t)n * KNN + t];
        sw[t] = wv[(size_t)n * KNN + t];
    }
    __syncthreads();
    int c = tt * 8;
    float acc0 = 0, acc1 = 0, acc2 = 0, acc3 = 0, acc4 = 0, acc5 = 0, acc6 = 0, acc7 = 0;
    int j0 = h * 20;
#pragma unroll 4
    for (int j = j0; j < j0 + 20; ++j) {
        bf16x8 v = *(const bf16x8*)(Tcbf + (size_t)si[j] * KP6 + c);
        float wj = sw[j];
        acc0 += wj * bf2f(v[0]); acc1 += wj * bf2f(v[1]);
        acc2 += wj * bf2f(v[2]); acc3 += wj * bf2f(v[3]);
        acc4 += wj * bf2f(v[4]); acc5 += wj * bf2f(v[5]);
        acc6 += wj * bf2f(v[6]); acc7 += wj * bf2f(v[7]);
    }
    if (h == 1) {
        part[tt][0] = acc0; part[tt][1] = acc1; part[tt][2] = acc2; part[tt][3] = acc3;
        part[tt][4] = acc4; part[tt][5] = acc5; part[tt][6] = acc6; part[tt][7] = acc7;
    }
    __syncthreads();
    if (h == 0) {
        acc0 += part[tt][0]; acc1 += part[tt][1]; acc2 += part[tt][2]; acc3 += part[tt][3];
        acc4 += part[tt][4]; acc5 += part[tt][5]; acc6 += part[tt][6]; acc7 += part[tt][7];
        bf16x8 tc = *(const bf16x8*)(Tcbf + (size_t)n * KP6 + c);
        float o0 = a * (bf2f(tc[0]) - acc0), o1 = a * (bf2f(tc[1]) - acc1);
        float o2 = a * (bf2f(tc[2]) - acc2), o3 = a * (bf2f(tc[3]) - acc3);
        float o4 = a * (bf2f(tc[4]) - acc4), o5 = a * (bf2f(tc[5]) - acc5);
        float o6 = a * (bf2f(tc[6]) - acc6), o7 = a * (bf2f(tc[7]) - acc7);
        if (b != 0.f) {
            bf16x8 tp = *(const bf16x8*)(Tpbf + (size_t)n * KP6 + c);
            o0 -= b * bf2f(tp[0]); o1 -= b * bf2f(tp[1]);
            o2 -= b * bf2f(tp[2]); o3 -= b * bf2f(tp[3]);
            o4 -= b * bf2f(tp[4]); o5 -= b * bf2f(tp[5]);
            o6 -= b * bf2f(tp[6]); o7 -= b * bf2f(tp[7]);
        }
        bf16x8 ob;
        ob[0] = (short)f2bf(o0); ob[1] = (short)f2bf(o1);
        ob[2] = (short)f2bf(o2); ob[3] = (short)f2bf(o3);
        ob[4] = (short)f2bf(o4); ob[5] = (short)f2bf(o5);
        ob[6] = (short)f2bf(o6); ob[7] = (short)f2bf(o7);
        *(bf16x8*)(Tnbf + (size_t)n * KP6 + c) = ob;
    }
}

// ---------------- bf16 conversion / transpose ----------------

__global__ __launch_bounds__(256) void cvt_bf16_kernel(const float* __restrict__ in,
                                                       unsigned short* __restrict__ out) {
    int i = blockIdx.x * 256 + threadIdx.x;
    int r = i >> 7, g = i & 127;
    bf16x8 v;
    if (g < 125) {
        float4 a = *(const float4*)(in + (size_t)r * CC + g * 8);
        float4 b = *(const float4*)(in + (size_t)r * CC + g * 8 + 4);
        v[0] = (short)f2bf(a.x); v[1] = (short)f2bf(a.y);
        v[2] = (short)f2bf(a.z); v[3] = (short)f2bf(a.w);
        v[4] = (short)f2bf(b.x); v[5] = (short)f2bf(b.y);
        v[6] = (short)f2bf(b.z); v[7] = (short)f2bf(b.w);
    } else {
#pragma unroll
        for (int q = 0; q < 8; ++q) v[q] = 0;
    }
    *(bf16x8*)(out + (size_t)r * KP6 + g * 8) = v;
}

// W2 [6*CC x CC] fp32 -> W2T6 [1024 rows(n)][KP6 cols(k)] bf16
__global__ __launch_bounds__(256) void w2t_kernel(const float* __restrict__ W2,
                                                  unsigned short* __restrict__ out) {
    __shared__ unsigned short tile[64][65];
    int t = threadIdx.x;
    int k0 = blockIdx.x * 64, n0 = blockIdx.y * 64, s = blockIdx.z;
#pragma unroll
    for (int p = 0; p < 16; ++p) {
        int i = p * 256 + t;
        int kk = i >> 6, nn = i & 63;
        int k = k0 + kk, n = n0 + nn;
        float v = (k < CC && n < CC) ? W2[((size_t)s * CC + k) * CC + n] : 0.f;
        tile[kk][nn] = f2bf(v);
    }
    __syncthreads();
#pragma unroll
    for (int p = 0; p < 16; ++p) {
        int i = p * 256 + t;
        int nn = i >> 6, kk = i & 63;
        out[(size_t)(n0 + nn) * KP6 + (size_t)s * KP + k0 + kk] = tile[kk][nn];
    }
}

// ---------------- MFMA GEMMs (128x256 tile, BK=32, bf16 in / fp32 acc) ----------------

#define LDP 40

// A-tile 128 rows (m), B-tile 256 rows (n), K range [kbeg,kend)
template<int STR>
__device__ __forceinline__ void gemm_core256(const unsigned short* __restrict__ Ag,
                                             const unsigned short* __restrict__ Bg,
                                             short* As, short* Bs, int t,
                                             int kbeg, int kend,
                                             f32x4 (&acc)[4][8]) {
    int l = t & 63, w = t >> 6;
    int wm = (w >> 1) * 64, wn = (w & 1) * 128;
    int ar = t >> 1, ak = (t & 1) * 16;
    int lr = l & 15, lq8 = (l >> 4) * 8;
    for (int k0 = kbeg; k0 < kend; k0 += 32) {
        bf16x8 a0 = *(const bf16x8*)(Ag + (size_t)ar * STR + k0 + ak);
        bf16x8 a1 = *(const bf16x8*)(Ag + (size_t)ar * STR + k0 + ak + 8);
        bf16x8 b0 = *(const bf16x8*)(Bg + (size_t)ar * STR + k0 + ak);
        bf16x8 b1 = *(const bf16x8*)(Bg + (size_t)ar * STR + k0 + ak + 8);
        bf16x8 b2 = *(const bf16x8*)(Bg + (size_t)(128 + ar) * STR + k0 + ak);
        bf16x8 b3 = *(const bf16x8*)(Bg + (size_t)(128 + ar) * STR + k0 + ak + 8);
        __syncthreads();
        *(bf16x8*)&As[ar * LDP + ak] = a0;
        *(bf16x8*)&As[ar * LDP + ak + 8] = a1;
        *(bf16x8*)&Bs[ar * LDP + ak] = b0;
        *(bf16x8*)&Bs[ar * LDP + ak + 8] = b1;
        *(bf16x8*)&Bs[(128 + ar) * LDP + ak] = b2;
        *(bf16x8*)&Bs[(128 + ar) * LDP + ak + 8] = b3;
        __syncthreads();
        bf16x8 af[4], bfr[8];
#pragma unroll
        for (int mi = 0; mi < 4; ++mi)
            af[mi] = *(const bf16x8*)&As[(wm + mi * 16 + lr) * LDP + lq8];
#pragma unroll
        for (int ni = 0; ni < 8; ++ni)
            bfr[ni] = *(const bf16x8*)&Bs[(wn + ni * 16 + lr) * LDP + lq8];
#pragma unroll
        for (int mi = 0; mi < 4; ++mi)
#pragma unroll
            for (int ni = 0; ni < 8; ++ni)
                acc[mi][ni] = __builtin_amdgcn_mfma_f32_16x16x32_bf16(af[mi], bfr[ni], acc[mi][ni], 0, 0, 0);
    }
}

// batched cheb2 GEMM: C_part[z] = Tall[:, z*2048:(z+1)*2048] @ W2T6[:, same]^T
__global__ __launch_bounds__(256, 2) void gemm_mfma_big(const unsigned short* __restrict__ A,
                                                        const unsigned short* __restrict__ B,
                                                        float* __restrict__ Cp) {
    __shared__ short As[128 * LDP];
    __shared__ short Bs[256 * LDP];
    int t = threadIdx.x;
    int n0 = blockIdx.x * 256, m0 = blockIdx.y * 128;
    int kz = blockIdx.z;
    float* C = Cp + (size_t)kz * N4 * CC;
    f32x4 acc[4][8] = {};
    gemm_core256<KP6>(A + (size_t)m0 * KP6, B + (size_t)n0 * KP6, As, Bs, t,
                      kz * 2048, kz * 2048 + 2048, acc);
    int l = t & 63, w = t >> 6;
    int wm = (w >> 1) * 64, wn = (w & 1) * 128;
    int lr = l & 15, lq4 = (l >> 4) * 4;
#pragma unroll
    for (int ni = 0; ni < 8; ++ni) {
        int n = n0 + wn + ni * 16 + lr;
        if (n >= CC) continue;
#pragma unroll
        for (int mi = 0; mi < 4; ++mi) {
            int m = m0 + wm + mi * 16 + lq4;
            f32x4 v = acc[mi][ni];
#pragma unroll
            for (int r = 0; r < 4; ++r) C[(size_t)(m + r) * CC + n] = v[r];
        }
    }
}

// out2 = relu(C0 + C1 + C2 + b2)   (in place into C0)
__global__ __launch_bounds__(256) void bias_relu_merge(float* __restrict__ C,
                                                       const float* __restrict__ b2) {
    size_t i = (size_t)blockIdx.x * 256 + threadIdx.x;
    if (i >= (size_t)N4 * CC) return;
    int c = (int)(i % CC);
    C[i] = fmaxf(C[i] + C[i + (size_t)N4 * CC] + C[i + 2 * (size_t)N4 * CC] + b2[c], 0.f);
}

// gram over Tall slice 0 -> raw distances (128x256 tiles)
__global__ __launch_bounds__(256, 2) void gram2_mfma(const unsigned short* __restrict__ Tall,
                                                     const float* __restrict__ sq2,
                                                     float* __restrict__ S) {
    __shared__ short As[128 * LDP];
    __shared__ short Bs[256 * LDP];
    int t = threadIdx.x;
    int n0 = blockIdx.x * 256, m0 = blockIdx.y * 128;
    f32x4 acc[4][8] = {};
    gemm_core256<KP6>(Tall + (size_t)m0 * KP6, Tall + (size_t)n0 * KP6, As, Bs, t, 0, KP, acc);
    int l = t & 63, w = t >> 6;
    int wm = (w >> 1) * 64, wn = (w & 1) * 128;
    int lr = l & 15, lq4 = (l >> 4) * 4;
#pragma unroll
    for (int ni = 0; ni < 8; ++ni) {
        int n = n0 + wn + ni * 16 + lr;
        float sn = sq2[n];
#pragma unroll
        for (int mi = 0; mi < 4; ++mi) {
            int mrow = m0 + wm + mi * 16 + lq4;
            f32x4 v = acc[mi][ni];
#pragma unroll
            for (int r = 0; r < 4; ++r) {
                S[(size_t)(mrow + r) * N4 + n] = sq2[mrow + r] + sn - 2.f * v[r];
            }
        }
    }
}

// ---------------- cheb conv 1 ----------------

__global__ __launch_bounds__(256) void cheb1_out_kernel(const float* __restrict__ xhat,
                                                        const float* __restrict__ W1,
                                                        const float* __restrict__ b1,
                                                        float* __restrict__ outF) {
    __shared__ float xh[16][18];
    int n0 = blockIdx.x * 16;
    int tid = threadIdx.x;
    for (int i = tid; i < 16 * 18; i += 256) xh[i / 18][i % 18] = xhat[(size_t)n0 * 18 + i];
    __syncthreads();
    for (int c0 = 0; c0 < CC; c0 += 256) {
        int c = c0 + tid;
        if (c < CC) {
            float acc[16];
#pragma unroll
            for (int r = 0; r < 16; ++r) acc[r] = 0.f;
            for (int f = 0; f < 18; ++f) {
                float wv = W1[(size_t)f * CC + c];
#pragma unroll
                for (int r = 0; r < 16; ++r) acc[r] += xh[r][f] * wv;
            }
            float bb = b1[c];
#pragma unroll
            for (int r = 0; r < 16; ++r)
                outF[(size_t)(n0 + r) * CC + c] = fmaxf(acc[r] + bb, 0.f);
        }
    }
}

// ---------------- regs (frobenius of O^T @ T) ----------------

__global__ __launch_bounds__(256) void matT6_partial(const float* __restrict__ O,
                                                     const float* __restrict__ T, int ts,
                                                     float* __restrict__ M) {
    __shared__ float sT[128][6];
    int t = threadIdx.x;
    int c = blockIdx.x * 256 + t;
    int n0 = blockIdx.y * 128;
    for (int i = t; i < 128 * 6; i += 256) {
        int nn = i / 6, f = i % 6;
        sT[nn][f] = T[(size_t)(n0 + nn) * ts + f];
    }
    __syncthreads();
    if (c >= CC) return;
    float a0 = 0, a1 = 0, a2 = 0, a3 = 0, a4 = 0, a5 = 0;
    for (int nn = 0; nn < 128; ++nn) {
        float o = O[(size_t)(n0 + nn) * CC + c];
        a0 += o * sT[nn][0]; a1 += o * sT[nn][1]; a2 += o * sT[nn][2];
        a3 += o * sT[nn][3]; a4 += o * sT[nn][4]; a5 += o * sT[nn][5];
    }
    atomicAdd(&M[0 * CC + c], a0);
    atomicAdd(&M[1 * CC + c], a1);
    atomicAdd(&M[2 * CC + c], a2);
    atomicAdd(&M[3 * CC + c], a3);
    atomicAdd(&M[4 * CC + c], a4);
    atomicAdd(&M[5 * CC + c], a5);
}

__global__ __launch_bounds__(256) void fro_kernel(const float* __restrict__ M, float* __restrict__ dst) {
    __shared__ float red[256];
    int t = threadIdx.x;
    int i = blockIdx.x * 256 + t;
    float v = (i < 6 * CC) ? M[i] : 0.f;
    red[t] = v * v;
    __syncthreads();
    for (int o = 128; o; o >>= 1) { if (t < o) red[t] += red[t + o]; __syncthreads(); }
    if (t == 0) atomicAdd(dst, red[0]);
}

// ---------------- pooling ----------------

__global__ __launch_bounds__(256) void vfr_kernel(const float* __restrict__ outF,
                                                  const int* __restrict__ sccs,
                                                  float* __restrict__ vfr) {
    int r = blockIdx.y;
    int c = blockIdx.x * 256 + threadIdx.x;
    if (c >= CC) return;
    int s0 = blockIdx.z * 41;
    float m = 0.f;
    for (int s = s0; s < s0 + 41; ++s) {
        int n = sccs[r * SSC + s];
        m = fmaxf(m, outF[(size_t)n * CC + c]);
    }
    atomicMax((int*)&vfr[(size_t)r * CC + c], __float_as_int(m));
}

__global__ __launch_bounds__(256) void sq2_kernel(const float* __restrict__ outF,
                                                  float* __restrict__ sq2) {
    int lane = threadIdx.x & 63, w = threadIdx.x >> 6;
    int n = blockIdx.x * 4 + w;
    const float* row = outF + (size_t)n * CC;
    float s = 0.f;
    for (int i = lane; i < CC; i += 64) { float v = row[i]; s += v * v; }
#pragma unroll
    for (int o = 32; o; o >>= 1) s += __shfl_down(s, o);
    if (lane == 0) sq2[n] = s;
}

// row-split column max; dst must be zeroed (values >= 0)
__global__ __launch_bounds__(256) void colmax_kernel(const float* __restrict__ O,
                                                     float* __restrict__ dst) {
    int c = blockIdx.x * 256 + threadIdx.x;
    if (c >= CC) return;
    int n0 = blockIdx.y * 64;
    float m = 0.f;
    for (int n = n0; n < n0 + 64; ++n) m = fmaxf(m, O[(size_t)n * CC + c]);
    atomicMax((int*)&dst[c], __float_as_int(m));
}

// ---------------- reeb branch ----------------

__global__ __launch_bounds__(256) void reeb_mm_kernel(const float* __restrict__ Lr,
                                                      const float* __restrict__ Vin,
                                                      const float* __restrict__ Vsub,
                                                      float* __restrict__ Vout, float a2) {
    int c = blockIdx.x * 256 + threadIdx.x;
    if (c >= CC) return;
    int r = blockIdx.y;
    float s = 0.f;
#pragma unroll
    for (int j = 0; j < NRB; ++j) s += Lr[r * NRB + j] * Vin[(size_t)j * CC + c];
    float v = a2 * s;
    if (Vsub) v -= Vsub[(size_t)r * CC + c];
    Vout[(size_t)r * CC + c] = v;
}

#define RKC 25
__global__ __launch_bounds__(256) void reeb_conv_splitk(const float* __restrict__ vfr,
                                                        const float* __restrict__ tr1,
                                                        const float* __restrict__ tr2,
                                                        const float* __restrict__ Wr,
                                                        float* __restrict__ rpre) {
    __shared__ float sA[NRB][RKC];
    int t = threadIdx.x;
    int kbase = blockIdx.y * RKC;
    for (int i = t; i < NRB * RKC; i += 256) {
        int r = i / RKC, kk = i % RKC;
        int kg = kbase + kk;
        float v;
        if (kg < CC)           v = vfr[(size_t)r * CC + kg];
        else if (kg < 2 * CC)  v = tr1[(size_t)r * CC + kg - CC];
        else                   v = tr2[(size_t)r * CC + kg - 2 * CC];
        sA[r][kk] = v;
    }
    __syncthreads();
    int c = blockIdx.x * 256 + t;
    if (c >= CC) return;
    float acc[NRB];
#pragma unroll
    for (int r = 0; r < NRB; ++r) acc[r] = 0.f;
    for (int kk = 0; kk < RKC; ++kk) {
        float wv = Wr[(size_t)(kbase + kk) * CC + c];
#pragma unroll
        for (int r = 0; r < NRB; ++r) acc[r] += sA[r][kk] * wv;
    }
#pragma unroll
    for (int r = 0; r < NRB; ++r) atomicAdd(&rpre[(size_t)r * CC + c], acc[r]);
}

__global__ __launch_bounds__(256) void reeb_max_kernel(const float* __restrict__ pre,
                                                       const float* __restrict__ br,
                                                       float* __restrict__ rbm) {
    int c = blockIdx.x * 256 + threadIdx.x;
    if (c >= CC) return;
    float bb = br[c];
    float m = 0.f;
    for (int r = 0; r < NRB; ++r) m = fmaxf(m, fmaxf(pre[(size_t)r * CC + c] + bb, 0.f));
    rbm[c] = m;
}

// ---------------- FC head ----------------

__global__ __launch_bounds__(256) void fc1_kernel(const float* __restrict__ rbm,
                                                  const float* __restrict__ otm,
                                                  const float* __restrict__ w,
                                                  float* __restrict__ h1pre) {
    int j = blockIdx.x * 256 + threadIdx.x;
    if (j >= 512) return;
    int i0 = blockIdx.y * 250;
    float s = 0.f;
    for (int i = i0; i < i0 + 250; ++i) {
        float v = (i < CC) ? rbm[i] : otm[i - CC];
        s += v * w[(size_t)i * 512 + j];
    }
    atomicAdd(&h1pre[j], s);
}

__global__ __launch_bounds__(512) void fc23_kernel(const float* __restrict__ h1pre,
                                                   const float* __restrict__ b1f,
                                                   const float* __restrict__ w2,
                                                   const float* __restrict__ b2f,
                                                   const float* __restrict__ w3,
                                                   const float* __restrict__ b3f,
                                                   float* __restrict__ dout) {
    __shared__ float h1[512];
    __shared__ float h2[128];
    int t = threadIdx.x;
    h1[t] = fmaxf(h1pre[t] + b1f[t], 0.f);
    __syncthreads();
    if (t < 128) {
        float s = b2f[t];
        for (int i = 0; i < 512; ++i) s += h1[i] * w2[(size_t)i * 128 + t];
        h2[t] = fmaxf(s, 0.f);
    }
    __syncthreads();
    if (t < 40) {
        float s = b3f[t];
        for (int i = 0; i < 128; ++i) s += h2[i] * w3[(size_t)i * 40 + t];
        dout[t] = s;
    }
}

__global__ __launch_bounds__(256) void finalize_kernel(const float* __restrict__ racc,
                                                       const float* __restrict__ f1w,
                                                       const float* __restrict__ f1b,
                                                       const float* __restrict__ f2w,
                                                       const float* __restrict__ f2b,
                                                       const float* __restrict__ f3w,
                                                       const float* __restrict__ f3b,
                                                       float* __restrict__ dout) {
    __shared__ float red[256];
    __shared__ float res[3];
    int t = threadIdx.x;
    float s1 = 0.f, s2 = 0.f, s3 = 0.f;
    for (int i = t; i < 2000; i += 256) { float v = f1w[(size_t)i * 512]; s1 += v * v; }
    for (int i = t; i < 512; i += 256) { float v = f2w[(size_t)i * 128]; s2 += v * v; }
    if (t < 128) { float v = f3w[(size_t)t * 40]; s3 = v * v; }

    red[t] = s1; __syncthreads();
    for (int o = 128; o; o >>= 1) { if (t < o) red[t] += red[t + o]; __syncthreads(); }
    if (t == 0) res[0] = red[0];
    __syncthreads();
    red[t] = s2; __syncthreads();
    for (int o = 128; o; o >>= 1) { if (t < o) red[t] += red[t + o]; __syncthreads(); }
    if (t == 0) res[1] = red[0];
    __syncthreads();
    red[t] = s3; __syncthreads();
    for (int o = 128; o; o >>= 1) { if (t < o) red[t] += red[t + o]; __syncthreads(); }
    if (t == 0) res[2] = red[0];
    __syncthreads();

    if (t == 0) {
        dout[40] = sqrtf(racc[0]);
        dout[41] = sqrtf(racc[1]);
        dout[42] = res[0];
        dout[43] = f1b[0] * f1b[0];
        dout[44] = res[1];
        dout[45] = f2b[0] * f2b[0];
        dout[46] = res[2];
        dout[47] = f3b[0] * f3b[0];
    }
}

// ---------------- host ----------------

extern "C" void kernel_launch(void* const* d_in, const int* in_sizes, int n_in,
                              void* d_out, int out_size, void* d_ws, size_t ws_size,
                              hipStream_t stream) {
    const float* x    = (const float*)d_in[0];
    const float* Lr   = (const float*)d_in[5];
    const int*   sccs = (const int*)d_in[6];
    const float* W1   = (const float*)d_in[7];
    const float* b1   = (const float*)d_in[8];
    const float* W2   = (const float*)d_in[9];
    const float* b2   = (const float*)d_in[10];
    const float* Wr   = (const float*)d_in[11];
    const float* br   = (const float*)d_in[12];
    const float* f1w  = (const float*)d_in[13];
    const float* f1b  = (const float*)d_in[14];
    const float* f2w  = (const float*)d_in[15];
    const float* f2b  = (const float*)d_in[16];
    const float* f3w  = (const float*)d_in[17];
    const float* f3b  = (const float*)d_in[18];
    float* dout = (float*)d_out;

    char* ws = (char*)d_ws;
    size_t off = 0;
    auto alloc = [&](size_t bytes) -> char* {
        char* p = ws + off;
        off = (off + bytes + 255) & ~(size_t)255;
        return p;
    };
    float* outF = (float*)alloc((size_t)N4 * CC * 4);
    float* Cp   = (float*)alloc((size_t)3 * N4 * CC * 4);
    float* Sb   = (float*)alloc((size_t)N4 * N4 * 4);
    unsigned short* Tall = (unsigned short*)alloc((size_t)N4 * KP6 * 2);
    unsigned short* W2T6 = (unsigned short*)Sb;   // alias: Sb dead after topk2
    float* xhat = (float*)alloc((size_t)N4 * 18 * 4);
    float* sq1  = (float*)alloc(N4 * 4);
    float* sq2  = (float*)alloc(N4 * 4);
    float* rs1  = (float*)alloc(N4 * 4);
    float* rs2  = (float*)alloc(N4 * 4);
    float* wv1  = (float*)alloc((size_t)N4 * KNN * 4);
    float* wv2  = (float*)alloc((size_t)N4 * KNN * 4);
    int*   ix1  = (int*)alloc((size_t)N4 * KNN * 4);
    int*   ix2  = (int*)alloc((size_t)N4 * KNN * 4);
    float* t2x  = (float*)alloc((size_t)N4 * FDIM * 4);
    float* tr1  = (float*)alloc((size_t)NRB * CC * 4);
    float* tr2  = (float*)alloc((size_t)NRB * CC * 4);
    char*  zbase = ws + off;
    float* Mb   = (float*)alloc(6 * CC * 4);
    float* Mb2  = (float*)alloc(6 * CC * 4);
    float* rbm  = (float*)alloc(CC * 4);
    float* otm  = (float*)alloc(CC * 4);
    float* h1p  = (float*)alloc(512 * 4);
    float* racc = (float*)alloc(64 * 4);
    float* rpre = (float*)alloc((size_t)NRB * CC * 4);
    float* vfr  = (float*)alloc((size_t)NRB * CC * 4);
    size_t zlen = (size_t)((ws + off) - zbase);
    if (off > ws_size) return;

    hipMemsetAsync(zbase, 0, zlen, stream);

    // ---- graph 1 (on x): fused distance + top-40 ----
    sqx_kernel<<<(N4 + 255) / 256, 256, 0, stream>>>(x, sq1, xhat);
    topk_fused1<<<N4, 512, 0, stream>>>(x, sq1, ix1, wv1, rs1);
    wnorm_kernel<<<(N4 * KNN + 255) / 256, 256, 0, stream>>>(wv1, ix1, rs1);

    // ---- cheb conv 1 ----
    spmv_cheb<<<N4, 64, 0, stream>>>(xhat, xhat, xhat + 6, ix1, wv1, FDIM, 18, 18, 18, 1.f, 0.f);
    spmv_cheb<<<N4, 64, 0, stream>>>(xhat + 6, xhat, xhat + 12, ix1, wv1, FDIM, 18, 18, 18, 2.f, 1.f);
    cheb1_out_kernel<<<N4 / 16, 256, 0, stream>>>(xhat, W1, b1, outF);

    matT6_partial<<<dim3(4, 32), 256, 0, stream>>>(outF, xhat + 6, 18, Mb);
    fro_kernel<<<24, 256, 0, stream>>>(Mb, racc + 0);

    vfr_kernel<<<dim3(4, NRB, 5), 256, 0, stream>>>(outF, sccs, vfr);

    // ---- graph 2 (on outF) ----
    sq2_kernel<<<N4 / 4, 256, 0, stream>>>(outF, sq2);
    cvt_bf16_kernel<<<N4 * 128 / 256, 256, 0, stream>>>(outF, Tall);  // slice 0
    gram2_mfma<<<dim3(N4 / 256, N4 / 128), 256, 0, stream>>>(Tall, sq2, Sb);
    topk_radix<<<N4, 512, 0, stream>>>(Sb, ix2, wv2, rs2);
    wnorm_kernel<<<(N4 * KNN + 255) / 256, 256, 0, stream>>>(wv2, ix2, rs2);

    // Sb dead -> build W2T6 in its space
    w2t_kernel<<<dim3(16, 16, 6), 256, 0, stream>>>(W2, W2T6);

    spmv_cheb<<<N4, 64, 0, stream>>>(x, x, t2x, ix2, wv2, FDIM, FDIM, FDIM, FDIM, 1.f, 0.f);

    // ---- cheb recursion (bf16, into Tall slices 1..5) ----
    spmv_cheb_bf<<<N4, 256, 0, stream>>>(Tall + 0 * KP, Tall + 0 * KP, Tall + 1 * KP, ix2, wv2, 1.f, 0.f);
    spmv_cheb_bf<<<N4, 256, 0, stream>>>(Tall + 1 * KP, Tall + 0 * KP, Tall + 2 * KP, ix2, wv2, 2.f, 1.f);
    spmv_cheb_bf<<<N4, 256, 0, stream>>>(Tall + 2 * KP, Tall + 1 * KP, Tall + 3 * KP, ix2, wv2, 2.f, 1.f);
    spmv_cheb_bf<<<N4, 256, 0, stream>>>(Tall + 3 * KP, Tall + 2 * KP, Tall + 4 * KP, ix2, wv2, 2.f, 1.f);
    spmv_cheb_bf<<<N4, 256, 0, stream>>>(Tall + 4 * KP, Tall + 3 * KP, Tall + 5 * KP, ix2, wv2, 2.f, 1.f);

    // ---- one batched K=6144 GEMM (split-K=3, plain stores) + merge ----
    gemm_mfma_big<<<dim3(4, 32, 3), 256, 0, stream>>>(Tall, W2T6, Cp);
    bias_relu_merge<<<(int)(((size_t)N4 * CC + 255) / 256), 256, 0, stream>>>(Cp, b2);

    matT6_partial<<<dim3(4, 32), 256, 0, stream>>>(Cp, t2x, FDIM, Mb2);
    fro_kernel<<<24, 256, 0, stream>>>(Mb2, racc + 1);

    colmax_kernel<<<dim3(4, 64), 256, 0, stream>>>(Cp, otm);

    // ---- reeb cheb conv (K=3) ----
    reeb_mm_kernel<<<dim3(4, NRB), 256, 0, stream>>>(Lr, vfr, nullptr, tr1, 1.f);
    reeb_mm_kernel<<<dim3(4, NRB), 256, 0, stream>>>(Lr, tr1, vfr, tr2, 2.f);
    reeb_conv_splitk<<<dim3(4, 120), 256, 0, stream>>>(vfr, tr1, tr2, Wr, rpre);
    reeb_max_kernel<<<4, 256, 0, stream>>>(rpre, br, rbm);

    // ---- FC head ----
    fc1_kernel<<<dim3(2, 8), 256, 0, stream>>>(rbm, otm, f1w, h1p);
    fc23_kernel<<<1, 512, 0, stream>>>(h1p, f1b, f2w, f2b, f3w, f3b, dout);
    finalize_kernel<<<1, 256, 0, stream>>>(racc, f1w, f1b, f2w, f2b, f3w, f3b, dout);
}